// Round 2
// baseline (12000.010 us; speedup 1.0000x reference)
//
#include <hip/hip_runtime.h>
#include <cstdint>
#include <cstddef>

// ---- problem constants ----
constexpr float DN = 0.35355339059327373f;   // 64^-0.25
constexpr float RATIO = 0.0625f;             // 256^-0.5
constexpr float EPSF = 1e-4f;

// ---- workspace layout (float offsets) ----
// small persistent buffers first (below the ffmid alias window)
constexpr size_t OFF_PROJT = 0;            // 16,384
constexpr size_t OFF_DIAGQ = 16384;        // 131,072
constexpr size_t OFF_DIAGK = 147456;       // 131,072
constexpr size_t OFF_CTX   = 278528;       // 524,288
constexpr size_t OFF_KSUM  = 802816;       // 8,192
constexpr size_t OFF_GMAX  = 811008;       // 64 (1 uint used)
constexpr size_t OFF_POOL  = 811264;       // 32,768
constexpr size_t OFF_ESP   = 844032;       // 16,384
constexpr size_t OFF_CTXP  = 860416;       // 1,048,576  (ends 1,908,992)
constexpr size_t OFF_H     = 2097152;      // 8,388,608
constexpr size_t OFF_Y     = 10485760;     // 8,388,608
constexpr size_t OFF_Q     = 18874368;     // 8,388,608  (o alias; ffmid starts here)
constexpr size_t OFF_K     = 27262976;     // 8,388,608
constexpr size_t OFF_V     = 35651584;     // 8,388,608
constexpr size_t OFF_DDB   = 44040192;     // 4,194,304  (ends 48,234,496)
constexpr size_t WS_FLOATS = 52428800;     // ffmid = OFF_Q + 33,554,432 = 52,428,800

__device__ __forceinline__ unsigned fkey(float f) {
    unsigned u = __float_as_uint(f);
    return (u & 0x80000000u) ? ~u : (u | 0x80000000u);
}
__device__ __forceinline__ float funkey(unsigned k) {
    unsigned u = (k & 0x80000000u) ? (k ^ 0x80000000u) : ~k;
    return __uint_as_float(u);
}
__device__ __forceinline__ float gelu_exact(float x) {
    return 0.5f * x * (1.0f + erff(x * 0.70710678118654752f));
}

__global__ void init_gmax(unsigned* g) { *g = 0u; }

__global__ void fill_sentinel(float* out, int n) {
    int i = threadIdx.x;
    if (i < n) out[i] = 12345.0f;
}

// ---- generic fp32 GEMM: C[M,N] = A[M,K]@B[K,N] (+bias) (+res) ----
// BM=128, BN=64, BK=16, thread tile 8x4, block 256. K multiple of 16, >=32.
template<bool BIAS, bool RES>
__global__ __launch_bounds__(256) void gemm_f32(
    const float* __restrict__ A, const float* __restrict__ Bm,
    const float* __restrict__ bias, const float* __restrict__ res,
    float* __restrict__ C, int M, int N, int K)
{
    constexpr int BK = 16, TM = 8, TN = 4;
    __shared__ float As[BK][128 + 4];
    __shared__ float Bs[BK][64 + 4];
    const int tid = threadIdx.x;
    const int m0 = blockIdx.y * 128, n0 = blockIdx.x * 64;
    const int ar = tid >> 1, ak = (tid & 1) * 8;
    const int br = tid >> 4, bc = (tid & 15) * 4;
    const int tr = tid >> 4, tc = tid & 15;

    const float* Ap = A + (size_t)(m0 + ar) * K + ak;
    const float* Bp = Bm + (size_t)br * N + (n0 + bc);

    float4 a0 = *(const float4*)(Ap);
    float4 a1 = *(const float4*)(Ap + 4);
    float4 b0 = *(const float4*)(Bp);

    float acc[TM][TN];
#pragma unroll
    for (int i = 0; i < TM; ++i)
#pragma unroll
        for (int j = 0; j < TN; ++j) acc[i][j] = 0.0f;

    for (int k0 = 0;;) {
        As[ak + 0][ar] = a0.x; As[ak + 1][ar] = a0.y; As[ak + 2][ar] = a0.z; As[ak + 3][ar] = a0.w;
        As[ak + 4][ar] = a1.x; As[ak + 5][ar] = a1.y; As[ak + 6][ar] = a1.z; As[ak + 7][ar] = a1.w;
        *(float4*)&Bs[br][bc] = b0;
        __syncthreads();
        const int kn = k0 + BK;
        if (kn < K) {
            a0 = *(const float4*)(Ap + kn);
            a1 = *(const float4*)(Ap + kn + 4);
            b0 = *(const float4*)(Bp + (size_t)kn * N);
        }
#pragma unroll
        for (int kk = 0; kk < BK; ++kk) {
            float av[TM], bv[TN];
            *(float4*)&av[0] = *(const float4*)&As[kk][tr * TM];
            *(float4*)&av[4] = *(const float4*)&As[kk][tr * TM + 4];
            *(float4*)&bv[0] = *(const float4*)&Bs[kk][tc * TN];
#pragma unroll
            for (int i = 0; i < TM; ++i)
#pragma unroll
                for (int j = 0; j < TN; ++j)
                    acc[i][j] = fmaf(av[i], bv[j], acc[i][j]);
        }
        k0 = kn;
        if (k0 >= K) break;
        __syncthreads();
    }

    float bb[TN] = {0.f, 0.f, 0.f, 0.f};
    if (BIAS) { *(float4*)&bb[0] = *(const float4*)&bias[n0 + tc * TN]; }
#pragma unroll
    for (int i = 0; i < TM; ++i) {
        const size_t off = (size_t)(m0 + tr * TM + i) * N + (n0 + tc * TN);
        float4 ov;
        ov.x = acc[i][0] + bb[0]; ov.y = acc[i][1] + bb[1];
        ov.z = acc[i][2] + bb[2]; ov.w = acc[i][3] + bb[3];
        if (RES) {
            float4 rv = *(const float4*)&res[off];
            ov.x += rv.x; ov.y += rv.y; ov.z += rv.z; ov.w += rv.w;
        }
        *(float4*)&C[off] = ov;
    }
}

// ---- fused GLU GEMM: out = gelu(A@W[:, :1024]+b1a) * (A@W[:,1024:]+b1g) ----
__global__ __launch_bounds__(256) void glu_gemm(
    const float* __restrict__ A, const float* __restrict__ W,
    const float* __restrict__ bias, float* __restrict__ out)
{
    constexpr int BK = 16;
    __shared__ float As[BK][132];
    __shared__ float Bs[BK][68];
    __shared__ float Gs[BK][68];
    const int tid = threadIdx.x;
    const int m0 = blockIdx.y * 128, n0 = blockIdx.x * 64;
    const int ar = tid >> 1, ak = (tid & 1) * 8;
    const int br = tid >> 4, bc = (tid & 15) * 4;
    const int tr = tid >> 4, tc = tid & 15;

    const float* Ap = A + (size_t)(m0 + ar) * 256 + ak;
    const float* Bp = W + (size_t)br * 2048 + (n0 + bc);
    const float* Gp = Bp + 1024;

    float4 a0 = *(const float4*)(Ap);
    float4 a1 = *(const float4*)(Ap + 4);
    float4 b0 = *(const float4*)(Bp);
    float4 g0 = *(const float4*)(Gp);

    float acc[8][4], acg[8][4];
#pragma unroll
    for (int i = 0; i < 8; ++i)
#pragma unroll
        for (int j = 0; j < 4; ++j) { acc[i][j] = 0.f; acg[i][j] = 0.f; }

    for (int k0 = 0;;) {
        As[ak + 0][ar] = a0.x; As[ak + 1][ar] = a0.y; As[ak + 2][ar] = a0.z; As[ak + 3][ar] = a0.w;
        As[ak + 4][ar] = a1.x; As[ak + 5][ar] = a1.y; As[ak + 6][ar] = a1.z; As[ak + 7][ar] = a1.w;
        *(float4*)&Bs[br][bc] = b0;
        *(float4*)&Gs[br][bc] = g0;
        __syncthreads();
        const int kn = k0 + BK;
        if (kn < 256) {
            a0 = *(const float4*)(Ap + kn);
            a1 = *(const float4*)(Ap + kn + 4);
            b0 = *(const float4*)(Bp + (size_t)kn * 2048);
            g0 = *(const float4*)(Gp + (size_t)kn * 2048);
        }
#pragma unroll
        for (int kk = 0; kk < BK; ++kk) {
            float av[8], bv[4], gv[4];
            *(float4*)&av[0] = *(const float4*)&As[kk][tr * 8];
            *(float4*)&av[4] = *(const float4*)&As[kk][tr * 8 + 4];
            *(float4*)&bv[0] = *(const float4*)&Bs[kk][tc * 4];
            *(float4*)&gv[0] = *(const float4*)&Gs[kk][tc * 4];
#pragma unroll
            for (int i = 0; i < 8; ++i)
#pragma unroll
                for (int j = 0; j < 4; ++j) {
                    acc[i][j] = fmaf(av[i], bv[j], acc[i][j]);
                    acg[i][j] = fmaf(av[i], gv[j], acg[i][j]);
                }
        }
        k0 = kn;
        if (k0 >= 256) break;
        __syncthreads();
    }

    float bb[4], bg[4];
    *(float4*)&bb[0] = *(const float4*)&bias[n0 + tc * 4];
    *(float4*)&bg[0] = *(const float4*)&bias[1024 + n0 + tc * 4];
#pragma unroll
    for (int i = 0; i < 8; ++i) {
        float4 ov;
        float u0 = acc[i][0] + bb[0], u1 = acc[i][1] + bb[1], u2 = acc[i][2] + bb[2], u3 = acc[i][3] + bb[3];
        ov.x = gelu_exact(u0) * (acg[i][0] + bg[0]);
        ov.y = gelu_exact(u1) * (acg[i][1] + bg[1]);
        ov.z = gelu_exact(u2) * (acg[i][2] + bg[2]);
        ov.w = gelu_exact(u3) * (acg[i][3] + bg[3]);
        *(float4*)&out[(size_t)(m0 + tr * 8 + i) * 1024 + (n0 + tc * 4)] = ov;
    }
}

// ---- LayerNorm: one wave per 256-wide row ----
__global__ __launch_bounds__(256) void ln_kernel(
    const float* __restrict__ x, const float* __restrict__ g,
    const float* __restrict__ b, float* __restrict__ y)
{
    const int row = blockIdx.x * 4 + (threadIdx.x >> 6);
    const int lane = threadIdx.x & 63;
    float4 t = *(const float4*)&x[(size_t)row * 256 + lane * 4];
    float s = t.x + t.y + t.z + t.w;
#pragma unroll
    for (int sh = 1; sh < 64; sh <<= 1) s += __shfl_xor(s, sh);
    const float mu = s * (1.0f / 256.0f);
    const float dx = t.x - mu, dy = t.y - mu, dz = t.z - mu, dw = t.w - mu;
    float vv = dx * dx + dy * dy + dz * dz + dw * dw;
#pragma unroll
    for (int sh = 1; sh < 64; sh <<= 1) vv += __shfl_xor(vv, sh);
    const float rstd = rsqrtf(vv * (1.0f / 256.0f) + 1e-5f);
    float4 gv = *(const float4*)&g[lane * 4];
    float4 bv = *(const float4*)&b[lane * 4];
    float4 ov;
    ov.x = dx * rstd * gv.x + bv.x;
    ov.y = dy * rstd * gv.y + bv.y;
    ov.z = dz * rstd * gv.z + bv.z;
    ov.w = dw * rstd * gv.w + bv.w;
    *(float4*)&y[(size_t)row * 256 + lane * 4] = ov;
}

// ---- proj_mat transpose with dn folding: projT[d][m] = proj[m][d]*dn ----
__global__ __launch_bounds__(256) void projT_kernel(const float* __restrict__ pm, float* __restrict__ pT)
{
    const int idx = blockIdx.x * 256 + threadIdx.x;   // 64*256
    const int d = idx >> 8, m = idx & 255;
    pT[idx] = pm[m * 64 + d] * DN;
}

// ---- per-row diag = 0.5*dn^2 * sum(x^2) over 64 dims (16 lanes per row) ----
__global__ __launch_bounds__(256) void diag_kernel(const float* __restrict__ qk, float* __restrict__ diag)
{
    const int row = blockIdx.x * 16 + (threadIdx.x >> 4);
    const int l16 = threadIdx.x & 15;
    float4 t = *(const float4*)&qk[(size_t)row * 64 + l16 * 4];
    float s = t.x * t.x + t.y * t.y + t.z * t.z + t.w * t.w;
    s += __shfl_xor(s, 1); s += __shfl_xor(s, 2); s += __shfl_xor(s, 4); s += __shfl_xor(s, 8);
    if (l16 == 0) diag[row] = s * 0.0625f;   // *0.5*dn^2 = /16
}

// ---- global max over dd_b (exact, via monotone uint keys) ----
__global__ __launch_bounds__(256) void maxk_kernel(const float* __restrict__ x, unsigned* __restrict__ gmax, int n4)
{
    float m = -3.4e38f;
    const int stride = gridDim.x * 256;
    for (int i = blockIdx.x * 256 + threadIdx.x; i < n4; i += stride) {
        float4 t = *(const float4*)&x[(size_t)i * 4];
        m = fmaxf(m, fmaxf(fmaxf(t.x, t.y), fmaxf(t.z, t.w)));
    }
#pragma unroll
    for (int s = 1; s < 64; s <<= 1) m = fmaxf(m, __shfl_xor(m, s));
    __shared__ float red[4];
    if ((threadIdx.x & 63) == 0) red[threadIdx.x >> 6] = m;
    __syncthreads();
    if (threadIdx.x == 0) {
        m = fmaxf(fmaxf(red[0], red[1]), fmaxf(red[2], red[3]));
        atomicMax(gmax, fkey(m));
    }
}

// ---- qp in-place on dd_b [16384,256]: rowmax then ratio*(exp(dd-diag-max)+eps) ----
__global__ __launch_bounds__(256) void qp_kernel(float* __restrict__ dd, const float* __restrict__ diag)
{
    const int row = blockIdx.x * 4 + (threadIdx.x >> 6);
    const int lane = threadIdx.x & 63;
    float* p = &dd[(size_t)row * 256 + lane * 4];
    float4 t = *(const float4*)p;
    float mx = fmaxf(fmaxf(t.x, t.y), fmaxf(t.z, t.w));
#pragma unroll
    for (int s = 1; s < 64; s <<= 1) mx = fmaxf(mx, __shfl_xor(mx, s));
    const float dg = diag[row] + mx;
    t.x = RATIO * (expf(t.x - dg) + EPSF);
    t.y = RATIO * (expf(t.y - dg) + EPSF);
    t.z = RATIO * (expf(t.z - dg) + EPSF);
    t.w = RATIO * (expf(t.w - dg) + EPSF);
    *(float4*)p = t;
}

// ---- ctx partials for batch b: per (n-chunk of 256, hh): ctx[m,d] += kp*v ; es[m] += kp ----
__global__ __launch_bounds__(256) void ctx_kernel(
    const float* __restrict__ ddk, const float* __restrict__ diagk,
    const unsigned* __restrict__ gmax, const float* __restrict__ v,
    float* __restrict__ ctxp, float* __restrict__ esp, int b)
{
    __shared__ float vlds[256][68];
    __shared__ float dl[256];
    const int chunk = blockIdx.x, hh = blockIdx.y;
    const int nb = chunk * 256;
    const int tid = threadIdx.x;
    for (int i = tid; i < 4096; i += 256) {
        const int n = i >> 4, seg = (i & 15) * 4;
        *(float4*)&vlds[n][seg] = *(const float4*)&v[((size_t)(b * 4096 + nb + n)) * 256 + hh * 64 + seg];
    }
    dl[tid] = diagk[(size_t)(b * 4096 + nb + tid) * 4 + hh];
    const float M = funkey(*gmax);
    __syncthreads();

    const int m0 = (tid & 31) * 8, d0 = (tid >> 5) * 8;
    float acc[8][8], es[8];
#pragma unroll
    for (int i = 0; i < 8; ++i) {
        es[i] = 0.f;
#pragma unroll
        for (int j = 0; j < 8; ++j) acc[i][j] = 0.f;
    }
    for (int n = 0; n < 256; ++n) {
        const float* row = &ddk[((size_t)(nb + n) * 4 + hh) * 256 + m0];
        const float4 t0 = *(const float4*)row;
        const float4 t1 = *(const float4*)(row + 4);
        const float dm = dl[n] + M;
        float e[8];
        e[0] = expf(t0.x - dm) + EPSF; e[1] = expf(t0.y - dm) + EPSF;
        e[2] = expf(t0.z - dm) + EPSF; e[3] = expf(t0.w - dm) + EPSF;
        e[4] = expf(t1.x - dm) + EPSF; e[5] = expf(t1.y - dm) + EPSF;
        e[6] = expf(t1.z - dm) + EPSF; e[7] = expf(t1.w - dm) + EPSF;
        float vv[8];
        *(float4*)&vv[0] = *(const float4*)&vlds[n][d0];
        *(float4*)&vv[4] = *(const float4*)&vlds[n][d0 + 4];
#pragma unroll
        for (int i = 0; i < 8; ++i) {
            es[i] += e[i];
#pragma unroll
            for (int j = 0; j < 8; ++j) acc[i][j] = fmaf(e[i], vv[j], acc[i][j]);
        }
    }
    const size_t base = ((size_t)(chunk * 4 + hh) * 256 + m0) * 64 + d0;
#pragma unroll
    for (int i = 0; i < 8; ++i) {
        float4 o1, o2;
        o1.x = acc[i][0]; o1.y = acc[i][1]; o1.z = acc[i][2]; o1.w = acc[i][3];
        o2.x = acc[i][4]; o2.y = acc[i][5]; o2.z = acc[i][6]; o2.w = acc[i][7];
        *(float4*)&ctxp[base + (size_t)i * 64] = o1;
        *(float4*)&ctxp[base + (size_t)i * 64 + 4] = o2;
    }
    if (d0 == 0) {
#pragma unroll
        for (int i = 0; i < 8; ++i)
            esp[(size_t)(chunk * 4 + hh) * 256 + m0 + i] = es[i];
    }
}

// ---- reduce ctx/es partials over 16 chunks for batch b, apply ratio ----
__global__ __launch_bounds__(256) void ctxred_kernel(
    const float* __restrict__ ctxp, const float* __restrict__ esp,
    float* __restrict__ ctx, float* __restrict__ ksum, int b)
{
    const int idx = blockIdx.x * 256 + threadIdx.x;   // 260*256 = 66,560 = 65,536 + 1,024
    if (idx < 65536) {
        float s = 0.f;
#pragma unroll
        for (int c = 0; c < 16; ++c) s += ctxp[(size_t)c * 65536 + idx];
        ctx[(size_t)b * 65536 + idx] = s * RATIO;
    } else {
        const int j = idx - 65536;
        float s = 0.f;
#pragma unroll
        for (int c = 0; c < 16; ++c) s += esp[(size_t)c * 1024 + j];
        ksum[(size_t)b * 1024 + j] = s * RATIO;
    }
}

// ---- o = d_inv * (qp @ ctx) for batch b; per (128-token tile, hh) ----
__global__ __launch_bounds__(256) void o_kernel(
    const float* __restrict__ qp, const float* __restrict__ ctx,
    const float* __restrict__ ksum, float* __restrict__ o, int b)
{
    __shared__ float As[128][69];
    __shared__ float Cs[64][64];
    __shared__ float Ks[64];
    const int hh = blockIdx.y;
    const int t0 = blockIdx.x * 128;
    const int tid = threadIdx.x;
    const int tr = tid >> 4, tc = tid & 15;
    const int bh = b * 4 + hh;
    float acc[8][4], den[8];
#pragma unroll
    for (int i = 0; i < 8; ++i) {
        den[i] = 0.f;
#pragma unroll
        for (int j = 0; j < 4; ++j) acc[i][j] = 0.f;
    }
    for (int k0 = 0; k0 < 256; k0 += 64) {
        __syncthreads();
        for (int i = tid; i < 2048; i += 256) {
            const int tok = i >> 4, seg = (i & 15) * 4;
            float4 t = *(const float4*)&qp[((size_t)(t0 + tok) * 4 + hh) * 256 + k0 + seg];
            As[tok][seg] = t.x; As[tok][seg + 1] = t.y; As[tok][seg + 2] = t.z; As[tok][seg + 3] = t.w;
        }
        for (int i = tid; i < 1024; i += 256) {
            const int kk = i >> 4, seg = (i & 15) * 4;
            *(float4*)&Cs[kk][seg] = *(const float4*)&ctx[((size_t)bh * 256 + k0 + kk) * 64 + seg];
        }
        if (tid < 64) Ks[tid] = ksum[bh * 256 + k0 + tid];
        __syncthreads();
#pragma unroll 4
        for (int kk = 0; kk < 64; ++kk) {
            float av[8];
#pragma unroll
            for (int i = 0; i < 8; ++i) av[i] = As[tr * 8 + i][kk];
            float bv[4];
            *(float4*)&bv[0] = *(const float4*)&Cs[kk][tc * 4];
            const float kv = Ks[kk];
#pragma unroll
            for (int i = 0; i < 8; ++i) {
                den[i] = fmaf(av[i], kv, den[i]);
#pragma unroll
                for (int j = 0; j < 4; ++j) acc[i][j] = fmaf(av[i], bv[j], acc[i][j]);
            }
        }
    }
#pragma unroll
    for (int i = 0; i < 8; ++i) {
        const float dinv = 1.0f / den[i];
        const int tok = t0 + tr * 8 + i;
        float4 ov;
        ov.x = acc[i][0] * dinv; ov.y = acc[i][1] * dinv;
        ov.z = acc[i][2] * dinv; ov.w = acc[i][3] * dinv;
        *(float4*)&o[((size_t)(b * 4096) + tok) * 256 + hh * 64 + tc * 4] = ov;
    }
}

// ---- pooling + classifier ----
__global__ __launch_bounds__(256) void pool1_kernel(const float* __restrict__ h, float* __restrict__ part)
{
    const int b = blockIdx.x >> 4, ch = blockIdx.x & 15;
    const int tid = threadIdx.x;
    float acc = 0.f;
    for (int n = 0; n < 256; ++n)
        acc += h[((size_t)(b * 4096 + ch * 256 + n)) * 256 + tid];
    part[(size_t)blockIdx.x * 256 + tid] = acc;
}

__global__ __launch_bounds__(256) void pool2_kernel(
    const float* __restrict__ part, const float* __restrict__ cw,
    const float* __restrict__ cb, float* __restrict__ out)
{
    const int b = blockIdx.x, tid = threadIdx.x;
    float acc = 0.f;
#pragma unroll
    for (int c = 0; c < 16; ++c) acc += part[(size_t)(b * 16 + c) * 256 + tid];
    float val = acc * (1.0f / 4096.0f) * cw[tid];
#pragma unroll
    for (int s = 1; s < 64; s <<= 1) val += __shfl_xor(val, s);
    __shared__ float red[4];
    if ((tid & 63) == 0) red[tid >> 6] = val;
    __syncthreads();
    if (tid == 0) out[b] = red[0] + red[1] + red[2] + red[3] + cb[0];
}

extern "C" void kernel_launch(void* const* d_in, const int* in_sizes, int n_in,
                              void* d_out, int out_size, void* d_ws, size_t ws_size,
                              hipStream_t stream)
{
    (void)in_sizes; (void)n_in;
    // Workspace guard: distinctive sentinel if scratch too small.
    if (ws_size < WS_FLOATS * sizeof(float)) {
        fill_sentinel<<<1, 64, 0, stream>>>((float*)d_out, out_size);
        return;
    }

    const float* x     = (const float*)d_in[0];
    const float* projw = (const float*)d_in[1];
    const float* projb = (const float*)d_in[2];
    const float* ln1g  = (const float*)d_in[3];
    const float* ln1b  = (const float*)d_in[4];
    const float* wq    = (const float*)d_in[5];
    const float* bq    = (const float*)d_in[6];
    const float* wk    = (const float*)d_in[7];
    const float* bk    = (const float*)d_in[8];
    const float* wv    = (const float*)d_in[9];
    const float* bv    = (const float*)d_in[10];
    const float* wo    = (const float*)d_in[11];
    const float* bo    = (const float*)d_in[12];
    const float* ln2g  = (const float*)d_in[13];
    const float* ln2b  = (const float*)d_in[14];
    const float* w1    = (const float*)d_in[15];
    const float* b1    = (const float*)d_in[16];
    const float* w2    = (const float*)d_in[17];
    const float* b2    = (const float*)d_in[18];
    const float* clfw  = (const float*)d_in[19];
    const float* clfb  = (const float*)d_in[20];
    const float* projm = (const float*)d_in[21];

    float* ws = (float*)d_ws;
    float* projT = ws + OFF_PROJT;
    float* diagq = ws + OFF_DIAGQ;
    float* diagk = ws + OFF_DIAGK;
    float* ctx   = ws + OFF_CTX;
    float* ksum  = ws + OFF_KSUM;
    unsigned* gmax = (unsigned*)(ws + OFF_GMAX);
    float* pool  = ws + OFF_POOL;
    float* esp   = ws + OFF_ESP;
    float* ctxp  = ws + OFF_CTXP;
    float* h     = ws + OFF_H;
    float* y     = ws + OFF_Y;
    float* q     = ws + OFF_Q;
    float* k     = ws + OFF_K;
    float* v     = ws + OFF_V;
    float* ddb   = ws + OFF_DDB;
    float* o     = q;        // alias (written per batch after that batch's q consumed)
    float* ffmid = q;        // alias over q,k,v,ddb (all dead during FF)

    projT_kernel<<<64, 256, 0, stream>>>(projm, projT);
    gemm_f32<true, false><<<dim3(4, 256), 256, 0, stream>>>(x, projw, projb, nullptr, h, 32768, 256, 64);

    for (int l = 0; l < 4; ++l) {
        ln_kernel<<<8192, 256, 0, stream>>>(h, ln1g + l * 256, ln1b + l * 256, y);
        gemm_f32<true, false><<<dim3(4, 256), 256, 0, stream>>>(y, wq + (size_t)l * 65536, bq + l * 256, nullptr, q, 32768, 256, 256);
        gemm_f32<true, false><<<dim3(4, 256), 256, 0, stream>>>(y, wk + (size_t)l * 65536, bk + l * 256, nullptr, k, 32768, 256, 256);
        gemm_f32<true, false><<<dim3(4, 256), 256, 0, stream>>>(y, wv + (size_t)l * 65536, bv + l * 256, nullptr, v, 32768, 256, 256);
        diag_kernel<<<8192, 256, 0, stream>>>(q, diagq);
        diag_kernel<<<8192, 256, 0, stream>>>(k, diagk);
        init_gmax<<<1, 1, 0, stream>>>(gmax);
        // pass 1: global max over all of dd_k
        for (int b = 0; b < 8; ++b) {
            gemm_f32<false, false><<<dim3(4, 128), 256, 0, stream>>>(k + (size_t)b * 1048576, projT, nullptr, nullptr, ddb, 16384, 256, 64);
            maxk_kernel<<<1024, 256, 0, stream>>>(ddb, gmax, 1048576);
        }
        // pass 2: ctx & ksum (recompute dd_k per batch)
        for (int b = 0; b < 8; ++b) {
            gemm_f32<false, false><<<dim3(4, 128), 256, 0, stream>>>(k + (size_t)b * 1048576, projT, nullptr, nullptr, ddb, 16384, 256, 64);
            ctx_kernel<<<dim3(16, 4), 256, 0, stream>>>(ddb, diagk, gmax, v, ctxp, esp, b);
            ctxred_kernel<<<260, 256, 0, stream>>>(ctxp, esp, ctx, ksum, b);
        }
        // pass 3: qp and o per batch
        for (int b = 0; b < 8; ++b) {
            gemm_f32<false, false><<<dim3(4, 128), 256, 0, stream>>>(q + (size_t)b * 1048576, projT, nullptr, nullptr, ddb, 16384, 256, 64);
            qp_kernel<<<4096, 256, 0, stream>>>(ddb, diagq + (size_t)b * 16384);
            o_kernel<<<dim3(32, 4), 256, 0, stream>>>(ddb, ctx, ksum, o, b);
        }
        gemm_f32<true, true><<<dim3(4, 256), 256, 0, stream>>>(o, wo + (size_t)l * 65536, bo + l * 256, h, h, 32768, 256, 256);
        ln_kernel<<<8192, 256, 0, stream>>>(h, ln2g + l * 256, ln2b + l * 256, y);
        glu_gemm<<<dim3(16, 256), 256, 0, stream>>>(y, w1 + (size_t)l * 524288, b1 + (size_t)l * 2048, ffmid);
        gemm_f32<true, true><<<dim3(4, 256), 256, 0, stream>>>(ffmid, w2 + (size_t)l * 262144, b2 + l * 256, h, h, 32768, 256, 1024);
    }

    pool1_kernel<<<128, 256, 0, stream>>>(h, pool);
    pool2_kernel<<<8, 256, 0, stream>>>(pool, clfw, clfb, (float*)d_out);
}

// Round 3
// 8917.217 us; speedup vs baseline: 1.3457x; 1.3457x over previous
//
#include <hip/hip_runtime.h>
#include <cstdint>
#include <cstddef>

// ---- problem constants ----
constexpr float DN = 0.35355339059327373f;   // 64^-0.25
constexpr float RATIO = 0.0625f;             // 256^-0.5
constexpr float EPSF = 1e-4f;

typedef __attribute__((ext_vector_type(8))) short short8;   // bf16 MFMA fragment (4 VGPR)
typedef __attribute__((ext_vector_type(4))) float f32x4;    // MFMA accumulator

// ---- workspace layout (byte offsets) ----
constexpr size_t OFF_H      = 0;              // fp32 residual  33,554,432
constexpr size_t OFF_YSPH   = 33554432;       // ln-out hi      16,777,216
constexpr size_t OFF_YSPL   = 50331648;       // ln-out lo
constexpr size_t OFF_QSPH   = 67108864;       // q hi   (xsp_h early; ff_h spans QSPH+QSPL in FF)
constexpr size_t OFF_QSPL   = 83886080;       // q lo   (xsp_l early)
constexpr size_t OFF_KSPH   = 100663296;      // k hi   (osp_h later; ff_l spans KSPH+KSPL in FF)
constexpr size_t OFF_KSPL   = 117440512;      // k lo   (osp_l later)
constexpr size_t OFF_V      = 134217728;      // fp32 v         33,554,432
constexpr size_t OFF_DDB    = 167772160;      // fp32 dd batch  16,777,216
constexpr size_t OFF_CTX    = 184549376;      // 2,097,152
constexpr size_t OFF_KSUM   = 186646528;      // 32,768
constexpr size_t OFF_DIAGQ  = 186679296;      // 524,288
constexpr size_t OFF_DIAGK  = 187203584;      // 524,288
constexpr size_t OFF_CTXP   = 187727872;      // 4,194,304
constexpr size_t OFF_ESP    = 191922176;      // 65,536
constexpr size_t OFF_POOL   = 191987712;      // 131,072
constexpr size_t OFF_GMAX   = 192118784;      // 256
constexpr size_t OFF_WQTH   = 192119040;      // per-layer weight splits
constexpr size_t OFF_WQTL   = 192250112;
constexpr size_t OFF_WKTH   = 192381184;
constexpr size_t OFF_WKTL   = 192512256;
constexpr size_t OFF_WVTH   = 192643328;
constexpr size_t OFF_WVTL   = 192774400;
constexpr size_t OFF_WOTH   = 192905472;
constexpr size_t OFF_WOTL   = 193036544;
constexpr size_t OFF_W1TH   = 193167616;      // 1,048,576
constexpr size_t OFF_W1TL   = 194216192;
constexpr size_t OFF_W2TH   = 195264768;      // 524,288
constexpr size_t OFF_W2TL   = 195789056;
constexpr size_t OFF_PMTH   = 196313344;      // 32,768
constexpr size_t OFF_PMTL   = 196346112;
constexpr size_t OFF_PWTH   = 196378880;
constexpr size_t OFF_PWTL   = 196411648;
constexpr size_t WS_BYTES   = 196444416;

__device__ __forceinline__ unsigned fkey(float f) {
    unsigned u = __float_as_uint(f);
    return (u & 0x80000000u) ? ~u : (u | 0x80000000u);
}
__device__ __forceinline__ float funkey(unsigned k) {
    unsigned u = (k & 0x80000000u) ? (k ^ 0x80000000u) : ~k;
    return __uint_as_float(u);
}
__device__ __forceinline__ float gelu_exact(float x) {
    return 0.5f * x * (1.0f + erff(x * 0.70710678118654752f));
}
// fp32 -> (hi,lo) bf16 split, round-to-nearest-even
__device__ __forceinline__ void splitf(float x, unsigned short& h, unsigned short& l) {
    unsigned u = __float_as_uint(x);
    unsigned hv = (u + 0x7FFFu + ((u >> 16) & 1)) >> 16;
    h = (unsigned short)hv;
    float lo = x - __uint_as_float(hv << 16);
    unsigned u2 = __float_as_uint(lo);
    l = (unsigned short)((u2 + 0x7FFFu + ((u2 >> 16) & 1)) >> 16);
}

__global__ void init_gmax(unsigned* g) { *g = 0u; }
__global__ void fill_sentinel(float* out, int n) {
    int i = threadIdx.x;
    if (i < n) out[i] = 12345.0f;
}

// ---- elementwise split (optional scale): src fp32 [n] -> hi/lo bf16 planes ----
__global__ __launch_bounds__(256) void split_scale(
    const float* __restrict__ src, unsigned short* __restrict__ hi,
    unsigned short* __restrict__ lo, int n, float scale)
{
    int i = blockIdx.x * 256 + threadIdx.x;
    if (i < n) {
        unsigned short h, l;
        splitf(src[i] * scale, h, l);
        hi[i] = h; lo[i] = l;
    }
}

// ---- transpose-split weights: W [K,N] fp32 -> Wt hi/lo [N,K] bf16 (K power of 2) ----
__global__ __launch_bounds__(256) void splitT(
    const float* __restrict__ W, unsigned short* __restrict__ hi,
    unsigned short* __restrict__ lo, int kshift, int N)
{
    int i = blockIdx.x * 256 + threadIdx.x;
    int K = 1 << kshift;
    int n = i >> kshift, k = i & (K - 1);
    unsigned short h, l;
    splitf(W[(size_t)k * N + n], h, l);
    hi[i] = h; lo[i] = l;
}

// ---- LayerNorm -> split bf16 planes ----
__global__ __launch_bounds__(256) void ln_split(
    const float* __restrict__ x, const float* __restrict__ g,
    const float* __restrict__ b, unsigned short* __restrict__ yhi,
    unsigned short* __restrict__ ylo)
{
    const int row = blockIdx.x * 4 + (threadIdx.x >> 6);
    const int lane = threadIdx.x & 63;
    float4 t = *(const float4*)&x[(size_t)row * 256 + lane * 4];
    float s = t.x + t.y + t.z + t.w;
#pragma unroll
    for (int sh = 1; sh < 64; sh <<= 1) s += __shfl_xor(s, sh);
    const float mu = s * (1.0f / 256.0f);
    const float dx = t.x - mu, dy = t.y - mu, dz = t.z - mu, dw = t.w - mu;
    float vv = dx * dx + dy * dy + dz * dz + dw * dw;
#pragma unroll
    for (int sh = 1; sh < 64; sh <<= 1) vv += __shfl_xor(vv, sh);
    const float rstd = rsqrtf(vv * (1.0f / 256.0f) + 1e-5f);
    float4 gv = *(const float4*)&g[lane * 4];
    float4 bv = *(const float4*)&b[lane * 4];
    float o0 = dx * rstd * gv.x + bv.x;
    float o1 = dy * rstd * gv.y + bv.y;
    float o2 = dz * rstd * gv.z + bv.z;
    float o3 = dw * rstd * gv.w + bv.w;
    unsigned short h0, l0, h1, l1, h2, l2, h3, l3;
    splitf(o0, h0, l0); splitf(o1, h1, l1); splitf(o2, h2, l2); splitf(o3, h3, l3);
    const size_t base = (size_t)row * 256 + lane * 4;
    uint2 ph, pl;
    ph.x = (unsigned)h0 | ((unsigned)h1 << 16); ph.y = (unsigned)h2 | ((unsigned)h3 << 16);
    pl.x = (unsigned)l0 | ((unsigned)l1 << 16); pl.y = (unsigned)l2 | ((unsigned)l3 << 16);
    *(uint2*)&yhi[base] = ph;
    *(uint2*)&ylo[base] = pl;
}

// ---- split-bf16 MFMA GEMM: C[M,N] = A@B, A split [M,K], Bt split [N,K] ----
// tile 128x128, BK=32, 256 thr / 4 waves (each 64x64 quadrant, 4x4 frags).
// EPI: 0 = bias -> fp32 C; 1 = bias(+nullable) + res -> fp32 C;
//      2 = bias -> split planes + per-head diag; 3 = raw fp32 C; 4 = global max only.
template<int EPI>
__global__ __launch_bounds__(256) void gemm_mf(
    const unsigned short* __restrict__ Ahi, const unsigned short* __restrict__ Alo, int lda,
    const unsigned short* __restrict__ Bhi, const unsigned short* __restrict__ Blo, int ldb,
    int K,
    const float* __restrict__ bias, const float* __restrict__ res,
    float* __restrict__ C, int ldc,
    unsigned short* __restrict__ Ohi, unsigned short* __restrict__ Olo,
    float* __restrict__ diag, unsigned* __restrict__ gmax)
{
    __shared__ unsigned short lds[4][128][56];
    __shared__ float red[4];
    const int tid = threadIdx.x;
    const int m0 = blockIdx.y * 128, n0 = blockIdx.x * 128;
    const int srow = tid >> 1, sseg = (tid & 1) * 16;
    const unsigned short* ga_h = Ahi + (size_t)(m0 + srow) * lda + sseg;
    const unsigned short* ga_l = Alo + (size_t)(m0 + srow) * lda + sseg;
    const unsigned short* gb_h = Bhi + (size_t)(n0 + srow) * ldb + sseg;
    const unsigned short* gb_l = Blo + (size_t)(n0 + srow) * ldb + sseg;
    const int l = tid & 63, w = tid >> 6;
    const int wr = (w >> 1) * 64, wc = (w & 1) * 64;
    const int fr = l & 15, fq = l >> 4;

    f32x4 acc[4][4];
#pragma unroll
    for (int i = 0; i < 4; ++i)
#pragma unroll
        for (int j = 0; j < 4; ++j) acc[i][j] = (f32x4){0.f, 0.f, 0.f, 0.f};

    for (int k0 = 0; k0 < K; k0 += 32) {
        *(uint4*)&lds[0][srow][sseg]     = *(const uint4*)(ga_h + k0);
        *(uint4*)&lds[0][srow][sseg + 8] = *(const uint4*)(ga_h + k0 + 8);
        *(uint4*)&lds[1][srow][sseg]     = *(const uint4*)(ga_l + k0);
        *(uint4*)&lds[1][srow][sseg + 8] = *(const uint4*)(ga_l + k0 + 8);
        *(uint4*)&lds[2][srow][sseg]     = *(const uint4*)(gb_h + k0);
        *(uint4*)&lds[2][srow][sseg + 8] = *(const uint4*)(gb_h + k0 + 8);
        *(uint4*)&lds[3][srow][sseg]     = *(const uint4*)(gb_l + k0);
        *(uint4*)&lds[3][srow][sseg + 8] = *(const uint4*)(gb_l + k0 + 8);
        __syncthreads();
        short8 ah[4], al[4];
#pragma unroll
        for (int mf = 0; mf < 4; ++mf) {
            ah[mf] = *(const short8*)&lds[0][wr + mf * 16 + fr][fq * 8];
            al[mf] = *(const short8*)&lds[1][wr + mf * 16 + fr][fq * 8];
        }
#pragma unroll
        for (int nf = 0; nf < 4; ++nf) {
            short8 bh = *(const short8*)&lds[2][wc + nf * 16 + fr][fq * 8];
            short8 bl = *(const short8*)&lds[3][wc + nf * 16 + fr][fq * 8];
#pragma unroll
            for (int mf = 0; mf < 4; ++mf) {
                acc[mf][nf] = __builtin_amdgcn_mfma_f32_16x16x32_bf16(ah[mf], bh, acc[mf][nf], 0, 0, 0);
                acc[mf][nf] = __builtin_amdgcn_mfma_f32_16x16x32_bf16(al[mf], bh, acc[mf][nf], 0, 0, 0);
                acc[mf][nf] = __builtin_amdgcn_mfma_f32_16x16x32_bf16(ah[mf], bl, acc[mf][nf], 0, 0, 0);
            }
        }
        __syncthreads();
    }

    if constexpr (EPI == 4) {
        float m = -3.4e38f;
#pragma unroll
        for (int mf = 0; mf < 4; ++mf)
#pragma unroll
            for (int nf = 0; nf < 4; ++nf)
#pragma unroll
                for (int v = 0; v < 4; ++v) m = fmaxf(m, acc[mf][nf][v]);
#pragma unroll
        for (int s = 1; s < 64; s <<= 1) m = fmaxf(m, __shfl_xor(m, s));
        if (l == 0) red[w] = m;
        __syncthreads();
        if (tid == 0)
            atomicMax(gmax, fkey(fmaxf(fmaxf(red[0], red[1]), fmaxf(red[2], red[3]))));
        return;
    } else if constexpr (EPI == 2) {
        const int head = (n0 + wc) >> 6;
#pragma unroll
        for (int mf = 0; mf < 4; ++mf) {
            float sq[4] = {0.f, 0.f, 0.f, 0.f};
#pragma unroll
            for (int nf = 0; nf < 4; ++nf) {
                const int col = n0 + wc + nf * 16 + fr;
                const float bb = bias[col];
#pragma unroll
                for (int v = 0; v < 4; ++v) {
                    const int row = m0 + wr + mf * 16 + fq * 4 + v;
                    float val = acc[mf][nf][v] + bb;
                    unsigned short hh_, ll_;
                    splitf(val, hh_, ll_);
                    Ohi[(size_t)row * 256 + col] = hh_;
                    Olo[(size_t)row * 256 + col] = ll_;
                    sq[v] += val * val;
                }
            }
#pragma unroll
            for (int v = 0; v < 4; ++v) {
                float s = sq[v];
                s += __shfl_xor(s, 1); s += __shfl_xor(s, 2);
                s += __shfl_xor(s, 4); s += __shfl_xor(s, 8);
                if (fr == 0)
                    diag[(size_t)(m0 + wr + mf * 16 + fq * 4 + v) * 4 + head] = s * 0.0625f;
            }
        }
        return;
    } else {
#pragma unroll
        for (int nf = 0; nf < 4; ++nf) {
            const int col = n0 + wc + nf * 16 + fr;
            float bb = 0.f;
            if (EPI != 3 && bias != nullptr) bb = bias[col];
#pragma unroll
            for (int mf = 0; mf < 4; ++mf) {
#pragma unroll
                for (int v = 0; v < 4; ++v) {
                    const int row = m0 + wr + mf * 16 + fq * 4 + v;
                    const size_t off = (size_t)row * ldc + col;
                    float val = acc[mf][nf][v] + bb;
                    if (EPI == 1) val += res[off];
                    C[off] = val;
                }
            }
        }
    }
}

// ---- fused GLU GEMM (split-bf16 MFMA): out = gelu(y@W1a+b1a)*(y@W1g+b1g) ----
// tile 128 x 64 pairs; half selected by nbase (0 or 512); writes split planes [32768,512].
__global__ __launch_bounds__(256) void gemm_glu(
    const unsigned short* __restrict__ Ahi, const unsigned short* __restrict__ Alo,
    const unsigned short* __restrict__ Whi, const unsigned short* __restrict__ Wlo,
    const float* __restrict__ b1,
    unsigned short* __restrict__ Ohi, unsigned short* __restrict__ Olo, int nbase)
{
    __shared__ unsigned short ldsA[2][128][56];
    __shared__ unsigned short ldsB[4][64][56];
    const int tid = threadIdx.x;
    const int m0 = blockIdx.y * 128, p0 = blockIdx.x * 64;
    const int srow = tid >> 1, sseg = (tid & 1) * 16;
    const unsigned short* ga_h = Ahi + (size_t)(m0 + srow) * 256 + sseg;
    const unsigned short* ga_l = Alo + (size_t)(m0 + srow) * 256 + sseg;
    const int brow = tid & 63, pp = tid >> 6;
    const int grow = (pp < 2 ? (nbase + p0 + brow) : (1024 + nbase + p0 + brow));
    const unsigned short* gw = ((pp & 1) ? Wlo : Whi) + (size_t)grow * 256;
    const int l = tid & 63, w = tid >> 6;
    const int wr = (w >> 1) * 64, wc = (w & 1) * 32;
    const int fr = l & 15, fq = l >> 4;

    f32x4 aa[4][2], ag[4][2];
#pragma unroll
    for (int i = 0; i < 4; ++i)
#pragma unroll
        for (int j = 0; j < 2; ++j) {
            aa[i][j] = (f32x4){0.f, 0.f, 0.f, 0.f};
            ag[i][j] = (f32x4){0.f, 0.f, 0.f, 0.f};
        }

    for (int k0 = 0; k0 < 256; k0 += 32) {
        *(uint4*)&ldsA[0][srow][sseg]     = *(const uint4*)(ga_h + k0);
        *(uint4*)&ldsA[0][srow][sseg + 8] = *(const uint4*)(ga_h + k0 + 8);
        *(uint4*)&ldsA[1][srow][sseg]     = *(const uint4*)(ga_l + k0);
        *(uint4*)&ldsA[1][srow][sseg + 8] = *(const uint4*)(ga_l + k0 + 8);
        *(uint4*)&ldsB[pp][brow][0]       = *(const uint4*)(gw + k0);
        *(uint4*)&ldsB[pp][brow][8]       = *(const uint4*)(gw + k0 + 8);
        *(uint4*)&ldsB[pp][brow][16]      = *(const uint4*)(gw + k0 + 16);
        *(uint4*)&ldsB[pp][brow][24]      = *(const uint4*)(gw + k0 + 24);
        __syncthreads();
        short8 ah[4], al[4];
#pragma unroll
        for (int mf = 0; mf < 4; ++mf) {
            ah[mf] = *(const short8*)&ldsA[0][wr + mf * 16 + fr][fq * 8];
            al[mf] = *(const short8*)&ldsA[1][wr + mf * 16 + fr][fq * 8];
        }
#pragma unroll
        for (int nf = 0; nf < 2; ++nf) {
            const int br_ = wc + nf * 16 + fr;
            short8 bah = *(const short8*)&ldsB[0][br_][fq * 8];
            short8 bal = *(const short8*)&ldsB[1][br_][fq * 8];
            short8 bgh = *(const short8*)&ldsB[2][br_][fq * 8];
            short8 bgl = *(const short8*)&ldsB[3][br_][fq * 8];
#pragma unroll
            for (int mf = 0; mf < 4; ++mf) {
                aa[mf][nf] = __builtin_amdgcn_mfma_f32_16x16x32_bf16(ah[mf], bah, aa[mf][nf], 0, 0, 0);
                aa[mf][nf] = __builtin_amdgcn_mfma_f32_16x16x32_bf16(al[mf], bah, aa[mf][nf], 0, 0, 0);
                aa[mf][nf] = __builtin_amdgcn_mfma_f32_16x16x32_bf16(ah[mf], bal, aa[mf][nf], 0, 0, 0);
                ag[mf][nf] = __builtin_amdgcn_mfma_f32_16x16x32_bf16(ah[mf], bgh, ag[mf][nf], 0, 0, 0);
                ag[mf][nf] = __builtin_amdgcn_mfma_f32_16x16x32_bf16(al[mf], bgh, ag[mf][nf], 0, 0, 0);
                ag[mf][nf] = __builtin_amdgcn_mfma_f32_16x16x32_bf16(ah[mf], bgl, ag[mf][nf], 0, 0, 0);
            }
        }
        __syncthreads();
    }
#pragma unroll
    for (int nf = 0; nf < 2; ++nf) {
        const int ch = p0 + wc + nf * 16 + fr;          // col within 512-half
        const float ba = b1[nbase + ch], bg = b1[1024 + nbase + ch];
#pragma unroll
        for (int mf = 0; mf < 4; ++mf) {
#pragma unroll
            for (int v = 0; v < 4; ++v) {
                const int row = m0 + wr + mf * 16 + fq * 4 + v;
                float u = aa[mf][nf][v] + ba, g = ag[mf][nf][v] + bg;
                float r = gelu_exact(u) * g;
                unsigned short hh_, ll_;
                splitf(r, hh_, ll_);
                Ohi[(size_t)row * 512 + ch] = hh_;
                Olo[(size_t)row * 512 + ch] = ll_;
            }
        }
    }
}

// ---- qp in-place on ddb [16384,256] ----
__global__ __launch_bounds__(256) void qp_kernel(float* __restrict__ dd, const float* __restrict__ diag)
{
    const int row = blockIdx.x * 4 + (threadIdx.x >> 6);
    const int lane = threadIdx.x & 63;
    float* p = &dd[(size_t)row * 256 + lane * 4];
    float4 t = *(const float4*)p;
    float mx = fmaxf(fmaxf(t.x, t.y), fmaxf(t.z, t.w));
#pragma unroll
    for (int s = 1; s < 64; s <<= 1) mx = fmaxf(mx, __shfl_xor(mx, s));
    const float dg = diag[row] + mx;
    t.x = RATIO * (expf(t.x - dg) + EPSF);
    t.y = RATIO * (expf(t.y - dg) + EPSF);
    t.z = RATIO * (expf(t.z - dg) + EPSF);
    t.w = RATIO * (expf(t.w - dg) + EPSF);
    *(float4*)p = t;
}

// ---- ctx partials for batch b ----
__global__ __launch_bounds__(256) void ctx_kernel(
    const float* __restrict__ ddk, const float* __restrict__ diagk,
    const unsigned* __restrict__ gmax, const float* __restrict__ v,
    float* __restrict__ ctxp, float* __restrict__ esp, int b)
{
    __shared__ float vlds[256][68];
    __shared__ float dl[256];
    const int chunk = blockIdx.x, hh = blockIdx.y;
    const int nb = chunk * 256;
    const int tid = threadIdx.x;
    for (int i = tid; i < 4096; i += 256) {
        const int n = i >> 4, seg = (i & 15) * 4;
        *(float4*)&vlds[n][seg] = *(const float4*)&v[((size_t)(b * 4096 + nb + n)) * 256 + hh * 64 + seg];
    }
    dl[tid] = diagk[(size_t)(b * 4096 + nb + tid) * 4 + hh];
    const float M = funkey(*gmax);
    __syncthreads();

    const int m0 = (tid & 31) * 8, d0 = (tid >> 5) * 8;
    float acc[8][8], es[8];
#pragma unroll
    for (int i = 0; i < 8; ++i) {
        es[i] = 0.f;
#pragma unroll
        for (int j = 0; j < 8; ++j) acc[i][j] = 0.f;
    }
    for (int n = 0; n < 256; ++n) {
        const float* row = &ddk[((size_t)(nb + n) * 4 + hh) * 256 + m0];
        const float4 t0 = *(const float4*)row;
        const float4 t1 = *(const float4*)(row + 4);
        const float dm = dl[n] + M;
        float e[8];
        e[0] = expf(t0.x - dm) + EPSF; e[1] = expf(t0.y - dm) + EPSF;
        e[2] = expf(t0.z - dm) + EPSF; e[3] = expf(t0.w - dm) + EPSF;
        e[4] = expf(t1.x - dm) + EPSF; e[5] = expf(t1.y - dm) + EPSF;
        e[6] = expf(t1.z - dm) + EPSF; e[7] = expf(t1.w - dm) + EPSF;
        float vv[8];
        *(float4*)&vv[0] = *(const float4*)&vlds[n][d0];
        *(float4*)&vv[4] = *(const float4*)&vlds[n][d0 + 4];
#pragma unroll
        for (int i = 0; i < 8; ++i) {
            es[i] += e[i];
#pragma unroll
            for (int j = 0; j < 8; ++j) acc[i][j] = fmaf(e[i], vv[j], acc[i][j]);
        }
    }
    const size_t base = ((size_t)(chunk * 4 + hh) * 256 + m0) * 64 + d0;
#pragma unroll
    for (int i = 0; i < 8; ++i) {
        float4 o1, o2;
        o1.x = acc[i][0]; o1.y = acc[i][1]; o1.z = acc[i][2]; o1.w = acc[i][3];
        o2.x = acc[i][4]; o2.y = acc[i][5]; o2.z = acc[i][6]; o2.w = acc[i][7];
        *(float4*)&ctxp[base + (size_t)i * 64] = o1;
        *(float4*)&ctxp[base + (size_t)i * 64 + 4] = o2;
    }
    if (d0 == 0) {
#pragma unroll
        for (int i = 0; i < 8; ++i)
            esp[(size_t)(chunk * 4 + hh) * 256 + m0 + i] = es[i];
    }
}

// ---- reduce ctx/es partials over 16 chunks for batch b ----
__global__ __launch_bounds__(256) void ctxred_kernel(
    const float* __restrict__ ctxp, const float* __restrict__ esp,
    float* __restrict__ ctx, float* __restrict__ ksum, int b)
{
    const int idx = blockIdx.x * 256 + threadIdx.x;
    if (idx < 65536) {
        float s = 0.f;
#pragma unroll
        for (int c = 0; c < 16; ++c) s += ctxp[(size_t)c * 65536 + idx];
        ctx[(size_t)b * 65536 + idx] = s * RATIO;
    } else if (idx < 66560) {
        const int j = idx - 65536;
        float s = 0.f;
#pragma unroll
        for (int c = 0; c < 16; ++c) s += esp[(size_t)c * 1024 + j];
        ksum[(size_t)b * 1024 + j] = s * RATIO;
    }
}

// ---- o = d_inv * (qp @ ctx) for batch b; writes split bf16 planes ----
__global__ __launch_bounds__(256) void o_kernel(
    const float* __restrict__ qp, const float* __restrict__ ctx,
    const float* __restrict__ ksum, unsigned short* __restrict__ ohi,
    unsigned short* __restrict__ olo, int b)
{
    __shared__ float As[128][69];
    __shared__ float Cs[64][64];
    __shared__ float Ks[64];
    const int hh = blockIdx.y;
    const int t0 = blockIdx.x * 128;
    const int tid = threadIdx.x;
    const int tr = tid >> 4, tc = tid & 15;
    const int bh = b * 4 + hh;
    float acc[8][4], den[8];
#pragma unroll
    for (int i = 0; i < 8; ++i) {
        den[i] = 0.f;
#pragma unroll
        for (int j = 0; j < 4; ++j) acc[i][j] = 0.f;
    }
    for (int k0 = 0; k0 < 256; k0 += 64) {
        __syncthreads();
        for (int i = tid; i < 2048; i += 256) {
            const int tok = i >> 4, seg = (i & 15) * 4;
            float4 t = *(const float4*)&qp[((size_t)(t0 + tok) * 4 + hh) * 256 + k0 + seg];
            As[tok][seg] = t.x; As[tok][seg + 1] = t.y; As[tok][seg + 2] = t.z; As[tok][seg + 3] = t.w;
        }
        for (int i = tid; i < 1024; i += 256) {
            const int kk = i >> 4, seg = (i & 15) * 4;
            *(float4*)&Cs[kk][seg] = *(const float4*)&ctx[((size_t)bh * 256 + k0 + kk) * 64 + seg];
        }
        if (tid < 64) Ks[tid] = ksum[bh * 256 + k0 + tid];
        __syncthreads();
#pragma unroll 4
        for (int kk = 0; kk < 64; ++kk) {
            float av[8];
#pragma unroll
            for (int i = 0; i < 8; ++i) av[i] = As[tr * 8 + i][kk];
            float bv[4];
            *(float4*)&bv[0] = *(const float4*)&Cs[kk][tc * 4];
            const float kv = Ks[kk];
#pragma unroll
            for (int i = 0; i < 8; ++i) {
                den[i] = fmaf(av[i], kv, den[i]);
#pragma unroll
                for (int j = 0; j < 4; ++j) acc[i][j] = fmaf(av[i], bv[j], acc[i][j]);
            }
        }
    }
#pragma unroll
    for (int i = 0; i < 8; ++i) {
        const float dinv = 1.0f / den[i];
        const int tok = t0 + tr * 8 + i;
        unsigned short h0, l0, h1, l1, h2, l2, h3, l3;
        splitf(acc[i][0] * dinv, h0, l0);
        splitf(acc[i][1] * dinv, h1, l1);
        splitf(acc[i][2] * dinv, h2, l2);
        splitf(acc[i][3] * dinv, h3, l3);
        const size_t base = ((size_t)(b * 4096) + tok) * 256 + hh * 64 + tc * 4;
        uint2 ph, pl;
        ph.x = (unsigned)h0 | ((unsigned)h1 << 16); ph.y = (unsigned)h2 | ((unsigned)h3 << 16);
        pl.x = (unsigned)l0 | ((unsigned)l1 << 16); pl.y = (unsigned)l2 | ((unsigned)l3 << 16);
        *(uint2*)&ohi[base] = ph;
        *(uint2*)&olo[base] = pl;
    }
}

// ---- pooling + classifier ----
__global__ __launch_bounds__(256) void pool1_kernel(const float* __restrict__ h, float* __restrict__ part)
{
    const int b = blockIdx.x >> 4, ch = blockIdx.x & 15;
    const int tid = threadIdx.x;
    float acc = 0.f;
    for (int n = 0; n < 256; ++n)
        acc += h[((size_t)(b * 4096 + ch * 256 + n)) * 256 + tid];
    part[(size_t)blockIdx.x * 256 + tid] = acc;
}

__global__ __launch_bounds__(256) void pool2_kernel(
    const float* __restrict__ part, const float* __restrict__ cw,
    const float* __restrict__ cb, float* __restrict__ out)
{
    const int b = blockIdx.x, tid = threadIdx.x;
    float acc = 0.f;
#pragma unroll
    for (int c = 0; c < 16; ++c) acc += part[(size_t)(b * 16 + c) * 256 + tid];
    float val = acc * (1.0f / 4096.0f) * cw[tid];
#pragma unroll
    for (int s = 1; s < 64; s <<= 1) val += __shfl_xor(val, s);
    __shared__ float red[4];
    if ((tid & 63) == 0) red[tid >> 6] = val;
    __syncthreads();
    if (tid == 0) out[b] = red[0] + red[1] + red[2] + red[3] + cb[0];
}

extern "C" void kernel_launch(void* const* d_in, const int* in_sizes, int n_in,
                              void* d_out, int out_size, void* d_ws, size_t ws_size,
                              hipStream_t stream)
{
    (void)in_sizes; (void)n_in;
    if (ws_size < WS_BYTES) {
        fill_sentinel<<<1, 64, 0, stream>>>((float*)d_out, out_size);
        return;
    }

    const float* x     = (const float*)d_in[0];
    const float* projw = (const float*)d_in[1];
    const float* projb = (const float*)d_in[2];
    const float* ln1g  = (const float*)d_in[3];
    const float* ln1b  = (const float*)d_in[4];
    const float* wq    = (const float*)d_in[5];
    const float* bq    = (const float*)d_in[6];
    const float* wk    = (const float*)d_in[7];
    const float* bk    = (const float*)d_in[8];
    const float* wv    = (const float*)d_in[9];
    const float* bv    = (const float*)d_in[10];
    const float* wo    = (const float*)d_in[11];
    const float* bo    = (const float*)d_in[12];
    const float* ln2g  = (const float*)d_in[13];
    const float* ln2b  = (const float*)d_in[14];
    const float* w1    = (const float*)d_in[15];
    const float* b1    = (const float*)d_in[16];
    const float* w2    = (const float*)d_in[17];
    const float* b2    = (const float*)d_in[18];
    const float* clfw  = (const float*)d_in[19];
    const float* clfb  = (const float*)d_in[20];
    const float* projm = (const float*)d_in[21];

    char* WS = (char*)d_ws;
    float* h            = (float*)(WS + OFF_H);
    unsigned short* ysh = (unsigned short*)(WS + OFF_YSPH);
    unsigned short* ysl = (unsigned short*)(WS + OFF_YSPL);
    unsigned short* qsh = (unsigned short*)(WS + OFF_QSPH);
    unsigned short* qsl = (unsigned short*)(WS + OFF_QSPL);
    unsigned short* ksh = (unsigned short*)(WS + OFF_KSPH);
    unsigned short* ksl = (unsigned short*)(WS + OFF_KSPL);
    float* v            = (float*)(WS + OFF_V);
    float* ddb          = (float*)(WS + OFF_DDB);
    float* ctxF         = (float*)(WS + OFF_CTX);
    float* ksum         = (float*)(WS + OFF_KSUM);
    float* diagq        = (float*)(WS + OFF_DIAGQ);
    float* diagk        = (float*)(WS + OFF_DIAGK);
    float* ctxp         = (float*)(WS + OFF_CTXP);
    float* esp          = (float*)(WS + OFF_ESP);
    float* pool         = (float*)(WS + OFF_POOL);
    unsigned* gmax      = (unsigned*)(WS + OFF_GMAX);
    unsigned short* wqt_h = (unsigned short*)(WS + OFF_WQTH);
    unsigned short* wqt_l = (unsigned short*)(WS + OFF_WQTL);
    unsigned short* wkt_h = (unsigned short*)(WS + OFF_WKTH);
    unsigned short* wkt_l = (unsigned short*)(WS + OFF_WKTL);
    unsigned short* wvt_h = (unsigned short*)(WS + OFF_WVTH);
    unsigned short* wvt_l = (unsigned short*)(WS + OFF_WVTL);
    unsigned short* wot_h = (unsigned short*)(WS + OFF_WOTH);
    unsigned short* wot_l = (unsigned short*)(WS + OFF_WOTL);
    unsigned short* w1t_h = (unsigned short*)(WS + OFF_W1TH);
    unsigned short* w1t_l = (unsigned short*)(WS + OFF_W1TL);
    unsigned short* w2t_h = (unsigned short*)(WS + OFF_W2TH);
    unsigned short* w2t_l = (unsigned short*)(WS + OFF_W2TL);
    unsigned short* pmt_h = (unsigned short*)(WS + OFF_PMTH);
    unsigned short* pmt_l = (unsigned short*)(WS + OFF_PMTL);
    unsigned short* pwt_h = (unsigned short*)(WS + OFF_PWTH);
    unsigned short* pwt_l = (unsigned short*)(WS + OFF_PWTL);
    // aliases
    unsigned short* xsh = qsh;   // [32768,64] input split (pre-layer only)
    unsigned short* xsl = qsl;
    unsigned short* osh = ksh;   // attention-out split (after k dead)
    unsigned short* osl = ksl;
    unsigned short* ffh = (unsigned short*)(WS + OFF_QSPH); // [32768,512] spans qsp planes
    unsigned short* ffl = (unsigned short*)(WS + OFF_KSPH); // spans ksp planes

    // ---- prologue: input proj ----
    split_scale<<<8192, 256, 0, stream>>>(x, xsh, xsl, 2097152, 1.0f);
    splitT<<<64, 256, 0, stream>>>(projw, pwt_h, pwt_l, 6, 256);
    split_scale<<<64, 256, 0, stream>>>(projm, pmt_h, pmt_l, 16384, DN);
    gemm_mf<0><<<dim3(2, 256), 256, 0, stream>>>(xsh, xsl, 64, pwt_h, pwt_l, 64, 64,
        projb, nullptr, h, 256, nullptr, nullptr, nullptr, nullptr);

    for (int l = 0; l < 4; ++l) {
        // weight splits
        splitT<<<256, 256, 0, stream>>>(wq + (size_t)l * 65536, wqt_h, wqt_l, 8, 256);
        splitT<<<256, 256, 0, stream>>>(wk + (size_t)l * 65536, wkt_h, wkt_l, 8, 256);
        splitT<<<256, 256, 0, stream>>>(wv + (size_t)l * 65536, wvt_h, wvt_l, 8, 256);
        splitT<<<256, 256, 0, stream>>>(wo + (size_t)l * 65536, wot_h, wot_l, 8, 256);
        splitT<<<2048, 256, 0, stream>>>(w1 + (size_t)l * 524288, w1t_h, w1t_l, 8, 2048);
        splitT<<<1024, 256, 0, stream>>>(w2 + (size_t)l * 262144, w2t_h, w2t_l, 10, 256);

        // attention
        ln_split<<<8192, 256, 0, stream>>>(h, ln1g + l * 256, ln1b + l * 256, ysh, ysl);
        gemm_mf<2><<<dim3(2, 256), 256, 0, stream>>>(ysh, ysl, 256, wqt_h, wqt_l, 256, 256,
            bq + l * 256, nullptr, nullptr, 256, qsh, qsl, diagq, nullptr);
        gemm_mf<2><<<dim3(2, 256), 256, 0, stream>>>(ysh, ysl, 256, wkt_h, wkt_l, 256, 256,
            bk + l * 256, nullptr, nullptr, 256, ksh, ksl, diagk, nullptr);
        gemm_mf<0><<<dim3(2, 256), 256, 0, stream>>>(ysh, ysl, 256, wvt_h, wvt_l, 256, 256,
            bv + l * 256, nullptr, v, 256, nullptr, nullptr, nullptr, nullptr);
        init_gmax<<<1, 1, 0, stream>>>(gmax);
        gemm_mf<4><<<dim3(2, 1024), 256, 0, stream>>>(ksh, ksl, 64, pmt_h, pmt_l, 64, 64,
            nullptr, nullptr, nullptr, 256, nullptr, nullptr, nullptr, gmax);
        for (int b = 0; b < 8; ++b) {
            gemm_mf<3><<<dim3(2, 128), 256, 0, stream>>>(ksh + (size_t)b * 1048576,
                ksl + (size_t)b * 1048576, 64, pmt_h, pmt_l, 64, 64,
                nullptr, nullptr, ddb, 256, nullptr, nullptr, nullptr, nullptr);
            ctx_kernel<<<dim3(16, 4), 256, 0, stream>>>(ddb, diagk, gmax, v, ctxp, esp, b);
            ctxred_kernel<<<260, 256, 0, stream>>>(ctxp, esp, ctxF, ksum, b);
        }
        for (int b = 0; b < 8; ++b) {
            gemm_mf<3><<<dim3(2, 128), 256, 0, stream>>>(qsh + (size_t)b * 1048576,
                qsl + (size_t)b * 1048576, 64, pmt_h, pmt_l, 64, 64,
                nullptr, nullptr, ddb, 256, nullptr, nullptr, nullptr, nullptr);
            qp_kernel<<<4096, 256, 0, stream>>>(ddb, diagq + (size_t)b * 16384);
            o_kernel<<<dim3(32, 4), 256, 0, stream>>>(ddb, ctxF, ksum, osh, osl, b);
        }
        gemm_mf<1><<<dim3(2, 256), 256, 0, stream>>>(osh, osl, 256, wot_h, wot_l, 256, 256,
            bo + l * 256, h, h, 256, nullptr, nullptr, nullptr, nullptr);

        // feed-forward (two K-halves to fit workspace)
        ln_split<<<8192, 256, 0, stream>>>(h, ln2g + l * 256, ln2b + l * 256, ysh, ysl);
        for (int half = 0; half < 2; ++half) {
            gemm_glu<<<dim3(8, 256), 256, 0, stream>>>(ysh, ysl, w1t_h, w1t_l,
                b1 + (size_t)l * 2048, ffh, ffl, half * 512);
            gemm_mf<1><<<dim3(2, 256), 256, 0, stream>>>(ffh, ffl, 512,
                w2t_h + half * 512, w2t_l + half * 512, 1024, 512,
                half == 0 ? (b2 + l * 256) : nullptr, h, h, 256,
                nullptr, nullptr, nullptr, nullptr);
        }
    }

    pool1_kernel<<<128, 256, 0, stream>>>(h, pool);
    pool2_kernel<<<8, 256, 0, stream>>>(pool, clfw, clfb, (float*)d_out);
}

// Round 4
// 3268.164 us; speedup vs baseline: 3.6718x; 2.7285x over previous
//
#include <hip/hip_runtime.h>
#include <cstdint>
#include <cstddef>

// ---- problem constants ----
constexpr float DN = 0.35355339059327373f;   // 64^-0.25
constexpr float RATIO = 0.0625f;             // 256^-0.5
constexpr float EPSF = 1e-4f;

typedef __attribute__((ext_vector_type(8))) short short8;   // bf16 MFMA fragment
typedef __attribute__((ext_vector_type(4))) float f32x4;    // MFMA accumulator

// ---- workspace layout (byte offsets) ----
constexpr size_t OFF_H     = 0;              // fp32 residual   33,554,432
constexpr size_t OFF_YS    = 33554432;       // ysh+ysl (alias osh/osl) 33,554,432
constexpr size_t OFF_QK    = 67108864;       // ksp then qsp planes     33,554,432
constexpr size_t OFF_PP    = 100663296;      // kp/qp half-batch bf16   33,554,432 (ffh alias)
constexpr size_t OFF_CTXP  = 134217728;      // ctx partials fp32       33,554,432 (ffl alias)
constexpr size_t OFF_VB    = 167772160;      // v bf16                  16,777,216
constexpr size_t OFF_ESP   = 184549376;      // 524,288
constexpr size_t OFF_CTX   = 185073664;      // 2,097,152
constexpr size_t OFF_KSUM  = 187170816;      // 32,768
constexpr size_t OFF_DIAGQ = 187203584;      // 524,288
constexpr size_t OFF_DIAGK = 187727872;      // 524,288
constexpr size_t OFF_RKEY  = 188252160;      // 524,288 (q row-max keys)
constexpr size_t OFF_GMAX  = 188776448;      // 256
constexpr size_t OFF_POOL  = 188776704;      // 131,072
constexpr size_t OFF_WQTH  = 188907776;      // weight split planes
constexpr size_t OFF_WQTL  = 189038848;
constexpr size_t OFF_WKTH  = 189169920;
constexpr size_t OFF_WKTL  = 189300992;
constexpr size_t OFF_WVTH  = 189432064;
constexpr size_t OFF_WVTL  = 189563136;
constexpr size_t OFF_WOTH  = 189694208;
constexpr size_t OFF_WOTL  = 189825280;
constexpr size_t OFF_W1TH  = 189956352;      // 1,048,576
constexpr size_t OFF_W1TL  = 191004928;
constexpr size_t OFF_W2TH  = 192053504;      // 524,288
constexpr size_t OFF_W2TL  = 192577792;
constexpr size_t OFF_PMTH  = 193102080;      // 32,768
constexpr size_t OFF_PMTL  = 193134848;
constexpr size_t OFF_PWTH  = 193167616;
constexpr size_t OFF_PWTL  = 193200384;
constexpr size_t WS_BYTES  = 193233152;

__device__ __forceinline__ unsigned fkey(float f) {
    unsigned u = __float_as_uint(f);
    return (u & 0x80000000u) ? ~u : (u | 0x80000000u);
}
__device__ __forceinline__ float funkey(unsigned k) {
    unsigned u = (k & 0x80000000u) ? (k ^ 0x80000000u) : ~k;
    return __uint_as_float(u);
}
__device__ __forceinline__ float gelu_exact(float x) {
    return 0.5f * x * (1.0f + erff(x * 0.70710678118654752f));
}
__device__ __forceinline__ void splitf(float x, unsigned short& h, unsigned short& l) {
    unsigned u = __float_as_uint(x);
    unsigned hv = (u + 0x7FFFu + ((u >> 16) & 1)) >> 16;
    h = (unsigned short)hv;
    float lo = x - __uint_as_float(hv << 16);
    unsigned u2 = __float_as_uint(lo);
    l = (unsigned short)((u2 + 0x7FFFu + ((u2 >> 16) & 1)) >> 16);
}
__device__ __forceinline__ unsigned short bf16rne(float x) {
    unsigned u = __float_as_uint(x);
    return (unsigned short)((u + 0x7FFFu + ((u >> 16) & 1)) >> 16);
}
__device__ __forceinline__ float blo16(unsigned u) { return __uint_as_float(u << 16); }
__device__ __forceinline__ float bhi16(unsigned u) { return __uint_as_float(u & 0xFFFF0000u); }

__global__ void fill_sentinel(float* out, int n) {
    int i = threadIdx.x;
    if (i < n) out[i] = 12345.0f;
}
__global__ __launch_bounds__(256) void fill_keys(unsigned* __restrict__ rk, unsigned* __restrict__ gm) {
    int i = blockIdx.x * 256 + threadIdx.x;
    if (i < 131072) rk[i] = 0u;
    if (i == 0) gm[0] = 0u;
}

// ---- elementwise split (optional scale) ----
__global__ __launch_bounds__(256) void split_scale(
    const float* __restrict__ src, unsigned short* __restrict__ hi,
    unsigned short* __restrict__ lo, int n, float scale)
{
    int i = blockIdx.x * 256 + threadIdx.x;
    if (i < n) {
        unsigned short h, l;
        splitf(src[i] * scale, h, l);
        hi[i] = h; lo[i] = l;
    }
}

// ---- transpose-split weights: W [K,N] fp32 -> Wt hi/lo [N,K] bf16 ----
__global__ __launch_bounds__(256) void splitT(
    const float* __restrict__ W, unsigned short* __restrict__ hi,
    unsigned short* __restrict__ lo, int kshift, int N)
{
    int i = blockIdx.x * 256 + threadIdx.x;
    int K = 1 << kshift;
    int n = i >> kshift, k = i & (K - 1);
    unsigned short h, l;
    splitf(W[(size_t)k * N + n], h, l);
    hi[i] = h; lo[i] = l;
}

// ---- LayerNorm -> split bf16 planes ----
__global__ __launch_bounds__(256) void ln_split(
    const float* __restrict__ x, const float* __restrict__ g,
    const float* __restrict__ b, unsigned short* __restrict__ yhi,
    unsigned short* __restrict__ ylo)
{
    const int row = blockIdx.x * 4 + (threadIdx.x >> 6);
    const int lane = threadIdx.x & 63;
    float4 t = *(const float4*)&x[(size_t)row * 256 + lane * 4];
    float s = t.x + t.y + t.z + t.w;
#pragma unroll
    for (int sh = 1; sh < 64; sh <<= 1) s += __shfl_xor(s, sh);
    const float mu = s * (1.0f / 256.0f);
    const float dx = t.x - mu, dy = t.y - mu, dz = t.z - mu, dw = t.w - mu;
    float vv = dx * dx + dy * dy + dz * dz + dw * dw;
#pragma unroll
    for (int sh = 1; sh < 64; sh <<= 1) vv += __shfl_xor(vv, sh);
    const float rstd = rsqrtf(vv * (1.0f / 256.0f) + 1e-5f);
    float4 gv = *(const float4*)&g[lane * 4];
    float4 bv = *(const float4*)&b[lane * 4];
    float o0 = dx * rstd * gv.x + bv.x;
    float o1 = dy * rstd * gv.y + bv.y;
    float o2 = dz * rstd * gv.z + bv.z;
    float o3 = dw * rstd * gv.w + bv.w;
    unsigned short h0, l0, h1, l1, h2, l2, h3, l3;
    splitf(o0, h0, l0); splitf(o1, h1, l1); splitf(o2, h2, l2); splitf(o3, h3, l3);
    const size_t base = (size_t)row * 256 + lane * 4;
    uint2 ph, pl;
    ph.x = (unsigned)h0 | ((unsigned)h1 << 16); ph.y = (unsigned)h2 | ((unsigned)h3 << 16);
    pl.x = (unsigned)l0 | ((unsigned)l1 << 16); pl.y = (unsigned)l2 | ((unsigned)l3 << 16);
    *(uint2*)&yhi[base] = ph;
    *(uint2*)&ylo[base] = pl;
}

// ---- split-bf16 MFMA GEMM, tile 128x128, BK=32, 4 waves ----
// EPI: 0 bias->fp32 C | 1 bias(+null)+res->fp32 C | 2 bias->split planes + per-head diag
//      4 global max only (keys[0]) | 5 per-row max (keys[row])
//      6 kp=bf16(RATIO*(exp(acc-diag[row]-funkey(*keys))+EPS))
//      7 qp=bf16(RATIO*(exp(acc-diag[row]-funkey(keys[row]))+EPS))
//      8 bias -> bf16 single plane
template<int EPI>
__global__ __launch_bounds__(256) void gemm_mf(
    const unsigned short* __restrict__ Ahi, const unsigned short* __restrict__ Alo, int lda,
    const unsigned short* __restrict__ Bhi, const unsigned short* __restrict__ Blo, int ldb,
    int K,
    const float* __restrict__ bias, const float* __restrict__ res,
    float* __restrict__ C, int ldc,
    unsigned short* __restrict__ Obf, unsigned short* __restrict__ Olo,
    const float* __restrict__ diag, unsigned* __restrict__ keys)
{
    __shared__ unsigned short lds[4][128][56];
    __shared__ float red[4];
    const int tid = threadIdx.x;
    const int m0 = blockIdx.y * 128, n0 = blockIdx.x * 128;
    const int srow = tid >> 1, sseg = (tid & 1) * 16;
    const unsigned short* ga_h = Ahi + (size_t)(m0 + srow) * lda + sseg;
    const unsigned short* ga_l = Alo + (size_t)(m0 + srow) * lda + sseg;
    const unsigned short* gb_h = Bhi + (size_t)(n0 + srow) * ldb + sseg;
    const unsigned short* gb_l = Blo + (size_t)(n0 + srow) * ldb + sseg;
    const int l = tid & 63, w = tid >> 6;
    const int wr = (w >> 1) * 64, wc = (w & 1) * 64;
    const int fr = l & 15, fq = l >> 4;

    f32x4 acc[4][4];
#pragma unroll
    for (int i = 0; i < 4; ++i)
#pragma unroll
        for (int j = 0; j < 4; ++j) acc[i][j] = (f32x4){0.f, 0.f, 0.f, 0.f};

    for (int k0 = 0; k0 < K; k0 += 32) {
        *(uint4*)&lds[0][srow][sseg]     = *(const uint4*)(ga_h + k0);
        *(uint4*)&lds[0][srow][sseg + 8] = *(const uint4*)(ga_h + k0 + 8);
        *(uint4*)&lds[1][srow][sseg]     = *(const uint4*)(ga_l + k0);
        *(uint4*)&lds[1][srow][sseg + 8] = *(const uint4*)(ga_l + k0 + 8);
        *(uint4*)&lds[2][srow][sseg]     = *(const uint4*)(gb_h + k0);
        *(uint4*)&lds[2][srow][sseg + 8] = *(const uint4*)(gb_h + k0 + 8);
        *(uint4*)&lds[3][srow][sseg]     = *(const uint4*)(gb_l + k0);
        *(uint4*)&lds[3][srow][sseg + 8] = *(const uint4*)(gb_l + k0 + 8);
        __syncthreads();
        short8 ah[4], al[4];
#pragma unroll
        for (int mf = 0; mf < 4; ++mf) {
            ah[mf] = *(const short8*)&lds[0][wr + mf * 16 + fr][fq * 8];
            al[mf] = *(const short8*)&lds[1][wr + mf * 16 + fr][fq * 8];
        }
#pragma unroll
        for (int nf = 0; nf < 4; ++nf) {
            short8 bh = *(const short8*)&lds[2][wc + nf * 16 + fr][fq * 8];
            short8 bl = *(const short8*)&lds[3][wc + nf * 16 + fr][fq * 8];
#pragma unroll
            for (int mf = 0; mf < 4; ++mf) {
                acc[mf][nf] = __builtin_amdgcn_mfma_f32_16x16x32_bf16(ah[mf], bh, acc[mf][nf], 0, 0, 0);
                acc[mf][nf] = __builtin_amdgcn_mfma_f32_16x16x32_bf16(al[mf], bh, acc[mf][nf], 0, 0, 0);
                acc[mf][nf] = __builtin_amdgcn_mfma_f32_16x16x32_bf16(ah[mf], bl, acc[mf][nf], 0, 0, 0);
            }
        }
        __syncthreads();
    }

    if constexpr (EPI == 4) {
        float m = -3.4e38f;
#pragma unroll
        for (int mf = 0; mf < 4; ++mf)
#pragma unroll
            for (int nf = 0; nf < 4; ++nf)
#pragma unroll
                for (int v = 0; v < 4; ++v) m = fmaxf(m, acc[mf][nf][v]);
#pragma unroll
        for (int s = 1; s < 64; s <<= 1) m = fmaxf(m, __shfl_xor(m, s));
        if (l == 0) red[w] = m;
        __syncthreads();
        if (tid == 0)
            atomicMax(keys, fkey(fmaxf(fmaxf(red[0], red[1]), fmaxf(red[2], red[3]))));
    } else if constexpr (EPI == 5) {
#pragma unroll
        for (int mf = 0; mf < 4; ++mf)
#pragma unroll
            for (int v = 0; v < 4; ++v) {
                float rm = fmaxf(fmaxf(acc[mf][0][v], acc[mf][1][v]),
                                 fmaxf(acc[mf][2][v], acc[mf][3][v]));
                rm = fmaxf(rm, __shfl_xor(rm, 1));
                rm = fmaxf(rm, __shfl_xor(rm, 2));
                rm = fmaxf(rm, __shfl_xor(rm, 4));
                rm = fmaxf(rm, __shfl_xor(rm, 8));
                if (fr == 0) atomicMax(&keys[m0 + wr + mf * 16 + fq * 4 + v], fkey(rm));
            }
    } else if constexpr (EPI == 6 || EPI == 7) {
        const float Mg = (EPI == 6) ? funkey(*keys) : 0.f;
#pragma unroll
        for (int mf = 0; mf < 4; ++mf) {
#pragma unroll
            for (int v = 0; v < 4; ++v) {
                const int row = m0 + wr + mf * 16 + fq * 4 + v;
                const float dg = diag[row] + ((EPI == 6) ? Mg : funkey(keys[row]));
#pragma unroll
                for (int nf = 0; nf < 4; ++nf) {
                    const int col = n0 + wc + nf * 16 + fr;
                    float kpv = RATIO * (expf(acc[mf][nf][v] - dg) + EPSF);
                    Obf[(size_t)row * 256 + col] = bf16rne(kpv);
                }
            }
        }
    } else if constexpr (EPI == 2) {
        const int head = (n0 + wc) >> 6;
#pragma unroll
        for (int mf = 0; mf < 4; ++mf) {
            float sq[4] = {0.f, 0.f, 0.f, 0.f};
#pragma unroll
            for (int nf = 0; nf < 4; ++nf) {
                const int col = n0 + wc + nf * 16 + fr;
                const float bb = bias[col];
#pragma unroll
                for (int v = 0; v < 4; ++v) {
                    const int row = m0 + wr + mf * 16 + fq * 4 + v;
                    float val = acc[mf][nf][v] + bb;
                    unsigned short hh_, ll_;
                    splitf(val, hh_, ll_);
                    Obf[(size_t)row * 256 + col] = hh_;
                    Olo[(size_t)row * 256 + col] = ll_;
                    sq[v] += val * val;
                }
            }
#pragma unroll
            for (int v = 0; v < 4; ++v) {
                float s = sq[v];
                s += __shfl_xor(s, 1); s += __shfl_xor(s, 2);
                s += __shfl_xor(s, 4); s += __shfl_xor(s, 8);
                if (fr == 0)
                    ((float*)diag)[(size_t)(m0 + wr + mf * 16 + fq * 4 + v) * 4 + head] = s * 0.0625f;
            }
        }
    } else if constexpr (EPI == 8) {
#pragma unroll
        for (int nf = 0; nf < 4; ++nf) {
            const int col = n0 + wc + nf * 16 + fr;
            const float bb = bias[col];
#pragma unroll
            for (int mf = 0; mf < 4; ++mf)
#pragma unroll
                for (int v = 0; v < 4; ++v) {
                    const int row = m0 + wr + mf * 16 + fq * 4 + v;
                    Obf[(size_t)row * 256 + col] = bf16rne(acc[mf][nf][v] + bb);
                }
        }
    } else {
#pragma unroll
        for (int nf = 0; nf < 4; ++nf) {
            const int col = n0 + wc + nf * 16 + fr;
            float bb = 0.f;
            if (bias != nullptr) bb = bias[col];
#pragma unroll
            for (int mf = 0; mf < 4; ++mf) {
#pragma unroll
                for (int v = 0; v < 4; ++v) {
                    const int row = m0 + wr + mf * 16 + fq * 4 + v;
                    const size_t off = (size_t)row * ldc + col;
                    float val = acc[mf][nf][v] + bb;
                    if (EPI == 1) val += res[off];
                    C[off] = val;
                }
            }
        }
    }
}

// ---- fused GLU GEMM (split-bf16 MFMA), half selected by nbase ----
__global__ __launch_bounds__(256) void gemm_glu(
    const unsigned short* __restrict__ Ahi, const unsigned short* __restrict__ Alo,
    const unsigned short* __restrict__ Whi, const unsigned short* __restrict__ Wlo,
    const float* __restrict__ b1,
    unsigned short* __restrict__ Ohi, unsigned short* __restrict__ Olo, int nbase)
{
    __shared__ unsigned short ldsA[2][128][56];
    __shared__ unsigned short ldsB[4][64][56];
    const int tid = threadIdx.x;
    const int m0 = blockIdx.y * 128, p0 = blockIdx.x * 64;
    const int srow = tid >> 1, sseg = (tid & 1) * 16;
    const unsigned short* ga_h = Ahi + (size_t)(m0 + srow) * 256 + sseg;
    const unsigned short* ga_l = Alo + (size_t)(m0 + srow) * 256 + sseg;
    const int brow = tid & 63, pp = tid >> 6;
    const int grow = (pp < 2 ? (nbase + p0 + brow) : (1024 + nbase + p0 + brow));
    const unsigned short* gw = ((pp & 1) ? Wlo : Whi) + (size_t)grow * 256;
    const int l = tid & 63, w = tid >> 6;
    const int wr = (w >> 1) * 64, wc = (w & 1) * 32;
    const int fr = l & 15, fq = l >> 4;

    f32x4 aa[4][2], ag[4][2];
#pragma unroll
    for (int i = 0; i < 4; ++i)
#pragma unroll
        for (int j = 0; j < 2; ++j) {
            aa[i][j] = (f32x4){0.f, 0.f, 0.f, 0.f};
            ag[i][j] = (f32x4){0.f, 0.f, 0.f, 0.f};
        }

    for (int k0 = 0; k0 < 256; k0 += 32) {
        *(uint4*)&ldsA[0][srow][sseg]     = *(const uint4*)(ga_h + k0);
        *(uint4*)&ldsA[0][srow][sseg + 8] = *(const uint4*)(ga_h + k0 + 8);
        *(uint4*)&ldsA[1][srow][sseg]     = *(const uint4*)(ga_l + k0);
        *(uint4*)&ldsA[1][srow][sseg + 8] = *(const uint4*)(ga_l + k0 + 8);
        *(uint4*)&ldsB[pp][brow][0]       = *(const uint4*)(gw + k0);
        *(uint4*)&ldsB[pp][brow][8]       = *(const uint4*)(gw + k0 + 8);
        *(uint4*)&ldsB[pp][brow][16]      = *(const uint4*)(gw + k0 + 16);
        *(uint4*)&ldsB[pp][brow][24]      = *(const uint4*)(gw + k0 + 24);
        __syncthreads();
        short8 ah[4], al[4];
#pragma unroll
        for (int mf = 0; mf < 4; ++mf) {
            ah[mf] = *(const short8*)&ldsA[0][wr + mf * 16 + fr][fq * 8];
            al[mf] = *(const short8*)&ldsA[1][wr + mf * 16 + fr][fq * 8];
        }
#pragma unroll
        for (int nf = 0; nf < 2; ++nf) {
            const int br_ = wc + nf * 16 + fr;
            short8 bah = *(const short8*)&ldsB[0][br_][fq * 8];
            short8 bal = *(const short8*)&ldsB[1][br_][fq * 8];
            short8 bgh = *(const short8*)&ldsB[2][br_][fq * 8];
            short8 bgl = *(const short8*)&ldsB[3][br_][fq * 8];
#pragma unroll
            for (int mf = 0; mf < 4; ++mf) {
                aa[mf][nf] = __builtin_amdgcn_mfma_f32_16x16x32_bf16(ah[mf], bah, aa[mf][nf], 0, 0, 0);
                aa[mf][nf] = __builtin_amdgcn_mfma_f32_16x16x32_bf16(al[mf], bah, aa[mf][nf], 0, 0, 0);
                aa[mf][nf] = __builtin_amdgcn_mfma_f32_16x16x32_bf16(ah[mf], bal, aa[mf][nf], 0, 0, 0);
                ag[mf][nf] = __builtin_amdgcn_mfma_f32_16x16x32_bf16(ah[mf], bgh, ag[mf][nf], 0, 0, 0);
                ag[mf][nf] = __builtin_amdgcn_mfma_f32_16x16x32_bf16(al[mf], bgh, ag[mf][nf], 0, 0, 0);
                ag[mf][nf] = __builtin_amdgcn_mfma_f32_16x16x32_bf16(ah[mf], bgl, ag[mf][nf], 0, 0, 0);
            }
        }
        __syncthreads();
    }
#pragma unroll
    for (int nf = 0; nf < 2; ++nf) {
        const int ch = p0 + wc + nf * 16 + fr;
        const float ba = b1[nbase + ch], bg = b1[1024 + nbase + ch];
#pragma unroll
        for (int mf = 0; mf < 4; ++mf) {
#pragma unroll
            for (int v = 0; v < 4; ++v) {
                const int row = m0 + wr + mf * 16 + fq * 4 + v;
                float u = aa[mf][nf][v] + ba, g = ag[mf][nf][v] + bg;
                float r = gelu_exact(u) * g;
                unsigned short hh_, ll_;
                splitf(r, hh_, ll_);
                Ohi[(size_t)row * 512 + ch] = hh_;
                Olo[(size_t)row * 512 + ch] = ll_;
            }
        }
    }
}

// ---- ctx partials: per (chunk, bh_local) for half-batch hb ----
__global__ __launch_bounds__(256) void ctx_kernel(
    const unsigned short* __restrict__ kp, const unsigned short* __restrict__ vb,
    float* __restrict__ ctxp, float* __restrict__ esp, int hb)
{
    __shared__ unsigned short vlds[256][72];
    const int chunk = blockIdx.x, bhl = blockIdx.y;
    const int bl = bhl >> 2, hh = bhl & 3;
    const int b = hb * 4 + bl;
    const int nb = chunk * 256;
    const int tid = threadIdx.x;
    for (int i = tid; i < 2048; i += 256) {
        const int n = i >> 3, g = (i & 7) * 8;
        *(uint4*)&vlds[n][g] = *(const uint4*)&vb[((size_t)(b * 4096 + nb + n)) * 256 + hh * 64 + g];
    }
    __syncthreads();
    const int m0 = (tid & 31) * 8, d0 = (tid >> 5) * 8;
    float acc[8][8], es[8];
#pragma unroll
    for (int i = 0; i < 8; ++i) {
        es[i] = 0.f;
#pragma unroll
        for (int j = 0; j < 8; ++j) acc[i][j] = 0.f;
    }
    for (int n = 0; n < 256; ++n) {
        const uint4 ku = *(const uint4*)&kp[((size_t)((bl * 4096 + nb + n) * 4 + hh)) * 256 + m0];
        float e[8];
        e[0] = blo16(ku.x); e[1] = bhi16(ku.x);
        e[2] = blo16(ku.y); e[3] = bhi16(ku.y);
        e[4] = blo16(ku.z); e[5] = bhi16(ku.z);
        e[6] = blo16(ku.w); e[7] = bhi16(ku.w);
        const uint4 vu = *(const uint4*)&vlds[n][d0];
        float vv[8];
        vv[0] = blo16(vu.x); vv[1] = bhi16(vu.x);
        vv[2] = blo16(vu.y); vv[3] = bhi16(vu.y);
        vv[4] = blo16(vu.z); vv[5] = bhi16(vu.z);
        vv[6] = blo16(vu.w); vv[7] = bhi16(vu.w);
#pragma unroll
        for (int i = 0; i < 8; ++i) {
            es[i] += e[i];
#pragma unroll
            for (int j = 0; j < 8; ++j) acc[i][j] = fmaf(e[i], vv[j], acc[i][j]);
        }
    }
    const int bh = hb * 16 + bhl;
    const size_t base = ((size_t)(chunk * 32 + bh) * 256 + m0) * 64 + d0;
#pragma unroll
    for (int i = 0; i < 8; ++i) {
        float4 o1, o2;
        o1.x = acc[i][0]; o1.y = acc[i][1]; o1.z = acc[i][2]; o1.w = acc[i][3];
        o2.x = acc[i][4]; o2.y = acc[i][5]; o2.z = acc[i][6]; o2.w = acc[i][7];
        *(float4*)&ctxp[base + (size_t)i * 64] = o1;
        *(float4*)&ctxp[base + (size_t)i * 64 + 4] = o2;
    }
    if (d0 == 0) {
#pragma unroll
        for (int i = 0; i < 8; ++i)
            esp[(size_t)(chunk * 32 + bh) * 256 + m0 + i] = es[i];
    }
}

// ---- reduce ctx/es partials over 16 chunks (all bh at once) ----
__global__ __launch_bounds__(256) void ctxred_kernel(
    const float* __restrict__ ctxp, const float* __restrict__ esp,
    float* __restrict__ ctx, float* __restrict__ ksum)
{
    const int idx = blockIdx.x * 256 + threadIdx.x;   // 2080*256 = 532,480
    if (idx < 524288) {
        float s = 0.f;
#pragma unroll
        for (int c = 0; c < 16; ++c) s += ctxp[(size_t)c * 524288 + idx];
        ctx[idx] = s;
    } else if (idx < 532480) {
        const int j = idx - 524288;
        float s = 0.f;
#pragma unroll
        for (int c = 0; c < 16; ++c) s += esp[(size_t)c * 8192 + j];
        ksum[j] = s;
    }
}

// ---- o = d_inv * (qp @ ctx) for half-batch hb; writes split bf16 planes ----
__global__ __launch_bounds__(256) void o_kernel(
    const unsigned short* __restrict__ qp, const float* __restrict__ ctx,
    const float* __restrict__ ksum, unsigned short* __restrict__ ohi,
    unsigned short* __restrict__ olo, int hb)
{
    __shared__ float As[128][69];
    __shared__ float Cs[64][64];
    __shared__ float Ks[64];
    const int hh = blockIdx.y, bl = blockIdx.z;
    const int b = hb * 4 + bl;
    const int t0 = blockIdx.x * 128;
    const int tid = threadIdx.x;
    const int tr = tid >> 4, tc = tid & 15;
    const int bh = b * 4 + hh;
    float acc[8][4], den[8];
#pragma unroll
    for (int i = 0; i < 8; ++i) {
        den[i] = 0.f;
#pragma unroll
        for (int j = 0; j < 4; ++j) acc[i][j] = 0.f;
    }
    for (int k0 = 0; k0 < 256; k0 += 64) {
        __syncthreads();
        for (int i = tid; i < 1024; i += 256) {
            const int tok = i >> 3, g = (i & 7) * 8;
            const uint4 qu = *(const uint4*)&qp[((size_t)((bl * 4096 + t0 + tok) * 4 + hh)) * 256 + k0 + g];
            As[tok][g + 0] = blo16(qu.x); As[tok][g + 1] = bhi16(qu.x);
            As[tok][g + 2] = blo16(qu.y); As[tok][g + 3] = bhi16(qu.y);
            As[tok][g + 4] = blo16(qu.z); As[tok][g + 5] = bhi16(qu.z);
            As[tok][g + 6] = blo16(qu.w); As[tok][g + 7] = bhi16(qu.w);
        }
        for (int i = tid; i < 1024; i += 256) {
            const int kk = i >> 4, seg = (i & 15) * 4;
            *(float4*)&Cs[kk][seg] = *(const float4*)&ctx[((size_t)bh * 256 + k0 + kk) * 64 + seg];
        }
        if (tid < 64) Ks[tid] = ksum[bh * 256 + k0 + tid];
        __syncthreads();
#pragma unroll 4
        for (int kk = 0; kk < 64; ++kk) {
            float av[8];
#pragma unroll
            for (int i = 0; i < 8; ++i) av[i] = As[tr * 8 + i][kk];
            float bv[4];
            *(float4*)&bv[0] = *(const float4*)&Cs[kk][tc * 4];
            const float kv = Ks[kk];
#pragma unroll
            for (int i = 0; i < 8; ++i) {
                den[i] = fmaf(av[i], kv, den[i]);
#pragma unroll
                for (int j = 0; j < 4; ++j) acc[i][j] = fmaf(av[i], bv[j], acc[i][j]);
            }
        }
    }
#pragma unroll
    for (int i = 0; i < 8; ++i) {
        const float dinv = 1.0f / den[i];
        const int tok = t0 + tr * 8 + i;
        unsigned short h0, l0, h1, l1, h2, l2, h3, l3;
        splitf(acc[i][0] * dinv, h0, l0);
        splitf(acc[i][1] * dinv, h1, l1);
        splitf(acc[i][2] * dinv, h2, l2);
        splitf(acc[i][3] * dinv, h3, l3);
        const size_t base = ((size_t)(b * 4096) + tok) * 256 + hh * 64 + tc * 4;
        uint2 ph, pl;
        ph.x = (unsigned)h0 | ((unsigned)h1 << 16); ph.y = (unsigned)h2 | ((unsigned)h3 << 16);
        pl.x = (unsigned)l0 | ((unsigned)l1 << 16); pl.y = (unsigned)l2 | ((unsigned)l3 << 16);
        *(uint2*)&ohi[base] = ph;
        *(uint2*)&olo[base] = pl;
    }
}

// ---- pooling + classifier ----
__global__ __launch_bounds__(256) void pool1_kernel(const float* __restrict__ h, float* __restrict__ part)
{
    const int b = blockIdx.x >> 4, ch = blockIdx.x & 15;
    const int tid = threadIdx.x;
    float acc = 0.f;
    for (int n = 0; n < 256; ++n)
        acc += h[((size_t)(b * 4096 + ch * 256 + n)) * 256 + tid];
    part[(size_t)blockIdx.x * 256 + tid] = acc;
}

__global__ __launch_bounds__(256) void pool2_kernel(
    const float* __restrict__ part, const float* __restrict__ cw,
    const float* __restrict__ cb, float* __restrict__ out)
{
    const int b = blockIdx.x, tid = threadIdx.x;
    float acc = 0.f;
#pragma unroll
    for (int c = 0; c < 16; ++c) acc += part[(size_t)(b * 16 + c) * 256 + tid];
    float val = acc * (1.0f / 4096.0f) * cw[tid];
#pragma unroll
    for (int s = 1; s < 64; s <<= 1) val += __shfl_xor(val, s);
    __shared__ float red[4];
    if ((tid & 63) == 0) red[tid >> 6] = val;
    __syncthreads();
    if (tid == 0) out[b] = red[0] + red[1] + red[2] + red[3] + cb[0];
}

extern "C" void kernel_launch(void* const* d_in, const int* in_sizes, int n_in,
                              void* d_out, int out_size, void* d_ws, size_t ws_size,
                              hipStream_t stream)
{
    (void)in_sizes; (void)n_in;
    if (ws_size < WS_BYTES) {
        fill_sentinel<<<1, 64, 0, stream>>>((float*)d_out, out_size);
        return;
    }

    const float* x     = (const float*)d_in[0];
    const float* projw = (const float*)d_in[1];
    const float* projb = (const float*)d_in[2];
    const float* ln1g  = (const float*)d_in[3];
    const float* ln1b  = (const float*)d_in[4];
    const float* wq    = (const float*)d_in[5];
    const float* bq    = (const float*)d_in[6];
    const float* wk    = (const float*)d_in[7];
    const float* bk    = (const float*)d_in[8];
    const float* wv    = (const float*)d_in[9];
    const float* bv    = (const float*)d_in[10];
    const float* wo    = (const float*)d_in[11];
    const float* bo    = (const float*)d_in[12];
    const float* ln2g  = (const float*)d_in[13];
    const float* ln2b  = (const float*)d_in[14];
    const float* w1    = (const float*)d_in[15];
    const float* b1    = (const float*)d_in[16];
    const float* w2    = (const float*)d_in[17];
    const float* b2    = (const float*)d_in[18];
    const float* clfw  = (const float*)d_in[19];
    const float* clfb  = (const float*)d_in[20];
    const float* projm = (const float*)d_in[21];

    char* WS = (char*)d_ws;
    float* h            = (float*)(WS + OFF_H);
    unsigned short* ysh = (unsigned short*)(WS + OFF_YS);
    unsigned short* ysl = ysh + 8388608;
    unsigned short* qkh = (unsigned short*)(WS + OFF_QK);   // k-splits then q-splits
    unsigned short* qkl = qkh + 8388608;
    unsigned short* pp  = (unsigned short*)(WS + OFF_PP);   // kp/qp half-batch bf16
    float* ctxp         = (float*)(WS + OFF_CTXP);
    unsigned short* vb  = (unsigned short*)(WS + OFF_VB);
    float* esp          = (float*)(WS + OFF_ESP);
    float* ctxF         = (float*)(WS + OFF_CTX);
    float* ksum         = (float*)(WS + OFF_KSUM);
    float* diagq        = (float*)(WS + OFF_DIAGQ);
    float* diagk        = (float*)(WS + OFF_DIAGK);
    unsigned* rkeys     = (unsigned*)(WS + OFF_RKEY);
    unsigned* gmax      = (unsigned*)(WS + OFF_GMAX);
    float* pool         = (float*)(WS + OFF_POOL);
    unsigned short* wqt_h = (unsigned short*)(WS + OFF_WQTH);
    unsigned short* wqt_l = (unsigned short*)(WS + OFF_WQTL);
    unsigned short* wkt_h = (unsigned short*)(WS + OFF_WKTH);
    unsigned short* wkt_l = (unsigned short*)(WS + OFF_WKTL);
    unsigned short* wvt_h = (unsigned short*)(WS + OFF_WVTH);
    unsigned short* wvt_l = (unsigned short*)(WS + OFF_WVTL);
    unsigned short* wot_h = (unsigned short*)(WS + OFF_WOTH);
    unsigned short* wot_l = (unsigned short*)(WS + OFF_WOTL);
    unsigned short* w1t_h = (unsigned short*)(WS + OFF_W1TH);
    unsigned short* w1t_l = (unsigned short*)(WS + OFF_W1TL);
    unsigned short* w2t_h = (unsigned short*)(WS + OFF_W2TH);
    unsigned short* w2t_l = (unsigned short*)(WS + OFF_W2TL);
    unsigned short* pmt_h = (unsigned short*)(WS + OFF_PMTH);
    unsigned short* pmt_l = (unsigned short*)(WS + OFF_PMTL);
    unsigned short* pwt_h = (unsigned short*)(WS + OFF_PWTH);
    unsigned short* pwt_l = (unsigned short*)(WS + OFF_PWTL);
    // aliases
    unsigned short* xsh = pp;               // [32768][64] input split (prologue only)
    unsigned short* xsl = pp + 2097152;
    unsigned short* osh = ysh;              // attention-out split (ys dead)
    unsigned short* osl = ysl;
    unsigned short* ffh = (unsigned short*)(WS + OFF_PP);    // [32768][512]
    unsigned short* ffl = (unsigned short*)(WS + OFF_CTXP);

    // ---- prologue ----
    split_scale<<<8192, 256, 0, stream>>>(x, xsh, xsl, 2097152, 1.0f);
    splitT<<<64, 256, 0, stream>>>(projw, pwt_h, pwt_l, 6, 256);
    split_scale<<<64, 256, 0, stream>>>(projm, pmt_h, pmt_l, 16384, DN);
    gemm_mf<0><<<dim3(2, 256), 256, 0, stream>>>(xsh, xsl, 64, pwt_h, pwt_l, 64, 64,
        projb, nullptr, h, 256, nullptr, nullptr, nullptr, nullptr);

    for (int l = 0; l < 4; ++l) {
        splitT<<<256, 256, 0, stream>>>(wq + (size_t)l * 65536, wqt_h, wqt_l, 8, 256);
        splitT<<<256, 256, 0, stream>>>(wk + (size_t)l * 65536, wkt_h, wkt_l, 8, 256);
        splitT<<<256, 256, 0, stream>>>(wv + (size_t)l * 65536, wvt_h, wvt_l, 8, 256);
        splitT<<<256, 256, 0, stream>>>(wo + (size_t)l * 65536, wot_h, wot_l, 8, 256);
        splitT<<<2048, 256, 0, stream>>>(w1 + (size_t)l * 524288, w1t_h, w1t_l, 8, 2048);
        splitT<<<1024, 256, 0, stream>>>(w2 + (size_t)l * 262144, w2t_h, w2t_l, 10, 256);

        // ---- attention ----
        ln_split<<<8192, 256, 0, stream>>>(h, ln1g + l * 256, ln1b + l * 256, ysh, ysl);
        gemm_mf<8><<<dim3(2, 256), 256, 0, stream>>>(ysh, ysl, 256, wvt_h, wvt_l, 256, 256,
            bv + l * 256, nullptr, nullptr, 256, vb, nullptr, nullptr, nullptr);
        gemm_mf<2><<<dim3(2, 256), 256, 0, stream>>>(ysh, ysl, 256, wkt_h, wkt_l, 256, 256,
            bk + l * 256, nullptr, nullptr, 256, qkh, qkl, diagk, nullptr);
        fill_keys<<<512, 256, 0, stream>>>(rkeys, gmax);
        gemm_mf<4><<<dim3(2, 1024), 256, 0, stream>>>(qkh, qkl, 64, pmt_h, pmt_l, 64, 64,
            nullptr, nullptr, nullptr, 256, nullptr, nullptr, nullptr, gmax);
        for (int hb = 0; hb < 2; ++hb) {
            gemm_mf<6><<<dim3(2, 512), 256, 0, stream>>>(
                qkh + (size_t)hb * 4194304, qkl + (size_t)hb * 4194304, 64,
                pmt_h, pmt_l, 64, 64, nullptr, nullptr, nullptr, 256,
                pp, nullptr, diagk + (size_t)hb * 65536, gmax);
            ctx_kernel<<<dim3(16, 16), 256, 0, stream>>>(pp, vb, ctxp, esp, hb);
        }
        ctxred_kernel<<<2080, 256, 0, stream>>>(ctxp, esp, ctxF, ksum);
        gemm_mf<2><<<dim3(2, 256), 256, 0, stream>>>(ysh, ysl, 256, wqt_h, wqt_l, 256, 256,
            bq + l * 256, nullptr, nullptr, 256, qkh, qkl, diagq, nullptr);
        gemm_mf<5><<<dim3(2, 1024), 256, 0, stream>>>(qkh, qkl, 64, pmt_h, pmt_l, 64, 64,
            nullptr, nullptr, nullptr, 256, nullptr, nullptr, nullptr, rkeys);
        for (int hb = 0; hb < 2; ++hb) {
            gemm_mf<7><<<dim3(2, 512), 256, 0, stream>>>(
                qkh + (size_t)hb * 4194304, qkl + (size_t)hb * 4194304, 64,
                pmt_h, pmt_l, 64, 64, nullptr, nullptr, nullptr, 256,
                pp, nullptr, diagq + (size_t)hb * 65536, rkeys + (size_t)hb * 65536);
            o_kernel<<<dim3(32, 4, 4), 256, 0, stream>>>(pp, ctxF, ksum, osh, osl, hb);
        }
        gemm_mf<1><<<dim3(2, 256), 256, 0, stream>>>(osh, osl, 256, wot_h, wot_l, 256, 256,
            bo + l * 256, h, h, 256, nullptr, nullptr, nullptr, nullptr);

        // ---- feed-forward (two K-halves) ----
        ln_split<<<8192, 256, 0, stream>>>(h, ln2g + l * 256, ln2b + l * 256, ysh, ysl);
        for (int half = 0; half < 2; ++half) {
            gemm_glu<<<dim3(8, 256), 256, 0, stream>>>(ysh, ysl, w1t_h, w1t_l,
                b1 + (size_t)l * 2048, ffh, ffl, half * 512);
            gemm_mf<1><<<dim3(2, 256), 256, 0, stream>>>(ffh, ffl, 512,
                w2t_h + half * 512, w2t_l + half * 512, 1024, 512,
                half == 0 ? (b2 + l * 256) : nullptr, h, h, 256,
                nullptr, nullptr, nullptr, nullptr);
        }
    }

    pool1_kernel<<<128, 256, 0, stream>>>(h, pool);
    pool2_kernel<<<8, 256, 0, stream>>>(pool, clfw, clfb, (float*)d_out);
}

// Round 5
// 2167.999 us; speedup vs baseline: 5.5351x; 1.5075x over previous
//
#include <hip/hip_runtime.h>
#include <cstdint>
#include <cstddef>

// ---- problem constants ----
constexpr float DN = 0.35355339059327373f;   // 64^-0.25
constexpr float RATIO = 0.0625f;             // 256^-0.5
constexpr float EPSF = 1e-4f;

typedef __attribute__((ext_vector_type(8))) short short8;   // bf16 MFMA fragment
typedef __attribute__((ext_vector_type(4))) float f32x4;    // MFMA accumulator

// ---- workspace layout (byte offsets); proven budget >= 209,715,200 B ----
constexpr size_t OFF_H     = 0;              // fp32 residual 33,554,432
constexpr size_t OFF_YS    = 33554432;       // ysh+ysl (osh/osl alias) 33,554,432
constexpr size_t OFF_QK    = 67108864;       // k then q split planes 33,554,432
constexpr size_t OFF_BIG   = 100663296;      // kpT / qp / ffb / x-split 67,108,864
constexpr size_t OFF_VT    = 167772160;      // vT [32][80][4096] bf16 20,971,520
constexpr size_t OFF_CTXP  = 188743680;      // ctx partials [4][32][256][80] f32 10,485,760
constexpr size_t OFF_CTXTH = 199229440;      // ctxT hi [32][80][256] 1,310,720
constexpr size_t OFF_CTXTL = 200540160;      // ctxT lo 1,310,720
constexpr size_t OFF_DIAGQ = 201850880;      // 524,288
constexpr size_t OFF_DIAGK = 202375168;      // 524,288
constexpr size_t OFF_RKEY  = 202899456;      // 524,288
constexpr size_t OFF_GMAX  = 203423744;      // 256
constexpr size_t OFF_POOL  = 203424000;      // 131,072
constexpr size_t OFF_WQTH  = 203555072;
constexpr size_t OFF_WQTL  = 203686144;
constexpr size_t OFF_WKTH  = 203817216;
constexpr size_t OFF_WKTL  = 203948288;
constexpr size_t OFF_WVTH  = 204079360;
constexpr size_t OFF_WVTL  = 204210432;
constexpr size_t OFF_WOTH  = 204341504;
constexpr size_t OFF_WOTL  = 204472576;
constexpr size_t OFF_W1TH  = 204603648;      // 1,048,576
constexpr size_t OFF_W1TL  = 205652224;
constexpr size_t OFF_W2TH  = 206700800;      // 524,288
constexpr size_t OFF_W2TL  = 207225088;
constexpr size_t OFF_PMTH  = 207749376;
constexpr size_t OFF_PMTL  = 207782144;
constexpr size_t OFF_PWTH  = 207814912;
constexpr size_t OFF_PWTL  = 207847680;
constexpr size_t WS_BYTES  = 207880448;

__device__ __forceinline__ unsigned fkey(float f) {
    unsigned u = __float_as_uint(f);
    return (u & 0x80000000u) ? ~u : (u | 0x80000000u);
}
__device__ __forceinline__ float funkey(unsigned k) {
    unsigned u = (k & 0x80000000u) ? (k ^ 0x80000000u) : ~k;
    return __uint_as_float(u);
}
__device__ __forceinline__ float gelu_exact(float x) {
    return 0.5f * x * (1.0f + erff(x * 0.70710678118654752f));
}
__device__ __forceinline__ void splitf(float x, unsigned short& h, unsigned short& l) {
    unsigned u = __float_as_uint(x);
    unsigned hv = (u + 0x7FFFu + ((u >> 16) & 1)) >> 16;
    h = (unsigned short)hv;
    float lo = x - __uint_as_float(hv << 16);
    unsigned u2 = __float_as_uint(lo);
    l = (unsigned short)((u2 + 0x7FFFu + ((u2 >> 16) & 1)) >> 16);
}
__device__ __forceinline__ unsigned short bf16rne(float x) {
    unsigned u = __float_as_uint(x);
    return (unsigned short)((u + 0x7FFFu + ((u >> 16) & 1)) >> 16);
}
// XCD-aware block swizzle (requires total blocks % 8 == 0)
__device__ __forceinline__ void xcd_swz(int& bx, int& by) {
    const int gx = gridDim.x;
    const int total = gx * gridDim.y;
    int flat = blockIdx.y * gx + blockIdx.x;
    flat = (flat & 7) * (total >> 3) + (flat >> 3);
    bx = flat % gx; by = flat / gx;
}

__global__ void fill_sentinel(float* out, int n) {
    int i = threadIdx.x;
    if (i < n) out[i] = 12345.0f;
}
__global__ __launch_bounds__(256) void fill_keys(unsigned* __restrict__ rk, unsigned* __restrict__ gm) {
    int i = blockIdx.x * 256 + threadIdx.x;
    if (i < 131072) rk[i] = 0u;
    if (i == 0) gm[0] = 0u;
}
// fill vT rows 64..79: row 64 = 1.0 (ksum fold), rows 65..79 = 0
__global__ __launch_bounds__(256) void vt_init(unsigned short* __restrict__ vT) {
    int i = blockIdx.x * 256 + threadIdx.x;        // 262,144 uint4
    const int bh = i >> 13;
    const int r = (i >> 9) & 15;
    const unsigned val = (r == 0) ? 0x3F803F80u : 0u;
    uint4 q; q.x = val; q.y = val; q.z = val; q.w = val;
    *(uint4*)(vT + ((size_t)bh * 80 + 64 + r) * 4096 + ((size_t)(i & 511) << 3)) = q;
}

// ---- elementwise split (optional scale) ----
__global__ __launch_bounds__(256) void split_scale(
    const float* __restrict__ src, unsigned short* __restrict__ hi,
    unsigned short* __restrict__ lo, int n, float scale)
{
    int i = blockIdx.x * 256 + threadIdx.x;
    if (i < n) {
        unsigned short h, l;
        splitf(src[i] * scale, h, l);
        hi[i] = h; lo[i] = l;
    }
}

// ---- transpose-split weights: W [K,N] fp32 -> Wt hi/lo [N,K] bf16 ----
__global__ __launch_bounds__(256) void splitT(
    const float* __restrict__ W, unsigned short* __restrict__ hi,
    unsigned short* __restrict__ lo, int kshift, int N)
{
    int i = blockIdx.x * 256 + threadIdx.x;
    int K = 1 << kshift;
    int n = i >> kshift, k = i & (K - 1);
    unsigned short h, l;
    splitf(W[(size_t)k * N + n], h, l);
    hi[i] = h; lo[i] = l;
}

// ---- LayerNorm -> split bf16 planes ----
__global__ __launch_bounds__(256) void ln_split(
    const float* __restrict__ x, const float* __restrict__ g,
    const float* __restrict__ b, unsigned short* __restrict__ yhi,
    unsigned short* __restrict__ ylo)
{
    const int row = blockIdx.x * 4 + (threadIdx.x >> 6);
    const int lane = threadIdx.x & 63;
    float4 t = *(const float4*)&x[(size_t)row * 256 + lane * 4];
    float s = t.x + t.y + t.z + t.w;
#pragma unroll
    for (int sh = 1; sh < 64; sh <<= 1) s += __shfl_xor(s, sh);
    const float mu = s * (1.0f / 256.0f);
    const float dx = t.x - mu, dy = t.y - mu, dz = t.z - mu, dw = t.w - mu;
    float vv = dx * dx + dy * dy + dz * dz + dw * dw;
#pragma unroll
    for (int sh = 1; sh < 64; sh <<= 1) vv += __shfl_xor(vv, sh);
    const float rstd = rsqrtf(vv * (1.0f / 256.0f) + 1e-5f);
    float4 gv = *(const float4*)&g[lane * 4];
    float4 bv = *(const float4*)&b[lane * 4];
    float o0 = dx * rstd * gv.x + bv.x;
    float o1 = dy * rstd * gv.y + bv.y;
    float o2 = dz * rstd * gv.z + bv.z;
    float o3 = dw * rstd * gv.w + bv.w;
    unsigned short h0, l0, h1, l1, h2, l2, h3, l3;
    splitf(o0, h0, l0); splitf(o1, h1, l1); splitf(o2, h2, l2); splitf(o3, h3, l3);
    const size_t base = (size_t)row * 256 + lane * 4;
    uint2 ph, pl;
    ph.x = (unsigned)h0 | ((unsigned)h1 << 16); ph.y = (unsigned)h2 | ((unsigned)h3 << 16);
    pl.x = (unsigned)l0 | ((unsigned)l1 << 16); pl.y = (unsigned)l2 | ((unsigned)l3 << 16);
    *(uint2*)&yhi[base] = ph;
    *(uint2*)&ylo[base] = pl;
}

// ---- split-bf16 MFMA GEMM, tile 128x128, BK=32, 4 waves ----
// EPI: 0 bias->f32 C | 1 bias(nullable)+res->f32 C | 2 bias->split planes+per-head diag
//      4 global max -> keys[0] | 5 per-row max -> keys[row]
//      6 kp = exp epilogue + TRANSPOSED write to kpT[bh][m][n]
//      7 qp = exp per-row-max epilogue -> Obf[row*256+col]
//      8 bias -> bf16 TRANSPOSED write to vT[bh][d][n] (80-row planes)
template<int EPI, bool ASPLIT>
__global__ __launch_bounds__(256) void gemm_mf(
    const unsigned short* __restrict__ Ahi, const unsigned short* __restrict__ Alo, int lda,
    const unsigned short* __restrict__ Bhi, const unsigned short* __restrict__ Blo, int ldb,
    int K,
    const float* __restrict__ bias, const float* __restrict__ res,
    float* __restrict__ C, int ldc,
    unsigned short* __restrict__ Obf, unsigned short* __restrict__ Olo,
    const float* __restrict__ diag, unsigned* __restrict__ keys)
{
    constexpr int NP = ASPLIT ? 4 : 3;
    constexpr int BH_ = ASPLIT ? 2 : 1;
    __shared__ unsigned short lds[NP][128][40];
    __shared__ float red[4];
    int bx, by; xcd_swz(bx, by);
    const int tid = threadIdx.x;
    const int m0 = by * 128, n0 = bx * 128;
    const int srow = tid >> 1, sseg = (tid & 1) * 16;
    const unsigned short* ga_h = Ahi + (size_t)(m0 + srow) * lda + sseg;
    const unsigned short* ga_l = ASPLIT ? (Alo + (size_t)(m0 + srow) * lda + sseg) : nullptr;
    const unsigned short* gb_h = Bhi + (size_t)(n0 + srow) * ldb + sseg;
    const unsigned short* gb_l = Blo + (size_t)(n0 + srow) * ldb + sseg;
    const int l = tid & 63, w = tid >> 6;
    const int wr = (w >> 1) * 64, wc = (w & 1) * 64;
    const int fr = l & 15, fq = l >> 4;

    f32x4 acc[4][4];
#pragma unroll
    for (int i = 0; i < 4; ++i)
#pragma unroll
        for (int j = 0; j < 4; ++j) acc[i][j] = (f32x4){0.f, 0.f, 0.f, 0.f};

    for (int k0 = 0; k0 < K; k0 += 32) {
        *(uint4*)&lds[0][srow][sseg]       = *(const uint4*)(ga_h + k0);
        *(uint4*)&lds[0][srow][sseg + 8]   = *(const uint4*)(ga_h + k0 + 8);
        if (ASPLIT) {
            *(uint4*)&lds[1][srow][sseg]     = *(const uint4*)(ga_l + k0);
            *(uint4*)&lds[1][srow][sseg + 8] = *(const uint4*)(ga_l + k0 + 8);
        }
        *(uint4*)&lds[BH_][srow][sseg]       = *(const uint4*)(gb_h + k0);
        *(uint4*)&lds[BH_][srow][sseg + 8]   = *(const uint4*)(gb_h + k0 + 8);
        *(uint4*)&lds[BH_ + 1][srow][sseg]     = *(const uint4*)(gb_l + k0);
        *(uint4*)&lds[BH_ + 1][srow][sseg + 8] = *(const uint4*)(gb_l + k0 + 8);
        __syncthreads();
        short8 ah[4], al[4];
#pragma unroll
        for (int mf = 0; mf < 4; ++mf) {
            ah[mf] = *(const short8*)&lds[0][wr + mf * 16 + fr][fq * 8];
            if (ASPLIT) al[mf] = *(const short8*)&lds[1][wr + mf * 16 + fr][fq * 8];
        }
#pragma unroll
        for (int nf = 0; nf < 4; ++nf) {
            short8 bh = *(const short8*)&lds[BH_][wc + nf * 16 + fr][fq * 8];
            short8 bl = *(const short8*)&lds[BH_ + 1][wc + nf * 16 + fr][fq * 8];
#pragma unroll
            for (int mf = 0; mf < 4; ++mf) {
                acc[mf][nf] = __builtin_amdgcn_mfma_f32_16x16x32_bf16(ah[mf], bh, acc[mf][nf], 0, 0, 0);
                if (ASPLIT)
                    acc[mf][nf] = __builtin_amdgcn_mfma_f32_16x16x32_bf16(al[mf], bh, acc[mf][nf], 0, 0, 0);
                acc[mf][nf] = __builtin_amdgcn_mfma_f32_16x16x32_bf16(ah[mf], bl, acc[mf][nf], 0, 0, 0);
            }
        }
        __syncthreads();
    }

    if constexpr (EPI == 4) {
        float m = -3.4e38f;
#pragma unroll
        for (int mf = 0; mf < 4; ++mf)
#pragma unroll
            for (int nf = 0; nf < 4; ++nf)
#pragma unroll
                for (int v = 0; v < 4; ++v) m = fmaxf(m, acc[mf][nf][v]);
#pragma unroll
        for (int s = 1; s < 64; s <<= 1) m = fmaxf(m, __shfl_xor(m, s));
        if (l == 0) red[w] = m;
        __syncthreads();
        if (tid == 0)
            atomicMax(keys, fkey(fmaxf(fmaxf(red[0], red[1]), fmaxf(red[2], red[3]))));
    } else if constexpr (EPI == 5) {
#pragma unroll
        for (int mf = 0; mf < 4; ++mf)
#pragma unroll
            for (int v = 0; v < 4; ++v) {
                float rm = fmaxf(fmaxf(acc[mf][0][v], acc[mf][1][v]),
                                 fmaxf(acc[mf][2][v], acc[mf][3][v]));
                rm = fmaxf(rm, __shfl_xor(rm, 1));
                rm = fmaxf(rm, __shfl_xor(rm, 2));
                rm = fmaxf(rm, __shfl_xor(rm, 4));
                rm = fmaxf(rm, __shfl_xor(rm, 8));
                if (fr == 0) atomicMax(&keys[m0 + wr + mf * 16 + fq * 4 + v], fkey(rm));
            }
    } else if constexpr (EPI == 6) {
        // kp = RATIO*(exp(acc - diag - gmax)+eps), transposed into kpT[bh][m][n]
        const float Mg = funkey(*keys);
        unsigned short* tb = &lds[0][0][0];            // reuse LDS: [128 rows][128 cols]
#pragma unroll
        for (int mf = 0; mf < 4; ++mf)
#pragma unroll
            for (int v = 0; v < 4; ++v) {
                const int rl = wr + mf * 16 + fq * 4 + v;
                const float dg = diag[m0 + rl] + Mg;
#pragma unroll
                for (int nf = 0; nf < 4; ++nf) {
                    const int cl = wc + nf * 16 + fr;
                    tb[rl * 128 + cl] = bf16rne(RATIO * (expf(acc[mf][nf][v] - dg) + EPSF));
                }
            }
        __syncthreads();
        const int tokbase = m0 >> 2;
        const int b = tokbase >> 12, nib = tokbase & 4095;
        const int ml = tid & 127, g2 = tid >> 7;
#pragma unroll
        for (int hh2 = 0; hh2 < 2; ++hh2) {
            const int hh = g2 * 2 + hh2;
            unsigned short* dst = Obf + ((size_t)((b * 4 + hh) * 256 + n0 + ml)) * 4096 + nib;
#pragma unroll
            for (int qq = 0; qq < 4; ++qq) {
                uint4 qv;
                unsigned wv[4];
#pragma unroll
                for (int j = 0; j < 4; ++j) {
                    unsigned s0 = tb[((qq * 8 + j * 2 + 0) * 4 + hh) * 128 + ml];
                    unsigned s1 = tb[((qq * 8 + j * 2 + 1) * 4 + hh) * 128 + ml];
                    wv[j] = s0 | (s1 << 16);
                }
                qv.x = wv[0]; qv.y = wv[1]; qv.z = wv[2]; qv.w = wv[3];
                *(uint4*)(dst + qq * 8) = qv;
            }
        }
    } else if constexpr (EPI == 7) {
#pragma unroll
        for (int mf = 0; mf < 4; ++mf) {
#pragma unroll
            for (int v = 0; v < 4; ++v) {
                const int row = m0 + wr + mf * 16 + fq * 4 + v;
                const float dg = diag[row] + funkey(keys[row]);
#pragma unroll
                for (int nf = 0; nf < 4; ++nf) {
                    const int col = n0 + wc + nf * 16 + fr;
                    Obf[(size_t)row * 256 + col] = bf16rne(RATIO * (expf(acc[mf][nf][v] - dg) + EPSF));
                }
            }
        }
    } else if constexpr (EPI == 8) {
        // v + bias -> bf16, transposed into vT[bh][d][n] (80-row planes)
        unsigned short* tb = &lds[0][0][0];            // [128 tok][128 ch]
#pragma unroll
        for (int mf = 0; mf < 4; ++mf)
#pragma unroll
            for (int nf = 0; nf < 4; ++nf) {
                const int cl = wc + nf * 16 + fr;
                const float bb = bias[n0 + cl];
#pragma unroll
                for (int v = 0; v < 4; ++v) {
                    const int rl = wr + mf * 16 + fq * 4 + v;
                    tb[rl * 128 + cl] = bf16rne(acc[mf][nf][v] + bb);
                }
            }
        __syncthreads();
        const int b = m0 >> 12, nib = m0 & 4095;
        const int cl = tid & 127, half = tid >> 7;
        const int ch = n0 + cl, hh = ch >> 6, d = ch & 63;
        unsigned short* dst = Obf + ((size_t)((b * 4 + hh) * 80 + d)) * 4096 + nib + half * 64;
#pragma unroll
        for (int qq = 0; qq < 8; ++qq) {
            uint4 qv;
            unsigned wv[4];
#pragma unroll
            for (int j = 0; j < 4; ++j) {
                unsigned s0 = tb[(half * 64 + qq * 8 + j * 2 + 0) * 128 + cl];
                unsigned s1 = tb[(half * 64 + qq * 8 + j * 2 + 1) * 128 + cl];
                wv[j] = s0 | (s1 << 16);
            }
            qv.x = wv[0]; qv.y = wv[1]; qv.z = wv[2]; qv.w = wv[3];
            *(uint4*)(dst + qq * 8) = qv;
        }
    } else if constexpr (EPI == 2) {
        const int head = (n0 + wc) >> 6;
#pragma unroll
        for (int mf = 0; mf < 4; ++mf) {
            float sq[4] = {0.f, 0.f, 0.f, 0.f};
#pragma unroll
            for (int nf = 0; nf < 4; ++nf) {
                const int col = n0 + wc + nf * 16 + fr;
                const float bb = bias[col];
#pragma unroll
                for (int v = 0; v < 4; ++v) {
                    const int row = m0 + wr + mf * 16 + fq * 4 + v;
                    float val = acc[mf][nf][v] + bb;
                    unsigned short hh_, ll_;
                    splitf(val, hh_, ll_);
                    Obf[(size_t)row * 256 + col] = hh_;
                    Olo[(size_t)row * 256 + col] = ll_;
                    sq[v] += val * val;
                }
            }
#pragma unroll
            for (int v = 0; v < 4; ++v) {
                float s = sq[v];
                s += __shfl_xor(s, 1); s += __shfl_xor(s, 2);
                s += __shfl_xor(s, 4); s += __shfl_xor(s, 8);
                if (fr == 0)
                    ((float*)diag)[(size_t)(m0 + wr + mf * 16 + fq * 4 + v) * 4 + head] = s * 0.0625f;
            }
        }
    } else {
#pragma unroll
        for (int nf = 0; nf < 4; ++nf) {
            const int col = n0 + wc + nf * 16 + fr;
            float bb = 0.f;
            if (bias != nullptr) bb = bias[col];
#pragma unroll
            for (int mf = 0; mf < 4; ++mf) {
#pragma unroll
                for (int v = 0; v < 4; ++v) {
                    const int row = m0 + wr + mf * 16 + fq * 4 + v;
                    const size_t off = (size_t)row * ldc + col;
                    float val = acc[mf][nf][v] + bb;
                    if (EPI == 1) val += res[off];
                    C[off] = val;
                }
            }
        }
    }
}

// ---- fused GLU GEMM (split-bf16 MFMA), full 1024 width, single bf16 output ----
__global__ __launch_bounds__(256) void gemm_glu(
    const unsigned short* __restrict__ Ahi, const unsigned short* __restrict__ Alo,
    const unsigned short* __restrict__ Whi, const unsigned short* __restrict__ Wlo,
    const float* __restrict__ b1, unsigned short* __restrict__ Obf)
{
    __shared__ unsigned short ldsA[2][128][40];
    __shared__ unsigned short ldsB[4][64][40];
    int bx, by; xcd_swz(bx, by);
    const int tid = threadIdx.x;
    const int m0 = by * 128, p0 = bx * 64;
    const int srow = tid >> 1, sseg = (tid & 1) * 16;
    const unsigned short* ga_h = Ahi + (size_t)(m0 + srow) * 256 + sseg;
    const unsigned short* ga_l = Alo + (size_t)(m0 + srow) * 256 + sseg;
    const int brow = tid & 63, pp = tid >> 6;
    const int grow = (pp < 2) ? (p0 + brow) : (1024 + p0 + brow);
    const unsigned short* gw = ((pp & 1) ? Wlo : Whi) + (size_t)grow * 256;
    const int l = tid & 63, w = tid >> 6;
    const int wr = (w >> 1) * 64, wc = (w & 1) * 32;
    const int fr = l & 15, fq = l >> 4;

    f32x4 aa[4][2], ag[4][2];
#pragma unroll
    for (int i = 0; i < 4; ++i)
#pragma unroll
        for (int j = 0; j < 2; ++j) {
            aa[i][j] = (f32x4){0.f, 0.f, 0.f, 0.f};
            ag[i][j] = (f32x4){0.f, 0.f, 0.f, 0.f};
        }

    for (int k0 = 0; k0 < 256; k0 += 32) {
        *(uint4*)&ldsA[0][srow][sseg]     = *(const uint4*)(ga_h + k0);
        *(uint4*)&ldsA[0][srow][sseg + 8] = *(const uint4*)(ga_h + k0 + 8);
        *(uint4*)&ldsA[1][srow][sseg]     = *(const uint4*)(ga_l + k0);
        *(uint4*)&ldsA[1][srow][sseg + 8] = *(const uint4*)(ga_l + k0 + 8);
        *(uint4*)&ldsB[pp][brow][0]       = *(const uint4*)(gw + k0);
        *(uint4*)&ldsB[pp][brow][8]       = *(const uint4*)(gw + k0 + 8);
        *(uint4*)&ldsB[pp][brow][16]      = *(const uint4*)(gw + k0 + 16);
        *(uint4*)&ldsB[pp][brow][24]      = *(const uint4*)(gw + k0 + 24);
        __syncthreads();
        short8 ah[4], al[4];
#pragma unroll
        for (int mf = 0; mf < 4; ++mf) {
            ah[mf] = *(const short8*)&ldsA[0][wr + mf * 16 + fr][fq * 8];
            al[mf] = *(const short8*)&ldsA[1][wr + mf * 16 + fr][fq * 8];
        }
#pragma unroll
        for (int nf = 0; nf < 2; ++nf) {
            const int br_ = wc + nf * 16 + fr;
            short8 bah = *(const short8*)&ldsB[0][br_][fq * 8];
            short8 bal = *(const short8*)&ldsB[1][br_][fq * 8];
            short8 bgh = *(const short8*)&ldsB[2][br_][fq * 8];
            short8 bgl = *(const short8*)&ldsB[3][br_][fq * 8];
#pragma unroll
            for (int mf = 0; mf < 4; ++mf) {
                aa[mf][nf] = __builtin_amdgcn_mfma_f32_16x16x32_bf16(ah[mf], bah, aa[mf][nf], 0, 0, 0);
                aa[mf][nf] = __builtin_amdgcn_mfma_f32_16x16x32_bf16(al[mf], bah, aa[mf][nf], 0, 0, 0);
                aa[mf][nf] = __builtin_amdgcn_mfma_f32_16x16x32_bf16(ah[mf], bal, aa[mf][nf], 0, 0, 0);
                ag[mf][nf] = __builtin_amdgcn_mfma_f32_16x16x32_bf16(ah[mf], bgh, ag[mf][nf], 0, 0, 0);
                ag[mf][nf] = __builtin_amdgcn_mfma_f32_16x16x32_bf16(al[mf], bgh, ag[mf][nf], 0, 0, 0);
                ag[mf][nf] = __builtin_amdgcn_mfma_f32_16x16x32_bf16(ah[mf], bgl, ag[mf][nf], 0, 0, 0);
            }
        }
        __syncthreads();
    }
#pragma unroll
    for (int nf = 0; nf < 2; ++nf) {
        const int ch = p0 + wc + nf * 16 + fr;
        const float ba = b1[ch], bg = b1[1024 + ch];
#pragma unroll
        for (int mf = 0; mf < 4; ++mf) {
#pragma unroll
            for (int v = 0; v < 4; ++v) {
                const int row = m0 + wr + mf * 16 + fq * 4 + v;
                float u = aa[mf][nf][v] + ba, g = ag[mf][nf][v] + bg;
                Obf[(size_t)row * 1024 + ch] = bf16rne(gelu_exact(u) * g);
            }
        }
    }
}

// ---- ctx GEMM: ctxp[kc][bh][m][dc] = sum_{n in kc-chunk} kpT[bh][m][n]*vT[bh][dc][n] ----
// dc row 64 of vT is all-ones -> column 64 = ksum. grid (8, 32): x = kc*2+mt, y = bh.
__global__ __launch_bounds__(256) void ctx_mfma(
    const unsigned short* __restrict__ kpT, const unsigned short* __restrict__ vT,
    float* __restrict__ ctxp)
{
    __shared__ unsigned short la[128][40];
    __shared__ unsigned short lb[80][40];
    int bx, by; xcd_swz(bx, by);
    const int bh = by, mt = bx & 1, kc = bx >> 1;
    const int tid = threadIdx.x;
    const int l = tid & 63, w = tid >> 6;
    const int wr = w * 32, fr = l & 15, fq = l >> 4;
    const unsigned short* A = kpT + ((size_t)bh * 256 + mt * 128) * 4096 + kc * 1024;
    const unsigned short* B = vT + (size_t)bh * 80 * 4096 + kc * 1024;

    f32x4 acc[2][5];
#pragma unroll
    for (int i = 0; i < 2; ++i)
#pragma unroll
        for (int j = 0; j < 5; ++j) acc[i][j] = (f32x4){0.f, 0.f, 0.f, 0.f};

    for (int k0 = 0; k0 < 1024; k0 += 32) {
        for (int i = tid; i < 512; i += 256) {
            const int row = i >> 2, seg = i & 3;
            *(uint4*)&la[row][seg * 8] = *(const uint4*)(A + (size_t)row * 4096 + k0 + seg * 8);
        }
        if (tid < 160) {
            const int i = tid * 2;
            const int row = i >> 2, seg = i & 3;
            *(uint4*)&lb[row][seg * 8] = *(const uint4*)(B + (size_t)row * 4096 + k0 + seg * 8);
            *(uint4*)&lb[row][(seg + 1) * 8] = *(const uint4*)(B + (size_t)row * 4096 + k0 + (seg + 1) * 8);
        }
        __syncthreads();
        short8 av[2];
#pragma unroll
        for (int mf = 0; mf < 2; ++mf)
            av[mf] = *(const short8*)&la[wr + mf * 16 + fr][fq * 8];
#pragma unroll
        for (int nf = 0; nf < 5; ++nf) {
            short8 bv = *(const short8*)&lb[nf * 16 + fr][fq * 8];
#pragma unroll
            for (int mf = 0; mf < 2; ++mf)
                acc[mf][nf] = __builtin_amdgcn_mfma_f32_16x16x32_bf16(av[mf], bv, acc[mf][nf], 0, 0, 0);
        }
        __syncthreads();
    }
#pragma unroll
    for (int mf = 0; mf < 2; ++mf)
#pragma unroll
        for (int v = 0; v < 4; ++v) {
            const int row = wr + mf * 16 + fq * 4 + v;
#pragma unroll
            for (int nf = 0; nf < 5; ++nf) {
                const int col = nf * 16 + fr;
                ctxp[((size_t)(kc * 32 + bh) * 256 + mt * 128 + row) * 80 + col] = acc[mf][nf][v];
            }
        }
}

// ---- reduce ctx partials over 4 k-chunks, transpose, split -> ctxT[bh][80][256] ----
__global__ __launch_bounds__(256) void ctx_fix(
    const float* __restrict__ ctxp, unsigned short* __restrict__ cth,
    unsigned short* __restrict__ ctl)
{
    __shared__ float s[64][81];
    const int m0 = blockIdx.x * 64, bh = blockIdx.y;
    const int tid = threadIdx.x;
    for (int i = tid; i < 5120; i += 256) {
        const int ml = i / 80, dc = i % 80;
        float sum = 0.f;
#pragma unroll
        for (int kc = 0; kc < 4; ++kc)
            sum += ctxp[((size_t)(kc * 32 + bh) * 256 + m0 + ml) * 80 + dc];
        s[ml][dc] = sum;
    }
    __syncthreads();
    for (int i = tid; i < 5120; i += 256) {
        const int dc = i >> 6, ml = i & 63;
        unsigned short hh_, ll_;
        splitf(s[ml][dc], hh_, ll_);
        cth[((size_t)bh * 80 + dc) * 256 + m0 + ml] = hh_;
        ctl[((size_t)bh * 80 + dc) * 256 + m0 + ml] = ll_;
    }
}

// ---- o = (qp @ ctx)/(qp . ksum) via MFMA; N=80 (col 64 = ksum) ----
// grid (16, 32): x = token-tile of 256, y = bh.
__global__ __launch_bounds__(256) void o_mfma(
    const unsigned short* __restrict__ qp,
    const unsigned short* __restrict__ cth, const unsigned short* __restrict__ ctl,
    unsigned short* __restrict__ osh, unsigned short* __restrict__ osl)
{
    __shared__ unsigned short la[256][40];
    __shared__ unsigned short lb[2][80][40];
    int bx, by; xcd_swz(bx, by);
    const int bh = by, b = bh >> 2, hh = bh & 3;
    const int r0 = bx * 256;
    const int tid = threadIdx.x;
    const int l = tid & 63, w = tid >> 6;
    const int wr = w * 64, fr = l & 15, fq = l >> 4;
    const size_t abase = ((size_t)(b * 4096 + r0) * 4 + hh) * 256;
    const size_t bbase = (size_t)bh * 80 * 256;

    f32x4 acc[4][5];
#pragma unroll
    for (int i = 0; i < 4; ++i)
#pragma unroll
        for (int j = 0; j < 5; ++j) acc[i][j] = (f32x4){0.f, 0.f, 0.f, 0.f};

    for (int k0 = 0; k0 < 256; k0 += 32) {
        for (int i = tid; i < 1024; i += 256) {
            const int row = i >> 2, seg = i & 3;
            *(uint4*)&la[row][seg * 8] = *(const uint4*)(qp + abase + (size_t)row * 1024 + k0 + seg * 8);
        }
        for (int i = tid; i < 640; i += 256) {
            const int rr = i >> 2, seg = i & 3;
            const int pl = (rr >= 80) ? 1 : 0;
            const int r80 = rr - pl * 80;
            const unsigned short* src = (pl ? ctl : cth) + bbase + (size_t)r80 * 256 + k0 + seg * 8;
            *(uint4*)&lb[pl][r80][seg * 8] = *(const uint4*)src;
        }
        __syncthreads();
        short8 av[4];
#pragma unroll
        for (int mf = 0; mf < 4; ++mf)
            av[mf] = *(const short8*)&la[wr + mf * 16 + fr][fq * 8];
#pragma unroll
        for (int nf = 0; nf < 5; ++nf) {
            short8 bvh = *(const short8*)&lb[0][nf * 16 + fr][fq * 8];
            short8 bvl = *(const short8*)&lb[1][nf * 16 + fr][fq * 8];
#pragma unroll
            for (int mf = 0; mf < 4; ++mf) {
                acc[mf][nf] = __builtin_amdgcn_mfma_f32_16x16x32_bf16(av[mf], bvh, acc[mf][nf], 0, 0, 0);
                acc[mf][nf] = __builtin_amdgcn_mfma_f32_16x16x32_bf16(av[mf], bvl, acc[mf][nf], 0, 0, 0);
            }
        }
        __syncthreads();
    }
#pragma unroll
    for (int mf = 0; mf < 4; ++mf)
#pragma unroll
        for (int v = 0; v < 4; ++v) {
            const float den = __shfl(acc[mf][4][v], (int)(l & 48));
            const float dinv = 1.0f / den;
            const int r = r0 + wr + mf * 16 + fq * 4 + v;
            const size_t obase = (size_t)(b * 4096 + r) * 256 + hh * 64;
#pragma unroll
            for (int nf = 0; nf < 4; ++nf) {
                unsigned short hh_, ll_;
                splitf(acc[mf][nf][v] * dinv, hh_, ll_);
                osh[obase + nf * 16 + fr] = hh_;
                osl[obase + nf * 16 + fr] = ll_;
            }
        }
}

// ---- pooling + classifier ----
__global__ __launch_bounds__(256) void pool1_kernel(const float* __restrict__ h, float* __restrict__ part)
{
    const int b = blockIdx.x >> 4, ch = blockIdx.x & 15;
    const int tid = threadIdx.x;
    float acc = 0.f;
    for (int n = 0; n < 256; ++n)
        acc += h[((size_t)(b * 4096 + ch * 256 + n)) * 256 + tid];
    part[(size_t)blockIdx.x * 256 + tid] = acc;
}

__global__ __launch_bounds__(256) void pool2_kernel(
    const float* __restrict__ part, const float* __restrict__ cw,
    const float* __restrict__ cb, float* __restrict__ out)
{
    const int b = blockIdx.x, tid = threadIdx.x;
    float acc = 0.f;
#pragma unroll
    for (int c = 0; c < 16; ++c) acc += part[(size_t)(b * 16 + c) * 256 + tid];
    float val = acc * (1.0f / 4096.0f) * cw[tid];
#pragma unroll
    for (int s = 1; s < 64; s <<= 1) val += __shfl_xor(val, s);
    __shared__ float red[4];
    if ((tid & 63) == 0) red[tid >> 6] = val;
    __syncthreads();
    if (tid == 0) out[b] = red[0] + red[1] + red[2] + red[3] + cb[0];
}

extern "C" void kernel_launch(void* const* d_in, const int* in_sizes, int n_in,
                              void* d_out, int out_size, void* d_ws, size_t ws_size,
                              hipStream_t stream)
{
    (void)in_sizes; (void)n_in;
    if (ws_size < WS_BYTES) {
        fill_sentinel<<<1, 64, 0, stream>>>((float*)d_out, out_size);
        return;
    }

    const float* x     = (const float*)d_in[0];
    const float* projw = (const float*)d_in[1];
    const float* projb = (const float*)d_in[2];
    const float* ln1g  = (const float*)d_in[3];
    const float* ln1b  = (const float*)d_in[4];
    const float* wq    = (const float*)d_in[5];
    const float* bq    = (const float*)d_in[6];
    const float* wk    = (const float*)d_in[7];
    const float* bk    = (const float*)d_in[8];
    const float* wv    = (const float*)d_in[9];
    const float* bv    = (const float*)d_in[10];
    const float* wo    = (const float*)d_in[11];
    const float* bo    = (const float*)d_in[12];
    const float* ln2g  = (const float*)d_in[13];
    const float* ln2b  = (const float*)d_in[14];
    const float* w1    = (const float*)d_in[15];
    const float* b1    = (const float*)d_in[16];
    const float* w2    = (const float*)d_in[17];
    const float* b2    = (const float*)d_in[18];
    const float* clfw  = (const float*)d_in[19];
    const float* clfb  = (const float*)d_in[20];
    const float* projm = (const float*)d_in[21];

    char* WS = (char*)d_ws;
    float* h            = (float*)(WS + OFF_H);
    unsigned short* ysh = (unsigned short*)(WS + OFF_YS);
    unsigned short* ysl = ysh + 8388608;
    unsigned short* qkh = (unsigned short*)(WS + OFF_QK);
    unsigned short* qkl = qkh + 8388608;
    unsigned short* big = (unsigned short*)(WS + OFF_BIG);   // kpT / qp / ffb
    unsigned short* vT  = (unsigned short*)(WS + OFF_VT);
    float* ctxp         = (float*)(WS + OFF_CTXP);
    unsigned short* cth = (unsigned short*)(WS + OFF_CTXTH);
    unsigned short* ctl = (unsigned short*)(WS + OFF_CTXTL);
    float* diagq        = (float*)(WS + OFF_DIAGQ);
    float* diagk        = (float*)(WS + OFF_DIAGK);
    unsigned* rkeys     = (unsigned*)(WS + OFF_RKEY);
    unsigned* gmax      = (unsigned*)(WS + OFF_GMAX);
    float* pool         = (float*)(WS + OFF_POOL);
    unsigned short* wqt_h = (unsigned short*)(WS + OFF_WQTH);
    unsigned short* wqt_l = (unsigned short*)(WS + OFF_WQTL);
    unsigned short* wkt_h = (unsigned short*)(WS + OFF_WKTH);
    unsigned short* wkt_l = (unsigned short*)(WS + OFF_WKTL);
    unsigned short* wvt_h = (unsigned short*)(WS + OFF_WVTH);
    unsigned short* wvt_l = (unsigned short*)(WS + OFF_WVTL);
    unsigned short* wot_h = (unsigned short*)(WS + OFF_WOTH);
    unsigned short* wot_l = (unsigned short*)(WS + OFF_WOTL);
    unsigned short* w1t_h = (unsigned short*)(WS + OFF_W1TH);
    unsigned short* w1t_l = (unsigned short*)(WS + OFF_W1TL);
    unsigned short* w2t_h = (unsigned short*)(WS + OFF_W2TH);
    unsigned short* w2t_l = (unsigned short*)(WS + OFF_W2TL);
    unsigned short* pmt_h = (unsigned short*)(WS + OFF_PMTH);
    unsigned short* pmt_l = (unsigned short*)(WS + OFF_PMTL);
    unsigned short* pwt_h = (unsigned short*)(WS + OFF_PWTH);
    unsigned short* pwt_l = (unsigned short*)(WS + OFF_PWTL);
    // aliases within BIG / YS
    unsigned short* xsh = big;               // prologue only
    unsigned short* xsl = big + 2097152;
    unsigned short* kpT = big;               // [32][256][4096]
    unsigned short* qp  = big;               // [131072][256]
    unsigned short* ffb = big;               // [32768][1024]
    unsigned short* osh = ysh;               // o split (ys dead by then)
    unsigned short* osl = ysl;

    // ---- prologue ----
    split_scale<<<8192, 256, 0, stream>>>(x, xsh, xsl, 2097152, 1.0f);
    splitT<<<64, 256, 0, stream>>>(projw, pwt_h, pwt_l, 6, 256);
    split_scale<<<64, 256, 0, stream>>>(projm, pmt_h, pmt_l, 16384, DN);
    vt_init<<<1024, 256, 0, stream>>>(vT);
    gemm_mf<0, true><<<dim3(2, 256), 256, 0, stream>>>(xsh, xsl, 64, pwt_h, pwt_l, 64, 64,
        projb, nullptr, h, 256, nullptr, nullptr, nullptr, nullptr);

    for (int l = 0; l < 4; ++l) {
        splitT<<<256, 256, 0, stream>>>(wq + (size_t)l * 65536, wqt_h, wqt_l, 8, 256);
        splitT<<<256, 256, 0, stream>>>(wk + (size_t)l * 65536, wkt_h, wkt_l, 8, 256);
        splitT<<<256, 256, 0, stream>>>(wv + (size_t)l * 65536, wvt_h, wvt_l, 8, 256);
        splitT<<<256, 256, 0, stream>>>(wo + (size_t)l * 65536, wot_h, wot_l, 8, 256);
        splitT<<<2048, 256, 0, stream>>>(w1 + (size_t)l * 524288, w1t_h, w1t_l, 8, 2048);
        splitT<<<1024, 256, 0, stream>>>(w2 + (size_t)l * 262144, w2t_h, w2t_l, 10, 256);

        // ---- attention ----
        ln_split<<<8192, 256, 0, stream>>>(h, ln1g + l * 256, ln1b + l * 256, ysh, ysl);
        gemm_mf<8, true><<<dim3(2, 256), 256, 0, stream>>>(ysh, ysl, 256, wvt_h, wvt_l, 256, 256,
            bv + l * 256, nullptr, nullptr, 256, vT, nullptr, nullptr, nullptr);
        gemm_mf<2, true><<<dim3(2, 256), 256, 0, stream>>>(ysh, ysl, 256, wkt_h, wkt_l, 256, 256,
            bk + l * 256, nullptr, nullptr, 256, qkh, qkl, diagk, nullptr);
        fill_keys<<<512, 256, 0, stream>>>(rkeys, gmax);
        gemm_mf<4, true><<<dim3(2, 1024), 256, 0, stream>>>(qkh, qkl, 64, pmt_h, pmt_l, 64, 64,
            nullptr, nullptr, nullptr, 256, nullptr, nullptr, nullptr, gmax);
        gemm_mf<6, true><<<dim3(2, 1024), 256, 0, stream>>>(qkh, qkl, 64, pmt_h, pmt_l, 64, 64,
            nullptr, nullptr, nullptr, 256, kpT, nullptr, diagk, gmax);
        ctx_mfma<<<dim3(8, 32), 256, 0, stream>>>(kpT, vT, ctxp);
        ctx_fix<<<dim3(4, 32), 256, 0, stream>>>(ctxp, cth, ctl);
        gemm_mf<2, true><<<dim3(2, 256), 256, 0, stream>>>(ysh, ysl, 256, wqt_h, wqt_l, 256, 256,
            bq + l * 256, nullptr, nullptr, 256, qkh, qkl, diagq, nullptr);
        gemm_mf<5, true><<<dim3(2, 1024), 256, 0, stream>>>(qkh, qkl, 64, pmt_h, pmt_l, 64, 64,
            nullptr, nullptr, nullptr, 256, nullptr, nullptr, nullptr, rkeys);
        gemm_mf<7, true><<<dim3(2, 1024), 256, 0, stream>>>(qkh, qkl, 64, pmt_h, pmt_l, 64, 64,
            nullptr, nullptr, nullptr, 256, qp, nullptr, diagq, rkeys);
        o_mfma<<<dim3(16, 32), 256, 0, stream>>>(qp, cth, ctl, osh, osl);
        gemm_mf<1, true><<<dim3(2, 256), 256, 0, stream>>>(osh, osl, 256, wot_h, wot_l, 256, 256,
            bo + l * 256, h, h, 256, nullptr, nullptr, nullptr, nullptr);

        // ---- feed-forward ----
        ln_split<<<8192, 256, 0, stream>>>(h, ln2g + l * 256, ln2b + l * 256, ysh, ysl);
        gemm_glu<<<dim3(16, 256), 256, 0, stream>>>(ysh, ysl, w1t_h, w1t_l,
            b1 + (size_t)l * 2048, ffb);
        gemm_mf<1, false><<<dim3(2, 256), 256, 0, stream>>>(ffb, nullptr, 1024,
            w2t_h, w2t_l, 1024, 1024, b2 + l * 256, h, h, 256,
            nullptr, nullptr, nullptr, nullptr);
    }

    pool1_kernel<<<128, 256, 0, stream>>>(h, pool);
    pool2_kernel<<<8, 256, 0, stream>>>(pool, clfw, clfb, (float*)d_out);
}

// Round 6
// 1825.549 us; speedup vs baseline: 6.5734x; 1.1876x over previous
//
#include <hip/hip_runtime.h>
#include <cstdint>
#include <cstddef>

// ---- problem constants ----
constexpr float DN = 0.35355339059327373f;   // 64^-0.25
constexpr float RATIO = 0.0625f;             // 256^-0.5
constexpr float EPSF = 1e-4f;

typedef __attribute__((ext_vector_type(8))) short short8;   // bf16 MFMA fragment
typedef __attribute__((ext_vector_type(4))) float f32x4;    // MFMA accumulator

// ---- workspace layout (byte offsets); proven budget >= 209,715,200 B ----
constexpr size_t OFF_H     = 0;              // fp32 residual 33,554,432
constexpr size_t OFF_YS    = 33554432;       // ysh (osh alias) 16,777,216 (+16.7MB spare)
constexpr size_t OFF_QK    = 67108864;       // khi 16,777,216 | qhi 16,777,216
constexpr size_t OFF_BIG   = 100663296;      // kpT / qp / ffb / x-split 67,108,864
constexpr size_t OFF_VT    = 167772160;      // vT [32][80][4096] bf16 20,971,520
constexpr size_t OFF_CTXP  = 188743680;      // ctx partials [4][32][256][80] f32 10,485,760
constexpr size_t OFF_CTXTH = 199229440;      // ctxT hi [32][80][256] 1,310,720
constexpr size_t OFF_CTXTL = 200540160;      // ctxT lo 1,310,720
constexpr size_t OFF_DIAGQ = 201850880;      // 524,288
constexpr size_t OFF_DIAGK = 202375168;      // 524,288
constexpr size_t OFF_RKEY  = 202899456;      // 524,288
constexpr size_t OFF_GMAX  = 203423744;      // 256
constexpr size_t OFF_POOL  = 203424000;      // 131,072
constexpr size_t OFF_WQTH  = 203555072;
constexpr size_t OFF_WQTL  = 203686144;
constexpr size_t OFF_WKTH  = 203817216;
constexpr size_t OFF_WKTL  = 203948288;
constexpr size_t OFF_WVTH  = 204079360;
constexpr size_t OFF_WVTL  = 204210432;
constexpr size_t OFF_WOTH  = 204341504;
constexpr size_t OFF_WOTL  = 204472576;
constexpr size_t OFF_W1TH  = 204603648;      // 1,048,576
constexpr size_t OFF_W1TL  = 205652224;
constexpr size_t OFF_W2TH  = 206700800;      // 524,288
constexpr size_t OFF_W2TL  = 207225088;
constexpr size_t OFF_PMTH  = 207749376;
constexpr size_t OFF_PMTL  = 207782144;
constexpr size_t OFF_PWTH  = 207814912;
constexpr size_t OFF_PWTL  = 207847680;
constexpr size_t WS_BYTES  = 207880448;

__device__ __forceinline__ unsigned fkey(float f) {
    unsigned u = __float_as_uint(f);
    return (u & 0x80000000u) ? ~u : (u | 0x80000000u);
}
__device__ __forceinline__ float funkey(unsigned k) {
    unsigned u = (k & 0x80000000u) ? (k ^ 0x80000000u) : ~k;
    return __uint_as_float(u);
}
__device__ __forceinline__ float gelu_exact(float x) {
    return 0.5f * x * (1.0f + erff(x * 0.70710678118654752f));
}
__device__ __forceinline__ void splitf(float x, unsigned short& h, unsigned short& l) {
    unsigned u = __float_as_uint(x);
    unsigned hv = (u + 0x7FFFu + ((u >> 16) & 1)) >> 16;
    h = (unsigned short)hv;
    float lo = x - __uint_as_float(hv << 16);
    unsigned u2 = __float_as_uint(lo);
    l = (unsigned short)((u2 + 0x7FFFu + ((u2 >> 16) & 1)) >> 16);
}
__device__ __forceinline__ unsigned short bf16rne(float x) {
    unsigned u = __float_as_uint(x);
    return (unsigned short)((u + 0x7FFFu + ((u >> 16) & 1)) >> 16);
}
// XCD-aware block swizzle (requires total blocks % 8 == 0)
__device__ __forceinline__ void xcd_swz(int& bx, int& by) {
    const int gx = gridDim.x;
    const int total = gx * gridDim.y;
    int flat = blockIdx.y * gx + blockIdx.x;
    flat = (flat & 7) * (total >> 3) + (flat >> 3);
    bx = flat % gx; by = flat / gx;
}

__global__ void fill_sentinel(float* out, int n) {
    int i = threadIdx.x;
    if (i < n) out[i] = 12345.0f;
}
__global__ __launch_bounds__(256) void fill_keys(unsigned* __restrict__ rk, unsigned* __restrict__ gm) {
    int i = blockIdx.x * 256 + threadIdx.x;
    if (i < 131072) rk[i] = 0u;
    if (i == 0) gm[0] = 0u;
}
// fill vT rows 64..79: row 64 = 1.0 (ksum fold), rows 65..79 = 0
__global__ __launch_bounds__(256) void vt_init(unsigned short* __restrict__ vT) {
    int i = blockIdx.x * 256 + threadIdx.x;        // 262,144 uint4
    const int bh = i >> 13;
    const int r = (i >> 9) & 15;
    const unsigned val = (r == 0) ? 0x3F803F80u : 0u;
    uint4 q; q.x = val; q.y = val; q.z = val; q.w = val;
    *(uint4*)(vT + ((size_t)bh * 80 + 64 + r) * 4096 + ((size_t)(i & 511) << 3)) = q;
}

// ---- elementwise split (optional scale) ----
__global__ __launch_bounds__(256) void split_scale(
    const float* __restrict__ src, unsigned short* __restrict__ hi,
    unsigned short* __restrict__ lo, int n, float scale)
{
    int i = blockIdx.x * 256 + threadIdx.x;
    if (i < n) {
        unsigned short h, l;
        splitf(src[i] * scale, h, l);
        hi[i] = h; lo[i] = l;
    }
}

// ---- transpose-split weights: W [K,N] fp32 -> Wt hi/lo [N,K] bf16 ----
__global__ __launch_bounds__(256) void splitT(
    const float* __restrict__ W, unsigned short* __restrict__ hi,
    unsigned short* __restrict__ lo, int kshift, int N)
{
    int i = blockIdx.x * 256 + threadIdx.x;
    int K = 1 << kshift;
    int n = i >> kshift, k = i & (K - 1);
    unsigned short h, l;
    splitf(W[(size_t)k * N + n], h, l);
    hi[i] = h; lo[i] = l;
}

// ---- LayerNorm -> single bf16 plane ----
__global__ __launch_bounds__(256) void ln_bf16(
    const float* __restrict__ x, const float* __restrict__ g,
    const float* __restrict__ b, unsigned short* __restrict__ yhi)
{
    const int row = blockIdx.x * 4 + (threadIdx.x >> 6);
    const int lane = threadIdx.x & 63;
    float4 t = *(const float4*)&x[(size_t)row * 256 + lane * 4];
    float s = t.x + t.y + t.z + t.w;
#pragma unroll
    for (int sh = 1; sh < 64; sh <<= 1) s += __shfl_xor(s, sh);
    const float mu = s * (1.0f / 256.0f);
    const float dx = t.x - mu, dy = t.y - mu, dz = t.z - mu, dw = t.w - mu;
    float vv = dx * dx + dy * dy + dz * dz + dw * dw;
#pragma unroll
    for (int sh = 1; sh < 64; sh <<= 1) vv += __shfl_xor(vv, sh);
    const float rstd = rsqrtf(vv * (1.0f / 256.0f) + 1e-5f);
    float4 gv = *(const float4*)&g[lane * 4];
    float4 bv = *(const float4*)&b[lane * 4];
    unsigned short h0 = bf16rne(dx * rstd * gv.x + bv.x);
    unsigned short h1 = bf16rne(dy * rstd * gv.y + bv.y);
    unsigned short h2 = bf16rne(dz * rstd * gv.z + bv.z);
    unsigned short h3 = bf16rne(dw * rstd * gv.w + bv.w);
    uint2 ph;
    ph.x = (unsigned)h0 | ((unsigned)h1 << 16); ph.y = (unsigned)h2 | ((unsigned)h3 << 16);
    *(uint2*)&yhi[(size_t)row * 256 + lane * 4] = ph;
}

// ---- bf16 MFMA GEMM, tile 128x128, BK=32, 4 waves; optional A/B lo planes ----
// EPI: 0 bias->f32 C | 1 bias(nullable)+res->f32 C | 2 bias->bf16 plane + per-head diag
//      4 global max -> keys[0] | 5 per-row max -> keys[row]
//      6 kp = exp epilogue + TRANSPOSED write to kpT[bh][m][n]
//      7 qp = exp per-row-max epilogue -> Obf[row*256+col]
//      8 bias -> bf16 TRANSPOSED write to vT[bh][d][n] (80-row planes)
template<int EPI, bool ASPLIT, bool BSPLIT>
__global__ __launch_bounds__(256) void gemm_mf(
    const unsigned short* __restrict__ Ahi, const unsigned short* __restrict__ Alo, int lda,
    const unsigned short* __restrict__ Bhi, const unsigned short* __restrict__ Blo, int ldb,
    int K,
    const float* __restrict__ bias, const float* __restrict__ res,
    float* __restrict__ C, int ldc,
    unsigned short* __restrict__ Obf,
    const float* __restrict__ diag, unsigned* __restrict__ keys)
{
    constexpr int NP = (ASPLIT ? 2 : 1) + (BSPLIT ? 2 : 1);
    constexpr int PB = ASPLIT ? 2 : 1;                 // B-hi plane index
    constexpr int NEED = (EPI == 6 || EPI == 8) ? 16384 : 0;
    constexpr int LDSN = (NP * 5120 > NEED) ? NP * 5120 : NEED;
    __shared__ unsigned short lds[LDSN];
    __shared__ float red[4];
#define LX(p, r, c) lds[((p) * 128 + (r)) * 40 + (c)]
    int bx, by; xcd_swz(bx, by);
    const int tid = threadIdx.x;
    const int m0 = by * 128, n0 = bx * 128;
    const int srow = tid >> 1, sseg = (tid & 1) * 16;
    const unsigned short* ga_h = Ahi + (size_t)(m0 + srow) * lda + sseg;
    const unsigned short* ga_l = ASPLIT ? (Alo + (size_t)(m0 + srow) * lda + sseg) : nullptr;
    const unsigned short* gb_h = Bhi + (size_t)(n0 + srow) * ldb + sseg;
    const unsigned short* gb_l = BSPLIT ? (Blo + (size_t)(n0 + srow) * ldb + sseg) : nullptr;
    const int l = tid & 63, w = tid >> 6;
    const int wr = (w >> 1) * 64, wc = (w & 1) * 64;
    const int fr = l & 15, fq = l >> 4;

    f32x4 acc[4][4];
#pragma unroll
    for (int i = 0; i < 4; ++i)
#pragma unroll
        for (int j = 0; j < 4; ++j) acc[i][j] = (f32x4){0.f, 0.f, 0.f, 0.f};

    for (int k0 = 0; k0 < K; k0 += 32) {
        *(uint4*)&LX(0, srow, sseg)     = *(const uint4*)(ga_h + k0);
        *(uint4*)&LX(0, srow, sseg + 8) = *(const uint4*)(ga_h + k0 + 8);
        if (ASPLIT) {
            *(uint4*)&LX(1, srow, sseg)     = *(const uint4*)(ga_l + k0);
            *(uint4*)&LX(1, srow, sseg + 8) = *(const uint4*)(ga_l + k0 + 8);
        }
        *(uint4*)&LX(PB, srow, sseg)     = *(const uint4*)(gb_h + k0);
        *(uint4*)&LX(PB, srow, sseg + 8) = *(const uint4*)(gb_h + k0 + 8);
        if (BSPLIT) {
            *(uint4*)&LX(PB + 1, srow, sseg)     = *(const uint4*)(gb_l + k0);
            *(uint4*)&LX(PB + 1, srow, sseg + 8) = *(const uint4*)(gb_l + k0 + 8);
        }
        __syncthreads();
        short8 ah[4], al[4];
#pragma unroll
        for (int mf = 0; mf < 4; ++mf) {
            ah[mf] = *(const short8*)&LX(0, wr + mf * 16 + fr, fq * 8);
            if (ASPLIT) al[mf] = *(const short8*)&LX(1, wr + mf * 16 + fr, fq * 8);
        }
#pragma unroll
        for (int nf = 0; nf < 4; ++nf) {
            short8 bh = *(const short8*)&LX(PB, wc + nf * 16 + fr, fq * 8);
#pragma unroll
            for (int mf = 0; mf < 4; ++mf) {
                acc[mf][nf] = __builtin_amdgcn_mfma_f32_16x16x32_bf16(ah[mf], bh, acc[mf][nf], 0, 0, 0);
                if (ASPLIT)
                    acc[mf][nf] = __builtin_amdgcn_mfma_f32_16x16x32_bf16(al[mf], bh, acc[mf][nf], 0, 0, 0);
            }
            if (BSPLIT) {
                short8 bl = *(const short8*)&LX(PB + 1, wc + nf * 16 + fr, fq * 8);
#pragma unroll
                for (int mf = 0; mf < 4; ++mf)
                    acc[mf][nf] = __builtin_amdgcn_mfma_f32_16x16x32_bf16(ah[mf], bl, acc[mf][nf], 0, 0, 0);
            }
        }
        __syncthreads();
    }

    if constexpr (EPI == 4) {
        float m = -3.4e38f;
#pragma unroll
        for (int mf = 0; mf < 4; ++mf)
#pragma unroll
            for (int nf = 0; nf < 4; ++nf)
#pragma unroll
                for (int v = 0; v < 4; ++v) m = fmaxf(m, acc[mf][nf][v]);
#pragma unroll
        for (int s = 1; s < 64; s <<= 1) m = fmaxf(m, __shfl_xor(m, s));
        if (l == 0) red[w] = m;
        __syncthreads();
        if (tid == 0)
            atomicMax(keys, fkey(fmaxf(fmaxf(red[0], red[1]), fmaxf(red[2], red[3]))));
    } else if constexpr (EPI == 5) {
#pragma unroll
        for (int mf = 0; mf < 4; ++mf)
#pragma unroll
            for (int v = 0; v < 4; ++v) {
                float rm = fmaxf(fmaxf(acc[mf][0][v], acc[mf][1][v]),
                                 fmaxf(acc[mf][2][v], acc[mf][3][v]));
                rm = fmaxf(rm, __shfl_xor(rm, 1));
                rm = fmaxf(rm, __shfl_xor(rm, 2));
                rm = fmaxf(rm, __shfl_xor(rm, 4));
                rm = fmaxf(rm, __shfl_xor(rm, 8));
                if (fr == 0) atomicMax(&keys[m0 + wr + mf * 16 + fq * 4 + v], fkey(rm));
            }
    } else if constexpr (EPI == 6) {
        const float Mg = funkey(*keys);
        unsigned short* tb = lds;
#pragma unroll
        for (int mf = 0; mf < 4; ++mf)
#pragma unroll
            for (int v = 0; v < 4; ++v) {
                const int rl = wr + mf * 16 + fq * 4 + v;
                const float dg = diag[m0 + rl] + Mg;
#pragma unroll
                for (int nf = 0; nf < 4; ++nf) {
                    const int cl = wc + nf * 16 + fr;
                    tb[rl * 128 + cl] = bf16rne(RATIO * (expf(acc[mf][nf][v] - dg) + EPSF));
                }
            }
        __syncthreads();
        const int tokbase = m0 >> 2;
        const int b = tokbase >> 12, nib = tokbase & 4095;
        const int ml = tid & 127, g2 = tid >> 7;
#pragma unroll
        for (int hh2 = 0; hh2 < 2; ++hh2) {
            const int hh = g2 * 2 + hh2;
            unsigned short* dst = Obf + ((size_t)((b * 4 + hh) * 256 + n0 + ml)) * 4096 + nib;
#pragma unroll
            for (int qq = 0; qq < 4; ++qq) {
                uint4 qv;
                unsigned wv[4];
#pragma unroll
                for (int j = 0; j < 4; ++j) {
                    unsigned s0 = tb[((qq * 8 + j * 2 + 0) * 4 + hh) * 128 + ml];
                    unsigned s1 = tb[((qq * 8 + j * 2 + 1) * 4 + hh) * 128 + ml];
                    wv[j] = s0 | (s1 << 16);
                }
                qv.x = wv[0]; qv.y = wv[1]; qv.z = wv[2]; qv.w = wv[3];
                *(uint4*)(dst + qq * 8) = qv;
            }
        }
    } else if constexpr (EPI == 7) {
#pragma unroll
        for (int mf = 0; mf < 4; ++mf) {
#pragma unroll
            for (int v = 0; v < 4; ++v) {
                const int row = m0 + wr + mf * 16 + fq * 4 + v;
                const float dg = diag[row] + funkey(keys[row]);
#pragma unroll
                for (int nf = 0; nf < 4; ++nf) {
                    const int col = n0 + wc + nf * 16 + fr;
                    Obf[(size_t)row * 256 + col] = bf16rne(RATIO * (expf(acc[mf][nf][v] - dg) + EPSF));
                }
            }
        }
    } else if constexpr (EPI == 8) {
        unsigned short* tb = lds;
#pragma unroll
        for (int mf = 0; mf < 4; ++mf)
#pragma unroll
            for (int nf = 0; nf < 4; ++nf) {
                const int cl = wc + nf * 16 + fr;
                const float bb = bias[n0 + cl];
#pragma unroll
                for (int v = 0; v < 4; ++v) {
                    const int rl = wr + mf * 16 + fq * 4 + v;
                    tb[rl * 128 + cl] = bf16rne(acc[mf][nf][v] + bb);
                }
            }
        __syncthreads();
        const int b = m0 >> 12, nib = m0 & 4095;
        const int cl = tid & 127, half = tid >> 7;
        const int ch = n0 + cl, hh = ch >> 6, d = ch & 63;
        unsigned short* dst = Obf + ((size_t)((b * 4 + hh) * 80 + d)) * 4096 + nib + half * 64;
#pragma unroll
        for (int qq = 0; qq < 8; ++qq) {
            uint4 qv;
            unsigned wv[4];
#pragma unroll
            for (int j = 0; j < 4; ++j) {
                unsigned s0 = tb[(half * 64 + qq * 8 + j * 2 + 0) * 128 + cl];
                unsigned s1 = tb[(half * 64 + qq * 8 + j * 2 + 1) * 128 + cl];
                wv[j] = s0 | (s1 << 16);
            }
            qv.x = wv[0]; qv.y = wv[1]; qv.z = wv[2]; qv.w = wv[3];
            *(uint4*)(dst + qq * 8) = qv;
        }
    } else if constexpr (EPI == 2) {
        const int head = (n0 + wc) >> 6;
#pragma unroll
        for (int mf = 0; mf < 4; ++mf) {
            float sq[4] = {0.f, 0.f, 0.f, 0.f};
#pragma unroll
            for (int nf = 0; nf < 4; ++nf) {
                const int col = n0 + wc + nf * 16 + fr;
                const float bb = bias[col];
#pragma unroll
                for (int v = 0; v < 4; ++v) {
                    const int row = m0 + wr + mf * 16 + fq * 4 + v;
                    float val = acc[mf][nf][v] + bb;
                    Obf[(size_t)row * 256 + col] = bf16rne(val);
                    sq[v] += val * val;
                }
            }
#pragma unroll
            for (int v = 0; v < 4; ++v) {
                float s = sq[v];
                s += __shfl_xor(s, 1); s += __shfl_xor(s, 2);
                s += __shfl_xor(s, 4); s += __shfl_xor(s, 8);
                if (fr == 0)
                    ((float*)diag)[(size_t)(m0 + wr + mf * 16 + fq * 4 + v) * 4 + head] = s * 0.0625f;
            }
        }
    } else {
#pragma unroll
        for (int nf = 0; nf < 4; ++nf) {
            const int col = n0 + wc + nf * 16 + fr;
            float bb = 0.f;
            if (bias != nullptr) bb = bias[col];
#pragma unroll
            for (int mf = 0; mf < 4; ++mf) {
#pragma unroll
                for (int v = 0; v < 4; ++v) {
                    const int row = m0 + wr + mf * 16 + fq * 4 + v;
                    const size_t off = (size_t)row * ldc + col;
                    float val = acc[mf][nf][v] + bb;
                    if (EPI == 1) val += res[off];
                    C[off] = val;
                }
            }
        }
    }
#undef LX
}

// ---- fused GLU GEMM: A single bf16 plane, W split -> 4 MFMA/site ----
__global__ __launch_bounds__(256) void gemm_glu(
    const unsigned short* __restrict__ Ahi,
    const unsigned short* __restrict__ Whi, const unsigned short* __restrict__ Wlo,
    const float* __restrict__ b1, unsigned short* __restrict__ Obf)
{
    __shared__ unsigned short ldsA[128][40];
    __shared__ unsigned short ldsB[4][64][40];
    int bx, by; xcd_swz(bx, by);
    const int tid = threadIdx.x;
    const int m0 = by * 128, p0 = bx * 64;
    const int srow = tid >> 1, sseg = (tid & 1) * 16;
    const unsigned short* ga_h = Ahi + (size_t)(m0 + srow) * 256 + sseg;
    const int brow = tid & 63, pp = tid >> 6;
    const int grow = (pp < 2) ? (p0 + brow) : (1024 + p0 + brow);
    const unsigned short* gw = ((pp & 1) ? Wlo : Whi) + (size_t)grow * 256;
    const int l = tid & 63, w = tid >> 6;
    const int wr = (w >> 1) * 64, wc = (w & 1) * 32;
    const int fr = l & 15, fq = l >> 4;

    f32x4 aa[4][2], ag[4][2];
#pragma unroll
    for (int i = 0; i < 4; ++i)
#pragma unroll
        for (int j = 0; j < 2; ++j) {
            aa[i][j] = (f32x4){0.f, 0.f, 0.f, 0.f};
            ag[i][j] = (f32x4){0.f, 0.f, 0.f, 0.f};
        }

    for (int k0 = 0; k0 < 256; k0 += 32) {
        *(uint4*)&ldsA[srow][sseg]     = *(const uint4*)(ga_h + k0);
        *(uint4*)&ldsA[srow][sseg + 8] = *(const uint4*)(ga_h + k0 + 8);
        *(uint4*)&ldsB[pp][brow][0]    = *(const uint4*)(gw + k0);
        *(uint4*)&ldsB[pp][brow][8]    = *(const uint4*)(gw + k0 + 8);
        *(uint4*)&ldsB[pp][brow][16]   = *(const uint4*)(gw + k0 + 16);
        *(uint4*)&ldsB[pp][brow][24]   = *(const uint4*)(gw + k0 + 24);
        __syncthreads();
        short8 ah[4];
#pragma unroll
        for (int mf = 0; mf < 4; ++mf)
            ah[mf] = *(const short8*)&ldsA[wr + mf * 16 + fr][fq * 8];
#pragma unroll
        for (int nf = 0; nf < 2; ++nf) {
            const int br_ = wc + nf * 16 + fr;
            short8 bah = *(const short8*)&ldsB[0][br_][fq * 8];
            short8 bal = *(const short8*)&ldsB[1][br_][fq * 8];
            short8 bgh = *(const short8*)&ldsB[2][br_][fq * 8];
            short8 bgl = *(const short8*)&ldsB[3][br_][fq * 8];
#pragma unroll
            for (int mf = 0; mf < 4; ++mf) {
                aa[mf][nf] = __builtin_amdgcn_mfma_f32_16x16x32_bf16(ah[mf], bah, aa[mf][nf], 0, 0, 0);
                aa[mf][nf] = __builtin_amdgcn_mfma_f32_16x16x32_bf16(ah[mf], bal, aa[mf][nf], 0, 0, 0);
                ag[mf][nf] = __builtin_amdgcn_mfma_f32_16x16x32_bf16(ah[mf], bgh, ag[mf][nf], 0, 0, 0);
                ag[mf][nf] = __builtin_amdgcn_mfma_f32_16x16x32_bf16(ah[mf], bgl, ag[mf][nf], 0, 0, 0);
            }
        }
        __syncthreads();
    }
#pragma unroll
    for (int nf = 0; nf < 2; ++nf) {
        const int ch = p0 + wc + nf * 16 + fr;
        const float ba = b1[ch], bg = b1[1024 + ch];
#pragma unroll
        for (int mf = 0; mf < 4; ++mf) {
#pragma unroll
            for (int v = 0; v < 4; ++v) {
                const int row = m0 + wr + mf * 16 + fq * 4 + v;
                float u = aa[mf][nf][v] + ba, g = ag[mf][nf][v] + bg;
                Obf[(size_t)row * 1024 + ch] = bf16rne(gelu_exact(u) * g);
            }
        }
    }
}

// ---- ctx GEMM: 64-row x 80-col tile, K-chunk 1024; grid (16,32): x = kc*4+mt ----
__global__ __launch_bounds__(256) void ctx_mfma(
    const unsigned short* __restrict__ kpT, const unsigned short* __restrict__ vT,
    float* __restrict__ ctxp)
{
    __shared__ unsigned short la[64][40];
    __shared__ unsigned short lb[80][40];
    int bx, by; xcd_swz(bx, by);
    const int bh = by, mt = bx & 3, kc = bx >> 2;
    const int tid = threadIdx.x;
    const int l = tid & 63, w = tid >> 6;
    const int wr = w * 16, fr = l & 15, fq = l >> 4;
    const unsigned short* A = kpT + ((size_t)bh * 256 + mt * 64) * 4096 + kc * 1024;
    const unsigned short* B = vT + (size_t)bh * 80 * 4096 + kc * 1024;

    f32x4 acc[5];
#pragma unroll
    for (int j = 0; j < 5; ++j) acc[j] = (f32x4){0.f, 0.f, 0.f, 0.f};

    for (int k0 = 0; k0 < 1024; k0 += 32) {
        {
            const int row = tid >> 2, seg = tid & 3;
            *(uint4*)&la[row][seg * 8] = *(const uint4*)(A + (size_t)row * 4096 + k0 + seg * 8);
        }
        for (int i = tid; i < 320; i += 256) {
            const int row = i >> 2, seg = i & 3;
            *(uint4*)&lb[row][seg * 8] = *(const uint4*)(B + (size_t)row * 4096 + k0 + seg * 8);
        }
        __syncthreads();
        short8 av = *(const short8*)&la[wr + fr][fq * 8];
#pragma unroll
        for (int nf = 0; nf < 5; ++nf) {
            short8 bv = *(const short8*)&lb[nf * 16 + fr][fq * 8];
            acc[nf] = __builtin_amdgcn_mfma_f32_16x16x32_bf16(av, bv, acc[nf], 0, 0, 0);
        }
        __syncthreads();
    }
#pragma unroll
    for (int v = 0; v < 4; ++v) {
        const int row = mt * 64 + wr + fq * 4 + v;
#pragma unroll
        for (int nf = 0; nf < 5; ++nf)
            ctxp[((size_t)(kc * 32 + bh) * 256 + row) * 80 + nf * 16 + fr] = acc[nf][v];
    }
}

// ---- reduce ctx partials over 4 k-chunks, transpose, split -> ctxT[bh][80][256] ----
__global__ __launch_bounds__(256) void ctx_fix(
    const float* __restrict__ ctxp, unsigned short* __restrict__ cth,
    unsigned short* __restrict__ ctl)
{
    __shared__ float s[64][81];
    const int m0 = blockIdx.x * 64, bh = blockIdx.y;
    const int tid = threadIdx.x;
    for (int i = tid; i < 5120; i += 256) {
        const int ml = i / 80, dc = i % 80;
        float sum = 0.f;
#pragma unroll
        for (int kc = 0; kc < 4; ++kc)
            sum += ctxp[((size_t)(kc * 32 + bh) * 256 + m0 + ml) * 80 + dc];
        s[ml][dc] = sum;
    }
    __syncthreads();
    for (int i = tid; i < 5120; i += 256) {
        const int dc = i >> 6, ml = i & 63;
        unsigned short hh_, ll_;
        splitf(s[ml][dc], hh_, ll_);
        cth[((size_t)bh * 80 + dc) * 256 + m0 + ml] = hh_;
        ctl[((size_t)bh * 80 + dc) * 256 + m0 + ml] = ll_;
    }
}

// ---- o = (qp @ ctx)/(qp . ksum) via MFMA; N=80 (col 64 = ksum); bf16 out ----
__global__ __launch_bounds__(256) void o_mfma(
    const unsigned short* __restrict__ qp,
    const unsigned short* __restrict__ cth, const unsigned short* __restrict__ ctl,
    unsigned short* __restrict__ osh)
{
    __shared__ unsigned short la[256][40];
    __shared__ unsigned short lb[2][80][40];
    int bx, by; xcd_swz(bx, by);
    const int bh = by, b = bh >> 2, hh = bh & 3;
    const int r0 = bx * 256;
    const int tid = threadIdx.x;
    const int l = tid & 63, w = tid >> 6;
    const int wr = w * 64, fr = l & 15, fq = l >> 4;
    const size_t abase = ((size_t)(b * 4096 + r0) * 4 + hh) * 256;
    const size_t bbase = (size_t)bh * 80 * 256;

    f32x4 acc[4][5];
#pragma unroll
    for (int i = 0; i < 4; ++i)
#pragma unroll
        for (int j = 0; j < 5; ++j) acc[i][j] = (f32x4){0.f, 0.f, 0.f, 0.f};

    for (int k0 = 0; k0 < 256; k0 += 32) {
        for (int i = tid; i < 1024; i += 256) {
            const int row = i >> 2, seg = i & 3;
            *(uint4*)&la[row][seg * 8] = *(const uint4*)(qp + abase + (size_t)row * 1024 + k0 + seg * 8);
        }
        for (int i = tid; i < 640; i += 256) {
            const int rr = i >> 2, seg = i & 3;
            const int pl = (rr >= 80) ? 1 : 0;
            const int r80 = rr - pl * 80;
            const unsigned short* src = (pl ? ctl : cth) + bbase + (size_t)r80 * 256 + k0 + seg * 8;
            *(uint4*)&lb[pl][r80][seg * 8] = *(const uint4*)src;
        }
        __syncthreads();
        short8 av[4];
#pragma unroll
        for (int mf = 0; mf < 4; ++mf)
            av[mf] = *(const short8*)&la[wr + mf * 16 + fr][fq * 8];
#pragma unroll
        for (int nf = 0; nf < 5; ++nf) {
            short8 bvh = *(const short8*)&lb[0][nf * 16 + fr][fq * 8];
            short8 bvl = *(const short8*)&lb[1][nf * 16 + fr][fq * 8];
#pragma unroll
            for (int mf = 0; mf < 4; ++mf) {
                acc[mf][nf] = __builtin_amdgcn_mfma_f32_16x16x32_bf16(av[mf], bvh, acc[mf][nf], 0, 0, 0);
                acc[mf][nf] = __builtin_amdgcn_mfma_f32_16x16x32_bf16(av[mf], bvl, acc[mf][nf], 0, 0, 0);
            }
        }
        __syncthreads();
    }
#pragma unroll
    for (int mf = 0; mf < 4; ++mf)
#pragma unroll
        for (int v = 0; v < 4; ++v) {
            const float den = __shfl(acc[mf][4][v], (int)(l & 48));
            const float dinv = 1.0f / den;
            const int r = r0 + wr + mf * 16 + fq * 4 + v;
            const size_t obase = (size_t)(b * 4096 + r) * 256 + hh * 64;
#pragma unroll
            for (int nf = 0; nf < 4; ++nf)
                osh[obase + nf * 16 + fr] = bf16rne(acc[mf][nf][v] * dinv);
        }
}

// ---- pooling + classifier ----
__global__ __launch_bounds__(256) void pool1_kernel(const float* __restrict__ h, float* __restrict__ part)
{
    const int b = blockIdx.x >> 4, ch = blockIdx.x & 15;
    const int tid = threadIdx.x;
    float acc = 0.f;
    for (int n = 0; n < 256; ++n)
        acc += h[((size_t)(b * 4096 + ch * 256 + n)) * 256 + tid];
    part[(size_t)blockIdx.x * 256 + tid] = acc;
}

__global__ __launch_bounds__(256) void pool2_kernel(
    const float* __restrict__ part, const float* __restrict__ cw,
    const float* __restrict__ cb, float* __restrict__ out)
{
    const int b = blockIdx.x, tid = threadIdx.x;
    float acc = 0.f;
#pragma unroll
    for (int c = 0; c < 16; ++c) acc += part[(size_t)(b * 16 + c) * 256 + tid];
    float val = acc * (1.0f / 4096.0f) * cw[tid];
#pragma unroll
    for (int s = 1; s < 64; s <<= 1) val += __shfl_xor(val, s);
    __shared__ float red[4];
    if ((tid & 63) == 0) red[tid >> 6] = val;
    __syncthreads();
    if (tid == 0) out[b] = red[0] + red[1] + red[2] + red[3] + cb[0];
}

extern "C" void kernel_launch(void* const* d_in, const int* in_sizes, int n_in,
                              void* d_out, int out_size, void* d_ws, size_t ws_size,
                              hipStream_t stream)
{
    (void)in_sizes; (void)n_in;
    if (ws_size < WS_BYTES) {
        fill_sentinel<<<1, 64, 0, stream>>>((float*)d_out, out_size);
        return;
    }

    const float* x     = (const float*)d_in[0];
    const float* projw = (const float*)d_in[1];
    const float* projb = (const float*)d_in[2];
    const float* ln1g  = (const float*)d_in[3];
    const float* ln1b  = (const float*)d_in[4];
    const float* wq    = (const float*)d_in[5];
    const float* bq    = (const float*)d_in[6];
    const float* wk    = (const float*)d_in[7];
    const float* bk    = (const float*)d_in[8];
    const float* wv    = (const float*)d_in[9];
    const float* bv    = (const float*)d_in[10];
    const float* wo    = (const float*)d_in[11];
    const float* bo    = (const float*)d_in[12];
    const float* ln2g  = (const float*)d_in[13];
    const float* ln2b  = (const float*)d_in[14];
    const float* w1    = (const float*)d_in[15];
    const float* b1    = (const float*)d_in[16];
    const float* w2    = (const float*)d_in[17];
    const float* b2    = (const float*)d_in[18];
    const float* clfw  = (const float*)d_in[19];
    const float* clfb  = (const float*)d_in[20];
    const float* projm = (const float*)d_in[21];

    char* WS = (char*)d_ws;
    float* h            = (float*)(WS + OFF_H);
    unsigned short* ysh = (unsigned short*)(WS + OFF_YS);
    unsigned short* khi = (unsigned short*)(WS + OFF_QK);
    unsigned short* qhi = khi + 8388608;
    unsigned short* big = (unsigned short*)(WS + OFF_BIG);   // kpT / qp / ffb
    unsigned short* vT  = (unsigned short*)(WS + OFF_VT);
    float* ctxp         = (float*)(WS + OFF_CTXP);
    unsigned short* cth = (unsigned short*)(WS + OFF_CTXTH);
    unsigned short* ctl = (unsigned short*)(WS + OFF_CTXTL);
    float* diagq        = (float*)(WS + OFF_DIAGQ);
    float* diagk        = (float*)(WS + OFF_DIAGK);
    unsigned* rkeys     = (unsigned*)(WS + OFF_RKEY);
    unsigned* gmax      = (unsigned*)(WS + OFF_GMAX);
    float* pool         = (float*)(WS + OFF_POOL);
    unsigned short* wqt_h = (unsigned short*)(WS + OFF_WQTH);
    unsigned short* wqt_l = (unsigned short*)(WS + OFF_WQTL);
    unsigned short* wkt_h = (unsigned short*)(WS + OFF_WKTH);
    unsigned short* wkt_l = (unsigned short*)(WS + OFF_WKTL);
    unsigned short* wvt_h = (unsigned short*)(WS + OFF_WVTH);
    unsigned short* wvt_l = (unsigned short*)(WS + OFF_WVTL);
    unsigned short* wot_h = (unsigned short*)(WS + OFF_WOTH);
    unsigned short* wot_l = (unsigned short*)(WS + OFF_WOTL);
    unsigned short* w1t_h = (unsigned short*)(WS + OFF_W1TH);
    unsigned short* w1t_l = (unsigned short*)(WS + OFF_W1TL);
    unsigned short* w2t_h = (unsigned short*)(WS + OFF_W2TH);
    unsigned short* w2t_l = (unsigned short*)(WS + OFF_W2TL);
    unsigned short* pmt_h = (unsigned short*)(WS + OFF_PMTH);
    unsigned short* pmt_l = (unsigned short*)(WS + OFF_PMTL);
    unsigned short* pwt_h = (unsigned short*)(WS + OFF_PWTH);
    unsigned short* pwt_l = (unsigned short*)(WS + OFF_PWTL);
    // aliases
    unsigned short* xsh = big;               // prologue only
    unsigned short* xsl = big + 2097152;
    unsigned short* kpT = big;               // [32][256][4096]
    unsigned short* qp  = big;               // [131072][256]
    unsigned short* ffb = big;               // [32768][1024]
    unsigned short* osh = ysh;               // o bf16 (ys dead by then)

    // ---- prologue ----
    split_scale<<<8192, 256, 0, stream>>>(x, xsh, xsl, 2097152, 1.0f);
    splitT<<<64, 256, 0, stream>>>(projw, pwt_h, pwt_l, 6, 256);
    split_scale<<<64, 256, 0, stream>>>(projm, pmt_h, pmt_l, 16384, DN);
    vt_init<<<1024, 256, 0, stream>>>(vT);
    gemm_mf<0, true, true><<<dim3(2, 256), 256, 0, stream>>>(xsh, xsl, 64, pwt_h, pwt_l, 64, 64,
        projb, nullptr, h, 256, nullptr, nullptr, nullptr);

    for (int l = 0; l < 4; ++l) {
        splitT<<<256, 256, 0, stream>>>(wq + (size_t)l * 65536, wqt_h, wqt_l, 8, 256);
        splitT<<<256, 256, 0, stream>>>(wk + (size_t)l * 65536, wkt_h, wkt_l, 8, 256);
        splitT<<<256, 256, 0, stream>>>(wv + (size_t)l * 65536, wvt_h, wvt_l, 8, 256);
        splitT<<<256, 256, 0, stream>>>(wo + (size_t)l * 65536, wot_h, wot_l, 8, 256);
        splitT<<<2048, 256, 0, stream>>>(w1 + (size_t)l * 524288, w1t_h, w1t_l, 8, 2048);
        splitT<<<1024, 256, 0, stream>>>(w2 + (size_t)l * 262144, w2t_h, w2t_l, 10, 256);

        // ---- attention ----
        ln_bf16<<<8192, 256, 0, stream>>>(h, ln1g + l * 256, ln1b + l * 256, ysh);
        gemm_mf<8, false, true><<<dim3(2, 256), 256, 0, stream>>>(ysh, nullptr, 256,
            wvt_h, wvt_l, 256, 256, bv + l * 256, nullptr, nullptr, 256, vT, nullptr, nullptr);
        gemm_mf<2, false, true><<<dim3(2, 256), 256, 0, stream>>>(ysh, nullptr, 256,
            wkt_h, wkt_l, 256, 256, bk + l * 256, nullptr, nullptr, 256, khi, diagk, nullptr);
        gemm_mf<2, false, true><<<dim3(2, 256), 256, 0, stream>>>(ysh, nullptr, 256,
            wqt_h, wqt_l, 256, 256, bq + l * 256, nullptr, nullptr, 256, qhi, diagq, nullptr);
        fill_keys<<<512, 256, 0, stream>>>(rkeys, gmax);
        gemm_mf<4, false, false><<<dim3(2, 1024), 256, 0, stream>>>(khi, nullptr, 64,
            pmt_h, nullptr, 64, 64, nullptr, nullptr, nullptr, 256, nullptr, nullptr, gmax);
        gemm_mf<5, false, false><<<dim3(2, 1024), 256, 0, stream>>>(qhi, nullptr, 64,
            pmt_h, nullptr, 64, 64, nullptr, nullptr, nullptr, 256, nullptr, nullptr, rkeys);
        gemm_mf<6, false, true><<<dim3(2, 1024), 256, 0, stream>>>(khi, nullptr, 64,
            pmt_h, pmt_l, 64, 64, nullptr, nullptr, nullptr, 256, kpT, diagk, gmax);
        ctx_mfma<<<dim3(16, 32), 256, 0, stream>>>(kpT, vT, ctxp);
        ctx_fix<<<dim3(4, 32), 256, 0, stream>>>(ctxp, cth, ctl);
        gemm_mf<7, false, true><<<dim3(2, 1024), 256, 0, stream>>>(qhi, nullptr, 64,
            pmt_h, pmt_l, 64, 64, nullptr, nullptr, nullptr, 256, qp, diagq, rkeys);
        o_mfma<<<dim3(16, 32), 256, 0, stream>>>(qp, cth, ctl, osh);
        gemm_mf<1, false, true><<<dim3(2, 256), 256, 0, stream>>>(osh, nullptr, 256,
            wot_h, wot_l, 256, 256, bo + l * 256, h, h, 256, nullptr, nullptr, nullptr);

        // ---- feed-forward ----
        ln_bf16<<<8192, 256, 0, stream>>>(h, ln2g + l * 256, ln2b + l * 256, ysh);
        gemm_glu<<<dim3(16, 256), 256, 0, stream>>>(ysh, w1t_h, w1t_l,
            b1 + (size_t)l * 2048, ffb);
        gemm_mf<1, false, true><<<dim3(2, 256), 256, 0, stream>>>(ffb, nullptr, 1024,
            w2t_h, w2t_l, 1024, 1024, b2 + l * 256, h, h, 256, nullptr, nullptr, nullptr);
    }

    pool1_kernel<<<128, 256, 0, stream>>>(h, pool);
    pool2_kernel<<<8, 256, 0, stream>>>(pool, clfw, clfb, (float*)d_out);
}

// Round 7
// 1648.873 us; speedup vs baseline: 7.2777x; 1.1071x over previous
//
#include <hip/hip_runtime.h>
#include <cstdint>
#include <cstddef>

// ---- problem constants ----
constexpr float DN = 0.35355339059327373f;   // 64^-0.25
constexpr float RATIO = 0.0625f;             // 256^-0.5
constexpr float EPSF = 1e-4f;

typedef __attribute__((ext_vector_type(8))) short short8;   // bf16 MFMA fragment
typedef __attribute__((ext_vector_type(4))) float f32x4;    // MFMA accumulator

// ---- workspace layout (byte offsets); proven budget >= 209,715,200 B ----
constexpr size_t OFF_H     = 0;              // fp32 residual 33,554,432
constexpr size_t OFF_YS    = 33554432;       // ysh (osh alias) 16,777,216 (+spare)
constexpr size_t OFF_QK    = 67108864;       // khi 16,777,216 | qhi 16,777,216
constexpr size_t OFF_BIG   = 100663296;      // kpT / qp / ffb / x-split 67,108,864
constexpr size_t OFF_VT    = 167772160;      // vT [32][80][4096] bf16 20,971,520
constexpr size_t OFF_CTXP  = 188743680;      // ctx partials [4][32][256][80] f32 10,485,760
constexpr size_t OFF_CTXTH = 199229440;      // ctxT hi [32][80][256] 1,310,720
constexpr size_t OFF_CTXTL = 200540160;      // ctxT lo 1,310,720
constexpr size_t OFF_DIAGQ = 201850880;      // 524,288
constexpr size_t OFF_DIAGK = 202375168;      // 524,288
constexpr size_t OFF_RKEY  = 202899456;      // 524,288
constexpr size_t OFF_GMAX  = 203423744;      // 256
constexpr size_t OFF_POOL  = 203424000;      // 131,072
constexpr size_t OFF_WQTH  = 203555072;
constexpr size_t OFF_WQTL  = 203686144;
constexpr size_t OFF_WKTH  = 203817216;
constexpr size_t OFF_WKTL  = 203948288;
constexpr size_t OFF_WVTH  = 204079360;
constexpr size_t OFF_WVTL  = 204210432;
constexpr size_t OFF_WOTH  = 204341504;
constexpr size_t OFF_WOTL  = 204472576;
constexpr size_t OFF_W1TH  = 204603648;      // 1,048,576
constexpr size_t OFF_W1TL  = 205652224;
constexpr size_t OFF_W2TH  = 206700800;      // 524,288
constexpr size_t OFF_W2TL  = 207225088;
constexpr size_t OFF_PMTH  = 207749376;
constexpr size_t OFF_PMTL  = 207782144;
constexpr size_t OFF_PWTH  = 207814912;
constexpr size_t OFF_PWTL  = 207847680;
constexpr size_t WS_BYTES  = 207880448;

__device__ __forceinline__ unsigned fkey(float f) {
    unsigned u = __float_as_uint(f);
    return (u & 0x80000000u) ? ~u : (u | 0x80000000u);
}
__device__ __forceinline__ float funkey(unsigned k) {
    unsigned u = (k & 0x80000000u) ? (k ^ 0x80000000u) : ~k;
    return __uint_as_float(u);
}
__device__ __forceinline__ float gelu_exact(float x) {
    return 0.5f * x * (1.0f + erff(x * 0.70710678118654752f));
}
__device__ __forceinline__ void splitf(float x, unsigned short& h, unsigned short& l) {
    unsigned u = __float_as_uint(x);
    unsigned hv = (u + 0x7FFFu + ((u >> 16) & 1)) >> 16;
    h = (unsigned short)hv;
    float lo = x - __uint_as_float(hv << 16);
    unsigned u2 = __float_as_uint(lo);
    l = (unsigned short)((u2 + 0x7FFFu + ((u2 >> 16) & 1)) >> 16);
}
__device__ __forceinline__ unsigned short bf16rne(float x) {
    unsigned u = __float_as_uint(x);
    return (unsigned short)((u + 0x7FFFu + ((u >> 16) & 1)) >> 16);
}
// XCD-aware block swizzle (requires total blocks % 8 == 0)
__device__ __forceinline__ void xcd_swz(int& bx, int& by) {
    const int gx = gridDim.x;
    const int total = gx * gridDim.y;
    int flat = blockIdx.y * gx + blockIdx.x;
    flat = (flat & 7) * (total >> 3) + (flat >> 3);
    bx = flat % gx; by = flat / gx;
}

// ---- async global->LDS 16B (wave-uniform base + lane*16, linear dest) ----
#if defined(__has_builtin)
#if __has_builtin(__builtin_amdgcn_global_load_lds)
#define HAVE_GLDS 1
#endif
#endif
__device__ __forceinline__ void glds16(const unsigned short* g, unsigned short* l) {
#ifdef HAVE_GLDS
    __builtin_amdgcn_global_load_lds(
        (const __attribute__((address_space(1))) unsigned int*)g,
        (__attribute__((address_space(3))) unsigned int*)l, 16, 0, 0);
#else
    *(uint4*)l = *(const uint4*)g;
#endif
}

__global__ void fill_sentinel(float* out, int n) {
    int i = threadIdx.x;
    if (i < n) out[i] = 12345.0f;
}
__global__ __launch_bounds__(256) void fill_keys(unsigned* __restrict__ rk, unsigned* __restrict__ gm) {
    int i = blockIdx.x * 256 + threadIdx.x;
    if (i < 131072) rk[i] = 0u;
    if (i == 0) gm[0] = 0u;
}
// fill vT rows 64..79: row 64 = 1.0 (ksum fold), rows 65..79 = 0
__global__ __launch_bounds__(256) void vt_init(unsigned short* __restrict__ vT) {
    int i = blockIdx.x * 256 + threadIdx.x;        // 262,144 uint4
    const int bh = i >> 13;
    const int r = (i >> 9) & 15;
    const unsigned val = (r == 0) ? 0x3F803F80u : 0u;
    uint4 q; q.x = val; q.y = val; q.z = val; q.w = val;
    *(uint4*)(vT + ((size_t)bh * 80 + 64 + r) * 4096 + ((size_t)(i & 511) << 3)) = q;
}

// ---- elementwise split (optional scale) ----
__global__ __launch_bounds__(256) void split_scale(
    const float* __restrict__ src, unsigned short* __restrict__ hi,
    unsigned short* __restrict__ lo, int n, float scale)
{
    int i = blockIdx.x * 256 + threadIdx.x;
    if (i < n) {
        unsigned short h, l;
        splitf(src[i] * scale, h, l);
        hi[i] = h; lo[i] = l;
    }
}

// ---- transpose-split weights: W [K,N] fp32 -> Wt hi/lo [N,K] bf16 ----
__global__ __launch_bounds__(256) void splitT(
    const float* __restrict__ W, unsigned short* __restrict__ hi,
    unsigned short* __restrict__ lo, int kshift, int N)
{
    int i = blockIdx.x * 256 + threadIdx.x;
    int K = 1 << kshift;
    int n = i >> kshift, k = i & (K - 1);
    unsigned short h, l;
    splitf(W[(size_t)k * N + n], h, l);
    hi[i] = h; lo[i] = l;
}

// ---- LayerNorm -> single bf16 plane ----
__global__ __launch_bounds__(256) void ln_bf16(
    const float* __restrict__ x, const float* __restrict__ g,
    const float* __restrict__ b, unsigned short* __restrict__ yhi)
{
    const int row = blockIdx.x * 4 + (threadIdx.x >> 6);
    const int lane = threadIdx.x & 63;
    float4 t = *(const float4*)&x[(size_t)row * 256 + lane * 4];
    float s = t.x + t.y + t.z + t.w;
#pragma unroll
    for (int sh = 1; sh < 64; sh <<= 1) s += __shfl_xor(s, sh);
    const float mu = s * (1.0f / 256.0f);
    const float dx = t.x - mu, dy = t.y - mu, dz = t.z - mu, dw = t.w - mu;
    float vv = dx * dx + dy * dy + dz * dz + dw * dw;
#pragma unroll
    for (int sh = 1; sh < 64; sh <<= 1) vv += __shfl_xor(vv, sh);
    const float rstd = rsqrtf(vv * (1.0f / 256.0f) + 1e-5f);
    float4 gv = *(const float4*)&g[lane * 4];
    float4 bv = *(const float4*)&b[lane * 4];
    unsigned short h0 = bf16rne(dx * rstd * gv.x + bv.x);
    unsigned short h1 = bf16rne(dy * rstd * gv.y + bv.y);
    unsigned short h2 = bf16rne(dz * rstd * gv.z + bv.z);
    unsigned short h3 = bf16rne(dw * rstd * gv.w + bv.w);
    uint2 ph;
    ph.x = (unsigned)h0 | ((unsigned)h1 << 16); ph.y = (unsigned)h2 | ((unsigned)h3 << 16);
    *(uint2*)&yhi[(size_t)row * 256 + lane * 4] = ph;
}

// ---- bf16 MFMA GEMM, tile 128x128, BK=32, 4 waves; gload_lds staging ----
// LDS planes: [128][32] shorts unpadded (4096 shorts each).
// EPI: 0 bias->f32 C | 1 bias(nullable)+res->f32 C | 2 bias->bf16 plane + per-head diag
//      4 global max -> keys[0] | 5 per-row max -> keys[row]
//      6 kp = exp epilogue + TRANSPOSED write to kpT[bh][m][n]
//      7 qp = exp per-row-max epilogue -> Obf[row*256+col]
//      8 bias -> bf16 TRANSPOSED write to vT[bh][d][n] (80-row planes)
template<int EPI, bool ASPLIT, bool BSPLIT>
__global__ __launch_bounds__(256) void gemm_mf(
    const unsigned short* __restrict__ Ahi, const unsigned short* __restrict__ Alo, int lda,
    const unsigned short* __restrict__ Bhi, const unsigned short* __restrict__ Blo, int ldb,
    int K,
    const float* __restrict__ bias, const float* __restrict__ res,
    float* __restrict__ C, int ldc,
    unsigned short* __restrict__ Obf,
    const float* __restrict__ diag, unsigned* __restrict__ keys)
{
    constexpr int NP = (ASPLIT ? 2 : 1) + (BSPLIT ? 2 : 1);
    constexpr int PB = ASPLIT ? 2 : 1;                 // B-hi plane index
    constexpr int NEED = (EPI == 6 || EPI == 8) ? 16384 : 0;
    constexpr int LDSN = (NP * 4096 > NEED) ? NP * 4096 : NEED;
    __shared__ unsigned short lds[LDSN];
    __shared__ float red[4];
#define LX(p, r, c) lds[(p) * 4096 + (r) * 32 + (c)]
    int bx, by; xcd_swz(bx, by);
    const int tid = threadIdx.x;
    const int m0 = by * 128, n0 = bx * 128;
    const int sr = tid >> 2, sc = (tid & 3) * 8;       // stage row / short col
    const unsigned short* ga_h = Ahi + (size_t)(m0 + sr) * lda + sc;
    const unsigned short* ga_l = ASPLIT ? (Alo + (size_t)(m0 + sr) * lda + sc) : nullptr;
    const unsigned short* gb_h = Bhi + (size_t)(n0 + sr) * ldb + sc;
    const unsigned short* gb_l = BSPLIT ? (Blo + (size_t)(n0 + sr) * ldb + sc) : nullptr;
    unsigned short* lp = lds + tid * 8;
    const int l = tid & 63, w = tid >> 6;
    const int wr = (w >> 1) * 64, wc = (w & 1) * 64;
    const int fr = l & 15, fq = l >> 4;

    f32x4 acc[4][4];
#pragma unroll
    for (int i = 0; i < 4; ++i)
#pragma unroll
        for (int j = 0; j < 4; ++j) acc[i][j] = (f32x4){0.f, 0.f, 0.f, 0.f};

    for (int k0 = 0; k0 < K; k0 += 32) {
        glds16(ga_h + k0, lp);
        glds16(ga_h + (size_t)64 * lda + k0, lp + 2048);
        if (ASPLIT) {
            glds16(ga_l + k0, lp + 4096);
            glds16(ga_l + (size_t)64 * lda + k0, lp + 6144);
        }
        glds16(gb_h + k0, lp + PB * 4096);
        glds16(gb_h + (size_t)64 * ldb + k0, lp + PB * 4096 + 2048);
        if (BSPLIT) {
            glds16(gb_l + k0, lp + (PB + 1) * 4096);
            glds16(gb_l + (size_t)64 * ldb + k0, lp + (PB + 1) * 4096 + 2048);
        }
        __syncthreads();
        short8 ah[4], al[4];
#pragma unroll
        for (int mf = 0; mf < 4; ++mf) {
            ah[mf] = *(const short8*)&LX(0, wr + mf * 16 + fr, fq * 8);
            if (ASPLIT) al[mf] = *(const short8*)&LX(1, wr + mf * 16 + fr, fq * 8);
        }
#pragma unroll
        for (int nf = 0; nf < 4; ++nf) {
            short8 bh = *(const short8*)&LX(PB, wc + nf * 16 + fr, fq * 8);
#pragma unroll
            for (int mf = 0; mf < 4; ++mf) {
                acc[mf][nf] = __builtin_amdgcn_mfma_f32_16x16x32_bf16(ah[mf], bh, acc[mf][nf], 0, 0, 0);
                if (ASPLIT)
                    acc[mf][nf] = __builtin_amdgcn_mfma_f32_16x16x32_bf16(al[mf], bh, acc[mf][nf], 0, 0, 0);
            }
            if (BSPLIT) {
                short8 bl = *(const short8*)&LX(PB + 1, wc + nf * 16 + fr, fq * 8);
#pragma unroll
                for (int mf = 0; mf < 4; ++mf)
                    acc[mf][nf] = __builtin_amdgcn_mfma_f32_16x16x32_bf16(ah[mf], bl, acc[mf][nf], 0, 0, 0);
            }
        }
        __syncthreads();
    }

    if constexpr (EPI == 4) {
        float m = -3.4e38f;
#pragma unroll
        for (int mf = 0; mf < 4; ++mf)
#pragma unroll
            for (int nf = 0; nf < 4; ++nf)
#pragma unroll
                for (int v = 0; v < 4; ++v) m = fmaxf(m, acc[mf][nf][v]);
#pragma unroll
        for (int s = 1; s < 64; s <<= 1) m = fmaxf(m, __shfl_xor(m, s));
        if (l == 0) red[w] = m;
        __syncthreads();
        if (tid == 0)
            atomicMax(keys, fkey(fmaxf(fmaxf(red[0], red[1]), fmaxf(red[2], red[3]))));
    } else if constexpr (EPI == 5) {
#pragma unroll
        for (int mf = 0; mf < 4; ++mf)
#pragma unroll
            for (int v = 0; v < 4; ++v) {
                float rm = fmaxf(fmaxf(acc[mf][0][v], acc[mf][1][v]),
                                 fmaxf(acc[mf][2][v], acc[mf][3][v]));
                rm = fmaxf(rm, __shfl_xor(rm, 1));
                rm = fmaxf(rm, __shfl_xor(rm, 2));
                rm = fmaxf(rm, __shfl_xor(rm, 4));
                rm = fmaxf(rm, __shfl_xor(rm, 8));
                if (fr == 0) atomicMax(&keys[m0 + wr + mf * 16 + fq * 4 + v], fkey(rm));
            }
    } else if constexpr (EPI == 6) {
        const float Mg = funkey(*keys);
        unsigned short* tb = lds;
#pragma unroll
        for (int mf = 0; mf < 4; ++mf)
#pragma unroll
            for (int v = 0; v < 4; ++v) {
                const int rl = wr + mf * 16 + fq * 4 + v;
                const float dg = diag[m0 + rl] + Mg;
#pragma unroll
                for (int nf = 0; nf < 4; ++nf) {
                    const int cl = wc + nf * 16 + fr;
                    tb[rl * 128 + cl] = bf16rne(RATIO * (expf(acc[mf][nf][v] - dg) + EPSF));
                }
            }
        __syncthreads();
        const int tokbase = m0 >> 2;
        const int b = tokbase >> 12, nib = tokbase & 4095;
        const int ml = tid & 127, g2 = tid >> 7;
#pragma unroll
        for (int hh2 = 0; hh2 < 2; ++hh2) {
            const int hh = g2 * 2 + hh2;
            unsigned short* dst = Obf + ((size_t)((b * 4 + hh) * 256 + n0 + ml)) * 4096 + nib;
#pragma unroll
            for (int qq = 0; qq < 4; ++qq) {
                uint4 qv;
                unsigned wv[4];
#pragma unroll
                for (int j = 0; j < 4; ++j) {
                    unsigned s0 = tb[((qq * 8 + j * 2 + 0) * 4 + hh) * 128 + ml];
                    unsigned s1 = tb[((qq * 8 + j * 2 + 1) * 4 + hh) * 128 + ml];
                    wv[j] = s0 | (s1 << 16);
                }
                qv.x = wv[0]; qv.y = wv[1]; qv.z = wv[2]; qv.w = wv[3];
                *(uint4*)(dst + qq * 8) = qv;
            }
        }
    } else if constexpr (EPI == 7) {
#pragma unroll
        for (int mf = 0; mf < 4; ++mf) {
#pragma unroll
            for (int v = 0; v < 4; ++v) {
                const int row = m0 + wr + mf * 16 + fq * 4 + v;
                const float dg = diag[row] + funkey(keys[row]);
#pragma unroll
                for (int nf = 0; nf < 4; ++nf) {
                    const int col = n0 + wc + nf * 16 + fr;
                    Obf[(size_t)row * 256 + col] = bf16rne(RATIO * (expf(acc[mf][nf][v] - dg) + EPSF));
                }
            }
        }
    } else if constexpr (EPI == 8) {
        unsigned short* tb = lds;
#pragma unroll
        for (int mf = 0; mf < 4; ++mf)
#pragma unroll
            for (int nf = 0; nf < 4; ++nf) {
                const int cl = wc + nf * 16 + fr;
                const float bb = bias[n0 + cl];
#pragma unroll
                for (int v = 0; v < 4; ++v) {
                    const int rl = wr + mf * 16 + fq * 4 + v;
                    tb[rl * 128 + cl] = bf16rne(acc[mf][nf][v] + bb);
                }
            }
        __syncthreads();
        const int b = m0 >> 12, nib = m0 & 4095;
        const int cl = tid & 127, half = tid >> 7;
        const int ch = n0 + cl, hh = ch >> 6, d = ch & 63;
        unsigned short* dst = Obf + ((size_t)((b * 4 + hh) * 80 + d)) * 4096 + nib + half * 64;
#pragma unroll
        for (int qq = 0; qq < 8; ++qq) {
            uint4 qv;
            unsigned wv[4];
#pragma unroll
            for (int j = 0; j < 4; ++j) {
                unsigned s0 = tb[(half * 64 + qq * 8 + j * 2 + 0) * 128 + cl];
                unsigned s1 = tb[(half * 64 + qq * 8 + j * 2 + 1) * 128 + cl];
                wv[j] = s0 | (s1 << 16);
            }
            qv.x = wv[0]; qv.y = wv[1]; qv.z = wv[2]; qv.w = wv[3];
            *(uint4*)(dst + qq * 8) = qv;
        }
    } else if constexpr (EPI == 2) {
        const int head = (n0 + wc) >> 6;
#pragma unroll
        for (int mf = 0; mf < 4; ++mf) {
            float sq[4] = {0.f, 0.f, 0.f, 0.f};
#pragma unroll
            for (int nf = 0; nf < 4; ++nf) {
                const int col = n0 + wc + nf * 16 + fr;
                const float bb = bias[col];
#pragma unroll
                for (int v = 0; v < 4; ++v) {
                    const int row = m0 + wr + mf * 16 + fq * 4 + v;
                    float val = acc[mf][nf][v] + bb;
                    Obf[(size_t)row * 256 + col] = bf16rne(val);
                    sq[v] += val * val;
                }
            }
#pragma unroll
            for (int v = 0; v < 4; ++v) {
                float s = sq[v];
                s += __shfl_xor(s, 1); s += __shfl_xor(s, 2);
                s += __shfl_xor(s, 4); s += __shfl_xor(s, 8);
                if (fr == 0)
                    ((float*)diag)[(size_t)(m0 + wr + mf * 16 + fq * 4 + v) * 4 + head] = s * 0.0625f;
            }
        }
    } else {
#pragma unroll
        for (int nf = 0; nf < 4; ++nf) {
            const int col = n0 + wc + nf * 16 + fr;
            float bb = 0.f;
            if (bias != nullptr) bb = bias[col];
#pragma unroll
            for (int mf = 0; mf < 4; ++mf) {
#pragma unroll
                for (int v = 0; v < 4; ++v) {
                    const int row = m0 + wr + mf * 16 + fq * 4 + v;
                    const size_t off = (size_t)row * ldc + col;
                    float val = acc[mf][nf][v] + bb;
                    if (EPI == 1) val += res[off];
                    C[off] = val;
                }
            }
        }
    }
#undef LX
}

// ---- fused GLU GEMM: A single bf16 plane, W split -> 4 MFMA/site; gload_lds ----
__global__ __launch_bounds__(256) void gemm_glu(
    const unsigned short* __restrict__ Ahi,
    const unsigned short* __restrict__ Whi, const unsigned short* __restrict__ Wlo,
    const float* __restrict__ b1, unsigned short* __restrict__ Obf)
{
    __shared__ unsigned short ldsA[4096];      // [128][32]
    __shared__ unsigned short ldsB[8192];      // 4 planes x [64][32]
    int bx, by; xcd_swz(bx, by);
    const int tid = threadIdx.x;
    const int m0 = by * 128, p0 = bx * 64;
    const int sr = tid >> 2, sc = (tid & 3) * 8;
    const unsigned short* ga  = Ahi + (size_t)(m0 + sr) * 256 + sc;
    const unsigned short* gb0 = Whi + (size_t)(p0 + sr) * 256 + sc;
    const unsigned short* gb1 = Wlo + (size_t)(p0 + sr) * 256 + sc;
    const unsigned short* gb2 = Whi + (size_t)(1024 + p0 + sr) * 256 + sc;
    const unsigned short* gb3 = Wlo + (size_t)(1024 + p0 + sr) * 256 + sc;
    unsigned short* lpA = ldsA + tid * 8;
    unsigned short* lpB = ldsB + tid * 8;
    const int l = tid & 63, w = tid >> 6;
    const int wr = (w >> 1) * 64, wc = (w & 1) * 32;
    const int fr = l & 15, fq = l >> 4;

    f32x4 aa[4][2], ag[4][2];
#pragma unroll
    for (int i = 0; i < 4; ++i)
#pragma unroll
        for (int j = 0; j < 2; ++j) {
            aa[i][j] = (f32x4){0.f, 0.f, 0.f, 0.f};
            ag[i][j] = (f32x4){0.f, 0.f, 0.f, 0.f};
        }

    for (int k0 = 0; k0 < 256; k0 += 32) {
        glds16(ga + k0, lpA);
        glds16(ga + 64 * 256 + k0, lpA + 2048);
        glds16(gb0 + k0, lpB);
        glds16(gb1 + k0, lpB + 2048);
        glds16(gb2 + k0, lpB + 4096);
        glds16(gb3 + k0, lpB + 6144);
        __syncthreads();
        short8 ah[4];
#pragma unroll
        for (int mf = 0; mf < 4; ++mf)
            ah[mf] = *(const short8*)&ldsA[(wr + mf * 16 + fr) * 32 + fq * 8];
#pragma unroll
        for (int nf = 0; nf < 2; ++nf) {
            const int br_ = (wc + nf * 16 + fr) * 32 + fq * 8;
            short8 bah = *(const short8*)&ldsB[br_];
            short8 bal = *(const short8*)&ldsB[2048 + br_];
            short8 bgh = *(const short8*)&ldsB[4096 + br_];
            short8 bgl = *(const short8*)&ldsB[6144 + br_];
#pragma unroll
            for (int mf = 0; mf < 4; ++mf) {
                aa[mf][nf] = __builtin_amdgcn_mfma_f32_16x16x32_bf16(ah[mf], bah, aa[mf][nf], 0, 0, 0);
                aa[mf][nf] = __builtin_amdgcn_mfma_f32_16x16x32_bf16(ah[mf], bal, aa[mf][nf], 0, 0, 0);
                ag[mf][nf] = __builtin_amdgcn_mfma_f32_16x16x32_bf16(ah[mf], bgh, ag[mf][nf], 0, 0, 0);
                ag[mf][nf] = __builtin_amdgcn_mfma_f32_16x16x32_bf16(ah[mf], bgl, ag[mf][nf], 0, 0, 0);
            }
        }
        __syncthreads();
    }
#pragma unroll
    for (int nf = 0; nf < 2; ++nf) {
        const int ch = p0 + wc + nf * 16 + fr;
        const float ba = b1[ch], bg = b1[1024 + ch];
#pragma unroll
        for (int mf = 0; mf < 4; ++mf) {
#pragma unroll
            for (int v = 0; v < 4; ++v) {
                const int row = m0 + wr + mf * 16 + fq * 4 + v;
                float u = aa[mf][nf][v] + ba, g = ag[mf][nf][v] + bg;
                Obf[(size_t)row * 1024 + ch] = bf16rne(gelu_exact(u) * g);
            }
        }
    }
}

// ---- ctx GEMM: 64-row x 80-col tile, K-chunk 1024; grid (16,32); gload_lds ----
__global__ __launch_bounds__(256) void ctx_mfma(
    const unsigned short* __restrict__ kpT, const unsigned short* __restrict__ vT,
    float* __restrict__ ctxp)
{
    __shared__ unsigned short la[2048];        // [64][32]
    __shared__ unsigned short lb[2560];        // [80][32]
    int bx, by; xcd_swz(bx, by);
    const int bh = by, mt = bx & 3, kc = bx >> 2;
    const int tid = threadIdx.x;
    const int l = tid & 63, w = tid >> 6;
    const int wr = w * 16, fr = l & 15, fq = l >> 4;
    const int sr = tid >> 2, sc = (tid & 3) * 8;
    const unsigned short* ga  = kpT + ((size_t)bh * 256 + mt * 64 + sr) * 4096 + kc * 1024 + sc;
    const unsigned short* gb  = vT + ((size_t)bh * 80 + sr) * 4096 + kc * 1024 + sc;
    const unsigned short* gb2 = vT + ((size_t)bh * 80 + 64 + sr) * 4096 + kc * 1024 + sc;

    f32x4 acc[5];
#pragma unroll
    for (int j = 0; j < 5; ++j) acc[j] = (f32x4){0.f, 0.f, 0.f, 0.f};

    for (int k0 = 0; k0 < 1024; k0 += 32) {
        glds16(ga + k0, la + tid * 8);
        glds16(gb + k0, lb + tid * 8);
        if (tid < 64) glds16(gb2 + k0, lb + 2048 + tid * 8);
        __syncthreads();
        short8 av = *(const short8*)&la[(wr + fr) * 32 + fq * 8];
#pragma unroll
        for (int nf = 0; nf < 5; ++nf) {
            short8 bv = *(const short8*)&lb[(nf * 16 + fr) * 32 + fq * 8];
            acc[nf] = __builtin_amdgcn_mfma_f32_16x16x32_bf16(av, bv, acc[nf], 0, 0, 0);
        }
        __syncthreads();
    }
#pragma unroll
    for (int v = 0; v < 4; ++v) {
        const int row = mt * 64 + wr + fq * 4 + v;
#pragma unroll
        for (int nf = 0; nf < 5; ++nf)
            ctxp[((size_t)(kc * 32 + bh) * 256 + row) * 80 + nf * 16 + fr] = acc[nf][v];
    }
}

// ---- reduce ctx partials over 4 k-chunks, transpose, split -> ctxT[bh][80][256] ----
__global__ __launch_bounds__(256) void ctx_fix(
    const float* __restrict__ ctxp, unsigned short* __restrict__ cth,
    unsigned short* __restrict__ ctl)
{
    __shared__ float s[64][81];
    const int m0 = blockIdx.x * 64, bh = blockIdx.y;
    const int tid = threadIdx.x;
    for (int i = tid; i < 5120; i += 256) {
        const int ml = i / 80, dc = i % 80;
        float sum = 0.f;
#pragma unroll
        for (int kc = 0; kc < 4; ++kc)
            sum += ctxp[((size_t)(kc * 32 + bh) * 256 + m0 + ml) * 80 + dc];
        s[ml][dc] = sum;
    }
    __syncthreads();
    for (int i = tid; i < 5120; i += 256) {
        const int dc = i >> 6, ml = i & 63;
        unsigned short hh_, ll_;
        splitf(s[ml][dc], hh_, ll_);
        cth[((size_t)bh * 80 + dc) * 256 + m0 + ml] = hh_;
        ctl[((size_t)bh * 80 + dc) * 256 + m0 + ml] = ll_;
    }
}

// ---- o = (qp @ ctx)/(qp . ksum) via MFMA; N=80 (col 64 = ksum); gload_lds ----
__global__ __launch_bounds__(256) void o_mfma(
    const unsigned short* __restrict__ qp,
    const unsigned short* __restrict__ cth, const unsigned short* __restrict__ ctl,
    unsigned short* __restrict__ osh)
{
    __shared__ unsigned short la[8192];        // [256][32]
    __shared__ unsigned short lb[5120];        // 2 planes x [80][32]
    int bx, by; xcd_swz(bx, by);
    const int bh = by, b = bh >> 2, hh = bh & 3;
    const int r0 = bx * 256;
    const int tid = threadIdx.x;
    const int l = tid & 63, w = tid >> 6;
    const int wr = w * 64, fr = l & 15, fq = l >> 4;
    const size_t abase = ((size_t)(b * 4096 + r0) * 4 + hh) * 256;
    const size_t bbase = (size_t)bh * 80 * 256;
    const int sr = tid >> 2, sc = (tid & 3) * 8;
    const unsigned short* gq   = qp + abase + (size_t)sr * 1024 + sc;
    const unsigned short* gbh  = cth + bbase + (size_t)sr * 256 + sc;
    const unsigned short* gbh2 = cth + bbase + (size_t)(64 + sr) * 256 + sc;
    const unsigned short* gbl  = ctl + bbase + (size_t)sr * 256 + sc;
    const unsigned short* gbl2 = ctl + bbase + (size_t)(64 + sr) * 256 + sc;

    f32x4 acc[4][5];
#pragma unroll
    for (int i = 0; i < 4; ++i)
#pragma unroll
        for (int j = 0; j < 5; ++j) acc[i][j] = (f32x4){0.f, 0.f, 0.f, 0.f};

    for (int k0 = 0; k0 < 256; k0 += 32) {
        glds16(gq + k0, la + tid * 8);
        glds16(gq + (size_t)64 * 1024 + k0, la + 2048 + tid * 8);
        glds16(gq + (size_t)128 * 1024 + k0, la + 4096 + tid * 8);
        glds16(gq + (size_t)192 * 1024 + k0, la + 6144 + tid * 8);
        glds16(gbh + k0, lb + tid * 8);
        glds16(gbl + k0, lb + 2560 + tid * 8);
        if (tid < 64) {
            glds16(gbh2 + k0, lb + 2048 + tid * 8);
            glds16(gbl2 + k0, lb + 2560 + 2048 + tid * 8);
        }
        __syncthreads();
        short8 av[4];
#pragma unroll
        for (int mf = 0; mf < 4; ++mf)
            av[mf] = *(const short8*)&la[(wr + mf * 16 + fr) * 32 + fq * 8];
#pragma unroll
        for (int nf = 0; nf < 5; ++nf) {
            const int off = (nf * 16 + fr) * 32 + fq * 8;
            short8 bvh = *(const short8*)&lb[off];
            short8 bvl = *(const short8*)&lb[2560 + off];
#pragma unroll
            for (int mf = 0; mf < 4; ++mf) {
                acc[mf][nf] = __builtin_amdgcn_mfma_f32_16x16x32_bf16(av[mf], bvh, acc[mf][nf], 0, 0, 0);
                acc[mf][nf] = __builtin_amdgcn_mfma_f32_16x16x32_bf16(av[mf], bvl, acc[mf][nf], 0, 0, 0);
            }
        }
        __syncthreads();
    }
#pragma unroll
    for (int mf = 0; mf < 4; ++mf)
#pragma unroll
        for (int v = 0; v < 4; ++v) {
            const float den = __shfl(acc[mf][4][v], (int)(l & 48));
            const float dinv = 1.0f / den;
            const int r = r0 + wr + mf * 16 + fq * 4 + v;
            const size_t obase = (size_t)(b * 4096 + r) * 256 + hh * 64;
#pragma unroll
            for (int nf = 0; nf < 4; ++nf)
                osh[obase + nf * 16 + fr] = bf16rne(acc[mf][nf][v] * dinv);
        }
}

// ---- pooling + classifier ----
__global__ __launch_bounds__(256) void pool1_kernel(const float* __restrict__ h, float* __restrict__ part)
{
    const int b = blockIdx.x >> 4, ch = blockIdx.x & 15;
    const int tid = threadIdx.x;
    float acc = 0.f;
    for (int n = 0; n < 256; ++n)
        acc += h[((size_t)(b * 4096 + ch * 256 + n)) * 256 + tid];
    part[(size_t)blockIdx.x * 256 + tid] = acc;
}

__global__ __launch_bounds__(256) void pool2_kernel(
    const float* __restrict__ part, const float* __restrict__ cw,
    const float* __restrict__ cb, float* __restrict__ out)
{
    const int b = blockIdx.x, tid = threadIdx.x;
    float acc = 0.f;
#pragma unroll
    for (int c = 0; c < 16; ++c) acc += part[(size_t)(b * 16 + c) * 256 + tid];
    float val = acc * (1.0f / 4096.0f) * cw[tid];
#pragma unroll
    for (int s = 1; s < 64; s <<= 1) val += __shfl_xor(val, s);
    __shared__ float red[4];
    if ((tid & 63) == 0) red[tid >> 6] = val;
    __syncthreads();
    if (tid == 0) out[b] = red[0] + red[1] + red[2] + red[3] + cb[0];
}

extern "C" void kernel_launch(void* const* d_in, const int* in_sizes, int n_in,
                              void* d_out, int out_size, void* d_ws, size_t ws_size,
                              hipStream_t stream)
{
    (void)in_sizes; (void)n_in;
    if (ws_size < WS_BYTES) {
        fill_sentinel<<<1, 64, 0, stream>>>((float*)d_out, out_size);
        return;
    }

    const float* x     = (const float*)d_in[0];
    const float* projw = (const float*)d_in[1];
    const float* projb = (const float*)d_in[2];
    const float* ln1g  = (const float*)d_in[3];
    const float* ln1b  = (const float*)d_in[4];
    const float* wq    = (const float*)d_in[5];
    const float* bq    = (const float*)d_in[6];
    const float* wk    = (const float*)d_in[7];
    const float* bk    = (const float*)d_in[8];
    const float* wv    = (const float*)d_in[9];
    const float* bv    = (const float*)d_in[10];
    const float* wo    = (const float*)d_in[11];
    const float* bo    = (const float*)d_in[12];
    const float* ln2g  = (const float*)d_in[13];
    const float* ln2b  = (const float*)d_in[14];
    const float* w1    = (const float*)d_in[15];
    const float* b1    = (const float*)d_in[16];
    const float* w2    = (const float*)d_in[17];
    const float* b2    = (const float*)d_in[18];
    const float* clfw  = (const float*)d_in[19];
    const float* clfb  = (const float*)d_in[20];
    const float* projm = (const float*)d_in[21];

    char* WS = (char*)d_ws;
    float* h            = (float*)(WS + OFF_H);
    unsigned short* ysh = (unsigned short*)(WS + OFF_YS);
    unsigned short* khi = (unsigned short*)(WS + OFF_QK);
    unsigned short* qhi = khi + 8388608;
    unsigned short* big = (unsigned short*)(WS + OFF_BIG);   // kpT / qp / ffb
    unsigned short* vT  = (unsigned short*)(WS + OFF_VT);
    float* ctxp         = (float*)(WS + OFF_CTXP);
    unsigned short* cth = (unsigned short*)(WS + OFF_CTXTH);
    unsigned short* ctl = (unsigned short*)(WS + OFF_CTXTL);
    float* diagq        = (float*)(WS + OFF_DIAGQ);
    float* diagk        = (float*)(WS + OFF_DIAGK);
    unsigned* rkeys     = (unsigned*)(WS + OFF_RKEY);
    unsigned* gmax      = (unsigned*)(WS + OFF_GMAX);
    float* pool         = (float*)(WS + OFF_POOL);
    unsigned short* wqt_h = (unsigned short*)(WS + OFF_WQTH);
    unsigned short* wqt_l = (unsigned short*)(WS + OFF_WQTL);
    unsigned short* wkt_h = (unsigned short*)(WS + OFF_WKTH);
    unsigned short* wkt_l = (unsigned short*)(WS + OFF_WKTL);
    unsigned short* wvt_h = (unsigned short*)(WS + OFF_WVTH);
    unsigned short* wvt_l = (unsigned short*)(WS + OFF_WVTL);
    unsigned short* wot_h = (unsigned short*)(WS + OFF_WOTH);
    unsigned short* wot_l = (unsigned short*)(WS + OFF_WOTL);
    unsigned short* w1t_h = (unsigned short*)(WS + OFF_W1TH);
    unsigned short* w1t_l = (unsigned short*)(WS + OFF_W1TL);
    unsigned short* w2t_h = (unsigned short*)(WS + OFF_W2TH);
    unsigned short* w2t_l = (unsigned short*)(WS + OFF_W2TL);
    unsigned short* pmt_h = (unsigned short*)(WS + OFF_PMTH);
    unsigned short* pmt_l = (unsigned short*)(WS + OFF_PMTL);
    unsigned short* pwt_h = (unsigned short*)(WS + OFF_PWTH);
    unsigned short* pwt_l = (unsigned short*)(WS + OFF_PWTL);
    // aliases
    unsigned short* xsh = big;               // prologue only
    unsigned short* xsl = big + 2097152;
    unsigned short* kpT = big;               // [32][256][4096]
    unsigned short* qp  = big;               // [131072][256]
    unsigned short* ffb = big;               // [32768][1024]
    unsigned short* osh = ysh;               // o bf16 (ys dead by then)

    // ---- prologue ----
    split_scale<<<8192, 256, 0, stream>>>(x, xsh, xsl, 2097152, 1.0f);
    splitT<<<64, 256, 0, stream>>>(projw, pwt_h, pwt_l, 6, 256);
    split_scale<<<64, 256, 0, stream>>>(projm, pmt_h, pmt_l, 16384, DN);
    vt_init<<<1024, 256, 0, stream>>>(vT);
    gemm_mf<0, true, true><<<dim3(2, 256), 256, 0, stream>>>(xsh, xsl, 64, pwt_h, pwt_l, 64, 64,
        projb, nullptr, h, 256, nullptr, nullptr, nullptr);

    for (int l = 0; l < 4; ++l) {
        splitT<<<256, 256, 0, stream>>>(wq + (size_t)l * 65536, wqt_h, wqt_l, 8, 256);
        splitT<<<256, 256, 0, stream>>>(wk + (size_t)l * 65536, wkt_h, wkt_l, 8, 256);
        splitT<<<256, 256, 0, stream>>>(wv + (size_t)l * 65536, wvt_h, wvt_l, 8, 256);
        splitT<<<256, 256, 0, stream>>>(wo + (size_t)l * 65536, wot_h, wot_l, 8, 256);
        splitT<<<2048, 256, 0, stream>>>(w1 + (size_t)l * 524288, w1t_h, w1t_l, 8, 2048);
        splitT<<<1024, 256, 0, stream>>>(w2 + (size_t)l * 262144, w2t_h, w2t_l, 10, 256);

        // ---- attention ----
        ln_bf16<<<8192, 256, 0, stream>>>(h, ln1g + l * 256, ln1b + l * 256, ysh);
        gemm_mf<8, false, true><<<dim3(2, 256), 256, 0, stream>>>(ysh, nullptr, 256,
            wvt_h, wvt_l, 256, 256, bv + l * 256, nullptr, nullptr, 256, vT, nullptr, nullptr);
        gemm_mf<2, false, true><<<dim3(2, 256), 256, 0, stream>>>(ysh, nullptr, 256,
            wkt_h, wkt_l, 256, 256, bk + l * 256, nullptr, nullptr, 256, khi, diagk, nullptr);
        gemm_mf<2, false, true><<<dim3(2, 256), 256, 0, stream>>>(ysh, nullptr, 256,
            wqt_h, wqt_l, 256, 256, bq + l * 256, nullptr, nullptr, 256, qhi, diagq, nullptr);
        fill_keys<<<512, 256, 0, stream>>>(rkeys, gmax);
        gemm_mf<4, false, false><<<dim3(2, 1024), 256, 0, stream>>>(khi, nullptr, 64,
            pmt_h, nullptr, 64, 64, nullptr, nullptr, nullptr, 256, nullptr, nullptr, gmax);
        gemm_mf<5, false, false><<<dim3(2, 1024), 256, 0, stream>>>(qhi, nullptr, 64,
            pmt_h, nullptr, 64, 64, nullptr, nullptr, nullptr, 256, nullptr, nullptr, rkeys);
        gemm_mf<6, false, true><<<dim3(2, 1024), 256, 0, stream>>>(khi, nullptr, 64,
            pmt_h, pmt_l, 64, 64, nullptr, nullptr, nullptr, 256, kpT, diagk, gmax);
        ctx_mfma<<<dim3(16, 32), 256, 0, stream>>>(kpT, vT, ctxp);
        ctx_fix<<<dim3(4, 32), 256, 0, stream>>>(ctxp, cth, ctl);
        gemm_mf<7, false, true><<<dim3(2, 1024), 256, 0, stream>>>(qhi, nullptr, 64,
            pmt_h, pmt_l, 64, 64, nullptr, nullptr, nullptr, 256, qp, diagq, rkeys);
        o_mfma<<<dim3(16, 32), 256, 0, stream>>>(qp, cth, ctl, osh);
        gemm_mf<1, false, true><<<dim3(2, 256), 256, 0, stream>>>(osh, nullptr, 256,
            wot_h, wot_l, 256, 256, bo + l * 256, h, h, 256, nullptr, nullptr, nullptr);

        // ---- feed-forward ----
        ln_bf16<<<8192, 256, 0, stream>>>(h, ln2g + l * 256, ln2b + l * 256, ysh);
        gemm_glu<<<dim3(16, 256), 256, 0, stream>>>(ysh, w1t_h, w1t_l,
            b1 + (size_t)l * 2048, ffb);
        gemm_mf<1, false, true><<<dim3(2, 256), 256, 0, stream>>>(ffb, nullptr, 1024,
            w2t_h, w2t_l, 1024, 1024, b2 + l * 256, h, h, 256, nullptr, nullptr, nullptr);
    }

    pool1_kernel<<<128, 256, 0, stream>>>(h, pool);
    pool2_kernel<<<8, 256, 0, stream>>>(pool, clfw, clfb, (float*)d_out);
}

// Round 8
// 1604.595 us; speedup vs baseline: 7.4785x; 1.0276x over previous
//
#include <hip/hip_runtime.h>
#include <cstdint>
#include <cstddef>

// ---- problem constants ----
constexpr float DN = 0.35355339059327373f;   // 64^-0.25
constexpr float RATIO = 0.0625f;             // 256^-0.5
constexpr float EPSF = 1e-4f;

typedef __attribute__((ext_vector_type(8))) short short8;   // bf16 MFMA fragment
typedef __attribute__((ext_vector_type(4))) float f32x4;    // MFMA accumulator

// ---- workspace layout (byte offsets); proven budget >= 209,715,200 B ----
constexpr size_t OFF_H     = 0;              // fp32 residual 33,554,432
constexpr size_t OFF_YS    = 33554432;       // ysh (osh alias) 16,777,216
constexpr size_t OFF_WTS   = 50331648;       // all-layer weight splits 16,777,216
constexpr size_t OFF_QK    = 67108864;       // khi 16,777,216 | qhi 16,777,216
constexpr size_t OFF_BIG   = 100663296;      // kpT / ffb / x-split 67,108,864
constexpr size_t OFF_VT    = 167772160;      // vT [32][80][4096] bf16 20,971,520
constexpr size_t OFF_CTXP  = 188743680;      // ctx partials [4][32][256][80] f32 10,485,760
constexpr size_t OFF_CTXTH = 199229440;      // ctxT hi [32][80][256] 1,310,720
constexpr size_t OFF_CTXTL = 200540160;      // ctxT lo 1,310,720
constexpr size_t OFF_DIAGQ = 201850880;      // 524,288
constexpr size_t OFF_DIAGK = 202375168;      // 524,288
constexpr size_t OFF_GMAX  = 203423744;      // 256 (4 per-layer slots used)
constexpr size_t OFF_POOL  = 203424000;      // 131,072
constexpr size_t OFF_PMTH  = 207749376;
constexpr size_t OFF_PMTL  = 207782144;
constexpr size_t OFF_PWTH  = 207814912;
constexpr size_t OFF_PWTL  = 207847680;
constexpr size_t WS_BYTES  = 207880448;

// per-layer short-offsets inside the WTS region (layer stride 2,097,152 shorts)
constexpr size_t WQ_H = 0,       WQ_L = 65536;
constexpr size_t WK_H = 131072,  WK_L = 196608;
constexpr size_t WV_H = 262144,  WV_L = 327680;
constexpr size_t WO_H = 393216,  WO_L = 458752;
constexpr size_t W1_H = 524288,  W1_L = 1048576;
constexpr size_t W2_H = 1572864, W2_L = 1835008;

__device__ __forceinline__ unsigned fkey(float f) {
    unsigned u = __float_as_uint(f);
    return (u & 0x80000000u) ? ~u : (u | 0x80000000u);
}
__device__ __forceinline__ float funkey(unsigned k) {
    unsigned u = (k & 0x80000000u) ? (k ^ 0x80000000u) : ~k;
    return __uint_as_float(u);
}
__device__ __forceinline__ float gelu_exact(float x) {
    return 0.5f * x * (1.0f + erff(x * 0.70710678118654752f));
}
__device__ __forceinline__ void splitf(float x, unsigned short& h, unsigned short& l) {
    unsigned u = __float_as_uint(x);
    unsigned hv = (u + 0x7FFFu + ((u >> 16) & 1)) >> 16;
    h = (unsigned short)hv;
    float lo = x - __uint_as_float(hv << 16);
    unsigned u2 = __float_as_uint(lo);
    l = (unsigned short)((u2 + 0x7FFFu + ((u2 >> 16) & 1)) >> 16);
}
__device__ __forceinline__ unsigned short bf16rne(float x) {
    unsigned u = __float_as_uint(x);
    return (unsigned short)((u + 0x7FFFu + ((u >> 16) & 1)) >> 16);
}
// XCD-aware block swizzle (requires total blocks % 8 == 0)
__device__ __forceinline__ void xcd_swz(int& bx, int& by) {
    const int gx = gridDim.x;
    const int total = gx * gridDim.y;
    int flat = blockIdx.y * gx + blockIdx.x;
    flat = (flat & 7) * (total >> 3) + (flat >> 3);
    bx = flat % gx; by = flat / gx;
}

// ---- async global->LDS 16B (wave-uniform base + lane*16, linear dest) ----
#if defined(__has_builtin)
#if __has_builtin(__builtin_amdgcn_global_load_lds)
#define HAVE_GLDS 1
#endif
#endif
__device__ __forceinline__ void glds16(const unsigned short* g, unsigned short* l) {
#ifdef HAVE_GLDS
    __builtin_amdgcn_global_load_lds(
        (const __attribute__((address_space(1))) unsigned int*)g,
        (__attribute__((address_space(3))) unsigned int*)l, 16, 0, 0);
#else
    *(uint4*)l = *(const uint4*)g;
#endif
}

__global__ void fill_sentinel(float* out, int n) {
    int i = threadIdx.x;
    if (i < n) out[i] = 12345.0f;
}
// fill vT rows 64..79 (row 64 = 1.0 for ksum fold) + zero per-layer gmax keys
__global__ __launch_bounds__(256) void vt_init(unsigned short* __restrict__ vT, unsigned* __restrict__ gm) {
    int i = blockIdx.x * 256 + threadIdx.x;        // 262,144 uint4
    if (i < 4) gm[i] = 0u;
    const int bh = i >> 13;
    const int r = (i >> 9) & 15;
    const unsigned val = (r == 0) ? 0x3F803F80u : 0u;
    uint4 q; q.x = val; q.y = val; q.z = val; q.w = val;
    *(uint4*)(vT + ((size_t)bh * 80 + 64 + r) * 4096 + ((size_t)(i & 511) << 3)) = q;
}

// ---- elementwise split (optional scale) ----
__global__ __launch_bounds__(256) void split_scale(
    const float* __restrict__ src, unsigned short* __restrict__ hi,
    unsigned short* __restrict__ lo, int n, float scale)
{
    int i = blockIdx.x * 256 + threadIdx.x;
    if (i < n) {
        unsigned short h, l;
        splitf(src[i] * scale, h, l);
        hi[i] = h; lo[i] = l;
    }
}

// ---- transpose-split weights: W [K,N] fp32 -> Wt hi/lo [N,K] bf16 ----
__global__ __launch_bounds__(256) void splitT(
    const float* __restrict__ W, unsigned short* __restrict__ hi,
    unsigned short* __restrict__ lo, int kshift, int N)
{
    int i = blockIdx.x * 256 + threadIdx.x;
    int K = 1 << kshift;
    int n = i >> kshift, k = i & (K - 1);
    unsigned short h, l;
    splitf(W[(size_t)k * N + n], h, l);
    hi[i] = h; lo[i] = l;
}

// ---- all-layer weight transpose-split: one dispatch, 4,194,304 elements ----
__global__ __launch_bounds__(256) void split_weights(
    const float* __restrict__ wq, const float* __restrict__ wk,
    const float* __restrict__ wv, const float* __restrict__ wo,
    const float* __restrict__ w1, const float* __restrict__ w2,
    unsigned short* __restrict__ dst)
{
    const int i = blockIdx.x * 256 + threadIdx.x;
    const int lay = i >> 20;
    const int r = i & 1048575;
    float val; size_t oh, ol;
    if (r < 262144) {
        const int m = r >> 16, e = r & 65535;
        const int n = e >> 8, k = e & 255;
        const float* W = (m == 0 ? wq : m == 1 ? wk : m == 2 ? wv : wo);
        val = W[(size_t)lay * 65536 + k * 256 + n];
        oh = (size_t)lay * 2097152 + (size_t)m * 131072 + e;
        ol = oh + 65536;
    } else if (r < 786432) {
        const int e = r - 262144;
        const int n = e >> 8, k = e & 255;
        val = w1[(size_t)lay * 524288 + (size_t)k * 2048 + n];
        oh = (size_t)lay * 2097152 + W1_H + e;
        ol = oh + 524288;
    } else {
        const int e = r - 786432;
        const int n = e >> 10, k = e & 1023;
        val = w2[(size_t)lay * 262144 + (size_t)k * 256 + n];
        oh = (size_t)lay * 2097152 + W2_H + e;
        ol = oh + 262144;
    }
    unsigned short h, l;
    splitf(val, h, l);
    dst[oh] = h; dst[ol] = l;
}

// ---- LayerNorm -> single bf16 plane ----
__global__ __launch_bounds__(256) void ln_bf16(
    const float* __restrict__ x, const float* __restrict__ g,
    const float* __restrict__ b, unsigned short* __restrict__ yhi)
{
    const int row = blockIdx.x * 4 + (threadIdx.x >> 6);
    const int lane = threadIdx.x & 63;
    float4 t = *(const float4*)&x[(size_t)row * 256 + lane * 4];
    float s = t.x + t.y + t.z + t.w;
#pragma unroll
    for (int sh = 1; sh < 64; sh <<= 1) s += __shfl_xor(s, sh);
    const float mu = s * (1.0f / 256.0f);
    const float dx = t.x - mu, dy = t.y - mu, dz = t.z - mu, dw = t.w - mu;
    float vv = dx * dx + dy * dy + dz * dz + dw * dw;
#pragma unroll
    for (int sh = 1; sh < 64; sh <<= 1) vv += __shfl_xor(vv, sh);
    const float rstd = rsqrtf(vv * (1.0f / 256.0f) + 1e-5f);
    float4 gv = *(const float4*)&g[lane * 4];
    float4 bv = *(const float4*)&b[lane * 4];
    unsigned short h0 = bf16rne(dx * rstd * gv.x + bv.x);
    unsigned short h1 = bf16rne(dy * rstd * gv.y + bv.y);
    unsigned short h2 = bf16rne(dz * rstd * gv.z + bv.z);
    unsigned short h3 = bf16rne(dw * rstd * gv.w + bv.w);
    uint2 ph;
    ph.x = (unsigned)h0 | ((unsigned)h1 << 16); ph.y = (unsigned)h2 | ((unsigned)h3 << 16);
    *(uint2*)&yhi[(size_t)row * 256 + lane * 4] = ph;
}

// ---- bf16 MFMA GEMM, tile 128x128, BK=32, 4 waves; gload_lds staging ----
// EPI: 0 bias->f32 C | 1 bias(nullable)+res->f32 C | 2 bias->bf16 plane + per-head diag
//      4 global max -> keys[0]
//      6 kp = exp epilogue + TRANSPOSED write to kpT[bh][m][n]
//      8 bias -> bf16 TRANSPOSED write to vT[bh][d][n] (80-row planes)
template<int EPI, bool ASPLIT, bool BSPLIT>
__global__ __launch_bounds__(256) void gemm_mf(
    const unsigned short* __restrict__ Ahi, const unsigned short* __restrict__ Alo, int lda,
    const unsigned short* __restrict__ Bhi, const unsigned short* __restrict__ Blo, int ldb,
    int K,
    const float* __restrict__ bias, const float* __restrict__ res,
    float* __restrict__ C, int ldc,
    unsigned short* __restrict__ Obf,
    const float* __restrict__ diag, unsigned* __restrict__ keys)
{
    constexpr int NP = (ASPLIT ? 2 : 1) + (BSPLIT ? 2 : 1);
    constexpr int PB = ASPLIT ? 2 : 1;                 // B-hi plane index
    constexpr int NEED = (EPI == 6 || EPI == 8) ? 16384 : 0;
    constexpr int LDSN = (NP * 4096 > NEED) ? NP * 4096 : NEED;
    __shared__ unsigned short lds[LDSN];
    __shared__ float red[4];
#define LX(p, r, c) lds[(p) * 4096 + (r) * 32 + (c)]
    int bx, by; xcd_swz(bx, by);
    const int tid = threadIdx.x;
    const int m0 = by * 128, n0 = bx * 128;
    const int sr = tid >> 2, sc = (tid & 3) * 8;       // stage row / short col
    const unsigned short* ga_h = Ahi + (size_t)(m0 + sr) * lda + sc;
    const unsigned short* ga_l = ASPLIT ? (Alo + (size_t)(m0 + sr) * lda + sc) : nullptr;
    const unsigned short* gb_h = Bhi + (size_t)(n0 + sr) * ldb + sc;
    const unsigned short* gb_l = BSPLIT ? (Blo + (size_t)(n0 + sr) * ldb + sc) : nullptr;
    unsigned short* lp = lds + tid * 8;
    const int l = tid & 63, w = tid >> 6;
    const int wr = (w >> 1) * 64, wc = (w & 1) * 64;
    const int fr = l & 15, fq = l >> 4;

    f32x4 acc[4][4];
#pragma unroll
    for (int i = 0; i < 4; ++i)
#pragma unroll
        for (int j = 0; j < 4; ++j) acc[i][j] = (f32x4){0.f, 0.f, 0.f, 0.f};

    for (int k0 = 0; k0 < K; k0 += 32) {
        glds16(ga_h + k0, lp);
        glds16(ga_h + (size_t)64 * lda + k0, lp + 2048);
        if (ASPLIT) {
            glds16(ga_l + k0, lp + 4096);
            glds16(ga_l + (size_t)64 * lda + k0, lp + 6144);
        }
        glds16(gb_h + k0, lp + PB * 4096);
        glds16(gb_h + (size_t)64 * ldb + k0, lp + PB * 4096 + 2048);
        if (BSPLIT) {
            glds16(gb_l + k0, lp + (PB + 1) * 4096);
            glds16(gb_l + (size_t)64 * ldb + k0, lp + (PB + 1) * 4096 + 2048);
        }
        __syncthreads();
        short8 ah[4], al[4];
#pragma unroll
        for (int mf = 0; mf < 4; ++mf) {
            ah[mf] = *(const short8*)&LX(0, wr + mf * 16 + fr, fq * 8);
            if (ASPLIT) al[mf] = *(const short8*)&LX(1, wr + mf * 16 + fr, fq * 8);
        }
#pragma unroll
        for (int nf = 0; nf < 4; ++nf) {
            short8 bh = *(const short8*)&LX(PB, wc + nf * 16 + fr, fq * 8);
#pragma unroll
            for (int mf = 0; mf < 4; ++mf) {
                acc[mf][nf] = __builtin_amdgcn_mfma_f32_16x16x32_bf16(ah[mf], bh, acc[mf][nf], 0, 0, 0);
                if (ASPLIT)
                    acc[mf][nf] = __builtin_amdgcn_mfma_f32_16x16x32_bf16(al[mf], bh, acc[mf][nf], 0, 0, 0);
            }
            if (BSPLIT) {
                short8 bl = *(const short8*)&LX(PB + 1, wc + nf * 16 + fr, fq * 8);
#pragma unroll
                for (int mf = 0; mf < 4; ++mf)
                    acc[mf][nf] = __builtin_amdgcn_mfma_f32_16x16x32_bf16(ah[mf], bl, acc[mf][nf], 0, 0, 0);
            }
        }
        __syncthreads();
    }

    if constexpr (EPI == 4) {
        float m = -3.4e38f;
#pragma unroll
        for (int mf = 0; mf < 4; ++mf)
#pragma unroll
            for (int nf = 0; nf < 4; ++nf)
#pragma unroll
                for (int v = 0; v < 4; ++v) m = fmaxf(m, acc[mf][nf][v]);
#pragma unroll
        for (int s = 1; s < 64; s <<= 1) m = fmaxf(m, __shfl_xor(m, s));
        if (l == 0) red[w] = m;
        __syncthreads();
        if (tid == 0)
            atomicMax(keys, fkey(fmaxf(fmaxf(red[0], red[1]), fmaxf(red[2], red[3]))));
    } else if constexpr (EPI == 6) {
        const float Mg = funkey(*keys);
        unsigned short* tb = lds;
#pragma unroll
        for (int mf = 0; mf < 4; ++mf)
#pragma unroll
            for (int v = 0; v < 4; ++v) {
                const int rl = wr + mf * 16 + fq * 4 + v;
                const float dg = diag[m0 + rl] + Mg;
#pragma unroll
                for (int nf = 0; nf < 4; ++nf) {
                    const int cl = wc + nf * 16 + fr;
                    tb[rl * 128 + cl] = bf16rne(RATIO * (expf(acc[mf][nf][v] - dg) + EPSF));
                }
            }
        __syncthreads();
        const int tokbase = m0 >> 2;
        const int b = tokbase >> 12, nib = tokbase & 4095;
        const int ml = tid & 127, g2 = tid >> 7;
#pragma unroll
        for (int hh2 = 0; hh2 < 2; ++hh2) {
            const int hh = g2 * 2 + hh2;
            unsigned short* dst = Obf + ((size_t)((b * 4 + hh) * 256 + n0 + ml)) * 4096 + nib;
#pragma unroll
            for (int qq = 0; qq < 4; ++qq) {
                uint4 qv;
                unsigned wv[4];
#pragma unroll
                for (int j = 0; j < 4; ++j) {
                    unsigned s0 = tb[((qq * 8 + j * 2 + 0) * 4 + hh) * 128 + ml];
                    unsigned s1 = tb[((qq * 8 + j * 2 + 1) * 4 + hh) * 128 + ml];
                    wv[j] = s0 | (s1 << 16);
                }
                qv.x = wv[0]; qv.y = wv[1]; qv.z = wv[2]; qv.w = wv[3];
                *(uint4*)(dst + qq * 8) = qv;
            }
        }
    } else if constexpr (EPI == 8) {
        unsigned short* tb = lds;
#pragma unroll
        for (int mf = 0; mf < 4; ++mf)
#pragma unroll
            for (int nf = 0; nf < 4; ++nf) {
                const int cl = wc + nf * 16 + fr;
                const float bb = bias[n0 + cl];
#pragma unroll
                for (int v = 0; v < 4; ++v) {
                    const int rl = wr + mf * 16 + fq * 4 + v;
                    tb[rl * 128 + cl] = bf16rne(acc[mf][nf][v] + bb);
                }
            }
        __syncthreads();
        const int b = m0 >> 12, nib = m0 & 4095;
        const int cl = tid & 127, half = tid >> 7;
        const int ch = n0 + cl, hh = ch >> 6, d = ch & 63;
        unsigned short* dst = Obf + ((size_t)((b * 4 + hh) * 80 + d)) * 4096 + nib + half * 64;
#pragma unroll
        for (int qq = 0; qq < 8; ++qq) {
            uint4 qv;
            unsigned wv[4];
#pragma unroll
            for (int j = 0; j < 4; ++j) {
                unsigned s0 = tb[(half * 64 + qq * 8 + j * 2 + 0) * 128 + cl];
                unsigned s1 = tb[(half * 64 + qq * 8 + j * 2 + 1) * 128 + cl];
                wv[j] = s0 | (s1 << 16);
            }
            qv.x = wv[0]; qv.y = wv[1]; qv.z = wv[2]; qv.w = wv[3];
            *(uint4*)(dst + qq * 8) = qv;
        }
    } else if constexpr (EPI == 2) {
        const int head = (n0 + wc) >> 6;
#pragma unroll
        for (int mf = 0; mf < 4; ++mf) {
            float sq[4] = {0.f, 0.f, 0.f, 0.f};
#pragma unroll
            for (int nf = 0; nf < 4; ++nf) {
                const int col = n0 + wc + nf * 16 + fr;
                const float bb = bias[col];
#pragma unroll
                for (int v = 0; v < 4; ++v) {
                    const int row = m0 + wr + mf * 16 + fq * 4 + v;
                    float val = acc[mf][nf][v] + bb;
                    Obf[(size_t)row * 256 + col] = bf16rne(val);
                    sq[v] += val * val;
                }
            }
#pragma unroll
            for (int v = 0; v < 4; ++v) {
                float s = sq[v];
                s += __shfl_xor(s, 1); s += __shfl_xor(s, 2);
                s += __shfl_xor(s, 4); s += __shfl_xor(s, 8);
                if (fr == 0)
                    ((float*)diag)[(size_t)(m0 + wr + mf * 16 + fq * 4 + v) * 4 + head] = s * 0.0625f;
            }
        }
    } else {
#pragma unroll
        for (int nf = 0; nf < 4; ++nf) {
            const int col = n0 + wc + nf * 16 + fr;
            float bb = 0.f;
            if (bias != nullptr) bb = bias[col];
#pragma unroll
            for (int mf = 0; mf < 4; ++mf) {
#pragma unroll
                for (int v = 0; v < 4; ++v) {
                    const int row = m0 + wr + mf * 16 + fq * 4 + v;
                    const size_t off = (size_t)row * ldc + col;
                    float val = acc[mf][nf][v] + bb;
                    if (EPI == 1) val += res[off];
                    C[off] = val;
                }
            }
        }
    }
#undef LX
}

// ---- fused GLU GEMM: A single bf16 plane, W split -> 4 MFMA/site; gload_lds ----
__global__ __launch_bounds__(256) void gemm_glu(
    const unsigned short* __restrict__ Ahi,
    const unsigned short* __restrict__ Whi, const unsigned short* __restrict__ Wlo,
    const float* __restrict__ b1, unsigned short* __restrict__ Obf)
{
    __shared__ unsigned short ldsA[4096];      // [128][32]
    __shared__ unsigned short ldsB[8192];      // 4 planes x [64][32]
    int bx, by; xcd_swz(bx, by);
    const int tid = threadIdx.x;
    const int m0 = by * 128, p0 = bx * 64;
    const int sr = tid >> 2, sc = (tid & 3) * 8;
    const unsigned short* ga  = Ahi + (size_t)(m0 + sr) * 256 + sc;
    const unsigned short* gb0 = Whi + (size_t)(p0 + sr) * 256 + sc;
    const unsigned short* gb1 = Wlo + (size_t)(p0 + sr) * 256 + sc;
    const unsigned short* gb2 = Whi + (size_t)(1024 + p0 + sr) * 256 + sc;
    const unsigned short* gb3 = Wlo + (size_t)(1024 + p0 + sr) * 256 + sc;
    unsigned short* lpA = ldsA + tid * 8;
    unsigned short* lpB = ldsB + tid * 8;
    const int l = tid & 63, w = tid >> 6;
    const int wr = (w >> 1) * 64, wc = (w & 1) * 32;
    const int fr = l & 15, fq = l >> 4;

    f32x4 aa[4][2], ag[4][2];
#pragma unroll
    for (int i = 0; i < 4; ++i)
#pragma unroll
        for (int j = 0; j < 2; ++j) {
            aa[i][j] = (f32x4){0.f, 0.f, 0.f, 0.f};
            ag[i][j] = (f32x4){0.f, 0.f, 0.f, 0.f};
        }

    for (int k0 = 0; k0 < 256; k0 += 32) {
        glds16(ga + k0, lpA);
        glds16(ga + 64 * 256 + k0, lpA + 2048);
        glds16(gb0 + k0, lpB);
        glds16(gb1 + k0, lpB + 2048);
        glds16(gb2 + k0, lpB + 4096);
        glds16(gb3 + k0, lpB + 6144);
        __syncthreads();
        short8 ah[4];
#pragma unroll
        for (int mf = 0; mf < 4; ++mf)
            ah[mf] = *(const short8*)&ldsA[(wr + mf * 16 + fr) * 32 + fq * 8];
#pragma unroll
        for (int nf = 0; nf < 2; ++nf) {
            const int br_ = (wc + nf * 16 + fr) * 32 + fq * 8;
            short8 bah = *(const short8*)&ldsB[br_];
            short8 bal = *(const short8*)&ldsB[2048 + br_];
            short8 bgh = *(const short8*)&ldsB[4096 + br_];
            short8 bgl = *(const short8*)&ldsB[6144 + br_];
#pragma unroll
            for (int mf = 0; mf < 4; ++mf) {
                aa[mf][nf] = __builtin_amdgcn_mfma_f32_16x16x32_bf16(ah[mf], bah, aa[mf][nf], 0, 0, 0);
                aa[mf][nf] = __builtin_amdgcn_mfma_f32_16x16x32_bf16(ah[mf], bal, aa[mf][nf], 0, 0, 0);
                ag[mf][nf] = __builtin_amdgcn_mfma_f32_16x16x32_bf16(ah[mf], bgh, ag[mf][nf], 0, 0, 0);
                ag[mf][nf] = __builtin_amdgcn_mfma_f32_16x16x32_bf16(ah[mf], bgl, ag[mf][nf], 0, 0, 0);
            }
        }
        __syncthreads();
    }
#pragma unroll
    for (int nf = 0; nf < 2; ++nf) {
        const int ch = p0 + wc + nf * 16 + fr;
        const float ba = b1[ch], bg = b1[1024 + ch];
#pragma unroll
        for (int mf = 0; mf < 4; ++mf) {
#pragma unroll
            for (int v = 0; v < 4; ++v) {
                const int row = m0 + wr + mf * 16 + fq * 4 + v;
                float u = aa[mf][nf][v] + ba, g = ag[mf][nf][v] + bg;
                Obf[(size_t)row * 1024 + ch] = bf16rne(gelu_exact(u) * g);
            }
        }
    }
}

// ---- ctx GEMM: 64-row x 80-col tile, K-chunk 1024; grid (16,32); gload_lds ----
__global__ __launch_bounds__(256) void ctx_mfma(
    const unsigned short* __restrict__ kpT, const unsigned short* __restrict__ vT,
    float* __restrict__ ctxp)
{
    __shared__ unsigned short la[2048];        // [64][32]
    __shared__ unsigned short lb[2560];        // [80][32]
    int bx, by; xcd_swz(bx, by);
    const int bh = by, mt = bx & 3, kc = bx >> 2;
    const int tid = threadIdx.x;
    const int l = tid & 63, w = tid >> 6;
    const int wr = w * 16, fr = l & 15, fq = l >> 4;
    const int sr = tid >> 2, sc = (tid & 3) * 8;
    const unsigned short* ga  = kpT + ((size_t)bh * 256 + mt * 64 + sr) * 4096 + kc * 1024 + sc;
    const unsigned short* gb  = vT + ((size_t)bh * 80 + sr) * 4096 + kc * 1024 + sc;
    const unsigned short* gb2 = vT + ((size_t)bh * 80 + 64 + sr) * 4096 + kc * 1024 + sc;

    f32x4 acc[5];
#pragma unroll
    for (int j = 0; j < 5; ++j) acc[j] = (f32x4){0.f, 0.f, 0.f, 0.f};

    for (int k0 = 0; k0 < 1024; k0 += 32) {
        glds16(ga + k0, la + tid * 8);
        glds16(gb + k0, lb + tid * 8);
        if (tid < 64) glds16(gb2 + k0, lb + 2048 + tid * 8);
        __syncthreads();
        short8 av = *(const short8*)&la[(wr + fr) * 32 + fq * 8];
#pragma unroll
        for (int nf = 0; nf < 5; ++nf) {
            short8 bv = *(const short8*)&lb[(nf * 16 + fr) * 32 + fq * 8];
            acc[nf] = __builtin_amdgcn_mfma_f32_16x16x32_bf16(av, bv, acc[nf], 0, 0, 0);
        }
        __syncthreads();
    }
#pragma unroll
    for (int v = 0; v < 4; ++v) {
        const int row = mt * 64 + wr + fq * 4 + v;
#pragma unroll
        for (int nf = 0; nf < 5; ++nf)
            ctxp[((size_t)(kc * 32 + bh) * 256 + row) * 80 + nf * 16 + fr] = acc[nf][v];
    }
}

// ---- reduce ctx partials over 4 k-chunks, transpose, split -> ctxT[bh][80][256] ----
__global__ __launch_bounds__(256) void ctx_fix(
    const float* __restrict__ ctxp, unsigned short* __restrict__ cth,
    unsigned short* __restrict__ ctl)
{
    __shared__ float s[64][81];
    const int m0 = blockIdx.x * 64, bh = blockIdx.y;
    const int tid = threadIdx.x;
    for (int i = tid; i < 5120; i += 256) {
        const int ml = i / 80, dc = i % 80;
        float sum = 0.f;
#pragma unroll
        for (int kc = 0; kc < 4; ++kc)
            sum += ctxp[((size_t)(kc * 32 + bh) * 256 + m0 + ml) * 80 + dc];
        s[ml][dc] = sum;
    }
    __syncthreads();
    for (int i = tid; i < 5120; i += 256) {
        const int dc = i >> 6, ml = i & 63;
        unsigned short hh_, ll_;
        splitf(s[ml][dc], hh_, ll_);
        cth[((size_t)bh * 80 + dc) * 256 + m0 + ml] = hh_;
        ctl[((size_t)bh * 80 + dc) * 256 + m0 + ml] = ll_;
    }
}

// ---- fused q-side: dd = q@projT (K=64) -> row max -> exp -> qp (swizzled LDS)
//      -> o = (qp @ ctxT)/(qp . ksum) (K=256). grid (32 tok-tiles, 32 bh). ----
__global__ __launch_bounds__(256) void qo_mfma(
    const unsigned short* __restrict__ qhi,
    const unsigned short* __restrict__ pmh, const unsigned short* __restrict__ pml,
    const unsigned short* __restrict__ cth, const unsigned short* __restrict__ ctl,
    const float* __restrict__ diagq, unsigned short* __restrict__ osh)
{
    __shared__ unsigned short lds[32768 + 5120];   // qp tile (unions phase1 staging) | ctx staging
    __shared__ float rmax2[128][2];
    int bx, by; xcd_swz(bx, by);
    const int bh = by, b = bh >> 2, hh = bh & 3;
    const int t0 = bx * 128;
    const int tid = threadIdx.x;
    const int l = tid & 63, w = tid >> 6;
    const int fr = l & 15, fq = l >> 4;

    // ---- phase 1: dd[128 tok][256 m], K = 64 ----
    const int wr1 = (w >> 1) * 64, wc1 = (w & 1) * 128;
    f32x4 a1[4][8];
#pragma unroll
    for (int i = 0; i < 4; ++i)
#pragma unroll
        for (int j = 0; j < 8; ++j) a1[i][j] = (f32x4){0.f, 0.f, 0.f, 0.f};

    const unsigned short* gq = qhi + (size_t)(b * 4096 + t0) * 256 + hh * 64;
#pragma unroll
    for (int ks = 0; ks < 2; ++ks) {
        const int k0 = ks * 32;
        // A: 128 rows x 32 (512 chunks), stride 256 shorts
        glds16(gq + (size_t)(tid >> 2) * 256 + k0 + (tid & 3) * 8, lds + tid * 8);
        glds16(gq + (size_t)(64 + (tid >> 2)) * 256 + k0 + (tid & 3) * 8, lds + (tid + 256) * 8);
        // B: 2 planes x 256 rows x 32 (1024 chunks each)
#pragma unroll
        for (int i2 = 0; i2 < 4; ++i2) {
            const int c = tid + i2 * 256;
            glds16(pmh + (size_t)(c >> 2) * 64 + k0 + (c & 3) * 8, lds + 4096 + c * 8);
            glds16(pml + (size_t)(c >> 2) * 64 + k0 + (c & 3) * 8, lds + 12288 + c * 8);
        }
        __syncthreads();
        short8 av[4];
#pragma unroll
        for (int mf = 0; mf < 4; ++mf)
            av[mf] = *(const short8*)&lds[(wr1 + mf * 16 + fr) * 32 + fq * 8];
#pragma unroll
        for (int nf = 0; nf < 8; ++nf) {
            short8 bh_ = *(const short8*)&lds[4096 + (wc1 + nf * 16 + fr) * 32 + fq * 8];
            short8 bl_ = *(const short8*)&lds[12288 + (wc1 + nf * 16 + fr) * 32 + fq * 8];
#pragma unroll
            for (int mf = 0; mf < 4; ++mf) {
                a1[mf][nf] = __builtin_amdgcn_mfma_f32_16x16x32_bf16(av[mf], bh_, a1[mf][nf], 0, 0, 0);
                a1[mf][nf] = __builtin_amdgcn_mfma_f32_16x16x32_bf16(av[mf], bl_, a1[mf][nf], 0, 0, 0);
            }
        }
        __syncthreads();
    }
    // ---- row max (in-block, replaces EPI5) ----
#pragma unroll
    for (int mf = 0; mf < 4; ++mf)
#pragma unroll
        for (int v = 0; v < 4; ++v) {
            float rm = a1[mf][0][v];
#pragma unroll
            for (int nf = 1; nf < 8; ++nf) rm = fmaxf(rm, a1[mf][nf][v]);
            rm = fmaxf(rm, __shfl_xor(rm, 1));
            rm = fmaxf(rm, __shfl_xor(rm, 2));
            rm = fmaxf(rm, __shfl_xor(rm, 4));
            rm = fmaxf(rm, __shfl_xor(rm, 8));
            if (fr == 0) rmax2[wr1 + mf * 16 + fq * 4 + v][w & 1] = rm;
        }
    __syncthreads();
    // ---- exp -> qp bf16 into swizzled LDS tile [128][256] ----
#pragma unroll
    for (int mf = 0; mf < 4; ++mf)
#pragma unroll
        for (int v = 0; v < 4; ++v) {
            const int tok = wr1 + mf * 16 + fq * 4 + v;
            const float dg = diagq[(size_t)(b * 4096 + t0 + tok) * 4 + hh]
                           + fmaxf(rmax2[tok][0], rmax2[tok][1]);
#pragma unroll
            for (int nf = 0; nf < 8; ++nf) {
                const int m = wc1 + nf * 16 + fr;
                lds[tok * 256 + (m ^ ((tok & 7) << 3))] =
                    bf16rne(RATIO * (expf(a1[mf][nf][v] - dg) + EPSF));
            }
        }
    __syncthreads();

    // ---- phase 2: o[128 tok][80] = qp @ ctxT (K=256, B split), col 64 = denominator ----
    unsigned short* lds2 = lds + 32768;
    f32x4 a2[2][5];
#pragma unroll
    for (int i = 0; i < 2; ++i)
#pragma unroll
        for (int j = 0; j < 5; ++j) a2[i][j] = (f32x4){0.f, 0.f, 0.f, 0.f};
    const size_t bbase = (size_t)bh * 80 * 256;

    for (int k0 = 0; k0 < 256; k0 += 32) {
        glds16(cth + bbase + (size_t)(tid >> 2) * 256 + k0 + (tid & 3) * 8, lds2 + tid * 8);
        glds16(ctl + bbase + (size_t)(tid >> 2) * 256 + k0 + (tid & 3) * 8, lds2 + 2560 + tid * 8);
        if (tid < 64) {
            const int c = 256 + tid;
            glds16(cth + bbase + (size_t)(c >> 2) * 256 + k0 + (c & 3) * 8, lds2 + c * 8);
            glds16(ctl + bbase + (size_t)(c >> 2) * 256 + k0 + (c & 3) * 8, lds2 + 2560 + c * 8);
        }
        __syncthreads();
        short8 av[2];
#pragma unroll
        for (int mf = 0; mf < 2; ++mf) {
            const int tok = w * 32 + mf * 16 + fr;
            const int c = ((k0 >> 3) + fq) ^ (tok & 7);
            av[mf] = *(const short8*)&lds[tok * 256 + c * 8];
        }
#pragma unroll
        for (int nf = 0; nf < 5; ++nf) {
            const int off = (nf * 16 + fr) * 32 + fq * 8;
            short8 bvh = *(const short8*)&lds2[off];
            short8 bvl = *(const short8*)&lds2[2560 + off];
#pragma unroll
            for (int mf = 0; mf < 2; ++mf) {
                a2[mf][nf] = __builtin_amdgcn_mfma_f32_16x16x32_bf16(av[mf], bvh, a2[mf][nf], 0, 0, 0);
                a2[mf][nf] = __builtin_amdgcn_mfma_f32_16x16x32_bf16(av[mf], bvl, a2[mf][nf], 0, 0, 0);
            }
        }
        __syncthreads();
    }
#pragma unroll
    for (int mf = 0; mf < 2; ++mf)
#pragma unroll
        for (int v = 0; v < 4; ++v) {
            const float den = __shfl(a2[mf][4][v], (int)(l & 48));
            const float dinv = 1.0f / den;
            const int tok = w * 32 + mf * 16 + fq * 4 + v;
            const size_t obase = (size_t)(b * 4096 + t0 + tok) * 256 + hh * 64;
#pragma unroll
            for (int nf = 0; nf < 4; ++nf)
                osh[obase + nf * 16 + fr] = bf16rne(a2[mf][nf][v] * dinv);
        }
}

// ---- pooling + classifier ----
__global__ __launch_bounds__(256) void pool1_kernel(const float* __restrict__ h, float* __restrict__ part)
{
    const int b = blockIdx.x >> 4, ch = blockIdx.x & 15;
    const int tid = threadIdx.x;
    float acc = 0.f;
    for (int n = 0; n < 256; ++n)
        acc += h[((size_t)(b * 4096 + ch * 256 + n)) * 256 + tid];
    part[(size_t)blockIdx.x * 256 + tid] = acc;
}

__global__ __launch_bounds__(256) void pool2_kernel(
    const float* __restrict__ part, const float* __restrict__ cw,
    const float* __restrict__ cb, float* __restrict__ out)
{
    const int b = blockIdx.x, tid = threadIdx.x;
    float acc = 0.f;
#pragma unroll
    for (int c = 0; c < 16; ++c) acc += part[(size_t)(b * 16 + c) * 256 + tid];
    float val = acc * (1.0f / 4096.0f) * cw[tid];
#pragma unroll
    for (int s = 1; s < 64; s <<= 1) val += __shfl_xor(val, s);
    __shared__ float red[4];
    if ((tid & 63) == 0) red[tid >> 6] = val;
    __syncthreads();
    if (tid == 0) out[b] = red[0] + red[1] + red[2] + red[3] + cb[0];
}

extern "C" void kernel_launch(void* const* d_in, const int* in_sizes, int n_in,
                              void* d_out, int out_size, void* d_ws, size_t ws_size,
                              hipStream_t stream)
{
    (void)in_sizes; (void)n_in;
    if (ws_size < WS_BYTES) {
        fill_sentinel<<<1, 64, 0, stream>>>((float*)d_out, out_size);
        return;
    }

    const float* x     = (const float*)d_in[0];
    const float* projw = (const float*)d_in[1];
    const float* projb = (const float*)d_in[2];
    const float* ln1g  = (const float*)d_in[3];
    const float* ln1b  = (const float*)d_in[4];
    const float* wq    = (const float*)d_in[5];
    const float* bq    = (const float*)d_in[6];
    const float* wk    = (const float*)d_in[7];
    const float* bk    = (const float*)d_in[8];
    const float* wv    = (const float*)d_in[9];
    const float* bv    = (const float*)d_in[10];
    const float* wo    = (const float*)d_in[11];
    const float* bo    = (const float*)d_in[12];
    const float* ln2g  = (const float*)d_in[13];
    const float* ln2b  = (const float*)d_in[14];
    const float* w1    = (const float*)d_in[15];
    const float* b1    = (const float*)d_in[16];
    const float* w2    = (const float*)d_in[17];
    const float* b2    = (const float*)d_in[18];
    const float* clfw  = (const float*)d_in[19];
    const float* clfb  = (const float*)d_in[20];
    const float* projm = (const float*)d_in[21];

    char* WS = (char*)d_ws;
    float* h            = (float*)(WS + OFF_H);
    unsigned short* ysh = (unsigned short*)(WS + OFF_YS);
    unsigned short* wts = (unsigned short*)(WS + OFF_WTS);
    unsigned short* khi = (unsigned short*)(WS + OFF_QK);
    unsigned short* qhi = khi + 8388608;
    unsigned short* big = (unsigned short*)(WS + OFF_BIG);   // kpT / ffb / x-split
    unsigned short* vT  = (unsigned short*)(WS + OFF_VT);
    float* ctxp         = (float*)(WS + OFF_CTXP);
    unsigned short* cth = (unsigned short*)(WS + OFF_CTXTH);
    unsigned short* ctl = (unsigned short*)(WS + OFF_CTXTL);
    float* diagq        = (float*)(WS + OFF_DIAGQ);
    float* diagk        = (float*)(WS + OFF_DIAGK);
    unsigned* gmax      = (unsigned*)(WS + OFF_GMAX);
    float* pool         = (float*)(WS + OFF_POOL);
    unsigned short* pmt_h = (unsigned short*)(WS + OFF_PMTH);
    unsigned short* pmt_l = (unsigned short*)(WS + OFF_PMTL);
    unsigned short* pwt_h = (unsigned short*)(WS + OFF_PWTH);
    unsigned short* pwt_l = (unsigned short*)(WS + OFF_PWTL);
    // aliases
    unsigned short* xsh = big;               // prologue only
    unsigned short* xsl = big + 2097152;
    unsigned short* kpT = big;               // [32][256][4096]
    unsigned short* ffb = big;               // [32768][1024]
    unsigned short* osh = ysh;               // o bf16 (ys dead by then)

    // ---- prologue ----
    split_scale<<<8192, 256, 0, stream>>>(x, xsh, xsl, 2097152, 1.0f);
    splitT<<<64, 256, 0, stream>>>(projw, pwt_h, pwt_l, 6, 256);
    split_scale<<<64, 256, 0, stream>>>(projm, pmt_h, pmt_l, 16384, DN);
    vt_init<<<1024, 256, 0, stream>>>(vT, gmax);
    split_weights<<<16384, 256, 0, stream>>>(wq, wk, wv, wo, w1, w2, wts);
    gemm_mf<0, true, true><<<dim3(2, 256), 256, 0, stream>>>(xsh, xsl, 64, pwt_h, pwt_l, 64, 64,
        projb, nullptr, h, 256, nullptr, nullptr, nullptr);

    for (int l = 0; l < 4; ++l) {
        unsigned short* wl = wts + (size_t)l * 2097152;

        // ---- attention ----
        ln_bf16<<<8192, 256, 0, stream>>>(h, ln1g + l * 256, ln1b + l * 256, ysh);
        gemm_mf<8, false, true><<<dim3(2, 256), 256, 0, stream>>>(ysh, nullptr, 256,
            wl + WV_H, wl + WV_L, 256, 256, bv + l * 256, nullptr, nullptr, 256, vT, nullptr, nullptr);
        gemm_mf<2, false, true><<<dim3(2, 256), 256, 0, stream>>>(ysh, nullptr, 256,
            wl + WK_H, wl + WK_L, 256, 256, bk + l * 256, nullptr, nullptr, 256, khi, diagk, nullptr);
        gemm_mf<2, false, true><<<dim3(2, 256), 256, 0, stream>>>(ysh, nullptr, 256,
            wl + WQ_H, wl + WQ_L, 256, 256, bq + l * 256, nullptr, nullptr, 256, qhi, diagq, nullptr);
        gemm_mf<4, false, false><<<dim3(2, 1024), 256, 0, stream>>>(khi, nullptr, 64,
            pmt_h, nullptr, 64, 64, nullptr, nullptr, nullptr, 256, nullptr, nullptr, gmax + l);
        gemm_mf<6, false, true><<<dim3(2, 1024), 256, 0, stream>>>(khi, nullptr, 64,
            pmt_h, pmt_l, 64, 64, nullptr, nullptr, nullptr, 256, kpT, diagk, gmax + l);
        ctx_mfma<<<dim3(16, 32), 256, 0, stream>>>(kpT, vT, ctxp);
        ctx_fix<<<dim3(4, 32), 256, 0, stream>>>(ctxp, cth, ctl);
        qo_mfma<<<dim3(32, 32), 256, 0, stream>>>(qhi, pmt_h, pmt_l, cth, ctl, diagq, osh);
        gemm_mf<1, false, true><<<dim3(2, 256), 256, 0, stream>>>(osh, nullptr, 256,
            wl + WO_H, wl + WO_L, 256, 256, bo + l * 256, h, h, 256, nullptr, nullptr, nullptr);

        // ---- feed-forward ----
        ln_bf16<<<8192, 256, 0, stream>>>(h, ln2g + l * 256, ln2b + l * 256, ysh);
        gemm_glu<<<dim3(16, 256), 256, 0, stream>>>(ysh, wl + W1_H, wl + W1_L,
            b1 + (size_t)l * 2048, ffb);
        gemm_mf<1, false, true><<<dim3(2, 256), 256, 0, stream>>>(ffb, nullptr, 1024,
            wl + W2_H, wl + W2_L, 1024, 1024, b2 + l * 256, h, h, 256, nullptr, nullptr, nullptr);
    }

    pool1_kernel<<<128, 256, 0, stream>>>(h, pool);
    pool2_kernel<<<8, 256, 0, stream>>>(pool, clfw, clfb, (float*)d_out);
}

// Round 9
// 1514.425 us; speedup vs baseline: 7.9238x; 1.0595x over previous
//
#include <hip/hip_runtime.h>
#include <cstdint>
#include <cstddef>

// ---- problem constants ----
constexpr float DN = 0.35355339059327373f;   // 64^-0.25
constexpr float RATIO = 0.0625f;             // 256^-0.5
constexpr float EPSF = 1e-4f;

typedef __attribute__((ext_vector_type(8))) short short8;   // bf16 MFMA fragment
typedef __attribute__((ext_vector_type(4))) float f32x4;    // MFMA accumulator

// ---- workspace layout (byte offsets); proven budget >= 209,715,200 B ----
constexpr size_t OFF_H     = 0;              // fp32 residual 33,554,432
constexpr size_t OFF_YS    = 33554432;       // ysh (osh alias) 16,777,216
constexpr size_t OFF_WTS   = 50331648;       // all-layer weight splits 16,777,216
constexpr size_t OFF_QK    = 67108864;       // khi 16,777,216 | qhi 16,777,216
constexpr size_t OFF_BIG   = 100663296;      // kpT / ffb / x-split 67,108,864
constexpr size_t OFF_VT    = 167772160;      // vT [32][80][4096] bf16 20,971,520
constexpr size_t OFF_CTXP  = 188743680;      // ctx partials [4][32][256][80] f32 10,485,760
constexpr size_t OFF_CTXTH = 199229440;      // ctxT hi [32][80][256] 1,310,720
constexpr size_t OFF_CTXTL = 200540160;      // ctxT lo 1,310,720
constexpr size_t OFF_DIAGQ = 201850880;      // 524,288
constexpr size_t OFF_DIAGK = 202375168;      // 524,288
constexpr size_t OFF_GMAX  = 203423744;      // 256 (4 per-layer slots used)
constexpr size_t OFF_POOL  = 203424000;      // 131,072
constexpr size_t OFF_PMTH  = 207749376;
constexpr size_t OFF_PMTL  = 207782144;
constexpr size_t OFF_PWTH  = 207814912;
constexpr size_t OFF_PWTL  = 207847680;
constexpr size_t WS_BYTES  = 207880448;

// per-layer short-offsets inside the WTS region (layer stride 2,097,152 shorts)
constexpr size_t WQ_H = 0,       WQ_L = 65536;
constexpr size_t WK_H = 131072,  WK_L = 196608;
constexpr size_t WV_H = 262144,  WV_L = 327680;
constexpr size_t WO_H = 393216,  WO_L = 458752;
constexpr size_t W1_H = 524288,  W1_L = 1048576;
constexpr size_t W2_H = 1572864, W2_L = 1835008;

__device__ __forceinline__ unsigned fkey(float f) {
    unsigned u = __float_as_uint(f);
    return (u & 0x80000000u) ? ~u : (u | 0x80000000u);
}
__device__ __forceinline__ float funkey(unsigned k) {
    unsigned u = (k & 0x80000000u) ? (k ^ 0x80000000u) : ~k;
    return __uint_as_float(u);
}
__device__ __forceinline__ float gelu_exact(float x) {
    return 0.5f * x * (1.0f + erff(x * 0.70710678118654752f));
}
__device__ __forceinline__ void splitf(float x, unsigned short& h, unsigned short& l) {
    unsigned u = __float_as_uint(x);
    unsigned hv = (u + 0x7FFFu + ((u >> 16) & 1)) >> 16;
    h = (unsigned short)hv;
    float lo = x - __uint_as_float(hv << 16);
    unsigned u2 = __float_as_uint(lo);
    l = (unsigned short)((u2 + 0x7FFFu + ((u2 >> 16) & 1)) >> 16);
}
__device__ __forceinline__ unsigned short bf16rne(float x) {
    unsigned u = __float_as_uint(x);
    return (unsigned short)((u + 0x7FFFu + ((u >> 16) & 1)) >> 16);
}
// XCD-aware block swizzle (requires total blocks % 8 == 0)
__device__ __forceinline__ void xcd_swz(int& bx, int& by) {
    const int gx = gridDim.x;
    const int total = gx * gridDim.y;
    int flat = blockIdx.y * gx + blockIdx.x;
    flat = (flat & 7) * (total >> 3) + (flat >> 3);
    bx = flat % gx; by = flat / gx;
}

// ---- async global->LDS 16B (wave-uniform base + lane*16, linear dest) ----
#if defined(__has_builtin)
#if __has_builtin(__builtin_amdgcn_global_load_lds)
#define HAVE_GLDS 1
#endif
#endif
__device__ __forceinline__ void glds16(const unsigned short* g, unsigned short* l) {
#ifdef HAVE_GLDS
    __builtin_amdgcn_global_load_lds(
        (const __attribute__((address_space(1))) unsigned int*)g,
        (__attribute__((address_space(3))) unsigned int*)l, 16, 0, 0);
#else
    *(uint4*)l = *(const uint4*)g;
#endif
}

__global__ void fill_sentinel(float* out, int n) {
    int i = threadIdx.x;
    if (i < n) out[i] = 12345.0f;
}
// fill vT rows 64..79 (row 64 = 1.0 for ksum fold) + zero per-layer gmax keys
__global__ __launch_bounds__(256) void vt_init(unsigned short* __restrict__ vT, unsigned* __restrict__ gm) {
    int i = blockIdx.x * 256 + threadIdx.x;        // 262,144 uint4
    if (i < 4) gm[i] = 0u;
    const int bh = i >> 13;
    const int r = (i >> 9) & 15;
    const unsigned val = (r == 0) ? 0x3F803F80u : 0u;
    uint4 q; q.x = val; q.y = val; q.z = val; q.w = val;
    *(uint4*)(vT + ((size_t)bh * 80 + 64 + r) * 4096 + ((size_t)(i & 511) << 3)) = q;
}

// ---- elementwise split (optional scale) ----
__global__ __launch_bounds__(256) void split_scale(
    const float* __restrict__ src, unsigned short* __restrict__ hi,
    unsigned short* __restrict__ lo, int n, float scale)
{
    int i = blockIdx.x * 256 + threadIdx.x;
    if (i < n) {
        unsigned short h, l;
        splitf(src[i] * scale, h, l);
        hi[i] = h; lo[i] = l;
    }
}

// ---- transpose-split weights: W [K,N] fp32 -> Wt hi/lo [N,K] bf16 ----
__global__ __launch_bounds__(256) void splitT(
    const float* __restrict__ W, unsigned short* __restrict__ hi,
    unsigned short* __restrict__ lo, int kshift, int N)
{
    int i = blockIdx.x * 256 + threadIdx.x;
    int K = 1 << kshift;
    int n = i >> kshift, k = i & (K - 1);
    unsigned short h, l;
    splitf(W[(size_t)k * N + n], h, l);
    hi[i] = h; lo[i] = l;
}

// ---- all-layer weight transpose-split: one dispatch, 4,194,304 elements ----
__global__ __launch_bounds__(256) void split_weights(
    const float* __restrict__ wq, const float* __restrict__ wk,
    const float* __restrict__ wv, const float* __restrict__ wo,
    const float* __restrict__ w1, const float* __restrict__ w2,
    unsigned short* __restrict__ dst)
{
    const int i = blockIdx.x * 256 + threadIdx.x;
    const int lay = i >> 20;
    const int r = i & 1048575;
    float val; size_t oh, ol;
    if (r < 262144) {
        const int m = r >> 16, e = r & 65535;
        const int n = e >> 8, k = e & 255;
        const float* W = (m == 0 ? wq : m == 1 ? wk : m == 2 ? wv : wo);
        val = W[(size_t)lay * 65536 + k * 256 + n];
        oh = (size_t)lay * 2097152 + (size_t)m * 131072 + e;
        ol = oh + 65536;
    } else if (r < 786432) {
        const int e = r - 262144;
        const int n = e >> 8, k = e & 255;
        val = w1[(size_t)lay * 524288 + (size_t)k * 2048 + n];
        oh = (size_t)lay * 2097152 + W1_H + e;
        ol = oh + 524288;
    } else {
        const int e = r - 786432;
        const int n = e >> 10, k = e & 1023;
        val = w2[(size_t)lay * 262144 + (size_t)k * 256 + n];
        oh = (size_t)lay * 2097152 + W2_H + e;
        ol = oh + 262144;
    }
    unsigned short h, l;
    splitf(val, h, l);
    dst[oh] = h; dst[ol] = l;
}

// ---- LayerNorm -> single bf16 plane ----
__global__ __launch_bounds__(256) void ln_bf16(
    const float* __restrict__ x, const float* __restrict__ g,
    const float* __restrict__ b, unsigned short* __restrict__ yhi)
{
    const int row = blockIdx.x * 4 + (threadIdx.x >> 6);
    const int lane = threadIdx.x & 63;
    float4 t = *(const float4*)&x[(size_t)row * 256 + lane * 4];
    float s = t.x + t.y + t.z + t.w;
#pragma unroll
    for (int sh = 1; sh < 64; sh <<= 1) s += __shfl_xor(s, sh);
    const float mu = s * (1.0f / 256.0f);
    const float dx = t.x - mu, dy = t.y - mu, dz = t.z - mu, dw = t.w - mu;
    float vv = dx * dx + dy * dy + dz * dz + dw * dw;
#pragma unroll
    for (int sh = 1; sh < 64; sh <<= 1) vv += __shfl_xor(vv, sh);
    const float rstd = rsqrtf(vv * (1.0f / 256.0f) + 1e-5f);
    float4 gv = *(const float4*)&g[lane * 4];
    float4 bv = *(const float4*)&b[lane * 4];
    unsigned short h0 = bf16rne(dx * rstd * gv.x + bv.x);
    unsigned short h1 = bf16rne(dy * rstd * gv.y + bv.y);
    unsigned short h2 = bf16rne(dz * rstd * gv.z + bv.z);
    unsigned short h3 = bf16rne(dw * rstd * gv.w + bv.w);
    uint2 ph;
    ph.x = (unsigned)h0 | ((unsigned)h1 << 16); ph.y = (unsigned)h2 | ((unsigned)h3 << 16);
    *(uint2*)&yhi[(size_t)row * 256 + lane * 4] = ph;
}

// ---- bf16 MFMA GEMM, tile 128x128, BK=64 (two 32-wide sub-planes), 4 waves ----
// LDS per logical plane: [2 halves][128][32] = 8192 shorts, linear dest for gload_lds.
// EPI: 0 bias->f32 C | 1 bias(nullable)+res->f32 C | 2 bias->bf16 plane + per-head diag
//      4 global max -> keys[0]
//      6 kp = exp epilogue + TRANSPOSED write to kpT[bh][m][n]
//      8 bias -> bf16 TRANSPOSED write to vT[bh][d][n] (80-row planes)
template<int EPI, bool ASPLIT, bool BSPLIT>
__global__ __launch_bounds__(256) void gemm_mf(
    const unsigned short* __restrict__ Ahi, const unsigned short* __restrict__ Alo, int lda,
    const unsigned short* __restrict__ Bhi, const unsigned short* __restrict__ Blo, int ldb,
    int K,
    const float* __restrict__ bias, const float* __restrict__ res,
    float* __restrict__ C, int ldc,
    unsigned short* __restrict__ Obf,
    const float* __restrict__ diag, unsigned* __restrict__ keys)
{
    constexpr int NP = (ASPLIT ? 2 : 1) + (BSPLIT ? 2 : 1);
    constexpr int PB = ASPLIT ? 2 : 1;                 // B-hi plane index
    constexpr int NEED = (EPI == 6 || EPI == 8) ? 16384 : 0;
    constexpr int LDSN = (NP * 8192 > NEED) ? NP * 8192 : NEED;
    __shared__ unsigned short lds[LDSN];
    __shared__ float red[4];
#define LX(p, h, r, c) lds[(p) * 8192 + (h) * 4096 + (r) * 32 + (c)]
    int bx, by; xcd_swz(bx, by);
    const int tid = threadIdx.x;
    const int m0 = by * 128, n0 = bx * 128;
    const int sr = tid >> 2, sc = (tid & 3) * 8;       // stage row / short col
    const unsigned short* ga_h = Ahi + (size_t)(m0 + sr) * lda + sc;
    const unsigned short* ga_l = ASPLIT ? (Alo + (size_t)(m0 + sr) * lda + sc) : nullptr;
    const unsigned short* gb_h = Bhi + (size_t)(n0 + sr) * ldb + sc;
    const unsigned short* gb_l = BSPLIT ? (Blo + (size_t)(n0 + sr) * ldb + sc) : nullptr;
    unsigned short* lp = lds + tid * 8;
    const int l = tid & 63, w = tid >> 6;
    const int wr = (w >> 1) * 64, wc = (w & 1) * 64;
    const int fr = l & 15, fq = l >> 4;

    f32x4 acc[4][4];
#pragma unroll
    for (int i = 0; i < 4; ++i)
#pragma unroll
        for (int j = 0; j < 4; ++j) acc[i][j] = (f32x4){0.f, 0.f, 0.f, 0.f};

    for (int k0 = 0; k0 < K; k0 += 64) {
        glds16(ga_h + k0, lp);
        glds16(ga_h + (size_t)64 * lda + k0, lp + 2048);
        glds16(ga_h + k0 + 32, lp + 4096);
        glds16(ga_h + (size_t)64 * lda + k0 + 32, lp + 6144);
        if (ASPLIT) {
            glds16(ga_l + k0, lp + 8192);
            glds16(ga_l + (size_t)64 * lda + k0, lp + 10240);
            glds16(ga_l + k0 + 32, lp + 12288);
            glds16(ga_l + (size_t)64 * lda + k0 + 32, lp + 14336);
        }
        glds16(gb_h + k0, lp + PB * 8192);
        glds16(gb_h + (size_t)64 * ldb + k0, lp + PB * 8192 + 2048);
        glds16(gb_h + k0 + 32, lp + PB * 8192 + 4096);
        glds16(gb_h + (size_t)64 * ldb + k0 + 32, lp + PB * 8192 + 6144);
        if (BSPLIT) {
            glds16(gb_l + k0, lp + (PB + 1) * 8192);
            glds16(gb_l + (size_t)64 * ldb + k0, lp + (PB + 1) * 8192 + 2048);
            glds16(gb_l + k0 + 32, lp + (PB + 1) * 8192 + 4096);
            glds16(gb_l + (size_t)64 * ldb + k0 + 32, lp + (PB + 1) * 8192 + 6144);
        }
        __syncthreads();
#pragma unroll
        for (int h2 = 0; h2 < 2; ++h2) {
            short8 ah[4], al[4];
#pragma unroll
            for (int mf = 0; mf < 4; ++mf) {
                ah[mf] = *(const short8*)&LX(0, h2, wr + mf * 16 + fr, fq * 8);
                if (ASPLIT) al[mf] = *(const short8*)&LX(1, h2, wr + mf * 16 + fr, fq * 8);
            }
#pragma unroll
            for (int nf = 0; nf < 4; ++nf) {
                short8 bh = *(const short8*)&LX(PB, h2, wc + nf * 16 + fr, fq * 8);
#pragma unroll
                for (int mf = 0; mf < 4; ++mf) {
                    acc[mf][nf] = __builtin_amdgcn_mfma_f32_16x16x32_bf16(ah[mf], bh, acc[mf][nf], 0, 0, 0);
                    if (ASPLIT)
                        acc[mf][nf] = __builtin_amdgcn_mfma_f32_16x16x32_bf16(al[mf], bh, acc[mf][nf], 0, 0, 0);
                }
                if (BSPLIT) {
                    short8 bl = *(const short8*)&LX(PB + 1, h2, wc + nf * 16 + fr, fq * 8);
#pragma unroll
                    for (int mf = 0; mf < 4; ++mf)
                        acc[mf][nf] = __builtin_amdgcn_mfma_f32_16x16x32_bf16(ah[mf], bl, acc[mf][nf], 0, 0, 0);
                }
            }
        }
        __syncthreads();
    }

    if constexpr (EPI == 4) {
        float m = -3.4e38f;
#pragma unroll
        for (int mf = 0; mf < 4; ++mf)
#pragma unroll
            for (int nf = 0; nf < 4; ++nf)
#pragma unroll
                for (int v = 0; v < 4; ++v) m = fmaxf(m, acc[mf][nf][v]);
#pragma unroll
        for (int s = 1; s < 64; s <<= 1) m = fmaxf(m, __shfl_xor(m, s));
        if (l == 0) red[w] = m;
        __syncthreads();
        if (tid == 0)
            atomicMax(keys, fkey(fmaxf(fmaxf(red[0], red[1]), fmaxf(red[2], red[3]))));
    } else if constexpr (EPI == 6) {
        const float Mg = funkey(*keys);
        unsigned short* tb = lds;
#pragma unroll
        for (int mf = 0; mf < 4; ++mf)
#pragma unroll
            for (int v = 0; v < 4; ++v) {
                const int rl = wr + mf * 16 + fq * 4 + v;
                const float dg = diag[m0 + rl] + Mg;
#pragma unroll
                for (int nf = 0; nf < 4; ++nf) {
                    const int cl = wc + nf * 16 + fr;
                    tb[rl * 128 + cl] = bf16rne(RATIO * (expf(acc[mf][nf][v] - dg) + EPSF));
                }
            }
        __syncthreads();
        const int tokbase = m0 >> 2;
        const int b = tokbase >> 12, nib = tokbase & 4095;
        const int ml = tid & 127, g2 = tid >> 7;
#pragma unroll
        for (int hh2 = 0; hh2 < 2; ++hh2) {
            const int hh = g2 * 2 + hh2;
            unsigned short* dst = Obf + ((size_t)((b * 4 + hh) * 256 + n0 + ml)) * 4096 + nib;
#pragma unroll
            for (int qq = 0; qq < 4; ++qq) {
                uint4 qv;
                unsigned wv[4];
#pragma unroll
                for (int j = 0; j < 4; ++j) {
                    unsigned s0 = tb[((qq * 8 + j * 2 + 0) * 4 + hh) * 128 + ml];
                    unsigned s1 = tb[((qq * 8 + j * 2 + 1) * 4 + hh) * 128 + ml];
                    wv[j] = s0 | (s1 << 16);
                }
                qv.x = wv[0]; qv.y = wv[1]; qv.z = wv[2]; qv.w = wv[3];
                *(uint4*)(dst + qq * 8) = qv;
            }
        }
    } else if constexpr (EPI == 8) {
        unsigned short* tb = lds;
#pragma unroll
        for (int mf = 0; mf < 4; ++mf)
#pragma unroll
            for (int nf = 0; nf < 4; ++nf) {
                const int cl = wc + nf * 16 + fr;
                const float bb = bias[n0 + cl];
#pragma unroll
                for (int v = 0; v < 4; ++v) {
                    const int rl = wr + mf * 16 + fq * 4 + v;
                    tb[rl * 128 + cl] = bf16rne(acc[mf][nf][v] + bb);
                }
            }
        __syncthreads();
        const int b = m0 >> 12, nib = m0 & 4095;
        const int cl = tid & 127, half = tid >> 7;
        const int ch = n0 + cl, hh = ch >> 6, d = ch & 63;
        unsigned short* dst = Obf + ((size_t)((b * 4 + hh) * 80 + d)) * 4096 + nib + half * 64;
#pragma unroll
        for (int qq = 0; qq < 8; ++qq) {
            uint4 qv;
            unsigned wv[4];
#pragma unroll
            for (int j = 0; j < 4; ++j) {
                unsigned s0 = tb[(half * 64 + qq * 8 + j * 2 + 0) * 128 + cl];
                unsigned s1 = tb[(half * 64 + qq * 8 + j * 2 + 1) * 128 + cl];
                wv[j] = s0 | (s1 << 16);
            }
            qv.x = wv[0]; qv.y = wv[1]; qv.z = wv[2]; qv.w = wv[3];
            *(uint4*)(dst + qq * 8) = qv;
        }
    } else if constexpr (EPI == 2) {
        const int head = (n0 + wc) >> 6;
#pragma unroll
        for (int mf = 0; mf < 4; ++mf) {
            float sq[4] = {0.f, 0.f, 0.f, 0.f};
#pragma unroll
            for (int nf = 0; nf < 4; ++nf) {
                const int col = n0 + wc + nf * 16 + fr;
                const float bb = bias[col];
#pragma unroll
                for (int v = 0; v < 4; ++v) {
                    const int row = m0 + wr + mf * 16 + fq * 4 + v;
                    float val = acc[mf][nf][v] + bb;
                    Obf[(size_t)row * 256 + col] = bf16rne(val);
                    sq[v] += val * val;
                }
            }
#pragma unroll
            for (int v = 0; v < 4; ++v) {
                float s = sq[v];
                s += __shfl_xor(s, 1); s += __shfl_xor(s, 2);
                s += __shfl_xor(s, 4); s += __shfl_xor(s, 8);
                if (fr == 0)
                    ((float*)diag)[(size_t)(m0 + wr + mf * 16 + fq * 4 + v) * 4 + head] = s * 0.0625f;
            }
        }
    } else {
#pragma unroll
        for (int nf = 0; nf < 4; ++nf) {
            const int col = n0 + wc + nf * 16 + fr;
            float bb = 0.f;
            if (bias != nullptr) bb = bias[col];
#pragma unroll
            for (int mf = 0; mf < 4; ++mf) {
#pragma unroll
                for (int v = 0; v < 4; ++v) {
                    const int row = m0 + wr + mf * 16 + fq * 4 + v;
                    const size_t off = (size_t)row * ldc + col;
                    float val = acc[mf][nf][v] + bb;
                    if (EPI == 1) val += res[off];
                    C[off] = val;
                }
            }
        }
    }
#undef LX
}

// ---- fused GLU GEMM: A single bf16 plane, W split; BK=64 sub-plane staging ----
__global__ __launch_bounds__(256) void gemm_glu(
    const unsigned short* __restrict__ Ahi,
    const unsigned short* __restrict__ Whi, const unsigned short* __restrict__ Wlo,
    const float* __restrict__ b1, unsigned short* __restrict__ Obf)
{
    __shared__ unsigned short ldsA[8192];      // [2 halves][128][32]
    __shared__ unsigned short ldsB[16384];     // 4 planes x [2 halves][64][32]
    int bx, by; xcd_swz(bx, by);
    const int tid = threadIdx.x;
    const int m0 = by * 128, p0 = bx * 64;
    const int sr = tid >> 2, sc = (tid & 3) * 8;
    const unsigned short* ga  = Ahi + (size_t)(m0 + sr) * 256 + sc;
    const unsigned short* gb0 = Whi + (size_t)(p0 + sr) * 256 + sc;
    const unsigned short* gb1 = Wlo + (size_t)(p0 + sr) * 256 + sc;
    const unsigned short* gb2 = Whi + (size_t)(1024 + p0 + sr) * 256 + sc;
    const unsigned short* gb3 = Wlo + (size_t)(1024 + p0 + sr) * 256 + sc;
    unsigned short* lpA = ldsA + tid * 8;
    unsigned short* lpB = ldsB + tid * 8;
    const int l = tid & 63, w = tid >> 6;
    const int wr = (w >> 1) * 64, wc = (w & 1) * 32;
    const int fr = l & 15, fq = l >> 4;

    f32x4 aa[4][2], ag[4][2];
#pragma unroll
    for (int i = 0; i < 4; ++i)
#pragma unroll
        for (int j = 0; j < 2; ++j) {
            aa[i][j] = (f32x4){0.f, 0.f, 0.f, 0.f};
            ag[i][j] = (f32x4){0.f, 0.f, 0.f, 0.f};
        }

    for (int k0 = 0; k0 < 256; k0 += 64) {
        glds16(ga + k0, lpA);
        glds16(ga + 64 * 256 + k0, lpA + 2048);
        glds16(ga + k0 + 32, lpA + 4096);
        glds16(ga + 64 * 256 + k0 + 32, lpA + 6144);
        glds16(gb0 + k0, lpB);
        glds16(gb0 + k0 + 32, lpB + 2048);
        glds16(gb1 + k0, lpB + 4096);
        glds16(gb1 + k0 + 32, lpB + 6144);
        glds16(gb2 + k0, lpB + 8192);
        glds16(gb2 + k0 + 32, lpB + 10240);
        glds16(gb3 + k0, lpB + 12288);
        glds16(gb3 + k0 + 32, lpB + 14336);
        __syncthreads();
#pragma unroll
        for (int h2 = 0; h2 < 2; ++h2) {
            short8 ah[4];
#pragma unroll
            for (int mf = 0; mf < 4; ++mf)
                ah[mf] = *(const short8*)&ldsA[h2 * 4096 + (wr + mf * 16 + fr) * 32 + fq * 8];
#pragma unroll
            for (int nf = 0; nf < 2; ++nf) {
                const int br_ = h2 * 2048 + (wc + nf * 16 + fr) * 32 + fq * 8;
                short8 bah = *(const short8*)&ldsB[br_];
                short8 bal = *(const short8*)&ldsB[4096 + br_];
                short8 bgh = *(const short8*)&ldsB[8192 + br_];
                short8 bgl = *(const short8*)&ldsB[12288 + br_];
#pragma unroll
                for (int mf = 0; mf < 4; ++mf) {
                    aa[mf][nf] = __builtin_amdgcn_mfma_f32_16x16x32_bf16(ah[mf], bah, aa[mf][nf], 0, 0, 0);
                    aa[mf][nf] = __builtin_amdgcn_mfma_f32_16x16x32_bf16(ah[mf], bal, aa[mf][nf], 0, 0, 0);
                    ag[mf][nf] = __builtin_amdgcn_mfma_f32_16x16x32_bf16(ah[mf], bgh, ag[mf][nf], 0, 0, 0);
                    ag[mf][nf] = __builtin_amdgcn_mfma_f32_16x16x32_bf16(ah[mf], bgl, ag[mf][nf], 0, 0, 0);
                }
            }
        }
        __syncthreads();
    }
#pragma unroll
    for (int nf = 0; nf < 2; ++nf) {
        const int ch = p0 + wc + nf * 16 + fr;
        const float ba = b1[ch], bg = b1[1024 + ch];
#pragma unroll
        for (int mf = 0; mf < 4; ++mf) {
#pragma unroll
            for (int v = 0; v < 4; ++v) {
                const int row = m0 + wr + mf * 16 + fq * 4 + v;
                float u = aa[mf][nf][v] + ba, g = ag[mf][nf][v] + bg;
                Obf[(size_t)row * 1024 + ch] = bf16rne(gelu_exact(u) * g);
            }
        }
    }
}

// ---- ctx GEMM: 64-row x 80-col tile, K-chunk 1024, BK=64; grid (16,32) ----
__global__ __launch_bounds__(256) void ctx_mfma(
    const unsigned short* __restrict__ kpT, const unsigned short* __restrict__ vT,
    float* __restrict__ ctxp)
{
    __shared__ unsigned short la[4096];        // [2 halves][64][32]
    __shared__ unsigned short lb[5120];        // [2 halves][80][32]
    int bx, by; xcd_swz(bx, by);
    const int bh = by, mt = bx & 3, kc = bx >> 2;
    const int tid = threadIdx.x;
    const int l = tid & 63, w = tid >> 6;
    const int wr = w * 16, fr = l & 15, fq = l >> 4;
    const int sr = tid >> 2, sc = (tid & 3) * 8;
    const unsigned short* ga  = kpT + ((size_t)bh * 256 + mt * 64 + sr) * 4096 + kc * 1024 + sc;
    const unsigned short* gb  = vT + ((size_t)bh * 80 + sr) * 4096 + kc * 1024 + sc;
    const unsigned short* gb2 = vT + ((size_t)bh * 80 + 64 + sr) * 4096 + kc * 1024 + sc;

    f32x4 acc[5];
#pragma unroll
    for (int j = 0; j < 5; ++j) acc[j] = (f32x4){0.f, 0.f, 0.f, 0.f};

    for (int k0 = 0; k0 < 1024; k0 += 64) {
        glds16(ga + k0, la + tid * 8);
        glds16(ga + k0 + 32, la + 2048 + tid * 8);
        glds16(gb + k0, lb + tid * 8);
        glds16(gb + k0 + 32, lb + 2560 + tid * 8);
        if (tid < 64) {
            glds16(gb2 + k0, lb + 2048 + tid * 8);
            glds16(gb2 + k0 + 32, lb + 2560 + 2048 + tid * 8);
        }
        __syncthreads();
#pragma unroll
        for (int h2 = 0; h2 < 2; ++h2) {
            short8 av = *(const short8*)&la[h2 * 2048 + (wr + fr) * 32 + fq * 8];
#pragma unroll
            for (int nf = 0; nf < 5; ++nf) {
                short8 bv = *(const short8*)&lb[h2 * 2560 + (nf * 16 + fr) * 32 + fq * 8];
                acc[nf] = __builtin_amdgcn_mfma_f32_16x16x32_bf16(av, bv, acc[nf], 0, 0, 0);
            }
        }
        __syncthreads();
    }
#pragma unroll
    for (int v = 0; v < 4; ++v) {
        const int row = mt * 64 + wr + fq * 4 + v;
#pragma unroll
        for (int nf = 0; nf < 5; ++nf)
            ctxp[((size_t)(kc * 32 + bh) * 256 + row) * 80 + nf * 16 + fr] = acc[nf][v];
    }
}

// ---- reduce ctx partials over 4 k-chunks, transpose, split -> ctxT[bh][80][256] ----
__global__ __launch_bounds__(256) void ctx_fix(
    const float* __restrict__ ctxp, unsigned short* __restrict__ cth,
    unsigned short* __restrict__ ctl)
{
    __shared__ float s[64][81];
    const int m0 = blockIdx.x * 64, bh = blockIdx.y;
    const int tid = threadIdx.x;
    for (int i = tid; i < 5120; i += 256) {
        const int ml = i / 80, dc = i % 80;
        float sum = 0.f;
#pragma unroll
        for (int kc = 0; kc < 4; ++kc)
            sum += ctxp[((size_t)(kc * 32 + bh) * 256 + m0 + ml) * 80 + dc];
        s[ml][dc] = sum;
    }
    __syncthreads();
    for (int i = tid; i < 5120; i += 256) {
        const int dc = i >> 6, ml = i & 63;
        unsigned short hh_, ll_;
        splitf(s[ml][dc], hh_, ll_);
        cth[((size_t)bh * 80 + dc) * 256 + m0 + ml] = hh_;
        ctl[((size_t)bh * 80 + dc) * 256 + m0 + ml] = ll_;
    }
}

// ---- fused q-side: dd = q@projT (K=64) -> row max -> exp -> qp (swizzled LDS)
//      -> o = (qp @ ctxT)/(qp . ksum) (K=256). grid (32 tok-tiles, 32 bh). ----
__global__ __launch_bounds__(256) void qo_mfma(
    const unsigned short* __restrict__ qhi,
    const unsigned short* __restrict__ pmh, const unsigned short* __restrict__ pml,
    const unsigned short* __restrict__ cth, const unsigned short* __restrict__ ctl,
    const float* __restrict__ diagq, unsigned short* __restrict__ osh)
{
    __shared__ unsigned short lds[32768 + 5120];   // qp tile (unions phase1 staging) | ctx staging
    __shared__ float rmax2[128][2];
    int bx, by; xcd_swz(bx, by);
    const int bh = by, b = bh >> 2, hh = bh & 3;
    const int t0 = bx * 128;
    const int tid = threadIdx.x;
    const int l = tid & 63, w = tid >> 6;
    const int fr = l & 15, fq = l >> 4;

    // ---- phase 1: dd[128 tok][256 m], K = 64 ----
    const int wr1 = (w >> 1) * 64, wc1 = (w & 1) * 128;
    f32x4 a1[4][8];
#pragma unroll
    for (int i = 0; i < 4; ++i)
#pragma unroll
        for (int j = 0; j < 8; ++j) a1[i][j] = (f32x4){0.f, 0.f, 0.f, 0.f};

    const unsigned short* gq = qhi + (size_t)(b * 4096 + t0) * 256 + hh * 64;
#pragma unroll
    for (int ks = 0; ks < 2; ++ks) {
        const int k0 = ks * 32;
        // A: 128 rows x 32 (512 chunks), stride 256 shorts
        glds16(gq + (size_t)(tid >> 2) * 256 + k0 + (tid & 3) * 8, lds + tid * 8);
        glds16(gq + (size_t)(64 + (tid >> 2)) * 256 + k0 + (tid & 3) * 8, lds + (tid + 256) * 8);
        // B: 2 planes x 256 rows x 32 (1024 chunks each)
#pragma unroll
        for (int i2 = 0; i2 < 4; ++i2) {
            const int c = tid + i2 * 256;
            glds16(pmh + (size_t)(c >> 2) * 64 + k0 + (c & 3) * 8, lds + 4096 + c * 8);
            glds16(pml + (size_t)(c >> 2) * 64 + k0 + (c & 3) * 8, lds + 12288 + c * 8);
        }
        __syncthreads();
        short8 av[4];
#pragma unroll
        for (int mf = 0; mf < 4; ++mf)
            av[mf] = *(const short8*)&lds[(wr1 + mf * 16 + fr) * 32 + fq * 8];
#pragma unroll
        for (int nf = 0; nf < 8; ++nf) {
            short8 bh_ = *(const short8*)&lds[4096 + (wc1 + nf * 16 + fr) * 32 + fq * 8];
            short8 bl_ = *(const short8*)&lds[12288 + (wc1 + nf * 16 + fr) * 32 + fq * 8];
#pragma unroll
            for (int mf = 0; mf < 4; ++mf) {
                a1[mf][nf] = __builtin_amdgcn_mfma_f32_16x16x32_bf16(av[mf], bh_, a1[mf][nf], 0, 0, 0);
                a1[mf][nf] = __builtin_amdgcn_mfma_f32_16x16x32_bf16(av[mf], bl_, a1[mf][nf], 0, 0, 0);
            }
        }
        __syncthreads();
    }
    // ---- row max ----
#pragma unroll
    for (int mf = 0; mf < 4; ++mf)
#pragma unroll
        for (int v = 0; v < 4; ++v) {
            float rm = a1[mf][0][v];
#pragma unroll
            for (int nf = 1; nf < 8; ++nf) rm = fmaxf(rm, a1[mf][nf][v]);
            rm = fmaxf(rm, __shfl_xor(rm, 1));
            rm = fmaxf(rm, __shfl_xor(rm, 2));
            rm = fmaxf(rm, __shfl_xor(rm, 4));
            rm = fmaxf(rm, __shfl_xor(rm, 8));
            if (fr == 0) rmax2[wr1 + mf * 16 + fq * 4 + v][w & 1] = rm;
        }
    __syncthreads();
    // ---- exp -> qp bf16 into swizzled LDS tile [128][256] ----
#pragma unroll
    for (int mf = 0; mf < 4; ++mf)
#pragma unroll
        for (int v = 0; v < 4; ++v) {
            const int tok = wr1 + mf * 16 + fq * 4 + v;
            const float dg = diagq[(size_t)(b * 4096 + t0 + tok) * 4 + hh]
                           + fmaxf(rmax2[tok][0], rmax2[tok][1]);
#pragma unroll
            for (int nf = 0; nf < 8; ++nf) {
                const int m = wc1 + nf * 16 + fr;
                lds[tok * 256 + (m ^ ((tok & 7) << 3))] =
                    bf16rne(RATIO * (expf(a1[mf][nf][v] - dg) + EPSF));
            }
        }
    __syncthreads();

    // ---- phase 2: o[128 tok][80] = qp @ ctxT (K=256, B split), col 64 = denominator ----
    unsigned short* lds2 = lds + 32768;
    f32x4 a2[2][5];
#pragma unroll
    for (int i = 0; i < 2; ++i)
#pragma unroll
        for (int j = 0; j < 5; ++j) a2[i][j] = (f32x4){0.f, 0.f, 0.f, 0.f};
    const size_t bbase = (size_t)bh * 80 * 256;

    for (int k0 = 0; k0 < 256; k0 += 32) {
        glds16(cth + bbase + (size_t)(tid >> 2) * 256 + k0 + (tid & 3) * 8, lds2 + tid * 8);
        glds16(ctl + bbase + (size_t)(tid >> 2) * 256 + k0 + (tid & 3) * 8, lds2 + 2560 + tid * 8);
        if (tid < 64) {
            const int c = 256 + tid;
            glds16(cth + bbase + (size_t)(c >> 2) * 256 + k0 + (c & 3) * 8, lds2 + c * 8);
            glds16(ctl + bbase + (size_t)(c >> 2) * 256 + k0 + (c & 3) * 8, lds2 + 2560 + c * 8);
        }
        __syncthreads();
        short8 av[2];
#pragma unroll
        for (int mf = 0; mf < 2; ++mf) {
            const int tok = w * 32 + mf * 16 + fr;
            const int c = ((k0 >> 3) + fq) ^ (tok & 7);
            av[mf] = *(const short8*)&lds[tok * 256 + c * 8];
        }
#pragma unroll
        for (int nf = 0; nf < 5; ++nf) {
            const int off = (nf * 16 + fr) * 32 + fq * 8;
            short8 bvh = *(const short8*)&lds2[off];
            short8 bvl = *(const short8*)&lds2[2560 + off];
#pragma unroll
            for (int mf = 0; mf < 2; ++mf) {
                a2[mf][nf] = __builtin_amdgcn_mfma_f32_16x16x32_bf16(av[mf], bvh, a2[mf][nf], 0, 0, 0);
                a2[mf][nf] = __builtin_amdgcn_mfma_f32_16x16x32_bf16(av[mf], bvl, a2[mf][nf], 0, 0, 0);
            }
        }
        __syncthreads();
    }
#pragma unroll
    for (int mf = 0; mf < 2; ++mf)
#pragma unroll
        for (int v = 0; v < 4; ++v) {
            const float den = __shfl(a2[mf][4][v], (int)(l & 48));
            const float dinv = 1.0f / den;
            const int tok = w * 32 + mf * 16 + fq * 4 + v;
            const size_t obase = (size_t)(b * 4096 + t0 + tok) * 256 + hh * 64;
#pragma unroll
            for (int nf = 0; nf < 4; ++nf)
                osh[obase + nf * 16 + fr] = bf16rne(a2[mf][nf][v] * dinv);
        }
}

// ---- pooling + classifier ----
__global__ __launch_bounds__(256) void pool1_kernel(const float* __restrict__ h, float* __restrict__ part)
{
    const int b = blockIdx.x >> 4, ch = blockIdx.x & 15;
    const int tid = threadIdx.x;
    float acc = 0.f;
    for (int n = 0; n < 256; ++n)
        acc += h[((size_t)(b * 4096 + ch * 256 + n)) * 256 + tid];
    part[(size_t)blockIdx.x * 256 + tid] = acc;
}

__global__ __launch_bounds__(256) void pool2_kernel(
    const float* __restrict__ part, const float* __restrict__ cw,
    const float* __restrict__ cb, float* __restrict__ out)
{
    const int b = blockIdx.x, tid = threadIdx.x;
    float acc = 0.f;
#pragma unroll
    for (int c = 0; c < 16; ++c) acc += part[(size_t)(b * 16 + c) * 256 + tid];
    float val = acc * (1.0f / 4096.0f) * cw[tid];
#pragma unroll
    for (int s = 1; s < 64; s <<= 1) val += __shfl_xor(val, s);
    __shared__ float red[4];
    if ((tid & 63) == 0) red[tid >> 6] = val;
    __syncthreads();
    if (tid == 0) out[b] = red[0] + red[1] + red[2] + red[3] + cb[0];
}

extern "C" void kernel_launch(void* const* d_in, const int* in_sizes, int n_in,
                              void* d_out, int out_size, void* d_ws, size_t ws_size,
                              hipStream_t stream)
{
    (void)in_sizes; (void)n_in;
    if (ws_size < WS_BYTES) {
        fill_sentinel<<<1, 64, 0, stream>>>((float*)d_out, out_size);
        return;
    }

    const float* x     = (const float*)d_in[0];
    const float* projw = (const float*)d_in[1];
    const float* projb = (const float*)d_in[2];
    const float* ln1g  = (const float*)d_in[3];
    const float* ln1b  = (const float*)d_in[4];
    const float* wq    = (const float*)d_in[5];
    const float* bq    = (const float*)d_in[6];
    const float* wk    = (const float*)d_in[7];
    const float* bk    = (const float*)d_in[8];
    const float* wv    = (const float*)d_in[9];
    const float* bv    = (const float*)d_in[10];
    const float* wo    = (const float*)d_in[11];
    const float* bo    = (const float*)d_in[12];
    const float* ln2g  = (const float*)d_in[13];
    const float* ln2b  = (const float*)d_in[14];
    const float* w1    = (const float*)d_in[15];
    const float* b1    = (const float*)d_in[16];
    const float* w2    = (const float*)d_in[17];
    const float* b2    = (const float*)d_in[18];
    const float* clfw  = (const float*)d_in[19];
    const float* clfb  = (const float*)d_in[20];
    const float* projm = (const float*)d_in[21];

    char* WS = (char*)d_ws;
    float* h            = (float*)(WS + OFF_H);
    unsigned short* ysh = (unsigned short*)(WS + OFF_YS);
    unsigned short* wts = (unsigned short*)(WS + OFF_WTS);
    unsigned short* khi = (unsigned short*)(WS + OFF_QK);
    unsigned short* qhi = khi + 8388608;
    unsigned short* big = (unsigned short*)(WS + OFF_BIG);   // kpT / ffb / x-split
    unsigned short* vT  = (unsigned short*)(WS + OFF_VT);
    float* ctxp         = (float*)(WS + OFF_CTXP);
    unsigned short* cth = (unsigned short*)(WS + OFF_CTXTH);
    unsigned short* ctl = (unsigned short*)(WS + OFF_CTXTL);
    float* diagq        = (float*)(WS + OFF_DIAGQ);
    float* diagk        = (float*)(WS + OFF_DIAGK);
    unsigned* gmax      = (unsigned*)(WS + OFF_GMAX);
    float* pool         = (float*)(WS + OFF_POOL);
    unsigned short* pmt_h = (unsigned short*)(WS + OFF_PMTH);
    unsigned short* pmt_l = (unsigned short*)(WS + OFF_PMTL);
    unsigned short* pwt_h = (unsigned short*)(WS + OFF_PWTH);
    unsigned short* pwt_l = (unsigned short*)(WS + OFF_PWTL);
    // aliases
    unsigned short* xsh = big;               // prologue only
    unsigned short* xsl = big + 2097152;
    unsigned short* kpT = big;               // [32][256][4096]
    unsigned short* ffb = big;               // [32768][1024]
    unsigned short* osh = ysh;               // o bf16 (ys dead by then)

    // ---- prologue ----
    split_scale<<<8192, 256, 0, stream>>>(x, xsh, xsl, 2097152, 1.0f);
    splitT<<<64, 256, 0, stream>>>(projw, pwt_h, pwt_l, 6, 256);
    split_scale<<<64, 256, 0, stream>>>(projm, pmt_h, pmt_l, 16384, DN);
    vt_init<<<1024, 256, 0, stream>>>(vT, gmax);
    split_weights<<<16384, 256, 0, stream>>>(wq, wk, wv, wo, w1, w2, wts);
    gemm_mf<0, true, true><<<dim3(2, 256), 256, 0, stream>>>(xsh, xsl, 64, pwt_h, pwt_l, 64, 64,
        projb, nullptr, h, 256, nullptr, nullptr, nullptr);

    for (int l = 0; l < 4; ++l) {
        unsigned short* wl = wts + (size_t)l * 2097152;

        // ---- attention ----
        ln_bf16<<<8192, 256, 0, stream>>>(h, ln1g + l * 256, ln1b + l * 256, ysh);
        gemm_mf<8, false, true><<<dim3(2, 256), 256, 0, stream>>>(ysh, nullptr, 256,
            wl + WV_H, wl + WV_L, 256, 256, bv + l * 256, nullptr, nullptr, 256, vT, nullptr, nullptr);
        gemm_mf<2, false, true><<<dim3(2, 256), 256, 0, stream>>>(ysh, nullptr, 256,
            wl + WK_H, wl + WK_L, 256, 256, bk + l * 256, nullptr, nullptr, 256, khi, diagk, nullptr);
        gemm_mf<2, false, true><<<dim3(2, 256), 256, 0, stream>>>(ysh, nullptr, 256,
            wl + WQ_H, wl + WQ_L, 256, 256, bq + l * 256, nullptr, nullptr, 256, qhi, diagq, nullptr);
        gemm_mf<4, false, false><<<dim3(2, 1024), 256, 0, stream>>>(khi, nullptr, 64,
            pmt_h, nullptr, 64, 64, nullptr, nullptr, nullptr, 256, nullptr, nullptr, gmax + l);
        gemm_mf<6, false, true><<<dim3(2, 1024), 256, 0, stream>>>(khi, nullptr, 64,
            pmt_h, pmt_l, 64, 64, nullptr, nullptr, nullptr, 256, kpT, diagk, gmax + l);
        ctx_mfma<<<dim3(16, 32), 256, 0, stream>>>(kpT, vT, ctxp);
        ctx_fix<<<dim3(4, 32), 256, 0, stream>>>(ctxp, cth, ctl);
        qo_mfma<<<dim3(32, 32), 256, 0, stream>>>(qhi, pmt_h, pmt_l, cth, ctl, diagq, osh);
        gemm_mf<1, false, true><<<dim3(2, 256), 256, 0, stream>>>(osh, nullptr, 256,
            wl + WO_H, wl + WO_L, 256, 256, bo + l * 256, h, h, 256, nullptr, nullptr, nullptr);

        // ---- feed-forward ----
        ln_bf16<<<8192, 256, 0, stream>>>(h, ln2g + l * 256, ln2b + l * 256, ysh);
        gemm_glu<<<dim3(16, 256), 256, 0, stream>>>(ysh, wl + W1_H, wl + W1_L,
            b1 + (size_t)l * 2048, ffb);
        gemm_mf<1, false, true><<<dim3(2, 256), 256, 0, stream>>>(ffb, nullptr, 1024,
            wl + W2_H, wl + W2_L, 1024, 1024, b2 + l * 256, h, h, 256, nullptr, nullptr, nullptr);
    }

    pool1_kernel<<<128, 256, 0, stream>>>(h, pool);
    pool2_kernel<<<8, 256, 0, stream>>>(pool, clfw, clfb, (float*)d_out);
}

// Round 10
// 1424.045 us; speedup vs baseline: 8.4267x; 1.0635x over previous
//
#include <hip/hip_runtime.h>
#include <cstdint>
#include <cstddef>

// ---- problem constants ----
constexpr float DN = 0.35355339059327373f;   // 64^-0.25
constexpr float RATIO = 0.0625f;             // 256^-0.5
constexpr float EPSF = 1e-4f;

typedef __attribute__((ext_vector_type(8))) short short8;   // bf16 MFMA fragment
typedef __attribute__((ext_vector_type(4))) float f32x4;    // MFMA accumulator

// ---- workspace layout (byte offsets); proven budget >= 209,715,200 B ----
constexpr size_t OFF_H     = 0;              // fp32 residual 33,554,432
constexpr size_t OFF_YS    = 33554432;       // ysh (osh alias) 16,777,216
constexpr size_t OFF_WTS   = 50331648;       // all-layer weight splits 16,777,216
constexpr size_t OFF_QK    = 67108864;       // khi 16,777,216 | qhi 16,777,216
constexpr size_t OFF_BIG   = 100663296;      // kpT / ffb / x-split 67,108,864
constexpr size_t OFF_VT    = 167772160;      // vT [32][80][4096] bf16 20,971,520
constexpr size_t OFF_CTXP  = 188743680;      // ctx partials [4][32][256][80] f32 10,485,760
constexpr size_t OFF_CTXTH = 199229440;      // ctxT hi [32][80][256] 1,310,720
constexpr size_t OFF_CTXTL = 200540160;      // ctxT lo 1,310,720
constexpr size_t OFF_DIAGQ = 201850880;      // 524,288
constexpr size_t OFF_DIAGK = 202375168;      // 524,288
constexpr size_t OFF_GMAX  = 203423744;      // 256 (4 per-layer slots used)
constexpr size_t OFF_POOL  = 203424000;      // 131,072
constexpr size_t OFF_PMTH  = 207749376;
constexpr size_t OFF_PMTL  = 207782144;
constexpr size_t OFF_PWTH  = 207814912;
constexpr size_t OFF_PWTL  = 207847680;
constexpr size_t WS_BYTES  = 207880448;

// per-layer short-offsets inside the WTS region (layer stride 2,097,152 shorts)
constexpr size_t WQ_H = 0,       WQ_L = 65536;
constexpr size_t WK_H = 131072,  WK_L = 196608;
constexpr size_t WV_H = 262144,  WV_L = 327680;
constexpr size_t WO_H = 393216,  WO_L = 458752;
constexpr size_t W1_H = 524288,  W1_L = 1048576;
constexpr size_t W2_H = 1572864, W2_L = 1835008;

__device__ __forceinline__ unsigned fkey(float f) {
    unsigned u = __float_as_uint(f);
    return (u & 0x80000000u) ? ~u : (u | 0x80000000u);
}
__device__ __forceinline__ float funkey(unsigned k) {
    unsigned u = (k & 0x80000000u) ? (k ^ 0x80000000u) : ~k;
    return __uint_as_float(u);
}
__device__ __forceinline__ float gelu_exact(float x) {
    return 0.5f * x * (1.0f + erff(x * 0.70710678118654752f));
}
__device__ __forceinline__ void splitf(float x, unsigned short& h, unsigned short& l) {
    unsigned u = __float_as_uint(x);
    unsigned hv = (u + 0x7FFFu + ((u >> 16) & 1)) >> 16;
    h = (unsigned short)hv;
    float lo = x - __uint_as_float(hv << 16);
    unsigned u2 = __float_as_uint(lo);
    l = (unsigned short)((u2 + 0x7FFFu + ((u2 >> 16) & 1)) >> 16);
}
__device__ __forceinline__ unsigned short bf16rne(float x) {
    unsigned u = __float_as_uint(x);
    return (unsigned short)((u + 0x7FFFu + ((u >> 16) & 1)) >> 16);
}
// XCD-aware block swizzle (requires total blocks % 8 == 0)
__device__ __forceinline__ void xcd_swz(int& bx, int& by) {
    const int gx = gridDim.x;
    const int total = gx * gridDim.y;
    int flat = blockIdx.y * gx + blockIdx.x;
    flat = (flat & 7) * (total >> 3) + (flat >> 3);
    bx = flat % gx; by = flat / gx;
}

// ---- async global->LDS 16B (wave-uniform base + lane*16, linear dest) ----
#if defined(__has_builtin)
#if __has_builtin(__builtin_amdgcn_global_load_lds)
#define HAVE_GLDS 1
#endif
#endif
__device__ __forceinline__ void glds16(const unsigned short* g, unsigned short* l) {
#ifdef HAVE_GLDS
    __builtin_amdgcn_global_load_lds(
        (const __attribute__((address_space(1))) unsigned int*)g,
        (__attribute__((address_space(3))) unsigned int*)l, 16, 0, 0);
#else
    *(uint4*)l = *(const uint4*)g;
#endif
}

__global__ void fill_sentinel(float* out, int n) {
    int i = threadIdx.x;
    if (i < n) out[i] = 12345.0f;
}
// fill vT rows 64..79 (row 64 = 1.0 for ksum fold) + zero per-layer gmax keys
__global__ __launch_bounds__(256) void vt_init(unsigned short* __restrict__ vT, unsigned* __restrict__ gm) {
    int i = blockIdx.x * 256 + threadIdx.x;        // 262,144 uint4
    if (i < 4) gm[i] = 0u;
    const int bh = i >> 13;
    const int r = (i >> 9) & 15;
    const unsigned val = (r == 0) ? 0x3F803F80u : 0u;
    uint4 q; q.x = val; q.y = val; q.z = val; q.w = val;
    *(uint4*)(vT + ((size_t)bh * 80 + 64 + r) * 4096 + ((size_t)(i & 511) << 3)) = q;
}

// ---- elementwise split (optional scale) ----
__global__ __launch_bounds__(256) void split_scale(
    const float* __restrict__ src, unsigned short* __restrict__ hi,
    unsigned short* __restrict__ lo, int n, float scale)
{
    int i = blockIdx.x * 256 + threadIdx.x;
    if (i < n) {
        unsigned short h, l;
        splitf(src[i] * scale, h, l);
        hi[i] = h; lo[i] = l;
    }
}

// ---- transpose-split weights: W [K,N] fp32 -> Wt hi/lo [N,K] bf16 ----
__global__ __launch_bounds__(256) void splitT(
    const float* __restrict__ W, unsigned short* __restrict__ hi,
    unsigned short* __restrict__ lo, int kshift, int N)
{
    int i = blockIdx.x * 256 + threadIdx.x;
    int K = 1 << kshift;
    int n = i >> kshift, k = i & (K - 1);
    unsigned short h, l;
    splitf(W[(size_t)k * N + n], h, l);
    hi[i] = h; lo[i] = l;
}

// ---- all-layer weight transpose-split: one dispatch, 4,194,304 elements ----
__global__ __launch_bounds__(256) void split_weights(
    const float* __restrict__ wq, const float* __restrict__ wk,
    const float* __restrict__ wv, const float* __restrict__ wo,
    const float* __restrict__ w1, const float* __restrict__ w2,
    unsigned short* __restrict__ dst)
{
    const int i = blockIdx.x * 256 + threadIdx.x;
    const int lay = i >> 20;
    const int r = i & 1048575;
    float val; size_t oh, ol;
    if (r < 262144) {
        const int m = r >> 16, e = r & 65535;
        const int n = e >> 8, k = e & 255;
        const float* W = (m == 0 ? wq : m == 1 ? wk : m == 2 ? wv : wo);
        val = W[(size_t)lay * 65536 + k * 256 + n];
        oh = (size_t)lay * 2097152 + (size_t)m * 131072 + e;
        ol = oh + 65536;
    } else if (r < 786432) {
        const int e = r - 262144;
        const int n = e >> 8, k = e & 255;
        val = w1[(size_t)lay * 524288 + (size_t)k * 2048 + n];
        oh = (size_t)lay * 2097152 + W1_H + e;
        ol = oh + 524288;
    } else {
        const int e = r - 786432;
        const int n = e >> 10, k = e & 1023;
        val = w2[(size_t)lay * 262144 + (size_t)k * 256 + n];
        oh = (size_t)lay * 2097152 + W2_H + e;
        ol = oh + 262144;
    }
    unsigned short h, l;
    splitf(val, h, l);
    dst[oh] = h; dst[ol] = l;
}

// ---- LayerNorm -> single bf16 plane ----
__global__ __launch_bounds__(256) void ln_bf16(
    const float* __restrict__ x, const float* __restrict__ g,
    const float* __restrict__ b, unsigned short* __restrict__ yhi)
{
    const int row = blockIdx.x * 4 + (threadIdx.x >> 6);
    const int lane = threadIdx.x & 63;
    float4 t = *(const float4*)&x[(size_t)row * 256 + lane * 4];
    float s = t.x + t.y + t.z + t.w;
#pragma unroll
    for (int sh = 1; sh < 64; sh <<= 1) s += __shfl_xor(s, sh);
    const float mu = s * (1.0f / 256.0f);
    const float dx = t.x - mu, dy = t.y - mu, dz = t.z - mu, dw = t.w - mu;
    float vv = dx * dx + dy * dy + dz * dz + dw * dw;
#pragma unroll
    for (int sh = 1; sh < 64; sh <<= 1) vv += __shfl_xor(vv, sh);
    const float rstd = rsqrtf(vv * (1.0f / 256.0f) + 1e-5f);
    float4 gv = *(const float4*)&g[lane * 4];
    float4 bv = *(const float4*)&b[lane * 4];
    unsigned short h0 = bf16rne(dx * rstd * gv.x + bv.x);
    unsigned short h1 = bf16rne(dy * rstd * gv.y + bv.y);
    unsigned short h2 = bf16rne(dz * rstd * gv.z + bv.z);
    unsigned short h3 = bf16rne(dw * rstd * gv.w + bv.w);
    uint2 ph;
    ph.x = (unsigned)h0 | ((unsigned)h1 << 16); ph.y = (unsigned)h2 | ((unsigned)h3 << 16);
    *(uint2*)&yhi[(size_t)row * 256 + lane * 4] = ph;
}

// ---- bf16 MFMA GEMM, tile 128x128, BK=64 (two 32-wide sub-planes), 4 waves ----
// EPI: 0 bias->f32 C | 1 bias(nullable)+res->f32 C | 2 bias->bf16 plane + per-head diag
//      4 global max -> keys[0]
//      6 kp = exp epilogue + TRANSPOSED write to kpT[bh][m][n]
//      8 bias -> bf16 TRANSPOSED write to vT[bh][d][n] (80-row planes)
template<int EPI, bool ASPLIT, bool BSPLIT>
__global__ __launch_bounds__(256) void gemm_mf(
    const unsigned short* __restrict__ Ahi, const unsigned short* __restrict__ Alo, int lda,
    const unsigned short* __restrict__ Bhi, const unsigned short* __restrict__ Blo, int ldb,
    int K,
    const float* __restrict__ bias, const float* __restrict__ res,
    float* __restrict__ C, int ldc,
    unsigned short* __restrict__ Obf,
    const float* __restrict__ diag, unsigned* __restrict__ keys)
{
    constexpr int NP = (ASPLIT ? 2 : 1) + (BSPLIT ? 2 : 1);
    constexpr int PB = ASPLIT ? 2 : 1;                 // B-hi plane index
    constexpr int NEED = (EPI == 6 || EPI == 8) ? 16384 : 0;
    constexpr int LDSN = (NP * 8192 > NEED) ? NP * 8192 : NEED;
    __shared__ unsigned short lds[LDSN];
    __shared__ float red[4];
#define LX(p, h, r, c) lds[(p) * 8192 + (h) * 4096 + (r) * 32 + (c)]
    int bx, by; xcd_swz(bx, by);
    const int tid = threadIdx.x;
    const int m0 = by * 128, n0 = bx * 128;
    const int sr = tid >> 2, sc = (tid & 3) * 8;       // stage row / short col
    const unsigned short* ga_h = Ahi + (size_t)(m0 + sr) * lda + sc;
    const unsigned short* ga_l = ASPLIT ? (Alo + (size_t)(m0 + sr) * lda + sc) : nullptr;
    const unsigned short* gb_h = Bhi + (size_t)(n0 + sr) * ldb + sc;
    const unsigned short* gb_l = BSPLIT ? (Blo + (size_t)(n0 + sr) * ldb + sc) : nullptr;
    unsigned short* lp = lds + tid * 8;
    const int l = tid & 63, w = tid >> 6;
    const int wr = (w >> 1) * 64, wc = (w & 1) * 64;
    const int fr = l & 15, fq = l >> 4;

    f32x4 acc[4][4];
#pragma unroll
    for (int i = 0; i < 4; ++i)
#pragma unroll
        for (int j = 0; j < 4; ++j) acc[i][j] = (f32x4){0.f, 0.f, 0.f, 0.f};

    for (int k0 = 0; k0 < K; k0 += 64) {
        glds16(ga_h + k0, lp);
        glds16(ga_h + (size_t)64 * lda + k0, lp + 2048);
        glds16(ga_h + k0 + 32, lp + 4096);
        glds16(ga_h + (size_t)64 * lda + k0 + 32, lp + 6144);
        if (ASPLIT) {
            glds16(ga_l + k0, lp + 8192);
            glds16(ga_l + (size_t)64 * lda + k0, lp + 10240);
            glds16(ga_l + k0 + 32, lp + 12288);
            glds16(ga_l + (size_t)64 * lda + k0 + 32, lp + 14336);
        }
        glds16(gb_h + k0, lp + PB * 8192);
        glds16(gb_h + (size_t)64 * ldb + k0, lp + PB * 8192 + 2048);
        glds16(gb_h + k0 + 32, lp + PB * 8192 + 4096);
        glds16(gb_h + (size_t)64 * ldb + k0 + 32, lp + PB * 8192 + 6144);
        if (BSPLIT) {
            glds16(gb_l + k0, lp + (PB + 1) * 8192);
            glds16(gb_l + (size_t)64 * ldb + k0, lp + (PB + 1) * 8192 + 2048);
            glds16(gb_l + k0 + 32, lp + (PB + 1) * 8192 + 4096);
            glds16(gb_l + (size_t)64 * ldb + k0 + 32, lp + (PB + 1) * 8192 + 6144);
        }
        __syncthreads();
#pragma unroll
        for (int h2 = 0; h2 < 2; ++h2) {
            short8 ah[4], al[4];
#pragma unroll
            for (int mf = 0; mf < 4; ++mf) {
                ah[mf] = *(const short8*)&LX(0, h2, wr + mf * 16 + fr, fq * 8);
                if (ASPLIT) al[mf] = *(const short8*)&LX(1, h2, wr + mf * 16 + fr, fq * 8);
            }
#pragma unroll
            for (int nf = 0; nf < 4; ++nf) {
                short8 bh = *(const short8*)&LX(PB, h2, wc + nf * 16 + fr, fq * 8);
#pragma unroll
                for (int mf = 0; mf < 4; ++mf) {
                    acc[mf][nf] = __builtin_amdgcn_mfma_f32_16x16x32_bf16(ah[mf], bh, acc[mf][nf], 0, 0, 0);
                    if (ASPLIT)
                        acc[mf][nf] = __builtin_amdgcn_mfma_f32_16x16x32_bf16(al[mf], bh, acc[mf][nf], 0, 0, 0);
                }
                if (BSPLIT) {
                    short8 bl = *(const short8*)&LX(PB + 1, h2, wc + nf * 16 + fr, fq * 8);
#pragma unroll
                    for (int mf = 0; mf < 4; ++mf)
                        acc[mf][nf] = __builtin_amdgcn_mfma_f32_16x16x32_bf16(ah[mf], bl, acc[mf][nf], 0, 0, 0);
                }
            }
        }
        __syncthreads();
    }

    if constexpr (EPI == 4) {
        float m = -3.4e38f;
#pragma unroll
        for (int mf = 0; mf < 4; ++mf)
#pragma unroll
            for (int nf = 0; nf < 4; ++nf)
#pragma unroll
                for (int v = 0; v < 4; ++v) m = fmaxf(m, acc[mf][nf][v]);
#pragma unroll
        for (int s = 1; s < 64; s <<= 1) m = fmaxf(m, __shfl_xor(m, s));
        if (l == 0) red[w] = m;
        __syncthreads();
        if (tid == 0)
            atomicMax(keys, fkey(fmaxf(fmaxf(red[0], red[1]), fmaxf(red[2], red[3]))));
    } else if constexpr (EPI == 6) {
        const float Mg = funkey(*keys);
        unsigned short* tb = lds;
#pragma unroll
        for (int mf = 0; mf < 4; ++mf)
#pragma unroll
            for (int v = 0; v < 4; ++v) {
                const int rl = wr + mf * 16 + fq * 4 + v;
                const float dg = diag[m0 + rl] + Mg;
#pragma unroll
                for (int nf = 0; nf < 4; ++nf) {
                    const int cl = wc + nf * 16 + fr;
                    tb[rl * 128 + cl] = bf16rne(RATIO * (__expf(acc[mf][nf][v] - dg) + EPSF));
                }
            }
        __syncthreads();
        const int tokbase = m0 >> 2;
        const int b = tokbase >> 12, nib = tokbase & 4095;
        const int ml = tid & 127, g2 = tid >> 7;
#pragma unroll
        for (int hh2 = 0; hh2 < 2; ++hh2) {
            const int hh = g2 * 2 + hh2;
            unsigned short* dst = Obf + ((size_t)((b * 4 + hh) * 256 + n0 + ml)) * 4096 + nib;
#pragma unroll
            for (int qq = 0; qq < 4; ++qq) {
                uint4 qv;
                unsigned wv[4];
#pragma unroll
                for (int j = 0; j < 4; ++j) {
                    unsigned s0 = tb[((qq * 8 + j * 2 + 0) * 4 + hh) * 128 + ml];
                    unsigned s1 = tb[((qq * 8 + j * 2 + 1) * 4 + hh) * 128 + ml];
                    wv[j] = s0 | (s1 << 16);
                }
                qv.x = wv[0]; qv.y = wv[1]; qv.z = wv[2]; qv.w = wv[3];
                *(uint4*)(dst + qq * 8) = qv;
            }
        }
    } else if constexpr (EPI == 8) {
        unsigned short* tb = lds;
#pragma unroll
        for (int mf = 0; mf < 4; ++mf)
#pragma unroll
            for (int nf = 0; nf < 4; ++nf) {
                const int cl = wc + nf * 16 + fr;
                const float bb = bias[n0 + cl];
#pragma unroll
                for (int v = 0; v < 4; ++v) {
                    const int rl = wr + mf * 16 + fq * 4 + v;
                    tb[rl * 128 + cl] = bf16rne(acc[mf][nf][v] + bb);
                }
            }
        __syncthreads();
        const int b = m0 >> 12, nib = m0 & 4095;
        const int cl = tid & 127, half = tid >> 7;
        const int ch = n0 + cl, hh = ch >> 6, d = ch & 63;
        unsigned short* dst = Obf + ((size_t)((b * 4 + hh) * 80 + d)) * 4096 + nib + half * 64;
#pragma unroll
        for (int qq = 0; qq < 8; ++qq) {
            uint4 qv;
            unsigned wv[4];
#pragma unroll
            for (int j = 0; j < 4; ++j) {
                unsigned s0 = tb[(half * 64 + qq * 8 + j * 2 + 0) * 128 + cl];
                unsigned s1 = tb[(half * 64 + qq * 8 + j * 2 + 1) * 128 + cl];
                wv[j] = s0 | (s1 << 16);
            }
            qv.x = wv[0]; qv.y = wv[1]; qv.z = wv[2]; qv.w = wv[3];
            *(uint4*)(dst + qq * 8) = qv;
        }
    } else if constexpr (EPI == 2) {
        const int head = (n0 + wc) >> 6;
#pragma unroll
        for (int mf = 0; mf < 4; ++mf) {
            float sq[4] = {0.f, 0.f, 0.f, 0.f};
#pragma unroll
            for (int nf = 0; nf < 4; ++nf) {
                const int col = n0 + wc + nf * 16 + fr;
                const float bb = bias[col];
#pragma unroll
                for (int v = 0; v < 4; ++v) {
                    const int row = m0 + wr + mf * 16 + fq * 4 + v;
                    float val = acc[mf][nf][v] + bb;
                    Obf[(size_t)row * 256 + col] = bf16rne(val);
                    sq[v] += val * val;
                }
            }
#pragma unroll
            for (int v = 0; v < 4; ++v) {
                float s = sq[v];
                s += __shfl_xor(s, 1); s += __shfl_xor(s, 2);
                s += __shfl_xor(s, 4); s += __shfl_xor(s, 8);
                if (fr == 0)
                    ((float*)diag)[(size_t)(m0 + wr + mf * 16 + fq * 4 + v) * 4 + head] = s * 0.0625f;
            }
        }
    } else {
#pragma unroll
        for (int nf = 0; nf < 4; ++nf) {
            const int col = n0 + wc + nf * 16 + fr;
            float bb = 0.f;
            if (bias != nullptr) bb = bias[col];
#pragma unroll
            for (int mf = 0; mf < 4; ++mf) {
#pragma unroll
                for (int v = 0; v < 4; ++v) {
                    const int row = m0 + wr + mf * 16 + fq * 4 + v;
                    const size_t off = (size_t)row * ldc + col;
                    float val = acc[mf][nf][v] + bb;
                    if (EPI == 1) val += res[off];
                    C[off] = val;
                }
            }
        }
    }
#undef LX
}

// ---- fused GLU GEMM: A single bf16 plane, W split; BK=64 sub-plane staging ----
__global__ __launch_bounds__(256) void gemm_glu(
    const unsigned short* __restrict__ Ahi,
    const unsigned short* __restrict__ Whi, const unsigned short* __restrict__ Wlo,
    const float* __restrict__ b1, unsigned short* __restrict__ Obf)
{
    __shared__ unsigned short ldsA[8192];      // [2 halves][128][32]
    __shared__ unsigned short ldsB[16384];     // 4 planes x [2 halves][64][32]
    int bx, by; xcd_swz(bx, by);
    const int tid = threadIdx.x;
    const int m0 = by * 128, p0 = bx * 64;
    const int sr = tid >> 2, sc = (tid & 3) * 8;
    const unsigned short* ga  = Ahi + (size_t)(m0 + sr) * 256 + sc;
    const unsigned short* gb0 = Whi + (size_t)(p0 + sr) * 256 + sc;
    const unsigned short* gb1 = Wlo + (size_t)(p0 + sr) * 256 + sc;
    const unsigned short* gb2 = Whi + (size_t)(1024 + p0 + sr) * 256 + sc;
    const unsigned short* gb3 = Wlo + (size_t)(1024 + p0 + sr) * 256 + sc;
    unsigned short* lpA = ldsA + tid * 8;
    unsigned short* lpB = ldsB + tid * 8;
    const int l = tid & 63, w = tid >> 6;
    const int wr = (w >> 1) * 64, wc = (w & 1) * 32;
    const int fr = l & 15, fq = l >> 4;

    f32x4 aa[4][2], ag[4][2];
#pragma unroll
    for (int i = 0; i < 4; ++i)
#pragma unroll
        for (int j = 0; j < 2; ++j) {
            aa[i][j] = (f32x4){0.f, 0.f, 0.f, 0.f};
            ag[i][j] = (f32x4){0.f, 0.f, 0.f, 0.f};
        }

    for (int k0 = 0; k0 < 256; k0 += 64) {
        glds16(ga + k0, lpA);
        glds16(ga + 64 * 256 + k0, lpA + 2048);
        glds16(ga + k0 + 32, lpA + 4096);
        glds16(ga + 64 * 256 + k0 + 32, lpA + 6144);
        glds16(gb0 + k0, lpB);
        glds16(gb0 + k0 + 32, lpB + 2048);
        glds16(gb1 + k0, lpB + 4096);
        glds16(gb1 + k0 + 32, lpB + 6144);
        glds16(gb2 + k0, lpB + 8192);
        glds16(gb2 + k0 + 32, lpB + 10240);
        glds16(gb3 + k0, lpB + 12288);
        glds16(gb3 + k0 + 32, lpB + 14336);
        __syncthreads();
#pragma unroll
        for (int h2 = 0; h2 < 2; ++h2) {
            short8 ah[4];
#pragma unroll
            for (int mf = 0; mf < 4; ++mf)
                ah[mf] = *(const short8*)&ldsA[h2 * 4096 + (wr + mf * 16 + fr) * 32 + fq * 8];
#pragma unroll
            for (int nf = 0; nf < 2; ++nf) {
                const int br_ = h2 * 2048 + (wc + nf * 16 + fr) * 32 + fq * 8;
                short8 bah = *(const short8*)&ldsB[br_];
                short8 bal = *(const short8*)&ldsB[4096 + br_];
                short8 bgh = *(const short8*)&ldsB[8192 + br_];
                short8 bgl = *(const short8*)&ldsB[12288 + br_];
#pragma unroll
                for (int mf = 0; mf < 4; ++mf) {
                    aa[mf][nf] = __builtin_amdgcn_mfma_f32_16x16x32_bf16(ah[mf], bah, aa[mf][nf], 0, 0, 0);
                    aa[mf][nf] = __builtin_amdgcn_mfma_f32_16x16x32_bf16(ah[mf], bal, aa[mf][nf], 0, 0, 0);
                    ag[mf][nf] = __builtin_amdgcn_mfma_f32_16x16x32_bf16(ah[mf], bgh, ag[mf][nf], 0, 0, 0);
                    ag[mf][nf] = __builtin_amdgcn_mfma_f32_16x16x32_bf16(ah[mf], bgl, ag[mf][nf], 0, 0, 0);
                }
            }
        }
        __syncthreads();
    }
#pragma unroll
    for (int nf = 0; nf < 2; ++nf) {
        const int ch = p0 + wc + nf * 16 + fr;
        const float ba = b1[ch], bg = b1[1024 + ch];
#pragma unroll
        for (int mf = 0; mf < 4; ++mf) {
#pragma unroll
            for (int v = 0; v < 4; ++v) {
                const int row = m0 + wr + mf * 16 + fq * 4 + v;
                float u = aa[mf][nf][v] + ba, g = ag[mf][nf][v] + bg;
                Obf[(size_t)row * 1024 + ch] = bf16rne(gelu_exact(u) * g);
            }
        }
    }
}

// ---- ctx GEMM: 64-row x 80-col tile, K-chunk 1024, BK=64; grid (16,32) ----
__global__ __launch_bounds__(256) void ctx_mfma(
    const unsigned short* __restrict__ kpT, const unsigned short* __restrict__ vT,
    float* __restrict__ ctxp)
{
    __shared__ unsigned short la[4096];        // [2 halves][64][32]
    __shared__ unsigned short lb[5120];        // [2 halves][80][32]
    int bx, by; xcd_swz(bx, by);
    const int bh = by, mt = bx & 3, kc = bx >> 2;
    const int tid = threadIdx.x;
    const int l = tid & 63, w = tid >> 6;
    const int wr = w * 16, fr = l & 15, fq = l >> 4;
    const int sr = tid >> 2, sc = (tid & 3) * 8;
    const unsigned short* ga  = kpT + ((size_t)bh * 256 + mt * 64 + sr) * 4096 + kc * 1024 + sc;
    const unsigned short* gb  = vT + ((size_t)bh * 80 + sr) * 4096 + kc * 1024 + sc;
    const unsigned short* gb2 = vT + ((size_t)bh * 80 + 64 + sr) * 4096 + kc * 1024 + sc;

    f32x4 acc[5];
#pragma unroll
    for (int j = 0; j < 5; ++j) acc[j] = (f32x4){0.f, 0.f, 0.f, 0.f};

    for (int k0 = 0; k0 < 1024; k0 += 64) {
        glds16(ga + k0, la + tid * 8);
        glds16(ga + k0 + 32, la + 2048 + tid * 8);
        glds16(gb + k0, lb + tid * 8);
        glds16(gb + k0 + 32, lb + 2560 + tid * 8);
        if (tid < 64) {
            glds16(gb2 + k0, lb + 2048 + tid * 8);
            glds16(gb2 + k0 + 32, lb + 2560 + 2048 + tid * 8);
        }
        __syncthreads();
#pragma unroll
        for (int h2 = 0; h2 < 2; ++h2) {
            short8 av = *(const short8*)&la[h2 * 2048 + (wr + fr) * 32 + fq * 8];
#pragma unroll
            for (int nf = 0; nf < 5; ++nf) {
                short8 bv = *(const short8*)&lb[h2 * 2560 + (nf * 16 + fr) * 32 + fq * 8];
                acc[nf] = __builtin_amdgcn_mfma_f32_16x16x32_bf16(av, bv, acc[nf], 0, 0, 0);
            }
        }
        __syncthreads();
    }
#pragma unroll
    for (int v = 0; v < 4; ++v) {
        const int row = mt * 64 + wr + fq * 4 + v;
#pragma unroll
        for (int nf = 0; nf < 5; ++nf)
            ctxp[((size_t)(kc * 32 + bh) * 256 + row) * 80 + nf * 16 + fr] = acc[nf][v];
    }
}

// ---- reduce ctx partials over 4 k-chunks, transpose, split -> ctxT[bh][80][256] ----
__global__ __launch_bounds__(256) void ctx_fix(
    const float* __restrict__ ctxp, unsigned short* __restrict__ cth,
    unsigned short* __restrict__ ctl)
{
    __shared__ float s[64][81];
    const int m0 = blockIdx.x * 64, bh = blockIdx.y;
    const int tid = threadIdx.x;
    for (int i = tid; i < 5120; i += 256) {
        const int ml = i / 80, dc = i % 80;
        float sum = 0.f;
#pragma unroll
        for (int kc = 0; kc < 4; ++kc)
            sum += ctxp[((size_t)(kc * 32 + bh) * 256 + m0 + ml) * 80 + dc];
        s[ml][dc] = sum;
    }
    __syncthreads();
    for (int i = tid; i < 5120; i += 256) {
        const int dc = i >> 6, ml = i & 63;
        unsigned short hh_, ll_;
        splitf(s[ml][dc], hh_, ll_);
        cth[((size_t)bh * 80 + dc) * 256 + m0 + ml] = hh_;
        ctl[((size_t)bh * 80 + dc) * 256 + m0 + ml] = ll_;
    }
}

// ---- fused q-side, 64-token tiles: dd = q@projT (K=64) -> row max -> exp ->
//      qp (XOR-swizzled LDS) -> o = (qp @ ctxT)/(qp . ksum). grid (64, 32). ----
__global__ __launch_bounds__(256) void qo_mfma(
    const unsigned short* __restrict__ qhi,
    const unsigned short* __restrict__ pmh, const unsigned short* __restrict__ pml,
    const unsigned short* __restrict__ cth, const unsigned short* __restrict__ ctl,
    const float* __restrict__ diagq, unsigned short* __restrict__ osh)
{
    __shared__ unsigned short lds[18432 + 5120];   // phase1 staging / qp tile | ctx staging
    __shared__ float rmax4[64][4];
    int bx, by; xcd_swz(bx, by);
    const int bh = by, b = bh >> 2, hh = bh & 3;
    const int t0 = bx * 64;
    const int tid = threadIdx.x;
    const int l = tid & 63, w = tid >> 6;
    const int fr = l & 15, fq = l >> 4;

    // ---- phase 1: dd[64 tok][256 m], K = 64; wave w owns cols wc1..wc1+63 ----
    const int wc1 = w * 64;
    f32x4 a1[4][4];
#pragma unroll
    for (int i = 0; i < 4; ++i)
#pragma unroll
        for (int j = 0; j < 4; ++j) a1[i][j] = (f32x4){0.f, 0.f, 0.f, 0.f};

    const unsigned short* gq = qhi + (size_t)(b * 4096 + t0) * 256 + hh * 64;
#pragma unroll
    for (int ks = 0; ks < 2; ++ks) {
        const int k0 = ks * 32;
        // A: 64 rows x 32 (256 chunks) at lds[0..2048)
        glds16(gq + (size_t)(tid >> 2) * 256 + k0 + (tid & 3) * 8, lds + tid * 8);
        // B planes: 256 rows x 32 each; hi at [2048..10240), lo at [10240..18432)
#pragma unroll
        for (int i2 = 0; i2 < 4; ++i2) {
            const int c = tid + i2 * 256;
            glds16(pmh + (size_t)(c >> 2) * 64 + k0 + (c & 3) * 8, lds + 2048 + c * 8);
            glds16(pml + (size_t)(c >> 2) * 64 + k0 + (c & 3) * 8, lds + 10240 + c * 8);
        }
        __syncthreads();
        short8 av[4];
#pragma unroll
        for (int mf = 0; mf < 4; ++mf)
            av[mf] = *(const short8*)&lds[(mf * 16 + fr) * 32 + fq * 8];
#pragma unroll
        for (int nf = 0; nf < 4; ++nf) {
            short8 bh_ = *(const short8*)&lds[2048 + (wc1 + nf * 16 + fr) * 32 + fq * 8];
            short8 bl_ = *(const short8*)&lds[10240 + (wc1 + nf * 16 + fr) * 32 + fq * 8];
#pragma unroll
            for (int mf = 0; mf < 4; ++mf) {
                a1[mf][nf] = __builtin_amdgcn_mfma_f32_16x16x32_bf16(av[mf], bh_, a1[mf][nf], 0, 0, 0);
                a1[mf][nf] = __builtin_amdgcn_mfma_f32_16x16x32_bf16(av[mf], bl_, a1[mf][nf], 0, 0, 0);
            }
        }
        __syncthreads();
    }
    // ---- row max (per-wave strip max, combined across 4 waves) ----
#pragma unroll
    for (int mf = 0; mf < 4; ++mf)
#pragma unroll
        for (int v = 0; v < 4; ++v) {
            float rm = a1[mf][0][v];
#pragma unroll
            for (int nf = 1; nf < 4; ++nf) rm = fmaxf(rm, a1[mf][nf][v]);
            rm = fmaxf(rm, __shfl_xor(rm, 1));
            rm = fmaxf(rm, __shfl_xor(rm, 2));
            rm = fmaxf(rm, __shfl_xor(rm, 4));
            rm = fmaxf(rm, __shfl_xor(rm, 8));
            if (fr == 0) rmax4[mf * 16 + fq * 4 + v][w] = rm;
        }
    __syncthreads();
    // ---- exp -> qp bf16 into XOR-swizzled LDS tile [64][256] ----
#pragma unroll
    for (int mf = 0; mf < 4; ++mf)
#pragma unroll
        for (int v = 0; v < 4; ++v) {
            const int tok = mf * 16 + fq * 4 + v;
            const float dg = diagq[(size_t)(b * 4096 + t0 + tok) * 4 + hh]
                           + fmaxf(fmaxf(rmax4[tok][0], rmax4[tok][1]),
                                   fmaxf(rmax4[tok][2], rmax4[tok][3]));
#pragma unroll
            for (int nf = 0; nf < 4; ++nf) {
                const int m = wc1 + nf * 16 + fr;
                lds[tok * 256 + (m ^ ((tok & 7) << 3))] =
                    bf16rne(RATIO * (__expf(a1[mf][nf][v] - dg) + EPSF));
            }
        }
    __syncthreads();

    // ---- phase 2: o[64 tok][80] = qp @ ctxT (K=256, B split); col 64 = denom ----
    unsigned short* lds2 = lds + 18432;
    f32x4 a2[5];
#pragma unroll
    for (int j = 0; j < 5; ++j) a2[j] = (f32x4){0.f, 0.f, 0.f, 0.f};
    const size_t bbase = (size_t)bh * 80 * 256;

    for (int k0 = 0; k0 < 256; k0 += 32) {
        glds16(cth + bbase + (size_t)(tid >> 2) * 256 + k0 + (tid & 3) * 8, lds2 + tid * 8);
        glds16(ctl + bbase + (size_t)(tid >> 2) * 256 + k0 + (tid & 3) * 8, lds2 + 2560 + tid * 8);
        if (tid < 64) {
            const int c = 256 + tid;
            glds16(cth + bbase + (size_t)(c >> 2) * 256 + k0 + (c & 3) * 8, lds2 + c * 8);
            glds16(ctl + bbase + (size_t)(c >> 2) * 256 + k0 + (c & 3) * 8, lds2 + 2560 + c * 8);
        }
        __syncthreads();
        const int tok = w * 16 + fr;
        const int c = ((k0 >> 3) + fq) ^ (tok & 7);
        short8 av = *(const short8*)&lds[tok * 256 + c * 8];
#pragma unroll
        for (int nf = 0; nf < 5; ++nf) {
            const int off = (nf * 16 + fr) * 32 + fq * 8;
            short8 bvh = *(const short8*)&lds2[off];
            short8 bvl = *(const short8*)&lds2[2560 + off];
            a2[nf] = __builtin_amdgcn_mfma_f32_16x16x32_bf16(av, bvh, a2[nf], 0, 0, 0);
            a2[nf] = __builtin_amdgcn_mfma_f32_16x16x32_bf16(av, bvl, a2[nf], 0, 0, 0);
        }
        __syncthreads();
    }
#pragma unroll
    for (int v = 0; v < 4; ++v) {
        const float den = __shfl(a2[4][v], (int)(l & 48));
        const float dinv = 1.0f / den;
        const int tok = w * 16 + fq * 4 + v;
        const size_t obase = (size_t)(b * 4096 + t0 + tok) * 256 + hh * 64;
#pragma unroll
        for (int nf = 0; nf < 4; ++nf)
            osh[obase + nf * 16 + fr] = bf16rne(a2[nf][v] * dinv);
    }
}

// ---- pooling + classifier ----
__global__ __launch_bounds__(256) void pool1_kernel(const float* __restrict__ h, float* __restrict__ part)
{
    const int b = blockIdx.x >> 4, ch = blockIdx.x & 15;
    const int tid = threadIdx.x;
    float acc = 0.f;
    for (int n = 0; n < 256; ++n)
        acc += h[((size_t)(b * 4096 + ch * 256 + n)) * 256 + tid];
    part[(size_t)blockIdx.x * 256 + tid] = acc;
}

__global__ __launch_bounds__(256) void pool2_kernel(
    const float* __restrict__ part, const float* __restrict__ cw,
    const float* __restrict__ cb, float* __restrict__ out)
{
    const int b = blockIdx.x, tid = threadIdx.x;
    float acc = 0.f;
#pragma unroll
    for (int c = 0; c < 16; ++c) acc += part[(size_t)(b * 16 + c) * 256 + tid];
    float val = acc * (1.0f / 4096.0f) * cw[tid];
#pragma unroll
    for (int s = 1; s < 64; s <<= 1) val += __shfl_xor(val, s);
    __shared__ float red[4];
    if ((tid & 63) == 0) red[tid >> 6] = val;
    __syncthreads();
    if (tid == 0) out[b] = red[0] + red[1] + red[2] + red[3] + cb[0];
}

extern "C" void kernel_launch(void* const* d_in, const int* in_sizes, int n_in,
                              void* d_out, int out_size, void* d_ws, size_t ws_size,
                              hipStream_t stream)
{
    (void)in_sizes; (void)n_in;
    if (ws_size < WS_BYTES) {
        fill_sentinel<<<1, 64, 0, stream>>>((float*)d_out, out_size);
        return;
    }

    const float* x     = (const float*)d_in[0];
    const float* projw = (const float*)d_in[1];
    const float* projb = (const float*)d_in[2];
    const float* ln1g  = (const float*)d_in[3];
    const float* ln1b  = (const float*)d_in[4];
    const float* wq    = (const float*)d_in[5];
    const float* bq    = (const float*)d_in[6];
    const float* wk    = (const float*)d_in[7];
    const float* bk    = (const float*)d_in[8];
    const float* wv    = (const float*)d_in[9];
    const float* bv    = (const float*)d_in[10];
    const float* wo    = (const float*)d_in[11];
    const float* bo    = (const float*)d_in[12];
    const float* ln2g  = (const float*)d_in[13];
    const float* ln2b  = (const float*)d_in[14];
    const float* w1    = (const float*)d_in[15];
    const float* b1    = (const float*)d_in[16];
    const float* w2    = (const float*)d_in[17];
    const float* b2    = (const float*)d_in[18];
    const float* clfw  = (const float*)d_in[19];
    const float* clfb  = (const float*)d_in[20];
    const float* projm = (const float*)d_in[21];

    char* WS = (char*)d_ws;
    float* h            = (float*)(WS + OFF_H);
    unsigned short* ysh = (unsigned short*)(WS + OFF_YS);
    unsigned short* wts = (unsigned short*)(WS + OFF_WTS);
    unsigned short* khi = (unsigned short*)(WS + OFF_QK);
    unsigned short* qhi = khi + 8388608;
    unsigned short* big = (unsigned short*)(WS + OFF_BIG);   // kpT / ffb / x-split
    unsigned short* vT  = (unsigned short*)(WS + OFF_VT);
    float* ctxp         = (float*)(WS + OFF_CTXP);
    unsigned short* cth = (unsigned short*)(WS + OFF_CTXTH);
    unsigned short* ctl = (unsigned short*)(WS + OFF_CTXTL);
    float* diagq        = (float*)(WS + OFF_DIAGQ);
    float* diagk        = (float*)(WS + OFF_DIAGK);
    unsigned* gmax      = (unsigned*)(WS + OFF_GMAX);
    float* pool         = (float*)(WS + OFF_POOL);
    unsigned short* pmt_h = (unsigned short*)(WS + OFF_PMTH);
    unsigned short* pmt_l = (unsigned short*)(WS + OFF_PMTL);
    unsigned short* pwt_h = (unsigned short*)(WS + OFF_PWTH);
    unsigned short* pwt_l = (unsigned short*)(WS + OFF_PWTL);
    // aliases
    unsigned short* xsh = big;               // prologue only
    unsigned short* xsl = big + 2097152;
    unsigned short* kpT = big;               // [32][256][4096]
    unsigned short* ffb = big;               // [32768][1024]
    unsigned short* osh = ysh;               // o bf16 (ys dead by then)

    // ---- prologue ----
    split_scale<<<8192, 256, 0, stream>>>(x, xsh, xsl, 2097152, 1.0f);
    splitT<<<64, 256, 0, stream>>>(projw, pwt_h, pwt_l, 6, 256);
    split_scale<<<64, 256, 0, stream>>>(projm, pmt_h, pmt_l, 16384, DN);
    vt_init<<<1024, 256, 0, stream>>>(vT, gmax);
    split_weights<<<16384, 256, 0, stream>>>(wq, wk, wv, wo, w1, w2, wts);
    gemm_mf<0, true, true><<<dim3(2, 256), 256, 0, stream>>>(xsh, xsl, 64, pwt_h, pwt_l, 64, 64,
        projb, nullptr, h, 256, nullptr, nullptr, nullptr);

    for (int l = 0; l < 4; ++l) {
        unsigned short* wl = wts + (size_t)l * 2097152;

        // ---- attention ----
        ln_bf16<<<8192, 256, 0, stream>>>(h, ln1g + l * 256, ln1b + l * 256, ysh);
        gemm_mf<8, false, true><<<dim3(2, 256), 256, 0, stream>>>(ysh, nullptr, 256,
            wl + WV_H, wl + WV_L, 256, 256, bv + l * 256, nullptr, nullptr, 256, vT, nullptr, nullptr);
        gemm_mf<2, false, true><<<dim3(2, 256), 256, 0, stream>>>(ysh, nullptr, 256,
            wl + WK_H, wl + WK_L, 256, 256, bk + l * 256, nullptr, nullptr, 256, khi, diagk, nullptr);
        gemm_mf<2, false, true><<<dim3(2, 256), 256, 0, stream>>>(ysh, nullptr, 256,
            wl + WQ_H, wl + WQ_L, 256, 256, bq + l * 256, nullptr, nullptr, 256, qhi, diagq, nullptr);
        gemm_mf<4, false, false><<<dim3(2, 1024), 256, 0, stream>>>(khi, nullptr, 64,
            pmt_h, nullptr, 64, 64, nullptr, nullptr, nullptr, 256, nullptr, nullptr, gmax + l);
        gemm_mf<6, false, true><<<dim3(2, 1024), 256, 0, stream>>>(khi, nullptr, 64,
            pmt_h, pmt_l, 64, 64, nullptr, nullptr, nullptr, 256, kpT, diagk, gmax + l);
        ctx_mfma<<<dim3(16, 32), 256, 0, stream>>>(kpT, vT, ctxp);
        ctx_fix<<<dim3(4, 32), 256, 0, stream>>>(ctxp, cth, ctl);
        qo_mfma<<<dim3(64, 32), 256, 0, stream>>>(qhi, pmt_h, pmt_l, cth, ctl, diagq, osh);
        gemm_mf<1, false, true><<<dim3(2, 256), 256, 0, stream>>>(osh, nullptr, 256,
            wl + WO_H, wl + WO_L, 256, 256, bo + l * 256, h, h, 256, nullptr, nullptr, nullptr);

        // ---- feed-forward ----
        ln_bf16<<<8192, 256, 0, stream>>>(h, ln2g + l * 256, ln2b + l * 256, ysh);
        gemm_glu<<<dim3(16, 256), 256, 0, stream>>>(ysh, wl + W1_H, wl + W1_L,
            b1 + (size_t)l * 2048, ffb);
        gemm_mf<1, false, true><<<dim3(2, 256), 256, 0, stream>>>(ffb, nullptr, 1024,
            wl + W2_H, wl + W2_L, 1024, 1024, b2 + l * 256, h, h, 256, nullptr, nullptr, nullptr);
    }

    pool1_kernel<<<128, 256, 0, stream>>>(h, pool);
    pool2_kernel<<<8, 256, 0, stream>>>(pool, clfw, clfb, (float*)d_out);
}

// Round 11
// 1340.833 us; speedup vs baseline: 8.9497x; 1.0621x over previous
//
#include <hip/hip_runtime.h>
#include <cstdint>
#include <cstddef>

// ---- problem constants ----
constexpr float DN = 0.35355339059327373f;   // 64^-0.25
constexpr float RATIO = 0.0625f;             // 256^-0.5
constexpr float EPSF = 1e-4f;

typedef __attribute__((ext_vector_type(8))) short short8;   // 16-bit MFMA fragment
typedef __attribute__((ext_vector_type(8))) _Float16 half8;
typedef __attribute__((ext_vector_type(4))) float f32x4;    // MFMA accumulator

// ---- workspace layout (byte offsets); proven budget >= 209,715,200 B ----
constexpr size_t OFF_H     = 0;              // fp32 residual 33,554,432
constexpr size_t OFF_YS    = 33554432;       // ysh (osh alias) 16,777,216
constexpr size_t OFF_WTS   = 50331648;       // all-layer weight splits 16,777,216
constexpr size_t OFF_QK    = 67108864;       // khi 16,777,216 | qhi 16,777,216 (fp16)
constexpr size_t OFF_BIG   = 100663296;      // kpT / ffb / x-split 67,108,864
constexpr size_t OFF_VT    = 167772160;      // vT [32][80][4096] fp16 20,971,520
constexpr size_t OFF_CTXP  = 188743680;      // ctx partials [4][32][256][80] f32 10,485,760
constexpr size_t OFF_CTXTH = 199229440;      // ctxT fp16 [32][80][256] 1,310,720
constexpr size_t OFF_CTXTL = 200540160;      // (unused)
constexpr size_t OFF_DIAGQ = 201850880;      // 524,288
constexpr size_t OFF_DIAGK = 202375168;      // 524,288
constexpr size_t OFF_GMAX  = 203423744;      // 256 (4 per-layer slots used)
constexpr size_t OFF_POOL  = 203424000;      // 131,072
constexpr size_t OFF_PMTH  = 207749376;      // pm fp16 32,768
constexpr size_t OFF_PMTL  = 207782144;      // (unused)
constexpr size_t OFF_PWTH  = 207814912;
constexpr size_t OFF_PWTL  = 207847680;
constexpr size_t WS_BYTES  = 207880448;

// per-layer short-offsets inside the WTS region (layer stride 2,097,152 shorts)
constexpr size_t WQ_H = 0,       WQ_L = 65536;
constexpr size_t WK_H = 131072,  WK_L = 196608;
constexpr size_t WV_H = 262144,  WV_L = 327680;
constexpr size_t WO_H = 393216,  WO_L = 458752;
constexpr size_t W1_H = 524288,  W1_L = 1048576;
constexpr size_t W2_H = 1572864, W2_L = 1835008;

__device__ __forceinline__ unsigned fkey(float f) {
    unsigned u = __float_as_uint(f);
    return (u & 0x80000000u) ? ~u : (u | 0x80000000u);
}
__device__ __forceinline__ float funkey(unsigned k) {
    unsigned u = (k & 0x80000000u) ? (k ^ 0x80000000u) : ~k;
    return __uint_as_float(u);
}
__device__ __forceinline__ float gelu_exact(float x) {
    return 0.5f * x * (1.0f + erff(x * 0.70710678118654752f));
}
__device__ __forceinline__ void splitf(float x, unsigned short& h, unsigned short& l) {
    unsigned u = __float_as_uint(x);
    unsigned hv = (u + 0x7FFFu + ((u >> 16) & 1)) >> 16;
    h = (unsigned short)hv;
    float lo = x - __uint_as_float(hv << 16);
    unsigned u2 = __float_as_uint(lo);
    l = (unsigned short)((u2 + 0x7FFFu + ((u2 >> 16) & 1)) >> 16);
}
__device__ __forceinline__ unsigned short bf16rne(float x) {
    unsigned u = __float_as_uint(x);
    return (unsigned short)((u + 0x7FFFu + ((u >> 16) & 1)) >> 16);
}
__device__ __forceinline__ unsigned short fp16rne(float x) {
    return __builtin_bit_cast(unsigned short, (_Float16)x);
}
template<bool F16>
__device__ __forceinline__ f32x4 mfma16(short8 a, short8 b, f32x4 c) {
    if constexpr (F16)
        return __builtin_amdgcn_mfma_f32_16x16x32_f16(
            __builtin_bit_cast(half8, a), __builtin_bit_cast(half8, b), c, 0, 0, 0);
    else
        return __builtin_amdgcn_mfma_f32_16x16x32_bf16(a, b, c, 0, 0, 0);
}
// XCD-aware block swizzle (requires total blocks % 8 == 0)
__device__ __forceinline__ void xcd_swz(int& bx, int& by) {
    const int gx = gridDim.x;
    const int total = gx * gridDim.y;
    int flat = blockIdx.y * gx + blockIdx.x;
    flat = (flat & 7) * (total >> 3) + (flat >> 3);
    bx = flat % gx; by = flat / gx;
}

// ---- async global->LDS 16B (wave-uniform base + lane*16, linear dest) ----
#if defined(__has_builtin)
#if __has_builtin(__builtin_amdgcn_global_load_lds)
#define HAVE_GLDS 1
#endif
#endif
__device__ __forceinline__ void glds16(const unsigned short* g, unsigned short* l) {
#ifdef HAVE_GLDS
    __builtin_amdgcn_global_load_lds(
        (const __attribute__((address_space(1))) unsigned int*)g,
        (__attribute__((address_space(3))) unsigned int*)l, 16, 0, 0);
#else
    *(uint4*)l = *(const uint4*)g;
#endif
}

__global__ void fill_sentinel(float* out, int n) {
    int i = threadIdx.x;
    if (i < n) out[i] = 12345.0f;
}
// fill vT rows 64..79 (row 64 = 1.0 fp16 for ksum fold) + zero per-layer gmax keys
__global__ __launch_bounds__(256) void vt_init(unsigned short* __restrict__ vT, unsigned* __restrict__ gm) {
    int i = blockIdx.x * 256 + threadIdx.x;        // 262,144 uint4
    if (i < 4) gm[i] = 0u;
    const int bh = i >> 13;
    const int r = (i >> 9) & 15;
    const unsigned val = (r == 0) ? 0x3C003C00u : 0u;
    uint4 q; q.x = val; q.y = val; q.z = val; q.w = val;
    *(uint4*)(vT + ((size_t)bh * 80 + 64 + r) * 4096 + ((size_t)(i & 511) << 3)) = q;
}

// ---- elementwise split (optional scale) ----
__global__ __launch_bounds__(256) void split_scale(
    const float* __restrict__ src, unsigned short* __restrict__ hi,
    unsigned short* __restrict__ lo, int n, float scale)
{
    int i = blockIdx.x * 256 + threadIdx.x;
    if (i < n) {
        unsigned short h, l;
        splitf(src[i] * scale, h, l);
        hi[i] = h; lo[i] = l;
    }
}

// ---- fp32 -> fp16 with scale ----
__global__ __launch_bounds__(256) void tofp16_scale(
    const float* __restrict__ src, unsigned short* __restrict__ dst, int n, float scale)
{
    int i = blockIdx.x * 256 + threadIdx.x;
    if (i < n) dst[i] = fp16rne(src[i] * scale);
}

// ---- transpose-split weights: W [K,N] fp32 -> Wt hi/lo [N,K] bf16 ----
__global__ __launch_bounds__(256) void splitT(
    const float* __restrict__ W, unsigned short* __restrict__ hi,
    unsigned short* __restrict__ lo, int kshift, int N)
{
    int i = blockIdx.x * 256 + threadIdx.x;
    int K = 1 << kshift;
    int n = i >> kshift, k = i & (K - 1);
    unsigned short h, l;
    splitf(W[(size_t)k * N + n], h, l);
    hi[i] = h; lo[i] = l;
}

// ---- all-layer weight transpose-split: one dispatch ----
__global__ __launch_bounds__(256) void split_weights(
    const float* __restrict__ wq, const float* __restrict__ wk,
    const float* __restrict__ wv, const float* __restrict__ wo,
    const float* __restrict__ w1, const float* __restrict__ w2,
    unsigned short* __restrict__ dst)
{
    const int i = blockIdx.x * 256 + threadIdx.x;
    const int lay = i >> 20;
    const int r = i & 1048575;
    float val; size_t oh, ol;
    if (r < 262144) {
        const int m = r >> 16, e = r & 65535;
        const int n = e >> 8, k = e & 255;
        const float* W = (m == 0 ? wq : m == 1 ? wk : m == 2 ? wv : wo);
        val = W[(size_t)lay * 65536 + k * 256 + n];
        oh = (size_t)lay * 2097152 + (size_t)m * 131072 + e;
        ol = oh + 65536;
    } else if (r < 786432) {
        const int e = r - 262144;
        const int n = e >> 8, k = e & 255;
        val = w1[(size_t)lay * 524288 + (size_t)k * 2048 + n];
        oh = (size_t)lay * 2097152 + W1_H + e;
        ol = oh + 524288;
    } else {
        const int e = r - 786432;
        const int n = e >> 10, k = e & 1023;
        val = w2[(size_t)lay * 262144 + (size_t)k * 256 + n];
        oh = (size_t)lay * 2097152 + W2_H + e;
        ol = oh + 262144;
    }
    unsigned short h, l;
    splitf(val, h, l);
    dst[oh] = h; dst[ol] = l;
}

// ---- LayerNorm -> single bf16 plane ----
__global__ __launch_bounds__(256) void ln_bf16(
    const float* __restrict__ x, const float* __restrict__ g,
    const float* __restrict__ b, unsigned short* __restrict__ yhi)
{
    const int row = blockIdx.x * 4 + (threadIdx.x >> 6);
    const int lane = threadIdx.x & 63;
    float4 t = *(const float4*)&x[(size_t)row * 256 + lane * 4];
    float s = t.x + t.y + t.z + t.w;
#pragma unroll
    for (int sh = 1; sh < 64; sh <<= 1) s += __shfl_xor(s, sh);
    const float mu = s * (1.0f / 256.0f);
    const float dx = t.x - mu, dy = t.y - mu, dz = t.z - mu, dw = t.w - mu;
    float vv = dx * dx + dy * dy + dz * dz + dw * dw;
#pragma unroll
    for (int sh = 1; sh < 64; sh <<= 1) vv += __shfl_xor(vv, sh);
    const float rstd = rsqrtf(vv * (1.0f / 256.0f) + 1e-5f);
    float4 gv = *(const float4*)&g[lane * 4];
    float4 bv = *(const float4*)&b[lane * 4];
    unsigned short h0 = bf16rne(dx * rstd * gv.x + bv.x);
    unsigned short h1 = bf16rne(dy * rstd * gv.y + bv.y);
    unsigned short h2 = bf16rne(dz * rstd * gv.z + bv.z);
    unsigned short h3 = bf16rne(dw * rstd * gv.w + bv.w);
    uint2 ph;
    ph.x = (unsigned)h0 | ((unsigned)h1 << 16); ph.y = (unsigned)h2 | ((unsigned)h3 << 16);
    *(uint2*)&yhi[(size_t)row * 256 + lane * 4] = ph;
}

// ---- bf16/f16 MFMA GEMM, tile 128x128, BK=64, 4 waves ----
// EPI: 0 bias->f32 C | 1 bias(nullable)+res->f32 C
//      4 global max -> keys[0]
//      6 kp = exp epilogue (fp16 if F16) + TRANSPOSED write to kpT[bh][m][n]
template<int EPI, bool ASPLIT, bool BSPLIT, bool F16>
__global__ __launch_bounds__(256) void gemm_mf(
    const unsigned short* __restrict__ Ahi, const unsigned short* __restrict__ Alo, int lda,
    const unsigned short* __restrict__ Bhi, const unsigned short* __restrict__ Blo, int ldb,
    int K,
    const float* __restrict__ bias, const float* __restrict__ res,
    float* __restrict__ C, int ldc,
    unsigned short* __restrict__ Obf,
    const float* __restrict__ diag, unsigned* __restrict__ keys)
{
    constexpr int NP = (ASPLIT ? 2 : 1) + (BSPLIT ? 2 : 1);
    constexpr int PB = ASPLIT ? 2 : 1;                 // B-hi plane index
    constexpr int NEED = (EPI == 6) ? 16384 : 0;
    constexpr int LDSN = (NP * 8192 > NEED) ? NP * 8192 : NEED;
    __shared__ unsigned short lds[LDSN];
    __shared__ float red[4];
#define LX(p, h, r, c) lds[(p) * 8192 + (h) * 4096 + (r) * 32 + (c)]
    int bx, by; xcd_swz(bx, by);
    const int tid = threadIdx.x;
    const int m0 = by * 128, n0 = bx * 128;
    const int sr = tid >> 2, sc = (tid & 3) * 8;
    const unsigned short* ga_h = Ahi + (size_t)(m0 + sr) * lda + sc;
    const unsigned short* ga_l = ASPLIT ? (Alo + (size_t)(m0 + sr) * lda + sc) : nullptr;
    const unsigned short* gb_h = Bhi + (size_t)(n0 + sr) * ldb + sc;
    const unsigned short* gb_l = BSPLIT ? (Blo + (size_t)(n0 + sr) * ldb + sc) : nullptr;
    unsigned short* lp = lds + tid * 8;
    const int l = tid & 63, w = tid >> 6;
    const int wr = (w >> 1) * 64, wc = (w & 1) * 64;
    const int fr = l & 15, fq = l >> 4;

    f32x4 acc[4][4];
#pragma unroll
    for (int i = 0; i < 4; ++i)
#pragma unroll
        for (int j = 0; j < 4; ++j) acc[i][j] = (f32x4){0.f, 0.f, 0.f, 0.f};

    for (int k0 = 0; k0 < K; k0 += 64) {
        glds16(ga_h + k0, lp);
        glds16(ga_h + (size_t)64 * lda + k0, lp + 2048);
        glds16(ga_h + k0 + 32, lp + 4096);
        glds16(ga_h + (size_t)64 * lda + k0 + 32, lp + 6144);
        if (ASPLIT) {
            glds16(ga_l + k0, lp + 8192);
            glds16(ga_l + (size_t)64 * lda + k0, lp + 10240);
            glds16(ga_l + k0 + 32, lp + 12288);
            glds16(ga_l + (size_t)64 * lda + k0 + 32, lp + 14336);
        }
        glds16(gb_h + k0, lp + PB * 8192);
        glds16(gb_h + (size_t)64 * ldb + k0, lp + PB * 8192 + 2048);
        glds16(gb_h + k0 + 32, lp + PB * 8192 + 4096);
        glds16(gb_h + (size_t)64 * ldb + k0 + 32, lp + PB * 8192 + 6144);
        if (BSPLIT) {
            glds16(gb_l + k0, lp + (PB + 1) * 8192);
            glds16(gb_l + (size_t)64 * ldb + k0, lp + (PB + 1) * 8192 + 2048);
            glds16(gb_l + k0 + 32, lp + (PB + 1) * 8192 + 4096);
            glds16(gb_l + (size_t)64 * ldb + k0 + 32, lp + (PB + 1) * 8192 + 6144);
        }
        __syncthreads();
#pragma unroll
        for (int h2 = 0; h2 < 2; ++h2) {
            short8 ah[4], al[4];
#pragma unroll
            for (int mf = 0; mf < 4; ++mf) {
                ah[mf] = *(const short8*)&LX(0, h2, wr + mf * 16 + fr, fq * 8);
                if (ASPLIT) al[mf] = *(const short8*)&LX(1, h2, wr + mf * 16 + fr, fq * 8);
            }
#pragma unroll
            for (int nf = 0; nf < 4; ++nf) {
                short8 bh = *(const short8*)&LX(PB, h2, wc + nf * 16 + fr, fq * 8);
#pragma unroll
                for (int mf = 0; mf < 4; ++mf) {
                    acc[mf][nf] = mfma16<F16>(ah[mf], bh, acc[mf][nf]);
                    if (ASPLIT) acc[mf][nf] = mfma16<F16>(al[mf], bh, acc[mf][nf]);
                }
                if (BSPLIT) {
                    short8 bl = *(const short8*)&LX(PB + 1, h2, wc + nf * 16 + fr, fq * 8);
#pragma unroll
                    for (int mf = 0; mf < 4; ++mf)
                        acc[mf][nf] = mfma16<F16>(ah[mf], bl, acc[mf][nf]);
                }
            }
        }
        __syncthreads();
    }

    if constexpr (EPI == 4) {
        float m = -3.4e38f;
#pragma unroll
        for (int mf = 0; mf < 4; ++mf)
#pragma unroll
            for (int nf = 0; nf < 4; ++nf)
#pragma unroll
                for (int v = 0; v < 4; ++v) m = fmaxf(m, acc[mf][nf][v]);
#pragma unroll
        for (int s = 1; s < 64; s <<= 1) m = fmaxf(m, __shfl_xor(m, s));
        if (l == 0) red[w] = m;
        __syncthreads();
        if (tid == 0)
            atomicMax(keys, fkey(fmaxf(fmaxf(red[0], red[1]), fmaxf(red[2], red[3]))));
    } else if constexpr (EPI == 6) {
        const float Mg = funkey(*keys);
        unsigned short* tb = lds;
#pragma unroll
        for (int mf = 0; mf < 4; ++mf)
#pragma unroll
            for (int v = 0; v < 4; ++v) {
                const int rl = wr + mf * 16 + fq * 4 + v;
                const float dg = diag[m0 + rl] + Mg;
#pragma unroll
                for (int nf = 0; nf < 4; ++nf) {
                    const int cl = wc + nf * 16 + fr;
                    const float kv = RATIO * (__expf(acc[mf][nf][v] - dg) + EPSF);
                    tb[rl * 128 + cl] = F16 ? fp16rne(kv) : bf16rne(kv);
                }
            }
        __syncthreads();
        const int tokbase = m0 >> 2;
        const int b = tokbase >> 12, nib = tokbase & 4095;
        const int ml = tid & 127, g2 = tid >> 7;
#pragma unroll
        for (int hh2 = 0; hh2 < 2; ++hh2) {
            const int hh = g2 * 2 + hh2;
            unsigned short* dst = Obf + ((size_t)((b * 4 + hh) * 256 + n0 + ml)) * 4096 + nib;
#pragma unroll
            for (int qq = 0; qq < 4; ++qq) {
                uint4 qv;
                unsigned wv[4];
#pragma unroll
                for (int j = 0; j < 4; ++j) {
                    unsigned s0 = tb[((qq * 8 + j * 2 + 0) * 4 + hh) * 128 + ml];
                    unsigned s1 = tb[((qq * 8 + j * 2 + 1) * 4 + hh) * 128 + ml];
                    wv[j] = s0 | (s1 << 16);
                }
                qv.x = wv[0]; qv.y = wv[1]; qv.z = wv[2]; qv.w = wv[3];
                *(uint4*)(dst + qq * 8) = qv;
            }
        }
    } else {
#pragma unroll
        for (int nf = 0; nf < 4; ++nf) {
            const int col = n0 + wc + nf * 16 + fr;
            float bb = 0.f;
            if (bias != nullptr) bb = bias[col];
#pragma unroll
            for (int mf = 0; mf < 4; ++mf) {
#pragma unroll
                for (int v = 0; v < 4; ++v) {
                    const int row = m0 + wr + mf * 16 + fq * 4 + v;
                    const size_t off = (size_t)row * ldc + col;
                    float val = acc[mf][nf][v] + bb;
                    if (EPI == 1) val += res[off];
                    C[off] = val;
                }
            }
        }
    }
#undef LX
}

// ---- merged QKV GEMM: A=ysh bf16, W split-bf16; grid (2, 768): by>>8 selects
//      0=V (fp16 transposed vT write), 1=K, 2=Q (fp16 plane + per-head diag). ----
__global__ __launch_bounds__(256) void gemm_qkv(
    const unsigned short* __restrict__ A, const unsigned short* __restrict__ wl,
    const float* __restrict__ bq, const float* __restrict__ bk, const float* __restrict__ bv,
    unsigned short* __restrict__ vT, unsigned short* __restrict__ khi,
    unsigned short* __restrict__ qhi, float* __restrict__ diagq, float* __restrict__ diagk)
{
    __shared__ unsigned short lds[24576];
    int bx, by; xcd_swz(bx, by);
    const int sel = by >> 8;
    const int m0 = (by & 255) * 128, n0 = bx * 128;
    const unsigned short* Bh = wl + (sel == 0 ? WV_H : sel == 1 ? WK_H : WQ_H);
    const unsigned short* Bl = wl + (sel == 0 ? WV_L : sel == 1 ? WK_L : WQ_L);
    const float* bias = (sel == 0 ? bv : sel == 1 ? bk : bq);
    const int tid = threadIdx.x;
    const int sr = tid >> 2, sc = (tid & 3) * 8;
    const unsigned short* ga_h = A + (size_t)(m0 + sr) * 256 + sc;
    const unsigned short* gb_h = Bh + (size_t)(n0 + sr) * 256 + sc;
    const unsigned short* gb_l = Bl + (size_t)(n0 + sr) * 256 + sc;
    unsigned short* lp = lds + tid * 8;
    const int l = tid & 63, w = tid >> 6;
    const int wr = (w >> 1) * 64, wc = (w & 1) * 64;
    const int fr = l & 15, fq = l >> 4;

    f32x4 acc[4][4];
#pragma unroll
    for (int i = 0; i < 4; ++i)
#pragma unroll
        for (int j = 0; j < 4; ++j) acc[i][j] = (f32x4){0.f, 0.f, 0.f, 0.f};

    for (int k0 = 0; k0 < 256; k0 += 64) {
        glds16(ga_h + k0, lp);
        glds16(ga_h + (size_t)64 * 256 + k0, lp + 2048);
        glds16(ga_h + k0 + 32, lp + 4096);
        glds16(ga_h + (size_t)64 * 256 + k0 + 32, lp + 6144);
        glds16(gb_h + k0, lp + 8192);
        glds16(gb_h + (size_t)64 * 256 + k0, lp + 10240);
        glds16(gb_h + k0 + 32, lp + 12288);
        glds16(gb_h + (size_t)64 * 256 + k0 + 32, lp + 14336);
        glds16(gb_l + k0, lp + 16384);
        glds16(gb_l + (size_t)64 * 256 + k0, lp + 18432);
        glds16(gb_l + k0 + 32, lp + 20480);
        glds16(gb_l + (size_t)64 * 256 + k0 + 32, lp + 22528);
        __syncthreads();
#pragma unroll
        for (int h2 = 0; h2 < 2; ++h2) {
            short8 ah[4];
#pragma unroll
            for (int mf = 0; mf < 4; ++mf)
                ah[mf] = *(const short8*)&lds[h2 * 4096 + (wr + mf * 16 + fr) * 32 + fq * 8];
#pragma unroll
            for (int nf = 0; nf < 4; ++nf) {
                short8 bh = *(const short8*)&lds[8192 + h2 * 4096 + (wc + nf * 16 + fr) * 32 + fq * 8];
                short8 bl = *(const short8*)&lds[16384 + h2 * 4096 + (wc + nf * 16 + fr) * 32 + fq * 8];
#pragma unroll
                for (int mf = 0; mf < 4; ++mf) {
                    acc[mf][nf] = mfma16<false>(ah[mf], bh, acc[mf][nf]);
                    acc[mf][nf] = mfma16<false>(ah[mf], bl, acc[mf][nf]);
                }
            }
        }
        __syncthreads();
    }

    if (sel == 0) {
        // V + bias -> fp16, transposed into vT[bh][d][n]
        unsigned short* tb = lds;
#pragma unroll
        for (int mf = 0; mf < 4; ++mf)
#pragma unroll
            for (int nf = 0; nf < 4; ++nf) {
                const int cl = wc + nf * 16 + fr;
                const float bb = bias[n0 + cl];
#pragma unroll
                for (int v = 0; v < 4; ++v) {
                    const int rl = wr + mf * 16 + fq * 4 + v;
                    tb[rl * 128 + cl] = fp16rne(acc[mf][nf][v] + bb);
                }
            }
        __syncthreads();
        const int b = m0 >> 12, nib = m0 & 4095;
        const int cl = tid & 127, half = tid >> 7;
        const int ch = n0 + cl, hh = ch >> 6, d = ch & 63;
        unsigned short* dst = vT + ((size_t)((b * 4 + hh) * 80 + d)) * 4096 + nib + half * 64;
#pragma unroll
        for (int qq = 0; qq < 8; ++qq) {
            uint4 qv;
            unsigned wv[4];
#pragma unroll
            for (int j = 0; j < 4; ++j) {
                unsigned s0 = tb[(half * 64 + qq * 8 + j * 2 + 0) * 128 + cl];
                unsigned s1 = tb[(half * 64 + qq * 8 + j * 2 + 1) * 128 + cl];
                wv[j] = s0 | (s1 << 16);
            }
            qv.x = wv[0]; qv.y = wv[1]; qv.z = wv[2]; qv.w = wv[3];
            *(uint4*)(dst + qq * 8) = qv;
        }
    } else {
        float* diag = (sel == 1 ? diagk : diagq);
        unsigned short* Obf = (sel == 1 ? khi : qhi);
        const int head = (n0 + wc) >> 6;
#pragma unroll
        for (int mf = 0; mf < 4; ++mf) {
            float sq[4] = {0.f, 0.f, 0.f, 0.f};
#pragma unroll
            for (int nf = 0; nf < 4; ++nf) {
                const int col = n0 + wc + nf * 16 + fr;
                const float bb = bias[col];
#pragma unroll
                for (int v = 0; v < 4; ++v) {
                    const int row = m0 + wr + mf * 16 + fq * 4 + v;
                    float val = acc[mf][nf][v] + bb;
                    Obf[(size_t)row * 256 + col] = fp16rne(val);
                    sq[v] += val * val;
                }
            }
#pragma unroll
            for (int v = 0; v < 4; ++v) {
                float s = sq[v];
                s += __shfl_xor(s, 1); s += __shfl_xor(s, 2);
                s += __shfl_xor(s, 4); s += __shfl_xor(s, 8);
                if (fr == 0)
                    diag[(size_t)(m0 + wr + mf * 16 + fq * 4 + v) * 4 + head] = s * 0.0625f;
            }
        }
    }
}

// ---- fused GLU GEMM: A single bf16 plane, W split; BK=64 sub-plane staging ----
__global__ __launch_bounds__(256) void gemm_glu(
    const unsigned short* __restrict__ Ahi,
    const unsigned short* __restrict__ Whi, const unsigned short* __restrict__ Wlo,
    const float* __restrict__ b1, unsigned short* __restrict__ Obf)
{
    __shared__ unsigned short ldsA[8192];      // [2 halves][128][32]
    __shared__ unsigned short ldsB[16384];     // 4 planes x [2 halves][64][32]
    int bx, by; xcd_swz(bx, by);
    const int tid = threadIdx.x;
    const int m0 = by * 128, p0 = bx * 64;
    const int sr = tid >> 2, sc = (tid & 3) * 8;
    const unsigned short* ga  = Ahi + (size_t)(m0 + sr) * 256 + sc;
    const unsigned short* gb0 = Whi + (size_t)(p0 + sr) * 256 + sc;
    const unsigned short* gb1 = Wlo + (size_t)(p0 + sr) * 256 + sc;
    const unsigned short* gb2 = Whi + (size_t)(1024 + p0 + sr) * 256 + sc;
    const unsigned short* gb3 = Wlo + (size_t)(1024 + p0 + sr) * 256 + sc;
    unsigned short* lpA = ldsA + tid * 8;
    unsigned short* lpB = ldsB + tid * 8;
    const int l = tid & 63, w = tid >> 6;
    const int wr = (w >> 1) * 64, wc = (w & 1) * 32;
    const int fr = l & 15, fq = l >> 4;

    f32x4 aa[4][2], ag[4][2];
#pragma unroll
    for (int i = 0; i < 4; ++i)
#pragma unroll
        for (int j = 0; j < 2; ++j) {
            aa[i][j] = (f32x4){0.f, 0.f, 0.f, 0.f};
            ag[i][j] = (f32x4){0.f, 0.f, 0.f, 0.f};
        }

    for (int k0 = 0; k0 < 256; k0 += 64) {
        glds16(ga + k0, lpA);
        glds16(ga + 64 * 256 + k0, lpA + 2048);
        glds16(ga + k0 + 32, lpA + 4096);
        glds16(ga + 64 * 256 + k0 + 32, lpA + 6144);
        glds16(gb0 + k0, lpB);
        glds16(gb0 + k0 + 32, lpB + 2048);
        glds16(gb1 + k0, lpB + 4096);
        glds16(gb1 + k0 + 32, lpB + 6144);
        glds16(gb2 + k0, lpB + 8192);
        glds16(gb2 + k0 + 32, lpB + 10240);
        glds16(gb3 + k0, lpB + 12288);
        glds16(gb3 + k0 + 32, lpB + 14336);
        __syncthreads();
#pragma unroll
        for (int h2 = 0; h2 < 2; ++h2) {
            short8 ah[4];
#pragma unroll
            for (int mf = 0; mf < 4; ++mf)
                ah[mf] = *(const short8*)&ldsA[h2 * 4096 + (wr + mf * 16 + fr) * 32 + fq * 8];
#pragma unroll
            for (int nf = 0; nf < 2; ++nf) {
                const int br_ = h2 * 2048 + (wc + nf * 16 + fr) * 32 + fq * 8;
                short8 bah = *(const short8*)&ldsB[br_];
                short8 bal = *(const short8*)&ldsB[4096 + br_];
                short8 bgh = *(const short8*)&ldsB[8192 + br_];
                short8 bgl = *(const short8*)&ldsB[12288 + br_];
#pragma unroll
                for (int mf = 0; mf < 4; ++mf) {
                    aa[mf][nf] = mfma16<false>(ah[mf], bah, aa[mf][nf]);
                    aa[mf][nf] = mfma16<false>(ah[mf], bal, aa[mf][nf]);
                    ag[mf][nf] = mfma16<false>(ah[mf], bgh, ag[mf][nf]);
                    ag[mf][nf] = mfma16<false>(ah[mf], bgl, ag[mf][nf]);
                }
            }
        }
        __syncthreads();
    }
#pragma unroll
    for (int nf = 0; nf < 2; ++nf) {
        const int ch = p0 + wc + nf * 16 + fr;
        const float ba = b1[ch], bg = b1[1024 + ch];
#pragma unroll
        for (int mf = 0; mf < 4; ++mf) {
#pragma unroll
            for (int v = 0; v < 4; ++v) {
                const int row = m0 + wr + mf * 16 + fq * 4 + v;
                float u = aa[mf][nf][v] + ba, g = ag[mf][nf][v] + bg;
                Obf[(size_t)row * 1024 + ch] = bf16rne(gelu_exact(u) * g);
            }
        }
    }
}

// ---- ctx GEMM (fp16): 64-row x 80-col tile, K-chunk 1024, BK=64; grid (16,32) ----
__global__ __launch_bounds__(256) void ctx_mfma(
    const unsigned short* __restrict__ kpT, const unsigned short* __restrict__ vT,
    float* __restrict__ ctxp)
{
    __shared__ unsigned short la[4096];        // [2 halves][64][32]
    __shared__ unsigned short lb[5120];        // [2 halves][80][32]
    int bx, by; xcd_swz(bx, by);
    const int bh = by, mt = bx & 3, kc = bx >> 2;
    const int tid = threadIdx.x;
    const int l = tid & 63, w = tid >> 6;
    const int wr = w * 16, fr = l & 15, fq = l >> 4;
    const int sr = tid >> 2, sc = (tid & 3) * 8;
    const unsigned short* ga  = kpT + ((size_t)bh * 256 + mt * 64 + sr) * 4096 + kc * 1024 + sc;
    const unsigned short* gb  = vT + ((size_t)bh * 80 + sr) * 4096 + kc * 1024 + sc;
    const unsigned short* gb2 = vT + ((size_t)bh * 80 + 64 + sr) * 4096 + kc * 1024 + sc;

    f32x4 acc[5];
#pragma unroll
    for (int j = 0; j < 5; ++j) acc[j] = (f32x4){0.f, 0.f, 0.f, 0.f};

    for (int k0 = 0; k0 < 1024; k0 += 64) {
        glds16(ga + k0, la + tid * 8);
        glds16(ga + k0 + 32, la + 2048 + tid * 8);
        glds16(gb + k0, lb + tid * 8);
        glds16(gb + k0 + 32, lb + 2560 + tid * 8);
        if (tid < 64) {
            glds16(gb2 + k0, lb + 2048 + tid * 8);
            glds16(gb2 + k0 + 32, lb + 2560 + 2048 + tid * 8);
        }
        __syncthreads();
#pragma unroll
        for (int h2 = 0; h2 < 2; ++h2) {
            short8 av = *(const short8*)&la[h2 * 2048 + (wr + fr) * 32 + fq * 8];
#pragma unroll
            for (int nf = 0; nf < 5; ++nf) {
                short8 bv = *(const short8*)&lb[h2 * 2560 + (nf * 16 + fr) * 32 + fq * 8];
                acc[nf] = mfma16<true>(av, bv, acc[nf]);
            }
        }
        __syncthreads();
    }
#pragma unroll
    for (int v = 0; v < 4; ++v) {
        const int row = mt * 64 + wr + fq * 4 + v;
#pragma unroll
        for (int nf = 0; nf < 5; ++nf)
            ctxp[((size_t)(kc * 32 + bh) * 256 + row) * 80 + nf * 16 + fr] = acc[nf][v];
    }
}

// ---- reduce ctx partials over 4 k-chunks, transpose -> ctxT fp16 [bh][80][256] ----
__global__ __launch_bounds__(256) void ctx_fix(
    const float* __restrict__ ctxp, unsigned short* __restrict__ cth)
{
    __shared__ float s[64][81];
    const int m0 = blockIdx.x * 64, bh = blockIdx.y;
    const int tid = threadIdx.x;
    for (int i = tid; i < 5120; i += 256) {
        const int ml = i / 80, dc = i % 80;
        float sum = 0.f;
#pragma unroll
        for (int kc = 0; kc < 4; ++kc)
            sum += ctxp[((size_t)(kc * 32 + bh) * 256 + m0 + ml) * 80 + dc];
        s[ml][dc] = sum;
    }
    __syncthreads();
    for (int i = tid; i < 5120; i += 256) {
        const int dc = i >> 6, ml = i & 63;
        cth[((size_t)bh * 80 + dc) * 256 + m0 + ml] = fp16rne(s[ml][dc]);
    }
}

// ---- fused q-side (fp16), 64-token tiles: dd = q@pm (K=64) -> row max -> exp ->
//      qp (XOR-swizzled LDS) -> o = (qp @ ctxT)/(qp . ksum). grid (64, 32). ----
__global__ __launch_bounds__(256) void qo_mfma(
    const unsigned short* __restrict__ qhi, const unsigned short* __restrict__ pmh,
    const unsigned short* __restrict__ cth, const float* __restrict__ diagq,
    unsigned short* __restrict__ osh)
{
    __shared__ unsigned short lds[16384 + 2560];   // qp tile (unions phase1 staging) | ctx staging
    __shared__ float rmax4[64][4];
    int bx, by; xcd_swz(bx, by);
    const int bh = by, b = bh >> 2, hh = bh & 3;
    const int t0 = bx * 64;
    const int tid = threadIdx.x;
    const int l = tid & 63, w = tid >> 6;
    const int fr = l & 15, fq = l >> 4;

    // ---- phase 1: dd[64 tok][256 m], K = 64; wave w owns cols wc1..wc1+63 ----
    const int wc1 = w * 64;
    f32x4 a1[4][4];
#pragma unroll
    for (int i = 0; i < 4; ++i)
#pragma unroll
        for (int j = 0; j < 4; ++j) a1[i][j] = (f32x4){0.f, 0.f, 0.f, 0.f};

    const unsigned short* gq = qhi + (size_t)(b * 4096 + t0) * 256 + hh * 64;
#pragma unroll
    for (int ks = 0; ks < 2; ++ks) {
        const int k0 = ks * 32;
        // A: 64 rows x 32 (256 chunks) at lds[0..2048)
        glds16(gq + (size_t)(tid >> 2) * 256 + k0 + (tid & 3) * 8, lds + tid * 8);
        // B: pm fp16, 256 rows x 32 at lds[2048..10240)
#pragma unroll
        for (int i2 = 0; i2 < 4; ++i2) {
            const int c = tid + i2 * 256;
            glds16(pmh + (size_t)(c >> 2) * 64 + k0 + (c & 3) * 8, lds + 2048 + c * 8);
        }
        __syncthreads();
        short8 av[4];
#pragma unroll
        for (int mf = 0; mf < 4; ++mf)
            av[mf] = *(const short8*)&lds[(mf * 16 + fr) * 32 + fq * 8];
#pragma unroll
        for (int nf = 0; nf < 4; ++nf) {
            short8 bh_ = *(const short8*)&lds[2048 + (wc1 + nf * 16 + fr) * 32 + fq * 8];
#pragma unroll
            for (int mf = 0; mf < 4; ++mf)
                a1[mf][nf] = mfma16<true>(av[mf], bh_, a1[mf][nf]);
        }
        __syncthreads();
    }
    // ---- row max (per-wave strip max, combined across 4 waves) ----
#pragma unroll
    for (int mf = 0; mf < 4; ++mf)
#pragma unroll
        for (int v = 0; v < 4; ++v) {
            float rm = a1[mf][0][v];
#pragma unroll
            for (int nf = 1; nf < 4; ++nf) rm = fmaxf(rm, a1[mf][nf][v]);
            rm = fmaxf(rm, __shfl_xor(rm, 1));
            rm = fmaxf(rm, __shfl_xor(rm, 2));
            rm = fmaxf(rm, __shfl_xor(rm, 4));
            rm = fmaxf(rm, __shfl_xor(rm, 8));
            if (fr == 0) rmax4[mf * 16 + fq * 4 + v][w] = rm;
        }
    __syncthreads();
    // ---- exp -> qp fp16 into XOR-swizzled LDS tile [64][256] ----
#pragma unroll
    for (int mf = 0; mf < 4; ++mf)
#pragma unroll
        for (int v = 0; v < 4; ++v) {
            const int tok = mf * 16 + fq * 4 + v;
            const float dg = diagq[(size_t)(b * 4096 + t0 + tok) * 4 + hh]
                           + fmaxf(fmaxf(rmax4[tok][0], rmax4[tok][1]),
                                   fmaxf(rmax4[tok][2], rmax4[tok][3]));
#pragma unroll
            for (int nf = 0; nf < 4; ++nf) {
                const int m = wc1 + nf * 16 + fr;
                lds[tok * 256 + (m ^ ((tok & 7) << 3))] =
                    fp16rne(RATIO * (__expf(a1[mf][nf][v] - dg) + EPSF));
            }
        }
    __syncthreads();

    // ---- phase 2: o[64 tok][80] = qp @ ctxT (K=256, fp16); col 64 = denom ----
    unsigned short* lds2 = lds + 16384;
    f32x4 a2[5];
#pragma unroll
    for (int j = 0; j < 5; ++j) a2[j] = (f32x4){0.f, 0.f, 0.f, 0.f};
    const size_t bbase = (size_t)bh * 80 * 256;

    for (int k0 = 0; k0 < 256; k0 += 32) {
        glds16(cth + bbase + (size_t)(tid >> 2) * 256 + k0 + (tid & 3) * 8, lds2 + tid * 8);
        if (tid < 64) {
            const int c = 256 + tid;
            glds16(cth + bbase + (size_t)(c >> 2) * 256 + k0 + (c & 3) * 8, lds2 + c * 8);
        }
        __syncthreads();
        const int tok = w * 16 + fr;
        const int c = ((k0 >> 3) + fq) ^ (tok & 7);
        short8 av = *(const short8*)&lds[tok * 256 + c * 8];
#pragma unroll
        for (int nf = 0; nf < 5; ++nf) {
            short8 bvh = *(const short8*)&lds2[(nf * 16 + fr) * 32 + fq * 8];
            a2[nf] = mfma16<true>(av, bvh, a2[nf]);
        }
        __syncthreads();
    }
#pragma unroll
    for (int v = 0; v < 4; ++v) {
        const float den = __shfl(a2[4][v], (int)(l & 48));
        const float dinv = 1.0f / den;
        const int tok = w * 16 + fq * 4 + v;
        const size_t obase = (size_t)(b * 4096 + t0 + tok) * 256 + hh * 64;
#pragma unroll
        for (int nf = 0; nf < 4; ++nf)
            osh[obase + nf * 16 + fr] = bf16rne(a2[nf][v] * dinv);
    }
}

// ---- pooling + classifier ----
__global__ __launch_bounds__(256) void pool1_kernel(const float* __restrict__ h, float* __restrict__ part)
{
    const int b = blockIdx.x >> 4, ch = blockIdx.x & 15;
    const int tid = threadIdx.x;
    float acc = 0.f;
    for (int n = 0; n < 256; ++n)
        acc += h[((size_t)(b * 4096 + ch * 256 + n)) * 256 + tid];
    part[(size_t)blockIdx.x * 256 + tid] = acc;
}

__global__ __launch_bounds__(256) void pool2_kernel(
    const float* __restrict__ part, const float* __restrict__ cw,
    const float* __restrict__ cb, float* __restrict__ out)
{
    const int b = blockIdx.x, tid = threadIdx.x;
    float acc = 0.f;
#pragma unroll
    for (int c = 0; c < 16; ++c) acc += part[(size_t)(b * 16 + c) * 256 + tid];
    float val = acc * (1.0f / 4096.0f) * cw[tid];
#pragma unroll
    for (int s = 1; s < 64; s <<= 1) val += __shfl_xor(val, s);
    __shared__ float red[4];
    if ((tid & 63) == 0) red[tid >> 6] = val;
    __syncthreads();
    if (tid == 0) out[b] = red[0] + red[1] + red[2] + red[3] + cb[0];
}

extern "C" void kernel_launch(void* const* d_in, const int* in_sizes, int n_in,
                              void* d_out, int out_size, void* d_ws, size_t ws_size,
                              hipStream_t stream)
{
    (void)in_sizes; (void)n_in;
    if (ws_size < WS_BYTES) {
        fill_sentinel<<<1, 64, 0, stream>>>((float*)d_out, out_size);
        return;
    }

    const float* x     = (const float*)d_in[0];
    const float* projw = (const float*)d_in[1];
    const float* projb = (const float*)d_in[2];
    const float* ln1g  = (const float*)d_in[3];
    const float* ln1b  = (const float*)d_in[4];
    const float* wq    = (const float*)d_in[5];
    const float* bq    = (const float*)d_in[6];
    const float* wk    = (const float*)d_in[7];
    const float* bk    = (const float*)d_in[8];
    const float* wv    = (const float*)d_in[9];
    const float* bv    = (const float*)d_in[10];
    const float* wo    = (const float*)d_in[11];
    const float* bo    = (const float*)d_in[12];
    const float* ln2g  = (const float*)d_in[13];
    const float* ln2b  = (const float*)d_in[14];
    const float* w1    = (const float*)d_in[15];
    const float* b1    = (const float*)d_in[16];
    const float* w2    = (const float*)d_in[17];
    const float* b2    = (const float*)d_in[18];
    const float* clfw  = (const float*)d_in[19];
    const float* clfb  = (const float*)d_in[20];
    const float* projm = (const float*)d_in[21];

    char* WS = (char*)d_ws;
    float* h            = (float*)(WS + OFF_H);
    unsigned short* ysh = (unsigned short*)(WS + OFF_YS);
    unsigned short* wts = (unsigned short*)(WS + OFF_WTS);
    unsigned short* khi = (unsigned short*)(WS + OFF_QK);
    unsigned short* qhi = khi + 8388608;
    unsigned short* big = (unsigned short*)(WS + OFF_BIG);   // kpT / ffb / x-split
    unsigned short* vT  = (unsigned short*)(WS + OFF_VT);
    float* ctxp         = (float*)(WS + OFF_CTXP);
    unsigned short* cth = (unsigned short*)(WS + OFF_CTXTH);
    float* diagq        = (float*)(WS + OFF_DIAGQ);
    float* diagk        = (float*)(WS + OFF_DIAGK);
    unsigned* gmax      = (unsigned*)(WS + OFF_GMAX);
    float* pool         = (float*)(WS + OFF_POOL);
    unsigned short* pmt_h = (unsigned short*)(WS + OFF_PMTH);
    unsigned short* pwt_h = (unsigned short*)(WS + OFF_PWTH);
    unsigned short* pwt_l = (unsigned short*)(WS + OFF_PWTL);
    // aliases
    unsigned short* xsh = big;               // prologue only
    unsigned short* xsl = big + 2097152;
    unsigned short* kpT = big;               // [32][256][4096] fp16
    unsigned short* ffb = big;               // [32768][1024] bf16
    unsigned short* osh = ysh;               // o bf16 (ys dead by then)

    // ---- prologue ----
    split_scale<<<8192, 256, 0, stream>>>(x, xsh, xsl, 2097152, 1.0f);
    splitT<<<64, 256, 0, stream>>>(projw, pwt_h, pwt_l, 6, 256);
    tofp16_scale<<<64, 256, 0, stream>>>(projm, pmt_h, 16384, DN);
    vt_init<<<1024, 256, 0, stream>>>(vT, gmax);
    split_weights<<<16384, 256, 0, stream>>>(wq, wk, wv, wo, w1, w2, wts);
    gemm_mf<0, true, true, false><<<dim3(2, 256), 256, 0, stream>>>(xsh, xsl, 64,
        pwt_h, pwt_l, 64, 64, projb, nullptr, h, 256, nullptr, nullptr, nullptr);

    for (int l = 0; l < 4; ++l) {
        unsigned short* wl = wts + (size_t)l * 2097152;

        // ---- attention ----
        ln_bf16<<<8192, 256, 0, stream>>>(h, ln1g + l * 256, ln1b + l * 256, ysh);
        gemm_qkv<<<dim3(2, 768), 256, 0, stream>>>(ysh, wl,
            bq + l * 256, bk + l * 256, bv + l * 256, vT, khi, qhi, diagq, diagk);
        gemm_mf<4, false, false, true><<<dim3(2, 1024), 256, 0, stream>>>(khi, nullptr, 64,
            pmt_h, nullptr, 64, 64, nullptr, nullptr, nullptr, 256, nullptr, nullptr, gmax + l);
        gemm_mf<6, false, false, true><<<dim3(2, 1024), 256, 0, stream>>>(khi, nullptr, 64,
            pmt_h, nullptr, 64, 64, nullptr, nullptr, nullptr, 256, kpT, diagk, gmax + l);
        ctx_mfma<<<dim3(16, 32), 256, 0, stream>>>(kpT, vT, ctxp);
        ctx_fix<<<dim3(4, 32), 256, 0, stream>>>(ctxp, cth);
        qo_mfma<<<dim3(64, 32), 256, 0, stream>>>(qhi, pmt_h, cth, diagq, osh);
        gemm_mf<1, false, true, false><<<dim3(2, 256), 256, 0, stream>>>(osh, nullptr, 256,
            wl + WO_H, wl + WO_L, 256, 256, bo + l * 256, h, h, 256, nullptr, nullptr, nullptr);

        // ---- feed-forward ----
        ln_bf16<<<8192, 256, 0, stream>>>(h, ln2g + l * 256, ln2b + l * 256, ysh);
        gemm_glu<<<dim3(16, 256), 256, 0, stream>>>(ysh, wl + W1_H, wl + W1_L,
            b1 + (size_t)l * 2048, ffb);
        gemm_mf<1, false, true, false><<<dim3(2, 256), 256, 0, stream>>>(ffb, nullptr, 1024,
            wl + W2_H, wl + W2_L, 1024, 1024, b2 + l * 256, h, h, 256, nullptr, nullptr, nullptr);
    }

    pool1_kernel<<<128, 256, 0, stream>>>(h, pool);
    pool2_kernel<<<8, 256, 0, stream>>>(pool, clfw, clfb, (float*)d_out);
}

// Round 12
// 1172.889 us; speedup vs baseline: 10.2312x; 1.1432x over previous
//
#include <hip/hip_runtime.h>
#include <cstdint>
#include <cstddef>

// ---- problem constants ----
constexpr float DN = 0.35355339059327373f;   // 64^-0.25
constexpr float RATIO = 0.0625f;             // 256^-0.5
constexpr float EPSF = 1e-4f;

typedef __attribute__((ext_vector_type(8))) short short8;   // 16-bit MFMA fragment
typedef __attribute__((ext_vector_type(8))) _Float16 half8;
typedef __attribute__((ext_vector_type(4))) float f32x4;    // MFMA accumulator

// ---- workspace layout (byte offsets); proven budget >= 209,715,200 B ----
constexpr size_t OFF_H     = 0;              // fp32 residual 33,554,432
constexpr size_t OFF_YS    = 33554432;       // ysh fp16 (osh alias) 16,777,216
constexpr size_t OFF_WTS   = 50331648;       // all-layer fp16 weights 8,388,608 (+spare)
constexpr size_t OFF_QK    = 67108864;       // khi 16,777,216 | qhi 16,777,216 (fp16)
constexpr size_t OFF_BIG   = 100663296;      // kpT / ffb / x-split 67,108,864
constexpr size_t OFF_VT    = 167772160;      // vT [32][80][4096] fp16 20,971,520
constexpr size_t OFF_CTXP  = 188743680;      // ctx partials [4][32][256][80] f32 10,485,760
constexpr size_t OFF_CTXTH = 199229440;      // ctxT fp16 [32][80][256] 1,310,720
constexpr size_t OFF_DIAGQ = 201850880;      // 524,288
constexpr size_t OFF_DIAGK = 202375168;      // 524,288
constexpr size_t OFF_GMAX  = 203423744;      // 256 (4 per-layer slots used)
constexpr size_t OFF_POOL  = 203424000;      // 131,072
constexpr size_t OFF_PMTH  = 207749376;      // pm fp16 32,768
constexpr size_t OFF_PWTH  = 207814912;
constexpr size_t OFF_PWTL  = 207847680;
constexpr size_t WS_BYTES  = 207880448;

// per-layer short-offsets inside the fp16 WTS region (layer stride 1,048,576 shorts)
constexpr size_t WQF = 0;
constexpr size_t WKF = 65536;
constexpr size_t WVF = 131072;
constexpr size_t WOF = 196608;
constexpr size_t W1F = 262144;     // 524,288 shorts ([2048][256])
constexpr size_t W2F = 786432;     // 262,144 shorts ([256][1024])

__device__ __forceinline__ unsigned fkey(float f) {
    unsigned u = __float_as_uint(f);
    return (u & 0x80000000u) ? ~u : (u | 0x80000000u);
}
__device__ __forceinline__ float funkey(unsigned k) {
    unsigned u = (k & 0x80000000u) ? (k ^ 0x80000000u) : ~k;
    return __uint_as_float(u);
}
__device__ __forceinline__ float gelu_exact(float x) {
    return 0.5f * x * (1.0f + erff(x * 0.70710678118654752f));
}
__device__ __forceinline__ void splitf(float x, unsigned short& h, unsigned short& l) {
    unsigned u = __float_as_uint(x);
    unsigned hv = (u + 0x7FFFu + ((u >> 16) & 1)) >> 16;
    h = (unsigned short)hv;
    float lo = x - __uint_as_float(hv << 16);
    unsigned u2 = __float_as_uint(lo);
    l = (unsigned short)((u2 + 0x7FFFu + ((u2 >> 16) & 1)) >> 16);
}
__device__ __forceinline__ unsigned short bf16rne(float x) {
    unsigned u = __float_as_uint(x);
    return (unsigned short)((u + 0x7FFFu + ((u >> 16) & 1)) >> 16);
}
__device__ __forceinline__ unsigned short fp16rne(float x) {
    return __builtin_bit_cast(unsigned short, (_Float16)x);
}
template<bool F16>
__device__ __forceinline__ f32x4 mfma16(short8 a, short8 b, f32x4 c) {
    if constexpr (F16)
        return __builtin_amdgcn_mfma_f32_16x16x32_f16(
            __builtin_bit_cast(half8, a), __builtin_bit_cast(half8, b), c, 0, 0, 0);
    else
        return __builtin_amdgcn_mfma_f32_16x16x32_bf16(a, b, c, 0, 0, 0);
}
// XCD-aware block swizzle (requires total blocks % 8 == 0)
__device__ __forceinline__ void xcd_swz(int& bx, int& by) {
    const int gx = gridDim.x;
    const int total = gx * gridDim.y;
    int flat = blockIdx.y * gx + blockIdx.x;
    flat = (flat & 7) * (total >> 3) + (flat >> 3);
    bx = flat % gx; by = flat / gx;
}

// ---- async global->LDS 16B (wave-uniform base + lane*16, linear dest) ----
#if defined(__has_builtin)
#if __has_builtin(__builtin_amdgcn_global_load_lds)
#define HAVE_GLDS 1
#endif
#endif
__device__ __forceinline__ void glds16(const unsigned short* g, unsigned short* l) {
#ifdef HAVE_GLDS
    __builtin_amdgcn_global_load_lds(
        (const __attribute__((address_space(1))) unsigned int*)g,
        (__attribute__((address_space(3))) unsigned int*)l, 16, 0, 0);
#else
    *(uint4*)l = *(const uint4*)g;
#endif
}

__global__ void fill_sentinel(float* out, int n) {
    int i = threadIdx.x;
    if (i < n) out[i] = 12345.0f;
}
// fill vT rows 64..79 (row 64 = 1.0 fp16 for ksum fold) + zero per-layer gmax keys
__global__ __launch_bounds__(256) void vt_init(unsigned short* __restrict__ vT, unsigned* __restrict__ gm) {
    int i = blockIdx.x * 256 + threadIdx.x;        // 262,144 uint4
    if (i < 4) gm[i] = 0u;
    const int bh = i >> 13;
    const int r = (i >> 9) & 15;
    const unsigned val = (r == 0) ? 0x3C003C00u : 0u;
    uint4 q; q.x = val; q.y = val; q.z = val; q.w = val;
    *(uint4*)(vT + ((size_t)bh * 80 + 64 + r) * 4096 + ((size_t)(i & 511) << 3)) = q;
}

// ---- elementwise split (optional scale) ----
__global__ __launch_bounds__(256) void split_scale(
    const float* __restrict__ src, unsigned short* __restrict__ hi,
    unsigned short* __restrict__ lo, int n, float scale)
{
    int i = blockIdx.x * 256 + threadIdx.x;
    if (i < n) {
        unsigned short h, l;
        splitf(src[i] * scale, h, l);
        hi[i] = h; lo[i] = l;
    }
}

// ---- fp32 -> fp16 with scale ----
__global__ __launch_bounds__(256) void tofp16_scale(
    const float* __restrict__ src, unsigned short* __restrict__ dst, int n, float scale)
{
    int i = blockIdx.x * 256 + threadIdx.x;
    if (i < n) dst[i] = fp16rne(src[i] * scale);
}

// ---- transpose-split weights: W [K,N] fp32 -> Wt hi/lo [N,K] bf16 (proj only) ----
__global__ __launch_bounds__(256) void splitT(
    const float* __restrict__ W, unsigned short* __restrict__ hi,
    unsigned short* __restrict__ lo, int kshift, int N)
{
    int i = blockIdx.x * 256 + threadIdx.x;
    int K = 1 << kshift;
    int n = i >> kshift, k = i & (K - 1);
    unsigned short h, l;
    splitf(W[(size_t)k * N + n], h, l);
    hi[i] = h; lo[i] = l;
}

// ---- all-layer weight transpose -> fp16 [N][K]; one dispatch, 4,194,304 elems ----
__global__ __launch_bounds__(256) void split_weights(
    const float* __restrict__ wq, const float* __restrict__ wk,
    const float* __restrict__ wv, const float* __restrict__ wo,
    const float* __restrict__ w1, const float* __restrict__ w2,
    unsigned short* __restrict__ dst)
{
    const int i = blockIdx.x * 256 + threadIdx.x;
    const int lay = i >> 20;
    const int r = i & 1048575;
    float val; size_t oh;
    if (r < 262144) {
        const int m = r >> 16, e = r & 65535;
        const int n = e >> 8, k = e & 255;
        const float* W = (m == 0 ? wq : m == 1 ? wk : m == 2 ? wv : wo);
        val = W[(size_t)lay * 65536 + k * 256 + n];
        oh = (size_t)lay * 1048576 + (size_t)m * 65536 + e;
    } else if (r < 786432) {
        const int e = r - 262144;
        const int n = e >> 8, k = e & 255;
        val = w1[(size_t)lay * 524288 + (size_t)k * 2048 + n];
        oh = (size_t)lay * 1048576 + W1F + e;
    } else {
        const int e = r - 786432;
        const int n = e >> 10, k = e & 1023;
        val = w2[(size_t)lay * 262144 + (size_t)k * 256 + n];
        oh = (size_t)lay * 1048576 + W2F + e;
    }
    dst[oh] = fp16rne(val);
}

// ---- LayerNorm -> single fp16 plane ----
__global__ __launch_bounds__(256) void ln_f16(
    const float* __restrict__ x, const float* __restrict__ g,
    const float* __restrict__ b, unsigned short* __restrict__ yhi)
{
    const int row = blockIdx.x * 4 + (threadIdx.x >> 6);
    const int lane = threadIdx.x & 63;
    float4 t = *(const float4*)&x[(size_t)row * 256 + lane * 4];
    float s = t.x + t.y + t.z + t.w;
#pragma unroll
    for (int sh = 1; sh < 64; sh <<= 1) s += __shfl_xor(s, sh);
    const float mu = s * (1.0f / 256.0f);
    const float dx = t.x - mu, dy = t.y - mu, dz = t.z - mu, dw = t.w - mu;
    float vv = dx * dx + dy * dy + dz * dz + dw * dw;
#pragma unroll
    for (int sh = 1; sh < 64; sh <<= 1) vv += __shfl_xor(vv, sh);
    const float rstd = rsqrtf(vv * (1.0f / 256.0f) + 1e-5f);
    float4 gv = *(const float4*)&g[lane * 4];
    float4 bv = *(const float4*)&b[lane * 4];
    unsigned short h0 = fp16rne(dx * rstd * gv.x + bv.x);
    unsigned short h1 = fp16rne(dy * rstd * gv.y + bv.y);
    unsigned short h2 = fp16rne(dz * rstd * gv.z + bv.z);
    unsigned short h3 = fp16rne(dw * rstd * gv.w + bv.w);
    uint2 ph;
    ph.x = (unsigned)h0 | ((unsigned)h1 << 16); ph.y = (unsigned)h2 | ((unsigned)h3 << 16);
    *(uint2*)&yhi[(size_t)row * 256 + lane * 4] = ph;
}

// ---- bf16/f16 MFMA GEMM, tile 128x128, BK=64, 4 waves ----
// EPI: 0 bias->f32 C | 1 bias(nullable)+res->f32 C
//      4 global max -> keys[0]
//      6 kp = exp epilogue fp16 + TRANSPOSED write to kpT[bh][m][n]
template<int EPI, bool ASPLIT, bool BSPLIT, bool F16>
__global__ __launch_bounds__(256) void gemm_mf(
    const unsigned short* __restrict__ Ahi, const unsigned short* __restrict__ Alo, int lda,
    const unsigned short* __restrict__ Bhi, const unsigned short* __restrict__ Blo, int ldb,
    int K,
    const float* __restrict__ bias, const float* __restrict__ res,
    float* __restrict__ C, int ldc,
    unsigned short* __restrict__ Obf,
    const float* __restrict__ diag, unsigned* __restrict__ keys)
{
    constexpr int NP = (ASPLIT ? 2 : 1) + (BSPLIT ? 2 : 1);
    constexpr int PB = ASPLIT ? 2 : 1;                 // B-hi plane index
    constexpr int NEED = (EPI == 6) ? 16384 : 0;
    constexpr int LDSN = (NP * 8192 > NEED) ? NP * 8192 : NEED;
    __shared__ unsigned short lds[LDSN];
    __shared__ float red[4];
#define LX(p, h, r, c) lds[(p) * 8192 + (h) * 4096 + (r) * 32 + (c)]
    int bx, by; xcd_swz(bx, by);
    const int tid = threadIdx.x;
    const int m0 = by * 128, n0 = bx * 128;
    const int sr = tid >> 2, sc = (tid & 3) * 8;
    const unsigned short* ga_h = Ahi + (size_t)(m0 + sr) * lda + sc;
    const unsigned short* ga_l = ASPLIT ? (Alo + (size_t)(m0 + sr) * lda + sc) : nullptr;
    const unsigned short* gb_h = Bhi + (size_t)(n0 + sr) * ldb + sc;
    const unsigned short* gb_l = BSPLIT ? (Blo + (size_t)(n0 + sr) * ldb + sc) : nullptr;
    unsigned short* lp = lds + tid * 8;
    const int l = tid & 63, w = tid >> 6;
    const int wr = (w >> 1) * 64, wc = (w & 1) * 64;
    const int fr = l & 15, fq = l >> 4;

    f32x4 acc[4][4];
#pragma unroll
    for (int i = 0; i < 4; ++i)
#pragma unroll
        for (int j = 0; j < 4; ++j) acc[i][j] = (f32x4){0.f, 0.f, 0.f, 0.f};

    for (int k0 = 0; k0 < K; k0 += 64) {
        glds16(ga_h + k0, lp);
        glds16(ga_h + (size_t)64 * lda + k0, lp + 2048);
        glds16(ga_h + k0 + 32, lp + 4096);
        glds16(ga_h + (size_t)64 * lda + k0 + 32, lp + 6144);
        if (ASPLIT) {
            glds16(ga_l + k0, lp + 8192);
            glds16(ga_l + (size_t)64 * lda + k0, lp + 10240);
            glds16(ga_l + k0 + 32, lp + 12288);
            glds16(ga_l + (size_t)64 * lda + k0 + 32, lp + 14336);
        }
        glds16(gb_h + k0, lp + PB * 8192);
        glds16(gb_h + (size_t)64 * ldb + k0, lp + PB * 8192 + 2048);
        glds16(gb_h + k0 + 32, lp + PB * 8192 + 4096);
        glds16(gb_h + (size_t)64 * ldb + k0 + 32, lp + PB * 8192 + 6144);
        if (BSPLIT) {
            glds16(gb_l + k0, lp + (PB + 1) * 8192);
            glds16(gb_l + (size_t)64 * ldb + k0, lp + (PB + 1) * 8192 + 2048);
            glds16(gb_l + k0 + 32, lp + (PB + 1) * 8192 + 4096);
            glds16(gb_l + (size_t)64 * ldb + k0 + 32, lp + (PB + 1) * 8192 + 6144);
        }
        __syncthreads();
#pragma unroll
        for (int h2 = 0; h2 < 2; ++h2) {
            short8 ah[4], al[4];
#pragma unroll
            for (int mf = 0; mf < 4; ++mf) {
                ah[mf] = *(const short8*)&LX(0, h2, wr + mf * 16 + fr, fq * 8);
                if (ASPLIT) al[mf] = *(const short8*)&LX(1, h2, wr + mf * 16 + fr, fq * 8);
            }
#pragma unroll
            for (int nf = 0; nf < 4; ++nf) {
                short8 bh = *(const short8*)&LX(PB, h2, wc + nf * 16 + fr, fq * 8);
#pragma unroll
                for (int mf = 0; mf < 4; ++mf) {
                    acc[mf][nf] = mfma16<F16>(ah[mf], bh, acc[mf][nf]);
                    if (ASPLIT) acc[mf][nf] = mfma16<F16>(al[mf], bh, acc[mf][nf]);
                }
                if (BSPLIT) {
                    short8 bl = *(const short8*)&LX(PB + 1, h2, wc + nf * 16 + fr, fq * 8);
#pragma unroll
                    for (int mf = 0; mf < 4; ++mf)
                        acc[mf][nf] = mfma16<F16>(ah[mf], bl, acc[mf][nf]);
                }
            }
        }
        __syncthreads();
    }

    if constexpr (EPI == 4) {
        float m = -3.4e38f;
#pragma unroll
        for (int mf = 0; mf < 4; ++mf)
#pragma unroll
            for (int nf = 0; nf < 4; ++nf)
#pragma unroll
                for (int v = 0; v < 4; ++v) m = fmaxf(m, acc[mf][nf][v]);
#pragma unroll
        for (int s = 1; s < 64; s <<= 1) m = fmaxf(m, __shfl_xor(m, s));
        if (l == 0) red[w] = m;
        __syncthreads();
        if (tid == 0)
            atomicMax(keys, fkey(fmaxf(fmaxf(red[0], red[1]), fmaxf(red[2], red[3]))));
    } else if constexpr (EPI == 6) {
        const float Mg = funkey(*keys);
        unsigned short* tb = lds;
#pragma unroll
        for (int mf = 0; mf < 4; ++mf)
#pragma unroll
            for (int v = 0; v < 4; ++v) {
                const int rl = wr + mf * 16 + fq * 4 + v;
                const float dg = diag[m0 + rl] + Mg;
#pragma unroll
                for (int nf = 0; nf < 4; ++nf) {
                    const int cl = wc + nf * 16 + fr;
                    tb[rl * 128 + cl] = fp16rne(RATIO * (__expf(acc[mf][nf][v] - dg) + EPSF));
                }
            }
        __syncthreads();
        const int tokbase = m0 >> 2;
        const int b = tokbase >> 12, nib = tokbase & 4095;
        const int ml = tid & 127, g2 = tid >> 7;
#pragma unroll
        for (int hh2 = 0; hh2 < 2; ++hh2) {
            const int hh = g2 * 2 + hh2;
            unsigned short* dst = Obf + ((size_t)((b * 4 + hh) * 256 + n0 + ml)) * 4096 + nib;
#pragma unroll
            for (int qq = 0; qq < 4; ++qq) {
                uint4 qv;
                unsigned wv[4];
#pragma unroll
                for (int j = 0; j < 4; ++j) {
                    unsigned s0 = tb[((qq * 8 + j * 2 + 0) * 4 + hh) * 128 + ml];
                    unsigned s1 = tb[((qq * 8 + j * 2 + 1) * 4 + hh) * 128 + ml];
                    wv[j] = s0 | (s1 << 16);
                }
                qv.x = wv[0]; qv.y = wv[1]; qv.z = wv[2]; qv.w = wv[3];
                *(uint4*)(dst + qq * 8) = qv;
            }
        }
    } else {
#pragma unroll
        for (int nf = 0; nf < 4; ++nf) {
            const int col = n0 + wc + nf * 16 + fr;
            float bb = 0.f;
            if (bias != nullptr) bb = bias[col];
#pragma unroll
            for (int mf = 0; mf < 4; ++mf) {
#pragma unroll
                for (int v = 0; v < 4; ++v) {
                    const int row = m0 + wr + mf * 16 + fq * 4 + v;
                    const size_t off = (size_t)row * ldc + col;
                    float val = acc[mf][nf][v] + bb;
                    if (EPI == 1) val += res[off];
                    C[off] = val;
                }
            }
        }
    }
#undef LX
}

// ---- merged QKV GEMM (fp16 A & W, 1 MFMA/site); grid (2, 768): by>>8 selects
//      0=V (fp16 transposed vT write), 1=K, 2=Q (fp16 plane + per-head diag). ----
__global__ __launch_bounds__(256) void gemm_qkv(
    const unsigned short* __restrict__ A, const unsigned short* __restrict__ wl,
    const float* __restrict__ bq, const float* __restrict__ bk, const float* __restrict__ bv,
    unsigned short* __restrict__ vT, unsigned short* __restrict__ khi,
    unsigned short* __restrict__ qhi, float* __restrict__ diagq, float* __restrict__ diagk)
{
    __shared__ unsigned short lds[16384];
    int bx, by; xcd_swz(bx, by);
    const int sel = by >> 8;
    const int m0 = (by & 255) * 128, n0 = bx * 128;
    const unsigned short* Bw = wl + (sel == 0 ? WVF : sel == 1 ? WKF : WQF);
    const float* bias = (sel == 0 ? bv : sel == 1 ? bk : bq);
    const int tid = threadIdx.x;
    const int sr = tid >> 2, sc = (tid & 3) * 8;
    const unsigned short* ga = A + (size_t)(m0 + sr) * 256 + sc;
    const unsigned short* gb = Bw + (size_t)(n0 + sr) * 256 + sc;
    unsigned short* lp = lds + tid * 8;
    const int l = tid & 63, w = tid >> 6;
    const int wr = (w >> 1) * 64, wc = (w & 1) * 64;
    const int fr = l & 15, fq = l >> 4;

    f32x4 acc[4][4];
#pragma unroll
    for (int i = 0; i < 4; ++i)
#pragma unroll
        for (int j = 0; j < 4; ++j) acc[i][j] = (f32x4){0.f, 0.f, 0.f, 0.f};

    for (int k0 = 0; k0 < 256; k0 += 64) {
        glds16(ga + k0, lp);
        glds16(ga + (size_t)64 * 256 + k0, lp + 2048);
        glds16(ga + k0 + 32, lp + 4096);
        glds16(ga + (size_t)64 * 256 + k0 + 32, lp + 6144);
        glds16(gb + k0, lp + 8192);
        glds16(gb + (size_t)64 * 256 + k0, lp + 10240);
        glds16(gb + k0 + 32, lp + 12288);
        glds16(gb + (size_t)64 * 256 + k0 + 32, lp + 14336);
        __syncthreads();
#pragma unroll
        for (int h2 = 0; h2 < 2; ++h2) {
            short8 ah[4];
#pragma unroll
            for (int mf = 0; mf < 4; ++mf)
                ah[mf] = *(const short8*)&lds[h2 * 4096 + (wr + mf * 16 + fr) * 32 + fq * 8];
#pragma unroll
            for (int nf = 0; nf < 4; ++nf) {
                short8 bh = *(const short8*)&lds[8192 + h2 * 4096 + (wc + nf * 16 + fr) * 32 + fq * 8];
#pragma unroll
                for (int mf = 0; mf < 4; ++mf)
                    acc[mf][nf] = mfma16<true>(ah[mf], bh, acc[mf][nf]);
            }
        }
        __syncthreads();
    }

    if (sel == 0) {
        // V + bias -> fp16, transposed into vT[bh][d][n]
        unsigned short* tb = lds;
#pragma unroll
        for (int mf = 0; mf < 4; ++mf)
#pragma unroll
            for (int nf = 0; nf < 4; ++nf) {
                const int cl = wc + nf * 16 + fr;
                const float bb = bias[n0 + cl];
#pragma unroll
                for (int v = 0; v < 4; ++v) {
                    const int rl = wr + mf * 16 + fq * 4 + v;
                    tb[rl * 128 + cl] = fp16rne(acc[mf][nf][v] + bb);
                }
            }
        __syncthreads();
        const int b = m0 >> 12, nib = m0 & 4095;
        const int cl = tid & 127, half = tid >> 7;
        const int ch = n0 + cl, hh = ch >> 6, d = ch & 63;
        unsigned short* dst = vT + ((size_t)((b * 4 + hh) * 80 + d)) * 4096 + nib + half * 64;
#pragma unroll
        for (int qq = 0; qq < 8; ++qq) {
            uint4 qv;
            unsigned wv[4];
#pragma unroll
            for (int j = 0; j < 4; ++j) {
                unsigned s0 = tb[(half * 64 + qq * 8 + j * 2 + 0) * 128 + cl];
                unsigned s1 = tb[(half * 64 + qq * 8 + j * 2 + 1) * 128 + cl];
                wv[j] = s0 | (s1 << 16);
            }
            qv.x = wv[0]; qv.y = wv[1]; qv.z = wv[2]; qv.w = wv[3];
            *(uint4*)(dst + qq * 8) = qv;
        }
    } else {
        float* diag = (sel == 1 ? diagk : diagq);
        unsigned short* Obf = (sel == 1 ? khi : qhi);
        const int head = (n0 + wc) >> 6;
#pragma unroll
        for (int mf = 0; mf < 4; ++mf) {
            float sq[4] = {0.f, 0.f, 0.f, 0.f};
#pragma unroll
            for (int nf = 0; nf < 4; ++nf) {
                const int col = n0 + wc + nf * 16 + fr;
                const float bb = bias[col];
#pragma unroll
                for (int v = 0; v < 4; ++v) {
                    const int row = m0 + wr + mf * 16 + fq * 4 + v;
                    float val = acc[mf][nf][v] + bb;
                    Obf[(size_t)row * 256 + col] = fp16rne(val);
                    sq[v] += val * val;
                }
            }
#pragma unroll
            for (int v = 0; v < 4; ++v) {
                float s = sq[v];
                s += __shfl_xor(s, 1); s += __shfl_xor(s, 2);
                s += __shfl_xor(s, 4); s += __shfl_xor(s, 8);
                if (fr == 0)
                    diag[(size_t)(m0 + wr + mf * 16 + fq * 4 + v) * 4 + head] = s * 0.0625f;
            }
        }
    }
}

// ---- fused GLU GEMM: A fp16, W fp16 single -> 2 MFMA/site; BK=64 ----
__global__ __launch_bounds__(256) void gemm_glu(
    const unsigned short* __restrict__ Ahi, const unsigned short* __restrict__ Wf,
    const float* __restrict__ b1, unsigned short* __restrict__ Obf)
{
    __shared__ unsigned short ldsA[8192];      // [2 halves][128][32]
    __shared__ unsigned short ldsB[8192];      // 2 planes x [2 halves][64][32]
    int bx, by; xcd_swz(bx, by);
    const int tid = threadIdx.x;
    const int m0 = by * 128, p0 = bx * 64;
    const int sr = tid >> 2, sc = (tid & 3) * 8;
    const unsigned short* ga  = Ahi + (size_t)(m0 + sr) * 256 + sc;
    const unsigned short* gba = Wf + (size_t)(p0 + sr) * 256 + sc;
    const unsigned short* gbg = Wf + (size_t)(1024 + p0 + sr) * 256 + sc;
    unsigned short* lpA = ldsA + tid * 8;
    unsigned short* lpB = ldsB + tid * 8;
    const int l = tid & 63, w = tid >> 6;
    const int wr = (w >> 1) * 64, wc = (w & 1) * 32;
    const int fr = l & 15, fq = l >> 4;

    f32x4 aa[4][2], ag[4][2];
#pragma unroll
    for (int i = 0; i < 4; ++i)
#pragma unroll
        for (int j = 0; j < 2; ++j) {
            aa[i][j] = (f32x4){0.f, 0.f, 0.f, 0.f};
            ag[i][j] = (f32x4){0.f, 0.f, 0.f, 0.f};
        }

    for (int k0 = 0; k0 < 256; k0 += 64) {
        glds16(ga + k0, lpA);
        glds16(ga + 64 * 256 + k0, lpA + 2048);
        glds16(ga + k0 + 32, lpA + 4096);
        glds16(ga + 64 * 256 + k0 + 32, lpA + 6144);
        glds16(gba + k0, lpB);
        glds16(gba + k0 + 32, lpB + 2048);
        glds16(gbg + k0, lpB + 4096);
        glds16(gbg + k0 + 32, lpB + 6144);
        __syncthreads();
#pragma unroll
        for (int h2 = 0; h2 < 2; ++h2) {
            short8 ah[4];
#pragma unroll
            for (int mf = 0; mf < 4; ++mf)
                ah[mf] = *(const short8*)&ldsA[h2 * 4096 + (wr + mf * 16 + fr) * 32 + fq * 8];
#pragma unroll
            for (int nf = 0; nf < 2; ++nf) {
                const int br_ = h2 * 2048 + (wc + nf * 16 + fr) * 32 + fq * 8;
                short8 bva = *(const short8*)&ldsB[br_];
                short8 bvg = *(const short8*)&ldsB[4096 + br_];
#pragma unroll
                for (int mf = 0; mf < 4; ++mf) {
                    aa[mf][nf] = mfma16<true>(ah[mf], bva, aa[mf][nf]);
                    ag[mf][nf] = mfma16<true>(ah[mf], bvg, ag[mf][nf]);
                }
            }
        }
        __syncthreads();
    }
#pragma unroll
    for (int nf = 0; nf < 2; ++nf) {
        const int ch = p0 + wc + nf * 16 + fr;
        const float ba = b1[ch], bg = b1[1024 + ch];
#pragma unroll
        for (int mf = 0; mf < 4; ++mf) {
#pragma unroll
            for (int v = 0; v < 4; ++v) {
                const int row = m0 + wr + mf * 16 + fq * 4 + v;
                float u = aa[mf][nf][v] + ba, g = ag[mf][nf][v] + bg;
                Obf[(size_t)row * 1024 + ch] = fp16rne(gelu_exact(u) * g);
            }
        }
    }
}

// ---- ctx GEMM (fp16): 64-row x 80-col tile, K-chunk 1024, BK=64; grid (16,32) ----
__global__ __launch_bounds__(256) void ctx_mfma(
    const unsigned short* __restrict__ kpT, const unsigned short* __restrict__ vT,
    float* __restrict__ ctxp)
{
    __shared__ unsigned short la[4096];        // [2 halves][64][32]
    __shared__ unsigned short lb[5120];        // [2 halves][80][32]
    int bx, by; xcd_swz(bx, by);
    const int bh = by, mt = bx & 3, kc = bx >> 2;
    const int tid = threadIdx.x;
    const int l = tid & 63, w = tid >> 6;
    const int wr = w * 16, fr = l & 15, fq = l >> 4;
    const int sr = tid >> 2, sc = (tid & 3) * 8;
    const unsigned short* ga  = kpT + ((size_t)bh * 256 + mt * 64 + sr) * 4096 + kc * 1024 + sc;
    const unsigned short* gb  = vT + ((size_t)bh * 80 + sr) * 4096 + kc * 1024 + sc;
    const unsigned short* gb2 = vT + ((size_t)bh * 80 + 64 + sr) * 4096 + kc * 1024 + sc;

    f32x4 acc[5];
#pragma unroll
    for (int j = 0; j < 5; ++j) acc[j] = (f32x4){0.f, 0.f, 0.f, 0.f};

    for (int k0 = 0; k0 < 1024; k0 += 64) {
        glds16(ga + k0, la + tid * 8);
        glds16(ga + k0 + 32, la + 2048 + tid * 8);
        glds16(gb + k0, lb + tid * 8);
        glds16(gb + k0 + 32, lb + 2560 + tid * 8);
        if (tid < 64) {
            glds16(gb2 + k0, lb + 2048 + tid * 8);
            glds16(gb2 + k0 + 32, lb + 2560 + 2048 + tid * 8);
        }
        __syncthreads();
#pragma unroll
        for (int h2 = 0; h2 < 2; ++h2) {
            short8 av = *(const short8*)&la[h2 * 2048 + (wr + fr) * 32 + fq * 8];
#pragma unroll
            for (int nf = 0; nf < 5; ++nf) {
                short8 bv = *(const short8*)&lb[h2 * 2560 + (nf * 16 + fr) * 32 + fq * 8];
                acc[nf] = mfma16<true>(av, bv, acc[nf]);
            }
        }
        __syncthreads();
    }
#pragma unroll
    for (int v = 0; v < 4; ++v) {
        const int row = mt * 64 + wr + fq * 4 + v;
#pragma unroll
        for (int nf = 0; nf < 5; ++nf)
            ctxp[((size_t)(kc * 32 + bh) * 256 + row) * 80 + nf * 16 + fr] = acc[nf][v];
    }
}

// ---- reduce ctx partials over 4 k-chunks, transpose -> ctxT fp16 [bh][80][256] ----
__global__ __launch_bounds__(256) void ctx_fix(
    const float* __restrict__ ctxp, unsigned short* __restrict__ cth)
{
    __shared__ float s[64][81];
    const int m0 = blockIdx.x * 64, bh = blockIdx.y;
    const int tid = threadIdx.x;
    for (int i = tid; i < 5120; i += 256) {
        const int ml = i / 80, dc = i % 80;
        float sum = 0.f;
#pragma unroll
        for (int kc = 0; kc < 4; ++kc)
            sum += ctxp[((size_t)(kc * 32 + bh) * 256 + m0 + ml) * 80 + dc];
        s[ml][dc] = sum;
    }
    __syncthreads();
    for (int i = tid; i < 5120; i += 256) {
        const int dc = i >> 6, ml = i & 63;
        cth[((size_t)bh * 80 + dc) * 256 + m0 + ml] = fp16rne(s[ml][dc]);
    }
}

// ---- fused q-side (fp16), 64-token tiles: dd = q@pm (K=64) -> row max -> exp ->
//      qp (XOR-swizzled LDS) -> o = (qp @ ctxT)/(qp . ksum). grid (64, 32). ----
__global__ __launch_bounds__(256) void qo_mfma(
    const unsigned short* __restrict__ qhi, const unsigned short* __restrict__ pmh,
    const unsigned short* __restrict__ cth, const float* __restrict__ diagq,
    unsigned short* __restrict__ osh)
{
    __shared__ unsigned short lds[16384 + 2560];   // qp tile (unions phase1 staging) | ctx staging
    __shared__ float rmax4[64][4];
    int bx, by; xcd_swz(bx, by);
    const int bh = by, b = bh >> 2, hh = bh & 3;
    const int t0 = bx * 64;
    const int tid = threadIdx.x;
    const int l = tid & 63, w = tid >> 6;
    const int fr = l & 15, fq = l >> 4;

    // ---- phase 1: dd[64 tok][256 m], K = 64; wave w owns cols wc1..wc1+63 ----
    const int wc1 = w * 64;
    f32x4 a1[4][4];
#pragma unroll
    for (int i = 0; i < 4; ++i)
#pragma unroll
        for (int j = 0; j < 4; ++j) a1[i][j] = (f32x4){0.f, 0.f, 0.f, 0.f};

    const unsigned short* gq = qhi + (size_t)(b * 4096 + t0) * 256 + hh * 64;
#pragma unroll
    for (int ks = 0; ks < 2; ++ks) {
        const int k0 = ks * 32;
        glds16(gq + (size_t)(tid >> 2) * 256 + k0 + (tid & 3) * 8, lds + tid * 8);
#pragma unroll
        for (int i2 = 0; i2 < 4; ++i2) {
            const int c = tid + i2 * 256;
            glds16(pmh + (size_t)(c >> 2) * 64 + k0 + (c & 3) * 8, lds + 2048 + c * 8);
        }
        __syncthreads();
        short8 av[4];
#pragma unroll
        for (int mf = 0; mf < 4; ++mf)
            av[mf] = *(const short8*)&lds[(mf * 16 + fr) * 32 + fq * 8];
#pragma unroll
        for (int nf = 0; nf < 4; ++nf) {
            short8 bh_ = *(const short8*)&lds[2048 + (wc1 + nf * 16 + fr) * 32 + fq * 8];
#pragma unroll
            for (int mf = 0; mf < 4; ++mf)
                a1[mf][nf] = mfma16<true>(av[mf], bh_, a1[mf][nf]);
        }
        __syncthreads();
    }
    // ---- row max (per-wave strip max, combined across 4 waves) ----
#pragma unroll
    for (int mf = 0; mf < 4; ++mf)
#pragma unroll
        for (int v = 0; v < 4; ++v) {
            float rm = a1[mf][0][v];
#pragma unroll
            for (int nf = 1; nf < 4; ++nf) rm = fmaxf(rm, a1[mf][nf][v]);
            rm = fmaxf(rm, __shfl_xor(rm, 1));
            rm = fmaxf(rm, __shfl_xor(rm, 2));
            rm = fmaxf(rm, __shfl_xor(rm, 4));
            rm = fmaxf(rm, __shfl_xor(rm, 8));
            if (fr == 0) rmax4[mf * 16 + fq * 4 + v][w] = rm;
        }
    __syncthreads();
    // ---- exp -> qp fp16 into XOR-swizzled LDS tile [64][256] ----
#pragma unroll
    for (int mf = 0; mf < 4; ++mf)
#pragma unroll
        for (int v = 0; v < 4; ++v) {
            const int tok = mf * 16 + fq * 4 + v;
            const float dg = diagq[(size_t)(b * 4096 + t0 + tok) * 4 + hh]
                           + fmaxf(fmaxf(rmax4[tok][0], rmax4[tok][1]),
                                   fmaxf(rmax4[tok][2], rmax4[tok][3]));
#pragma unroll
            for (int nf = 0; nf < 4; ++nf) {
                const int m = wc1 + nf * 16 + fr;
                lds[tok * 256 + (m ^ ((tok & 7) << 3))] =
                    fp16rne(RATIO * (__expf(a1[mf][nf][v] - dg) + EPSF));
            }
        }
    __syncthreads();

    // ---- phase 2: o[64 tok][80] = qp @ ctxT (K=256, fp16); col 64 = denom ----
    unsigned short* lds2 = lds + 16384;
    f32x4 a2[5];
#pragma unroll
    for (int j = 0; j < 5; ++j) a2[j] = (f32x4){0.f, 0.f, 0.f, 0.f};
    const size_t bbase = (size_t)bh * 80 * 256;

    for (int k0 = 0; k0 < 256; k0 += 32) {
        glds16(cth + bbase + (size_t)(tid >> 2) * 256 + k0 + (tid & 3) * 8, lds2 + tid * 8);
        if (tid < 64) {
            const int c = 256 + tid;
            glds16(cth + bbase + (size_t)(c >> 2) * 256 + k0 + (c & 3) * 8, lds2 + c * 8);
        }
        __syncthreads();
        const int tok = w * 16 + fr;
        const int c = ((k0 >> 3) + fq) ^ (tok & 7);
        short8 av = *(const short8*)&lds[tok * 256 + c * 8];
#pragma unroll
        for (int nf = 0; nf < 5; ++nf) {
            short8 bvh = *(const short8*)&lds2[(nf * 16 + fr) * 32 + fq * 8];
            a2[nf] = mfma16<true>(av, bvh, a2[nf]);
        }
        __syncthreads();
    }
#pragma unroll
    for (int v = 0; v < 4; ++v) {
        const float den = __shfl(a2[4][v], (int)(l & 48));
        const float dinv = 1.0f / den;
        const int tok = w * 16 + fq * 4 + v;
        const size_t obase = (size_t)(b * 4096 + t0 + tok) * 256 + hh * 64;
#pragma unroll
        for (int nf = 0; nf < 4; ++nf)
            osh[obase + nf * 16 + fr] = fp16rne(a2[nf][v] * dinv);
    }
}

// ---- pooling + classifier ----
__global__ __launch_bounds__(256) void pool1_kernel(const float* __restrict__ h, float* __restrict__ part)
{
    const int b = blockIdx.x >> 4, ch = blockIdx.x & 15;
    const int tid = threadIdx.x;
    float acc = 0.f;
    for (int n = 0; n < 256; ++n)
        acc += h[((size_t)(b * 4096 + ch * 256 + n)) * 256 + tid];
    part[(size_t)blockIdx.x * 256 + tid] = acc;
}

__global__ __launch_bounds__(256) void pool2_kernel(
    const float* __restrict__ part, const float* __restrict__ cw,
    const float* __restrict__ cb, float* __restrict__ out)
{
    const int b = blockIdx.x, tid = threadIdx.x;
    float acc = 0.f;
#pragma unroll
    for (int c = 0; c < 16; ++c) acc += part[(size_t)(b * 16 + c) * 256 + tid];
    float val = acc * (1.0f / 4096.0f) * cw[tid];
#pragma unroll
    for (int s = 1; s < 64; s <<= 1) val += __shfl_xor(val, s);
    __shared__ float red[4];
    if ((tid & 63) == 0) red[tid >> 6] = val;
    __syncthreads();
    if (tid == 0) out[b] = red[0] + red[1] + red[2] + red[3] + cb[0];
}

extern "C" void kernel_launch(void* const* d_in, const int* in_sizes, int n_in,
                              void* d_out, int out_size, void* d_ws, size_t ws_size,
                              hipStream_t stream)
{
    (void)in_sizes; (void)n_in;
    if (ws_size < WS_BYTES) {
        fill_sentinel<<<1, 64, 0, stream>>>((float*)d_out, out_size);
        return;
    }

    const float* x     = (const float*)d_in[0];
    const float* projw = (const float*)d_in[1];
    const float* projb = (const float*)d_in[2];
    const float* ln1g  = (const float*)d_in[3];
    const float* ln1b  = (const float*)d_in[4];
    const float* wq    = (const float*)d_in[5];
    const float* bq    = (const float*)d_in[6];
    const float* wk    = (const float*)d_in[7];
    const float* bk    = (const float*)d_in[8];
    const float* wv    = (const float*)d_in[9];
    const float* bv    = (const float*)d_in[10];
    const float* wo    = (const float*)d_in[11];
    const float* bo    = (const float*)d_in[12];
    const float* ln2g  = (const float*)d_in[13];
    const float* ln2b  = (const float*)d_in[14];
    const float* w1    = (const float*)d_in[15];
    const float* b1    = (const float*)d_in[16];
    const float* w2    = (const float*)d_in[17];
    const float* b2    = (const float*)d_in[18];
    const float* clfw  = (const float*)d_in[19];
    const float* clfb  = (const float*)d_in[20];
    const float* projm = (const float*)d_in[21];

    char* WS = (char*)d_ws;
    float* h            = (float*)(WS + OFF_H);
    unsigned short* ysh = (unsigned short*)(WS + OFF_YS);
    unsigned short* wts = (unsigned short*)(WS + OFF_WTS);
    unsigned short* khi = (unsigned short*)(WS + OFF_QK);
    unsigned short* qhi = khi + 8388608;
    unsigned short* big = (unsigned short*)(WS + OFF_BIG);   // kpT / ffb / x-split
    unsigned short* vT  = (unsigned short*)(WS + OFF_VT);
    float* ctxp         = (float*)(WS + OFF_CTXP);
    unsigned short* cth = (unsigned short*)(WS + OFF_CTXTH);
    float* diagq        = (float*)(WS + OFF_DIAGQ);
    float* diagk        = (float*)(WS + OFF_DIAGK);
    unsigned* gmax      = (unsigned*)(WS + OFF_GMAX);
    float* pool         = (float*)(WS + OFF_POOL);
    unsigned short* pmt_h = (unsigned short*)(WS + OFF_PMTH);
    unsigned short* pwt_h = (unsigned short*)(WS + OFF_PWTH);
    unsigned short* pwt_l = (unsigned short*)(WS + OFF_PWTL);
    // aliases
    unsigned short* xsh = big;               // prologue only
    unsigned short* xsl = big + 2097152;
    unsigned short* kpT = big;               // [32][256][4096] fp16
    unsigned short* ffb = big;               // [32768][1024] fp16
    unsigned short* osh = ysh;               // o fp16 (ys dead by then)

    // ---- prologue ----
    split_scale<<<8192, 256, 0, stream>>>(x, xsh, xsl, 2097152, 1.0f);
    splitT<<<64, 256, 0, stream>>>(projw, pwt_h, pwt_l, 6, 256);
    tofp16_scale<<<64, 256, 0, stream>>>(projm, pmt_h, 16384, DN);
    vt_init<<<1024, 256, 0, stream>>>(vT, gmax);
    split_weights<<<16384, 256, 0, stream>>>(wq, wk, wv, wo, w1, w2, wts);
    gemm_mf<0, true, true, false><<<dim3(2, 256), 256, 0, stream>>>(xsh, xsl, 64,
        pwt_h, pwt_l, 64, 64, projb, nullptr, h, 256, nullptr, nullptr, nullptr);

    for (int l = 0; l < 4; ++l) {
        unsigned short* wl = wts + (size_t)l * 1048576;

        // ---- attention ----
        ln_f16<<<8192, 256, 0, stream>>>(h, ln1g + l * 256, ln1b + l * 256, ysh);
        gemm_qkv<<<dim3(2, 768), 256, 0, stream>>>(ysh, wl,
            bq + l * 256, bk + l * 256, bv + l * 256, vT, khi, qhi, diagq, diagk);
        gemm_mf<4, false, false, true><<<dim3(2, 1024), 256, 0, stream>>>(khi, nullptr, 64,
            pmt_h, nullptr, 64, 64, nullptr, nullptr, nullptr, 256, nullptr, nullptr, gmax + l);
        gemm_mf<6, false, false, true><<<dim3(2, 1024), 256, 0, stream>>>(khi, nullptr, 64,
            pmt_h, nullptr, 64, 64, nullptr, nullptr, nullptr, 256, kpT, diagk, gmax + l);
        ctx_mfma<<<dim3(16, 32), 256, 0, stream>>>(kpT, vT, ctxp);
        ctx_fix<<<dim3(4, 32), 256, 0, stream>>>(ctxp, cth);
        qo_mfma<<<dim3(64, 32), 256, 0, stream>>>(qhi, pmt_h, cth, diagq, osh);
        gemm_mf<1, false, false, true><<<dim3(2, 256), 256, 0, stream>>>(osh, nullptr, 256,
            wl + WOF, nullptr, 256, 256, bo + l * 256, h, h, 256, nullptr, nullptr, nullptr);

        // ---- feed-forward ----
        ln_f16<<<8192, 256, 0, stream>>>(h, ln2g + l * 256, ln2b + l * 256, ysh);
        gemm_glu<<<dim3(16, 256), 256, 0, stream>>>(ysh, wl + W1F,
            b1 + (size_t)l * 2048, ffb);
        gemm_mf<1, false, false, true><<<dim3(2, 256), 256, 0, stream>>>(ffb, nullptr, 1024,
            wl + W2F, nullptr, 1024, 1024, b2 + l * 256, h, h, 256, nullptr, nullptr, nullptr);
    }

    pool1_kernel<<<128, 256, 0, stream>>>(h, pool);
    pool2_kernel<<<8, 256, 0, stream>>>(pool, clfw, clfb, (float*)d_out);
}